// Round 6
// baseline (1362.564 us; speedup 1.0000x reference)
//
#include <hip/hip_runtime.h>
#include <hip/hip_bf16.h>
#include <cstddef>

// ---------------- problem constants ----------------
#define TT   365
#define NN   400
#define TN   (TT*NN)            // 146000
#define HD   26                 // head dim
#define NH   4                  // heads

#define CEILDIV(a,b) (((a)+(b)-1)/(b))

typedef __hip_bfloat16 bf16;
typedef short short8v __attribute__((ext_vector_type(8)));
typedef float float4v __attribute__((ext_vector_type(4)));
typedef float float16v __attribute__((ext_vector_type(16)));
__device__ __forceinline__ float b2f(bf16 v){ return __bfloat162float(v); }
__device__ __forceinline__ bf16  f2b(float v){ return __float2bfloat16(v); }

// ---------------- workspace layout ----------------
static constexpr size_t NB0 = (size_t)TN*104;   // h / h1
static constexpr size_t NB1 = (size_t)TN*104;   // z1 -> att1
static constexpr size_t NB2 = (size_t)TN*312;   // hcat -> [adp_bf|hT] -> qkv+concat -> hidden
static constexpr size_t NB3 = (size_t)TN*104;   // att0 -> h2
static constexpr size_t NBF = NB0+NB1+NB2+NB3;
// compact band KV tiles: per b, 108 rows x 32 (band cols 0..25), bf16
static constexpr size_t NTILE   = (size_t)108*32;
static constexpr size_t NKVSB_S = (size_t)TT*NTILE;
static constexpr size_t NKVSB_T = (size_t)NN*NTILE;
static constexpr size_t NY      = (size_t)NN*104;
// transposed bf16 weights (Wt[n][kp], zero-padded k)
static constexpr size_t NW_TP   = 104*128;
static constexpr size_t NW_QKV  = 312*128;   // x2
static constexpr size_t NW_OP   = 104*224;   // x2
static constexpr size_t NW_PW   = 104*128;   // x2
static constexpr size_t NW_FC1  = 208*128;
static constexpr size_t NW_FC2  = 104*224;
static constexpr size_t NW_EPT  = (size_t)104*37960;   // ep_w transposed, no pad
static constexpr size_t NWT     = NW_TP + 2*NW_QKV + 2*NW_OP + 2*NW_PW + NW_FC1 + NW_FC2 + NW_EPT;
static constexpr size_t WS_NEEDED = NBF*2 + (NKVSB_S+NKVSB_T)*2 + NY*4 + NWT*2;
// z1 scratch lives inside B2 (dead between step 2 and step 4):
static constexpr size_t NADP_ROWS = (size_t)TN + 64;
static constexpr size_t NADP = NADP_ROWS*96;
static constexpr size_t NHT  = ((size_t)TT*104 + 8)*448;
static_assert(NADP + NHT <= NB2, "z1 scratch must fit in B2");

// ---------------- weight prep: Wt[n*KP+k] = bf16(W[k*Nc+n]), zero pad k>=K ----------------
__global__ void __launch_bounds__(256) prep_w(
    const float* __restrict__ W, bf16* __restrict__ Wt, int K, int Nc, int KP)
{
    int idx = blockIdx.x*256 + threadIdx.x;
    if (idx >= Nc*KP) return;
    int n = idx / KP, k = idx - n*KP;
    Wt[idx] = (k < K) ? f2b(W[(size_t)k*Nc + n]) : f2b(0.f);
}

// coalesced LDS transpose for ep weights: Wt[n][k] = bf16(W[k][n]); W is 37960x104 fp32
__global__ void __launch_bounds__(256) prep_wT(
    const float* __restrict__ W, bf16* __restrict__ Wt)
{
    __shared__ float T[64][105];
    int k0 = blockIdx.x * 64;
    int tid = threadIdx.x;
    for (int idx = tid; idx < 64*104; idx += 256) {
        int r = idx / 104, c = idx - r*104;
        int k = k0 + r;
        T[r][c] = (k < 37960) ? W[(size_t)k*104 + c] : 0.f;
    }
    __syncthreads();
    for (int idx = tid; idx < 104*32; idx += 256) {
        int n = idx >> 5, kp = idx & 31;
        int k = kp*2;
        if (k0 + k + 1 < 37960 || k0 + k < 37960) {
            if (k0 + k < 37960) {
                bf16 lo = f2b(T[k][n]);
                bf16 hi = f2b(T[k+1][n]);   // k+1 row is zero-padded if OOB of tile data
                uint v = ((uint)(*(ushort*)&hi) << 16) | (*(ushort*)&lo);
                if (k0 + k + 1 < 37960) *(uint*)(Wt + (size_t)n*37960 + k0 + k) = v;
                else Wt[(size_t)n*37960 + k0 + k] = lo;
            }
        }
    }
}

// adp_bf[row][e] = bf16(adp[row][e]) for e<80 else 0; rows >= TN are zero.
__global__ void __launch_bounds__(256) prep_adp(
    const float* __restrict__ adp, bf16* __restrict__ out)
{
    size_t i = (size_t)blockIdx.x*256 + threadIdx.x;
    if (i >= NADP) return;
    size_t row = i / 96; int e = (int)(i - row*96);
    float v = (row < TN && e < 80) ? adp[row*80 + e] : 0.f;
    out[i] = f2b(v);
}

// hT[t][d][n] = h[t][n][d], n padded to 448 with zeros
__global__ void __launch_bounds__(256) ht_kernel(
    const bf16* __restrict__ h, bf16* __restrict__ hT)
{
    __shared__ bf16 As[64*106];
    int t = blockIdx.y, n0 = blockIdx.x*64;
    int tid = threadIdx.x;
    for (int idx = tid; idx < 64*52; idx += 256) {
        int r = idx / 52, k = idx - r*52;
        int n = n0 + r;
        uint v = 0;
        if (n < NN) v = *(const uint*)(h + ((size_t)t*NN + n)*104 + k*2);
        *(uint*)(&As[r*106 + k*2]) = v;
    }
    __syncthreads();
    for (int idx = tid; idx < 104*32; idx += 256) {
        int d = idx >> 5, np = idx & 31;
        int n = np*2;
        ushort lo = *(ushort*)&As[n*106 + d];
        ushort hi = *(ushort*)&As[(n+1)*106 + d];
        uint v = ((uint)hi << 16) | lo;
        *(uint*)(hT + ((size_t)t*104 + d)*448 + n0 + n) = v;
    }
}

// ---------------- hcat (R6: 16 rows/block, LDS-staged uint4 row writes) ----------------
// Was 146000 blocks x 128 threads with scalar bf16 stores.
__global__ void __launch_bounds__(256) hcat_kernel(
    const float* __restrict__ x, const float* __restrict__ W_in,
    const float* __restrict__ b_in, const float* __restrict__ adp,
    bf16* __restrict__ hcat)
{
    __shared__ bf16 T[16][112];          // 104 used; 224B row stride (16B-aligned)
    int r0 = blockIdx.x * 16;
    int tid = threadIdx.x;
    // proj cols 0..23
    for (int idx = tid; idx < 16*24; idx += 256) {
        int r = idx / 24, c = idx - r*24;
        int row = r0 + r;
        int t = row / NN, n = row - t*NN;
        size_t xb = ((size_t)n*TT + t)*3;
        float s = b_in[c] + x[xb]*W_in[c] + x[xb+1]*W_in[24+c] + x[xb+2]*W_in[48+c];
        T[r][c] = f2b(s);
    }
    // adp cols 24..103 (coalesced f32 reads)
    for (int idx = tid; idx < 16*80; idx += 256) {
        int r = idx / 80, e = idx - r*80;
        T[r][24+e] = f2b(adp[(size_t)(r0+r)*80 + e]);
    }
    __syncthreads();
    for (int idx = tid; idx < 16*13; idx += 256) {
        int r = idx / 13, q = idx - r*13;
        *(uint4*)(hcat + ((size_t)(r0+r))*104 + q*8) = *(const uint4*)(&T[r][q*8]);
    }
}

// ---------------- MFMA GEMM 64-tile (kept for K=208 op gemms) ----------------
template<int KP>
__global__ void __launch_bounds__(256) gemm_mf(
    const bf16* __restrict__ A, int lda, int K,
    const bf16* __restrict__ Wt, const float* __restrict__ bias,
    bf16* __restrict__ C, int M, int Nc, int relu)
{
    constexpr int STR = KP + 8;
    constexpr int KPQ = KP/8;
    __shared__ bf16 As[64*STR];
    __shared__ bf16 Ws[64*STR];
    int nCol = (Nc + 63) >> 6;
    int nwg = gridDim.x;
    int bid = blockIdx.x;
    int xcd = bid & 7, kk = bid >> 3;
    int q8 = nwg >> 3, r8 = nwg & 7;
    int widx = (xcd < r8 ? xcd*(q8+1) : r8*(q8+1) + (xcd - r8)*q8) + kk;
    int mblk = widx / nCol;
    int m0 = mblk * 64;
    int c0 = (widx - mblk*nCol) * 64;
    int tid = threadIdx.x;
    const int KQ = K/8;
    uint4 z4 = {0u,0u,0u,0u};
    for (int idx = tid; idx < 64*KPQ; idx += 256) {
        int r = idx / KPQ, q = idx - r*KPQ;
        int m = m0 + r;
        uint4 v = z4;
        if (m < M && q < KQ) v = *(const uint4*)(A + (size_t)m*lda + q*8);
        *(uint4*)(&As[r*STR + q*8]) = v;
    }
    for (int idx = tid; idx < 64*KPQ; idx += 256) {
        int r = idx / KPQ, q = idx - r*KPQ;
        int n = c0 + r;
        uint4 v = z4;
        if (n < Nc) v = *(const uint4*)(Wt + (size_t)n*KP + q*8);
        *(uint4*)(&Ws[r*STR + q*8]) = v;
    }
    __syncthreads();

    int lane = tid & 63, w = tid >> 6;
    int n16 = lane & 15, quad = lane >> 4;
    constexpr int KS = KP/32;
    short8v af[KS];
    #pragma unroll
    for (int s = 0; s < KS; ++s)
        af[s] = *(const short8v*)(&As[(16*w + n16)*STR + s*32 + quad*8]);
    float4v acc[4];
    #pragma unroll
    for (int ct = 0; ct < 4; ++ct) { float4v z = {0.f,0.f,0.f,0.f}; acc[ct] = z; }
    #pragma unroll
    for (int ct = 0; ct < 4; ++ct) {
        #pragma unroll
        for (int s = 0; s < KS; ++s) {
            short8v bfr = *(const short8v*)(&Ws[(ct*16 + n16)*STR + s*32 + quad*8]);
            acc[ct] = __builtin_amdgcn_mfma_f32_16x16x32_bf16(af[s], bfr, acc[ct], 0, 0, 0);
        }
    }
    #pragma unroll
    for (int ct = 0; ct < 4; ++ct) {
        int c = c0 + ct*16 + n16;
        if (c < Nc) {
            float b = bias ? bias[c] : 0.f;
            #pragma unroll
            for (int reg = 0; reg < 4; ++reg) {
                int m = m0 + 16*w + quad*4 + reg;
                if (m < M) {
                    float v = acc[ct][reg] + b;
                    if (relu) v = fmaxf(v, 0.f);
                    C[(size_t)m*Nc + c] = f2b(v);
                }
            }
        }
    }
}

// ---------------- MFMA GEMM 128x128 tile (R6; K<=128 ops: tp, qkv, fc1) ----------------
// Halves staged bytes per output elem (6.5 -> 3.25 B) and 4x MFMA per barrier
// vs the 64-tile. 69.6 KB LDS -> 2 blocks/CU. XCD-bijective grouping as before.
template<int KP>
__global__ void __launch_bounds__(256, 2) gemm_mf2(
    const bf16* __restrict__ A, int lda, int K,
    const bf16* __restrict__ Wt, const float* __restrict__ bias,
    bf16* __restrict__ C, int M, int Nc, int relu)
{
    constexpr int STR = KP + 8;
    constexpr int KPQ = KP/8;
    __shared__ bf16 As[128*STR];
    __shared__ bf16 Ws[128*STR];
    int nCol = (Nc + 127) >> 7;
    int nwg = gridDim.x;
    int bid = blockIdx.x;
    int xcd = bid & 7, kk = bid >> 3;
    int q8 = nwg >> 3, r8 = nwg & 7;
    int widx = (xcd < r8 ? xcd*(q8+1) : r8*(q8+1) + (xcd - r8)*q8) + kk;
    int mblk = widx / nCol;
    int m0 = mblk * 128;
    int c0 = (widx - mblk*nCol) * 128;
    int tid = threadIdx.x;
    const int KQ = K/8;
    uint4 z4 = {0u,0u,0u,0u};
    for (int idx = tid; idx < 128*KPQ; idx += 256) {
        int r = idx / KPQ, q = idx - r*KPQ;
        int m = m0 + r;
        uint4 v = z4;
        if (m < M && q < KQ) v = *(const uint4*)(A + (size_t)m*lda + q*8);
        *(uint4*)(&As[r*STR + q*8]) = v;
    }
    for (int idx = tid; idx < 128*KPQ; idx += 256) {
        int r = idx / KPQ, q = idx - r*KPQ;
        int n = c0 + r;
        uint4 v = z4;
        if (n < Nc) v = *(const uint4*)(Wt + (size_t)n*KP + q*8);
        *(uint4*)(&Ws[r*STR + q*8]) = v;
    }
    __syncthreads();

    int lane = tid & 63, w = tid >> 6;
    int wr = (w >> 1)*64, wc = (w & 1)*64;     // wave's 64x64 quadrant
    int n16 = lane & 15, quad = lane >> 4;
    constexpr int KS = KP/32;
    float4v acc[4][4];
    #pragma unroll
    for (int mt = 0; mt < 4; ++mt)
        #pragma unroll
        for (int ct = 0; ct < 4; ++ct) { float4v z = {0.f,0.f,0.f,0.f}; acc[mt][ct] = z; }
    #pragma unroll
    for (int mt = 0; mt < 4; ++mt) {
        short8v af[KS];
        #pragma unroll
        for (int s = 0; s < KS; ++s)
            af[s] = *(const short8v*)(&As[(wr + mt*16 + n16)*STR + s*32 + quad*8]);
        #pragma unroll
        for (int ct = 0; ct < 4; ++ct) {
            #pragma unroll
            for (int s = 0; s < KS; ++s) {
                short8v bfr = *(const short8v*)(&Ws[(wc + ct*16 + n16)*STR + s*32 + quad*8]);
                acc[mt][ct] = __builtin_amdgcn_mfma_f32_16x16x32_bf16(af[s], bfr, acc[mt][ct], 0, 0, 0);
            }
        }
    }
    #pragma unroll
    for (int ct = 0; ct < 4; ++ct) {
        int c = c0 + wc + ct*16 + n16;
        if (c < Nc) {
            float b = bias ? bias[c] : 0.f;
            #pragma unroll
            for (int mt = 0; mt < 4; ++mt) {
                #pragma unroll
                for (int reg = 0; reg < 4; ++reg) {
                    int m = m0 + wr + mt*16 + quad*4 + reg;
                    if (m < M) {
                        float v = acc[mt][ct][reg] + b;
                        if (relu) v = fmaxf(v, 0.f);
                        C[(size_t)m*Nc + c] = f2b(v);
                    }
                }
            }
        }
    }
}

// ---------------- fused gates + LN1 ----------------
// h1 = LN(2*(h + att0*(h@pw0+b0) + 0.01*att1*(att0@pw1+b1))) in-place into h.
__global__ void __launch_bounds__(256) gate_ln1(
    bf16* __restrict__ h, const bf16* __restrict__ att0, const bf16* __restrict__ att1,
    const bf16* __restrict__ w0t, const bf16* __restrict__ w1t, const float* __restrict__ pwb,
    const float* __restrict__ gamma, const float* __restrict__ beta)
{
    constexpr int STR = 136;
    __shared__ bf16 A0s[64*STR];
    __shared__ bf16 A1s[64*STR];
    __shared__ bf16 Ws[112*STR];
    __shared__ float prm[416];     // pwb(208) | gamma(104) | beta(104)
    int m0 = blockIdx.x * 64;
    int tid = threadIdx.x;
    int lane = tid & 63, w = tid >> 6, n16 = lane & 15, quad = lane >> 4;
    uint4 z4 = {0u,0u,0u,0u};

    for (int idx = tid; idx < 64*16; idx += 256) {
        int r = idx >> 4, q = idx & 15;
        int m = m0 + r;
        uint4 v0 = z4, v1 = z4;
        if (m < TN && q < 13) {
            v0 = *(const uint4*)(h    + (size_t)m*104 + q*8);
            v1 = *(const uint4*)(att0 + (size_t)m*104 + q*8);
        }
        *(uint4*)(&A0s[r*STR + q*8]) = v0;
        *(uint4*)(&A1s[r*STR + q*8]) = v1;
    }
    for (int idx = tid; idx < 112*16; idx += 256) {
        int c = idx >> 4, q = idx & 15;
        uint4 v = z4;
        if (c < 104) v = *(const uint4*)(w0t + (size_t)c*128 + q*8);
        *(uint4*)(&Ws[c*STR + q*8]) = v;
    }
    for (int i = tid; i < 416; i += 256)
        prm[i] = (i < 208) ? pwb[i] : (i < 312 ? gamma[i-208] : beta[i-312]);
    __syncthreads();

    short8v a0f[4], a1f[4];
    #pragma unroll
    for (int s = 0; s < 4; ++s) {
        a0f[s] = *(const short8v*)(&A0s[(16*w + n16)*STR + s*32 + quad*8]);
        a1f[s] = *(const short8v*)(&A1s[(16*w + n16)*STR + s*32 + quad*8]);
    }
    float4v acc0[7], acc1[7];
    #pragma unroll
    for (int ct = 0; ct < 7; ++ct) { float4v z = {0.f,0.f,0.f,0.f}; acc0[ct] = z; acc1[ct] = z; }
    #pragma unroll
    for (int ct = 0; ct < 7; ++ct)
        #pragma unroll
        for (int s = 0; s < 4; ++s) {
            short8v bfr = *(const short8v*)(&Ws[(ct*16 + n16)*STR + s*32 + quad*8]);
            acc0[ct] = __builtin_amdgcn_mfma_f32_16x16x32_bf16(a0f[s], bfr, acc0[ct], 0, 0, 0);
        }
    __syncthreads();
    for (int idx = tid; idx < 112*16; idx += 256) {
        int c = idx >> 4, q = idx & 15;
        uint4 v = z4;
        if (c < 104) v = *(const uint4*)(w1t + (size_t)c*128 + q*8);
        *(uint4*)(&Ws[c*STR + q*8]) = v;
    }
    __syncthreads();
    #pragma unroll
    for (int ct = 0; ct < 7; ++ct)
        #pragma unroll
        for (int s = 0; s < 4; ++s) {
            short8v bfr = *(const short8v*)(&Ws[(ct*16 + n16)*STR + s*32 + quad*8]);
            acc1[ct] = __builtin_amdgcn_mfma_f32_16x16x32_bf16(a1f[s], bfr, acc1[ct], 0, 0, 0);
        }

    // epilogue: g -> LN (row distributed across the 16 n16 lanes)
    float sum[4] = {0.f,0.f,0.f,0.f};
    #pragma unroll
    for (int ct = 0; ct < 7; ++ct) {
        int c = ct*16 + n16;
        bool colok = c < 104;
        float b0 = colok ? prm[c] : 0.f;
        float b1 = colok ? prm[104 + c] : 0.f;
        #pragma unroll
        for (int reg = 0; reg < 4; ++reg) {
            int r = 16*w + quad*4 + reg;
            int m = m0 + r;
            float xv = 0.f;
            if (colok && m < TN) {
                float p0 = acc0[ct][reg] + b0;
                float p1 = acc1[ct][reg] + b1;
                float hv = b2f(A0s[r*STR + c]);
                float a0 = b2f(A1s[r*STR + c]);
                float a1 = b2f(att1[(size_t)m*104 + c]);
                xv = 2.f*(hv + a0*p0 + 0.01f*a1*p1);
            }
            acc0[ct][reg] = xv;
            sum[reg] += xv;
        }
    }
    #pragma unroll
    for (int reg = 0; reg < 4; ++reg) {
        float v = sum[reg];
        v += __shfl_xor(v,1,64); v += __shfl_xor(v,2,64);
        v += __shfl_xor(v,4,64); v += __shfl_xor(v,8,64);
        sum[reg] = v * (1.f/104.f);                     // mean
    }
    float var[4] = {0.f,0.f,0.f,0.f};
    #pragma unroll
    for (int ct = 0; ct < 7; ++ct) {
        bool colok = (ct*16 + n16) < 104;
        #pragma unroll
        for (int reg = 0; reg < 4; ++reg) {
            if (colok) {
                float d = acc0[ct][reg] - sum[reg];
                acc0[ct][reg] = d;
                var[reg] += d*d;
            }
        }
    }
    #pragma unroll
    for (int reg = 0; reg < 4; ++reg) {
        float v = var[reg];
        v += __shfl_xor(v,1,64); v += __shfl_xor(v,2,64);
        v += __shfl_xor(v,4,64); v += __shfl_xor(v,8,64);
        var[reg] = rsqrtf(v * (1.f/104.f) + 1e-5f);
    }
    #pragma unroll
    for (int ct = 0; ct < 7; ++ct) {
        int c = ct*16 + n16;
        if (c < 104) {
            float g = prm[208 + c], be = prm[312 + c];
            #pragma unroll
            for (int reg = 0; reg < 4; ++reg) {
                int m = m0 + 16*w + quad*4 + reg;
                if (m < TN)
                    h[(size_t)m*104 + c] = f2b(acc0[ct][reg]*var[reg]*g + be);
            }
        }
    }
}

// ---------------- fused fc2 + LN2: h2 = LN(h1 + hidden@fc_w2 + b) ----------------
__global__ void __launch_bounds__(256) fc2_ln2(
    const bf16* __restrict__ hidden, const bf16* __restrict__ w2t, const float* __restrict__ b2,
    const bf16* __restrict__ h1, const float* __restrict__ gamma, const float* __restrict__ beta,
    bf16* __restrict__ h2)
{
    constexpr int STRA = 232;   // 224 + 8
    constexpr int STRW = 136;   // 128 + 8 (per half)
    __shared__ bf16 As[64*STRA];
    __shared__ bf16 Ws[112*STRW];
    __shared__ float prm[312];  // b2(104) | gamma(104) | beta(104)
    int m0 = blockIdx.x * 64;
    int tid = threadIdx.x;
    int lane = tid & 63, w = tid >> 6, n16 = lane & 15, quad = lane >> 4;
    uint4 z4 = {0u,0u,0u,0u};

    for (int idx = tid; idx < 64*28; idx += 256) {
        int r = idx / 28, q = idx - r*28;
        int m = m0 + r;
        uint4 v = z4;
        if (m < TN && q < 26) v = *(const uint4*)(hidden + (size_t)m*208 + q*8);
        *(uint4*)(&As[r*STRA + q*8]) = v;
    }
    for (int idx = tid; idx < 112*16; idx += 256) {
        int c = idx >> 4, q = idx & 15;
        uint4 v = z4;
        if (c < 104) v = *(const uint4*)(w2t + (size_t)c*224 + q*8);
        *(uint4*)(&Ws[c*STRW + q*8]) = v;
    }
    for (int i = tid; i < 312; i += 256)
        prm[i] = (i < 104) ? b2[i] : (i < 208 ? gamma[i-104] : beta[i-208]);
    __syncthreads();

    short8v af[7];
    #pragma unroll
    for (int s = 0; s < 7; ++s)
        af[s] = *(const short8v*)(&As[(16*w + n16)*STRA + s*32 + quad*8]);
    float4v acc[7];
    #pragma unroll
    for (int ct = 0; ct < 7; ++ct) { float4v z = {0.f,0.f,0.f,0.f}; acc[ct] = z; }
    #pragma unroll
    for (int ct = 0; ct < 7; ++ct)
        #pragma unroll
        for (int s = 0; s < 4; ++s) {
            short8v bfr = *(const short8v*)(&Ws[(ct*16 + n16)*STRW + s*32 + quad*8]);
            acc[ct] = __builtin_amdgcn_mfma_f32_16x16x32_bf16(af[s], bfr, acc[ct], 0, 0, 0);
        }
    __syncthreads();
    for (int idx = tid; idx < 112*16; idx += 256) {   // half 2: k 128..223 (12 data uint4)
        int c = idx >> 4, q = idx & 15;
        uint4 v = z4;
        if (c < 104 && q < 12) v = *(const uint4*)(w2t + (size_t)c*224 + 128 + q*8);
        *(uint4*)(&Ws[c*STRW + q*8]) = v;
    }
    __syncthreads();
    #pragma unroll
    for (int ct = 0; ct < 7; ++ct)
        #pragma unroll
        for (int s = 4; s < 7; ++s) {
            short8v bfr = *(const short8v*)(&Ws[(ct*16 + n16)*STRW + (s-4)*32 + quad*8]);
            acc[ct] = __builtin_amdgcn_mfma_f32_16x16x32_bf16(af[s], bfr, acc[ct], 0, 0, 0);
        }

    // epilogue: x = h1 + m  -> LN
    float sum[4] = {0.f,0.f,0.f,0.f};
    #pragma unroll
    for (int ct = 0; ct < 7; ++ct) {
        int c = ct*16 + n16;
        bool colok = c < 104;
        float bb = colok ? prm[c] : 0.f;
        #pragma unroll
        for (int reg = 0; reg < 4; ++reg) {
            int m = m0 + 16*w + quad*4 + reg;
            float xv = 0.f;
            if (colok && m < TN)
                xv = b2f(h1[(size_t)m*104 + c]) + acc[ct][reg] + bb;
            acc[ct][reg] = xv;
            sum[reg] += xv;
        }
    }
    #pragma unroll
    for (int reg = 0; reg < 4; ++reg) {
        float v = sum[reg];
        v += __shfl_xor(v,1,64); v += __shfl_xor(v,2,64);
        v += __shfl_xor(v,4,64); v += __shfl_xor(v,8,64);
        sum[reg] = v * (1.f/104.f);
    }
    float var[4] = {0.f,0.f,0.f,0.f};
    #pragma unroll
    for (int ct = 0; ct < 7; ++ct) {
        bool colok = (ct*16 + n16) < 104;
        #pragma unroll
        for (int reg = 0; reg < 4; ++reg) {
            if (colok) {
                float d = acc[ct][reg] - sum[reg];
                acc[ct][reg] = d;
                var[reg] += d*d;
            }
        }
    }
    #pragma unroll
    for (int reg = 0; reg < 4; ++reg) {
        float v = var[reg];
        v += __shfl_xor(v,1,64); v += __shfl_xor(v,2,64);
        v += __shfl_xor(v,4,64); v += __shfl_xor(v,8,64);
        var[reg] = rsqrtf(v * (1.f/104.f) + 1e-5f);
    }
    #pragma unroll
    for (int ct = 0; ct < 7; ++ct) {
        int c = ct*16 + n16;
        if (c < 104) {
            float g = prm[104 + c], be = prm[208 + c];
            #pragma unroll
            for (int reg = 0; reg < 4; ++reg) {
                int m = m0 + 16*w + quad*4 + reg;
                if (m < TN)
                    h2[(size_t)m*104 + c] = f2b(acc[ct][reg]*var[reg]*g + be);
            }
        }
    }
}

// ---------------- MFMA encoder_proj ----------------
__global__ void __launch_bounds__(256) ep_mf(
    const bf16* __restrict__ h2, const bf16* __restrict__ wt, float* __restrict__ y)
{
    constexpr int STR = 136;
    __shared__ bf16 As[64*STR];
    __shared__ bf16 Ws[64*STR];
    int m0 = blockIdx.x * 64;
    int c0 = blockIdx.y * 64;
    int t0 = blockIdx.z * 8;
    int t1 = min(TT, t0 + 8);
    int tid = threadIdx.x;
    int lane = tid & 63, w = tid >> 6, n16 = lane & 15, quad = lane >> 4;
    uint4 z4 = {0u,0u,0u,0u};

    float4v acc[4];
    #pragma unroll
    for (int ct = 0; ct < 4; ++ct) { float4v z = {0.f,0.f,0.f,0.f}; acc[ct] = z; }

    for (int t = t0; t < t1; ++t) {
        for (int idx = tid; idx < 64*16; idx += 256) {
            int r = idx >> 4, q = idx & 15;
            int m = m0 + r;
            uint4 va = z4;
            if (m < NN && q < 13) va = *(const uint4*)(h2 + ((size_t)t*NN + m)*104 + q*8);
            *(uint4*)(&As[r*STR + q*8]) = va;
            int c = c0 + r;
            uint4 vw = z4;
            if (c < 104 && q < 13) vw = *(const uint4*)(wt + (size_t)c*37960 + t*104 + q*8);
            *(uint4*)(&Ws[r*STR + q*8]) = vw;
        }
        __syncthreads();
        short8v af[4];
        #pragma unroll
        for (int s = 0; s < 4; ++s)
            af[s] = *(const short8v*)(&As[(16*w + n16)*STR + s*32 + quad*8]);
        #pragma unroll
        for (int ct = 0; ct < 4; ++ct) {
            #pragma unroll
            for (int s = 0; s < 4; ++s) {
                short8v bfr = *(const short8v*)(&Ws[(ct*16 + n16)*STR + s*32 + quad*8]);
                acc[ct] = __builtin_amdgcn_mfma_f32_16x16x32_bf16(af[s], bfr, acc[ct], 0, 0, 0);
            }
        }
        __syncthreads();
    }
    #pragma unroll
    for (int ct = 0; ct < 4; ++ct) {
        int c = c0 + ct*16 + n16;
        if (c < 104) {
            #pragma unroll
            for (int reg = 0; reg < 4; ++reg) {
                int m = m0 + 16*w + quad*4 + reg;
                if (m < NN) atomicAdd(&y[(size_t)m*104 + c], acc[ct][reg]);
            }
        }
    }
}

// ---------------- MFMA z1 (R5 structure, unchanged) ----------------
static constexpr int Z1_TQ = CEILDIV(TT, 8);          // 46
static constexpr int Z1_BLOCKS = 8 * Z1_TQ * 4;       // 1472
__global__ void __launch_bounds__(512, 4) z1_mf(
    const bf16* __restrict__ adp_bf, const bf16* __restrict__ hT, bf16* __restrict__ z1)
{
    constexpr int SA  = 104;   // Asq/Bt row stride (96 data + pad), 16B-aligned
    constexpr int SH  = 72;    // Hs row stride (64 data + pad)
    constexpr int SPP = 72;    // P  row stride (64 data + pad)
    __shared__ bf16 Asq[2][64*SA];   // 26624 B: per-slab q rows (persist)
    __shared__ bf16 Bt[64*SA];       // 13312 B: shared c-rows tile
    __shared__ bf16 Hs[128*SH];      // 18432 B: shared hT tile (rows 104..127 zero)
    __shared__ bf16 P[2][64*SPP];    // 18432 B: per-slab probabilities
    __shared__ float rsb[2][2][64];  //  2048 B

    int bid = blockIdx.x;
    int xcd = bid & 7;               // all blocks of one t share an XCD/L2
    int j = bid >> 3;
    int tq = j >> 2, pair = j & 3;
    int t = tq*8 + xcd;
    if (t >= TT) return;

    int tid = threadIdx.x;
    int lane = tid & 63, w = tid >> 6;            // 8 waves
    int slab = w >> 2, wsl = w & 3;
    int qi = wsl >> 1, ci = wsl & 1;
    int n32 = lane & 31, koct = lane >> 5;
    int r0 = (pair*2 + slab)*64;                  // up to 448; masked at write

    {
        const uint4* src = (const uint4*)(adp_bf + ((size_t)t*NN + pair*128)*96);
        #pragma unroll
        for (int i = 0; i < 3; ++i) {
            int idx = tid + i*512;                // < 1536
            int s2 = idx / 768, rem = idx - s2*768;
            int r = rem / 12, q = rem - r*12;
            *(uint4*)(&Asq[s2][r*SA + q*8]) = src[idx];
        }
    }
    {
        uint4 z4v = {0u,0u,0u,0u};
        for (int idx = tid; idx < 216; idx += 512) {
            int rr = idx / 9;
            int r = 104 + rr, q = idx - rr*9;
            *(uint4*)(&Hs[r*SH + q*8]) = z4v;
        }
    }

    float16v on0, on1;
    #pragma unroll
    for (int i = 0; i < 16; ++i) { on0[i] = 0.f; on1[i] = 0.f; }
    float rs2[16];
    #pragma unroll
    for (int i = 0; i < 16; ++i) rs2[i] = 0.f;

    const bf16* hbase = hT + (size_t)t*104*448;

    uint4 preB0, preB1, preH0, preH1;
    {
        const uint4* srcB = (const uint4*)(adp_bf + (size_t)t*NN*96);
        preB0 = srcB[tid];
        if (tid < 256) preB1 = srcB[tid + 512];
        { int r = tid >> 3, q = tid & 7;
          preH0 = *(const uint4*)(hbase + (size_t)r*448 + q*8); }
        if (tid < 320) { int idx = tid + 512; int r = idx >> 3, q = idx & 7;
          preH1 = *(const uint4*)(hbase + (size_t)r*448 + q*8); }
    }

    for (int c0 = 0; c0 < NN; c0 += 64) {
        { int r = tid / 12, q = tid - (tid/12)*12;
          *(uint4*)(&Bt[r*SA + q*8]) = preB0; }
        if (tid < 256) { int idx = tid + 512; int r = idx / 12, q = idx - r*12;
          *(uint4*)(&Bt[r*SA + q*8]) = preB1; }
        { int r = tid >> 3, q = tid & 7;
          *(uint4*)(&Hs[r*SH + q*8]) = preH0; }
        if (tid < 320) { int idx = tid + 512; int r = idx >> 3, q = idx & 7;
          *(uint4*)(&Hs[r*SH + q*8]) = preH1; }
        __syncthreads();                          // barA (covers Asq on iter 0)
        int cn = c0 + 64;
        if (cn < NN) {
            const uint4* srcB = (const uint4*)(adp_bf + ((size_t)t*NN + cn)*96);
            preB0 = srcB[tid];
            if (tid < 256) preB1 = srcB[tid + 512];
            { int r = tid >> 3, q = tid & 7;
              preH0 = *(const uint4*)(hbase + (size_t)r*448 + cn + q*8); }
            if (tid < 320) { int idx = tid + 512; int r = idx >> 3, q = idx & 7;
              preH1 = *(const uint4*)(hbase + (size_t)r*448 + cn + q*8); }
        }
        float16v sc;
        #pragma unroll
        for (int i = 0; i < 16; ++i) sc[i] = 0.f;
        #pragma unroll
        for (int s = 0; s < 6; ++s) {
            short8v afq = *(const short8v*)(&Asq[slab][(qi*32 + n32)*SA + s*16 + koct*8]);
            short8v bfr = *(const short8v*)(&Bt[(ci*32 + n32)*SA + s*16 + koct*8]);
            sc = __builtin_amdgcn_mfma_f32_32x32x16_bf16(afq, bfr, sc, 0, 0, 0);
        }
        bool colok = (c0 + ci*32 + n32) < NN;
        #pragma unroll
        for (int reg = 0; reg < 16; ++reg) {
            int crow = (reg & 3) + 8*(reg >> 2) + 4*koct;
            float e = colok ? __expf(fmaxf(sc[reg], 0.f)) : 0.f;
            rs2[reg] += e;
            P[slab][(qi*32 + crow)*SPP + ci*32 + n32] = f2b(e);
        }
        __syncthreads();                          // barB: P complete (cross-wave)
        short8v pA[4];
        #pragma unroll
        for (int s = 0; s < 4; ++s)
            pA[s] = *(const short8v*)(&P[slab][(qi*32 + n32)*SPP + s*16 + koct*8]);
        #pragma unroll
        for (int s = 0; s < 4; ++s) {
            short8v hb0 = *(const short8v*)(&Hs[(ci*32 + n32)*SH + s*16 + koct*8]);
            on0 = __builtin_amdgcn_mfma_f32_32x32x16_bf16(pA[s], hb0, on0, 0, 0, 0);
        }
        #pragma unroll
        for (int s = 0; s < 4; ++s) {
            short8v hb1 = *(const short8v*)(&Hs[((ci+2)*32 + n32)*SH + s*16 + koct*8]);
            on1 = __builtin_amdgcn_mfma_f32_32x32x16_bf16(pA[s], hb1, on1, 0, 0, 0);
        }
        __syncthreads();                          // barC: reads done before restage
    }

    #pragma unroll
    for (int reg = 0; reg < 16; ++reg) {
        float v = rs2[reg];
        v += __shfl_xor(v, 1, 64);
        v += __shfl_xor(v, 2, 64);
        v += __shfl_xor(v, 4, 64);
        v += __shfl_xor(v, 8, 64);
        v += __shfl_xor(v, 16, 64);
        if (n32 == 0) {
            int crow = (reg & 3) + 8*(reg >> 2) + 4*koct;
            rsb[slab][ci][qi*32 + crow] = v;
        }
    }
    __syncthreads();

    #pragma unroll
    for (int reg = 0; reg < 16; ++reg) {
        int crow = (reg & 3) + 8*(reg >> 2) + 4*koct;
        int qrow = qi*32 + crow;
        int gq = r0 + qrow;
        if (gq < NN) {
            float inv = 1.f / (rsb[slab][0][qrow] + rsb[slab][1][qrow]);
            int d0 = ci*32 + n32;
            z1[((size_t)t*NN + gq)*104 + d0] = f2b(on0[reg] * inv);
            int d1 = (ci + 2)*32 + n32;
            if (d1 < 104)
                z1[((size_t)t*NN + gq)*104 + d1] = f2b(on1[reg] * inv);
        }
    }
}

// ---------------- MFMA KV summaries (spatial + temporal) ----------------
__global__ void __launch_bounds__(256) kvs_mf(
    const bf16* __restrict__ qkv, bf16* __restrict__ kvsb_s, bf16* __restrict__ kvsb_t)
{
    constexpr int CK = 32;          // l-chunk
    constexpr int TS = 40;          // padded row stride
    __shared__ bf16 raw[CK][216];   // 208 used (k|v span, qkv cols 104..311)
    __shared__ bf16 kTn[4][32][TS]; // per-head kn^T tile (rows 26..31 unused)
    __shared__ bf16 vT [4][32][TS]; // per-head v^T tile + ones row 26
    __shared__ float invs[CK][4];

    int bb = blockIdx.x;
    bf16* out; int L; long long strideL, base;
    if (bb < TT) { out = kvsb_s + (size_t)bb*NTILE; L = NN; base = (long long)bb*NN*312 + 104; strideL = 312; }
    else { int n = bb - TT; out = kvsb_t + (size_t)n*NTILE; L = TT; base = (long long)n*312 + 104; strideL = (long long)NN*312; }

    int tid = threadIdx.x;
    int lane = tid & 63, w = tid >> 6;       // wave = head
    int n32 = lane & 31, koct = lane >> 5;
    uint4 z4 = {0u,0u,0u,0u};

    float16v acc;
    #pragma unroll
    for (int i = 0; i < 16; ++i) acc[i] = 0.f;

    uint4 pre[4];
    #pragma unroll
    for (int j = 0; j < 4; ++j) {
        int idx = tid + j*256;
        uint4 v = z4;
        if (idx < CK*26) {
            int r = idx / 26, q = idx - r*26;
            if (r < L) v = *(const uint4*)(qkv + base + (long long)r*strideL + q*8);
        }
        pre[j] = v;
    }

    for (int l0 = 0; l0 < L; l0 += CK) {
        int lw = min(CK, L - l0);
        __syncthreads();
        #pragma unroll
        for (int j = 0; j < 4; ++j) {
            int idx = tid + j*256;
            if (idx < CK*26) {
                int r = idx / 26, q = idx - r*26;
                *(uint4*)(&raw[r][q*8]) = pre[j];
            }
        }
        __syncthreads();
        {
            int ln0 = l0 + CK;
            #pragma unroll
            for (int j = 0; j < 4; ++j) {
                int idx = tid + j*256;
                uint4 v = z4;
                if (idx < CK*26 && ln0 < L) {
                    int r = idx / 26, q = idx - r*26;
                    if (r < L - ln0) v = *(const uint4*)(qkv + base + (long long)(ln0 + r)*strideL + q*8);
                }
                pre[j] = v;
            }
        }
        if (tid < CK*4) {
            int l = tid >> 2, h = tid & 3;
            float ss = 0.f;
            #pragma unroll
            for (int m = 0; m < HD; ++m) { float v = b2f(raw[l][h*HD + m]); ss += v*v; }
            invs[l][h] = (l < lw) ? 1.f/fmaxf(sqrtf(ss), 1e-12f) : 0.f;
        }
        __syncthreads();
        for (int idx = tid; idx < 4*CK*HD; idx += 256) {
            int h = idx / (CK*HD); int rem = idx - h*CK*HD;
            int l = rem / HD; int m = rem - l*HD;
            float iv = invs[l][h];
            kTn[h][m][l] = f2b(b2f(raw[l][h*HD + m]) * iv);
            vT[h][m][l]  = raw[l][104 + h*HD + m];
        }
        if (tid < 4*CK) {
            int h = tid >> 5, l = tid & 31;
            vT[h][26][l] = f2b((l < lw) ? 1.f : 0.f);
        }
        __syncthreads();
        #pragma unroll
        for (int s = 0; s < 2; ++s) {
            short8v a = *(const short8v*)(&kTn[w][n32][s*16 + koct*8]);
            short8v b = *(const short8v*)(&vT [w][n32][s*16 + koct*8]);
            acc = __builtin_amdgcn_mfma_f32_32x32x16_bf16(a, b, acc, 0, 0, 0);
        }
    }

    int lo = w*HD;
    #pragma unroll
    for (int reg = 0; reg < 16; ++reg) {
        int m = (reg & 3) + 8*(reg >> 2) + 4*koct;
        if (m < HD) {
            if (n32 < HD)       out[(size_t)(lo + n32)*32 + m] = f2b(acc[reg]);
            else if (n32 == HD) out[(size_t)(104 + w)*32 + m] = f2b(acc[reg]);
        }
    }
}

// ---------------- MFMA linear-attention apply ----------------
__global__ void __launch_bounds__(256) attn_mm(
    bf16* __restrict__ qkv, const bf16* __restrict__ kvsb,
    int M, long long bStride, long long rowStride, float Lf, int outOff)
{
    constexpr int STR = 136;
    __shared__ bf16 As[64*STR];
    __shared__ bf16 Ws[112*STR];
    __shared__ float nsqL[64*4];
    __shared__ float denL[64*4];
    int mt = blockIdx.x, bb = blockIdx.y;
    int tid = threadIdx.x;
    int lane = tid & 63, w = tid >> 6, n16 = lane & 15, quad = lane >> 4;
    bf16* base = qkv + (size_t)bb * bStride;
    int r0 = mt*64;
    uint4 z4 = {0u,0u,0u,0u};

    for (int idx = tid; idx < 64*16; idx += 256) {
        int r = idx >> 4, q = idx & 15;
        int m = r0 + r;
        uint4 v = z4;
        if (m < M && q < 13) v = *(const uint4*)(base + (size_t)m*rowStride + q*8);
        *(uint4*)(&As[r*STR + q*8]) = v;
    }
    for (int idx = tid; idx < 112*16; idx += 256) {
        int c = idx >> 4, q = idx & 15;
        *(uint4*)(&Ws[c*STR + q*8]) = z4;
    }
    __syncthreads();
    {
        const bf16* kb = kvsb + (size_t)bb * NTILE;
        for (int idx = tid; idx < 108*13; idx += 256) {
            int c = idx / 13, qu = idx - c*13;
            int lo = (c < 104) ? (c/26)*26 : (c-104)*26;
            *(uint*)(&Ws[c*STR + lo + qu*2]) = *(const uint*)(kb + (size_t)c*32 + qu*2);
        }
    }
    __syncthreads();

    short8v af[4];
    #pragma unroll
    for (int s = 0; s < 4; ++s)
        af[s] = *(const short8v*)(&As[(16*w + n16)*STR + s*32 + quad*8]);
    float4v acc[7];
    #pragma unroll
    for (int ct = 0; ct < 7; ++ct) { float4v z = {0.f,0.f,0.f,0.f}; acc[ct] = z; }
    #pragma unroll
    for (int ct = 0; ct < 7; ++ct) {
        #pragma unroll
        for (int s = 0; s < 4; ++s) {
            short8v bfr = *(const short8v*)(&Ws[(ct*16 + n16)*STR + s*32 + quad*8]);
            acc[ct] = __builtin_amdgcn_mfma_f32_16x16x32_bf16(af[s], bfr, acc[ct], 0, 0, 0);
        }
    }
    {
        int row = tid >> 2, hh = tid & 3;
        const bf16* qr = &As[row*STR + hh*26];
        float ss = 0.f;
        #pragma unroll
        for (int m = 0; m < HD; ++m) { float v = b2f(qr[m]); ss += v*v; }
        nsqL[row*4 + hh] = ss;
    }
    if (n16 >= 8 && n16 < 12) {
        #pragma unroll
        for (int reg = 0; reg < 4; ++reg)
            denL[(16*w + quad*4 + reg)*4 + (n16 - 8)] = acc[6][reg];
    }
    __syncthreads();
    #pragma unroll
    for (int ct = 0; ct < 7; ++ct) {
        int c = ct*16 + n16;
        if (c < 104) {
            int hh = c / 26;
            #pragma unroll
            for (int reg = 0; reg < 4; ++reg) {
                int lr = 16*w + quad*4 + reg;
                int m = r0 + lr;
                if (m < M) {
                    float iq = 1.f / fmaxf(sqrtf(nsqL[lr*4 + hh]), 1e-12f);
                    float den = iq * denL[lr*4 + hh] + Lf;
                    bf16* rp = base + (size_t)m*rowStride;
                    float num = iq * acc[ct][reg] + Lf * b2f(rp[208 + c]);
                    rp[outOff + c] = f2b(num / den);
                }
            }
        }
    }
}

__global__ void __launch_bounds__(256) y_init_kernel(float* __restrict__ y, const float* __restrict__ ep_b) {
    int i = blockIdx.x*256 + threadIdx.x;
    if (i < NN*104) y[i] = ep_b[i % 104];
}

// ---------------- fused tail: 3 residual MLP blocks + output projection ----------------
// Rows (n) are independent; one block per n replaces 4 dependent dispatches.
__global__ void __launch_bounds__(256) tail_kernel(
    const float* __restrict__ y,
    const float* __restrict__ ew1, const float* __restrict__ eb1,
    const float* __restrict__ ew2, const float* __restrict__ eb2,
    const float* __restrict__ out_w, const float* __restrict__ out_b,
    float* __restrict__ out)
{
    int n = blockIdx.x;
    int tid = threadIdx.x;
    __shared__ float yr[104], hid[208];
    if (tid < 104) yr[tid] = y[(size_t)n*104 + tid];
    __syncthreads();
    for (int i = 0; i < 3; ++i) {
        const float* w1 = ew1 + (size_t)i*104*208;
        const float* b1 = eb1 + (size_t)i*208;
        const float* w2 = ew2 + (size_t)i*208*104;
        const float* b2 = eb2 + (size_t)i*104;
        if (tid < 208) {
            float s = b1[tid];
            for (int k = 0; k < 104; ++k) s += yr[k] * w1[(size_t)k*208 + tid];
            hid[tid] = fmaxf(s, 0.f);
        }
        __syncthreads();
        float ynew = 0.f;
        if (tid < 104) {
            float s = b2[tid];
            for (int k = 0; k < 208; ++k) s += hid[k] * w2[(size_t)k*104 + tid];
            ynew = yr[tid] + s;
        }
        __syncthreads();
        if (tid < 104) yr[tid] = ynew;
        __syncthreads();
    }
    for (int t = tid; t < TT; t += 256) {
        float s = out_b[t];
        for (int d = 0; d < 104; ++d) s += yr[d] * out_w[(size_t)d*TT + t];
        out[(size_t)n*TT + t] = s;
    }
}

// ---------------- launch ----------------
extern "C" void kernel_launch(void* const* d_in, const int* in_sizes, int n_in,
                              void* d_out, int out_size, void* d_ws, size_t ws_size,
                              hipStream_t stream) {
    if (ws_size < WS_NEEDED) return;

    const float* x      = (const float*)d_in[0];
    const float* W_in   = (const float*)d_in[1];
    const float* b_in   = (const float*)d_in[2];
    const float* adp    = (const float*)d_in[3];
    const float* W_tp   = (const float*)d_in[4];
    const float* b_tp   = (const float*)d_in[5];
    const float* qkv_w  = (const float*)d_in[6];
    const float* op_w   = (const float*)d_in[7];
    const float* op_b   = (const float*)d_in[8];
    const float* pw_w   = (const float*)d_in[9];
    const float* pw_b   = (const float*)d_in[10];
    const float* fc_w1  = (const float*)d_in[11];
    const float* fc_b1  = (const float*)d_in[12];
    const float* fc_w2  = (const float*)d_in[13];
    const float* fc_b2  = (const float*)d_in[14];
    const float* ln1_g  = (const float*)d_in[15];
    const float* ln1_b  = (const float*)d_in[16];
    const float* ln2_g  = (const float*)d_in[17];
    const float* ln2_b  = (const float*)d_in[18];
    const float* ep_w   = (const float*)d_in[19];
    const float* ep_b   = (const float*)d_in[20];
    const float* enc_w1 = (const float*)d_in[21];
    const float* enc_b1 = (const float*)d_in[22];
    const float* enc_w2 = (const float*)d_in[23];
    const float* enc_b2 = (const float*)d_in[24];
    const float* out_w  = (const float*)d_in[25];
    const float* out_b  = (const float*)d_in[26];

    bf16* B0 = (bf16*)d_ws;
    bf16* B1 = B0 + NB0;
    bf16* B2 = B1 + NB1;
    bf16* B3 = B2 + NB2;
    bf16* kvsb_s = B3 + NB3;
    bf16* kvsb_t = kvsb_s + NKVSB_S;
    float* ybuf  = (float*)(kvsb_t + NKVSB_T);
    bf16* wtp   = (bf16*)(ybuf + NY);
    bf16* wqkv0 = wtp + NW_TP;
    bf16* wqkv1 = wqkv0 + NW_QKV;
    bf16* wop0  = wqkv1 + NW_QKV;
    bf16* wop1  = wop0 + NW_OP;
    bf16* wpw0  = wop1 + NW_OP;
    bf16* wpw1  = wpw0 + NW_PW;
    bf16* wfc1  = wpw1 + NW_PW;
    bf16* wfc2  = wfc1 + NW_FC1;
    bf16* wept  = wfc2 + NW_FC2;
    bf16* adp_bf = B2;
    bf16* hTbuf  = B2 + NADP;

    // 0. weight prep
    prep_w<<<CEILDIV(104*128,256), 256, 0, stream>>>(W_tp, wtp, 104, 104, 128);
    prep_w<<<CEILDIV(312*128,256), 256, 0, stream>>>(qkv_w, wqkv0, 104, 312, 128);
    prep_w<<<CEILDIV(312*128,256), 256, 0, stream>>>(qkv_w + 104*312, wqkv1, 104, 312, 128);
    prep_w<<<CEILDIV(104*224,256), 256, 0, stream>>>(op_w, wop0, 208, 104, 224);
    prep_w<<<CEILDIV(104*224,256), 256, 0, stream>>>(op_w + 208*104, wop1, 208, 104, 224);
    prep_w<<<CEILDIV(104*128,256), 256, 0, stream>>>(pw_w, wpw0, 104, 104, 128);
    prep_w<<<CEILDIV(104*128,256), 256, 0, stream>>>(pw_w + 104*104, wpw1, 104, 104, 128);
    prep_w<<<CEILDIV(208*128,256), 256, 0, stream>>>(fc_w1, wfc1, 104, 208, 128);
    prep_w<<<CEILDIV(104*224,256), 256, 0, stream>>>(fc_w2, wfc2, 208, 104, 224);
    prep_wT<<<CEILDIV(37960,64), 256, 0, stream>>>(ep_w, wept);

    const int GX  = CEILDIV(TN, 64);     // 2282
    const int GM2 = CEILDIV(TN, 128);    // 1141

    // 1. hcat -> B2
    hcat_kernel<<<CEILDIV(TN,16), 256, 0, stream>>>(x, W_in, b_in, adp, B2);
    // 2. h = hcat @ W_tp + b_tp -> B0
    gemm_mf2<128><<<GM2, 256, 0, stream>>>(B2, 104, 104, wtp, b_tp, B0, TN, 104, 0);
    // 2b. z1 pre-staging into B2
    prep_adp<<<CEILDIV((int)NADP,256), 256, 0, stream>>>(adp, adp_bf);
    ht_kernel<<<dim3(7, TT), 256, 0, stream>>>(B0, hTbuf);
    // 3. z1 -> B1
    z1_mf<<<Z1_BLOCKS, 512, 0, stream>>>(adp_bf, hTbuf, B1);
    // 4. attention 0 on h
    gemm_mf2<128><<<GM2*3, 256, 0, stream>>>(B0, 104, 104, wqkv0, nullptr, B2, TN, 312, 0);
    kvs_mf<<<TT+NN, 256, 0, stream>>>(B2, kvsb_s, kvsb_t);
    attn_mm<<<dim3(6, NN), 256, 0, stream>>>(B2, kvsb_t, TT, 312, (long long)NN*312, (float)TT, 104);
    attn_mm<<<dim3(7, TT), 256, 0, stream>>>(B2, kvsb_s, NN, (long long)NN*312, 312, (float)NN, 0);
    gemm_mf<224><<<GX*2, 256, 0, stream>>>(B2, 312, 208, wop0, op_b, B3, TN, 104, 0);   // att0 -> B3
    // 5. attention 1 on z1
    gemm_mf2<128><<<GM2*3, 256, 0, stream>>>(B1, 104, 104, wqkv1, nullptr, B2, TN, 312, 0);
    kvs_mf<<<TT+NN, 256, 0, stream>>>(B2, kvsb_s, kvsb_t);
    attn_mm<<<dim3(6, NN), 256, 0, stream>>>(B2, kvsb_t, TT, 312, (long long)NN*312, (float)TT, 104);
    attn_mm<<<dim3(7, TT), 256, 0, stream>>>(B2, kvsb_s, NN, (long long)NN*312, 312, (float)NN, 0);
    gemm_mf<224><<<GX*2, 256, 0, stream>>>(B2, 312, 208, wop1, op_b + 104, B1, TN, 104, 0); // att1 -> B1
    // 6+7. fused gates + LN1 (in-place B0 -> h1)
    gate_ln1<<<GX, 256, 0, stream>>>(B0, B3, B1, wpw0, wpw1, pw_b, ln1_g, ln1_b);
    // 8. MLP: fc1 -> hidden (B2), fused fc2+LN2 -> h2 (B3)
    gemm_mf2<128><<<GM2*2, 256, 0, stream>>>(B0, 104, 104, wfc1, fc_b1, B2, TN, 208, 1);
    fc2_ln2<<<GX, 256, 0, stream>>>(B2, wfc2, fc_b2, B0, ln2_g, ln2_b, B3);
    // 9. encoder_proj
    y_init_kernel<<<CEILDIV(NN*104,256), 256, 0, stream>>>(ybuf, ep_b);
    ep_mf<<<dim3(CEILDIV(NN,64), 2, CEILDIV(TT,8)), 256, 0, stream>>>(B3, wept, ybuf);
    // 10+11. fused residual MLP blocks + output projection
    tail_kernel<<<NN, 256, 0, stream>>>(ybuf, enc_w1, enc_b1, enc_w2, enc_b2,
                                        out_w, out_b, (float*)d_out);
}

// Round 7
// 1253.534 us; speedup vs baseline: 1.0870x; 1.0870x over previous
//
#include <hip/hip_runtime.h>
#include <hip/hip_bf16.h>
#include <cstddef>

// ---------------- problem constants ----------------
#define TT   365
#define NN   400
#define TN   (TT*NN)            // 146000
#define HD   26                 // head dim
#define NH   4                  // heads

#define CEILDIV(a,b) (((a)+(b)-1)/(b))

typedef __hip_bfloat16 bf16;
typedef short short8v __attribute__((ext_vector_type(8)));
typedef float float4v __attribute__((ext_vector_type(4)));
typedef float float16v __attribute__((ext_vector_type(16)));
__device__ __forceinline__ float b2f(bf16 v){ return __bfloat162float(v); }
__device__ __forceinline__ bf16  f2b(float v){ return __float2bfloat16(v); }

// ---------------- workspace layout ----------------
static constexpr size_t NB0 = (size_t)TN*104;   // h / h1
static constexpr size_t NB1 = (size_t)TN*104;   // z1 -> att1
static constexpr size_t NB2 = (size_t)TN*312;   // hcat -> [adp_bf|hT] -> qkv+concat -> hidden
static constexpr size_t NB3 = (size_t)TN*104;   // att0 -> h2
static constexpr size_t NBF = NB0+NB1+NB2+NB3;
// compact band KV tiles: per b, 108 rows x 32 (band cols 0..25), bf16
static constexpr size_t NTILE   = (size_t)108*32;
static constexpr size_t NKVSB_S = (size_t)TT*NTILE;
static constexpr size_t NKVSB_T = (size_t)NN*NTILE;
static constexpr size_t NY      = (size_t)NN*104;
// transposed bf16 weights (Wt[n][kp], zero-padded k)
static constexpr size_t NW_TP   = 104*128;
static constexpr size_t NW_QKV  = 312*128;   // x2
static constexpr size_t NW_OP   = 104*224;   // x2
static constexpr size_t NW_PW   = 104*128;   // x2
static constexpr size_t NW_FC1  = 208*128;
static constexpr size_t NW_FC2  = 104*224;
static constexpr size_t NW_EPT  = (size_t)104*37960;   // ep_w transposed, no pad
static constexpr size_t NWT     = NW_TP + 2*NW_QKV + 2*NW_OP + 2*NW_PW + NW_FC1 + NW_FC2 + NW_EPT;
static constexpr size_t WS_NEEDED = NBF*2 + (NKVSB_S+NKVSB_T)*2 + NY*4 + NWT*2;
// z1 scratch lives inside B2 (dead between step 2 and step 4):
static constexpr size_t NADP_ROWS = (size_t)TN + 64;
static constexpr size_t NADP = NADP_ROWS*96;
static constexpr size_t NHT  = ((size_t)TT*104 + 8)*448;
static_assert(NADP + NHT <= NB2, "z1 scratch must fit in B2");

// ---------------- weight prep: Wt[n*KP+k] = bf16(W[k*Nc+n]), zero pad k>=K ----------------
__global__ void __launch_bounds__(256) prep_w(
    const float* __restrict__ W, bf16* __restrict__ Wt, int K, int Nc, int KP)
{
    int idx = blockIdx.x*256 + threadIdx.x;
    if (idx >= Nc*KP) return;
    int n = idx / KP, k = idx - n*KP;
    Wt[idx] = (k < K) ? f2b(W[(size_t)k*Nc + n]) : f2b(0.f);
}

// coalesced LDS transpose for ep weights: Wt[n][k] = bf16(W[k][n]); W is 37960x104 fp32
__global__ void __launch_bounds__(256) prep_wT(
    const float* __restrict__ W, bf16* __restrict__ Wt)
{
    __shared__ float T[64][105];
    int k0 = blockIdx.x * 64;
    int tid = threadIdx.x;
    for (int idx = tid; idx < 64*104; idx += 256) {
        int r = idx / 104, c = idx - r*104;
        int k = k0 + r;
        T[r][c] = (k < 37960) ? W[(size_t)k*104 + c] : 0.f;
    }
    __syncthreads();
    for (int idx = tid; idx < 104*32; idx += 256) {
        int n = idx >> 5, kp = idx & 31;
        int k = kp*2;
        if (k0 + k + 1 < 37960 || k0 + k < 37960) {
            if (k0 + k < 37960) {
                bf16 lo = f2b(T[k][n]);
                bf16 hi = f2b(T[k+1][n]);   // k+1 row is zero-padded if OOB of tile data
                uint v = ((uint)(*(ushort*)&hi) << 16) | (*(ushort*)&lo);
                if (k0 + k + 1 < 37960) *(uint*)(Wt + (size_t)n*37960 + k0 + k) = v;
                else Wt[(size_t)n*37960 + k0 + k] = lo;
            }
        }
    }
}

// adp_bf[row][e] = bf16(adp[row][e]) for e<80 else 0; rows >= TN are zero.
__global__ void __launch_bounds__(256) prep_adp(
    const float* __restrict__ adp, bf16* __restrict__ out)
{
    size_t i = (size_t)blockIdx.x*256 + threadIdx.x;
    if (i >= NADP) return;
    size_t row = i / 96; int e = (int)(i - row*96);
    float v = (row < TN && e < 80) ? adp[row*80 + e] : 0.f;
    out[i] = f2b(v);
}

// hT[t][d][n] = h[t][n][d], n padded to 448 with zeros
__global__ void __launch_bounds__(256) ht_kernel(
    const bf16* __restrict__ h, bf16* __restrict__ hT)
{
    __shared__ bf16 As[64*106];
    int t = blockIdx.y, n0 = blockIdx.x*64;
    int tid = threadIdx.x;
    for (int idx = tid; idx < 64*52; idx += 256) {
        int r = idx / 52, k = idx - r*52;
        int n = n0 + r;
        uint v = 0;
        if (n < NN) v = *(const uint*)(h + ((size_t)t*NN + n)*104 + k*2);
        *(uint*)(&As[r*106 + k*2]) = v;
    }
    __syncthreads();
    for (int idx = tid; idx < 104*32; idx += 256) {
        int d = idx >> 5, np = idx & 31;
        int n = np*2;
        ushort lo = *(ushort*)&As[n*106 + d];
        ushort hi = *(ushort*)&As[(n+1)*106 + d];
        uint v = ((uint)hi << 16) | lo;
        *(uint*)(hT + ((size_t)t*104 + d)*448 + n0 + n) = v;
    }
}

// ---------------- hcat (16 rows/block, LDS-staged uint4 row writes) ----------------
__global__ void __launch_bounds__(256) hcat_kernel(
    const float* __restrict__ x, const float* __restrict__ W_in,
    const float* __restrict__ b_in, const float* __restrict__ adp,
    bf16* __restrict__ hcat)
{
    __shared__ bf16 T[16][112];          // 104 used; 224B row stride (16B-aligned)
    int r0 = blockIdx.x * 16;
    int tid = threadIdx.x;
    // proj cols 0..23
    for (int idx = tid; idx < 16*24; idx += 256) {
        int r = idx / 24, c = idx - r*24;
        int row = r0 + r;
        int t = row / NN, n = row - t*NN;
        size_t xb = ((size_t)n*TT + t)*3;
        float s = b_in[c] + x[xb]*W_in[c] + x[xb+1]*W_in[24+c] + x[xb+2]*W_in[48+c];
        T[r][c] = f2b(s);
    }
    // adp cols 24..103 (coalesced f32 reads)
    for (int idx = tid; idx < 16*80; idx += 256) {
        int r = idx / 80, e = idx - r*80;
        T[r][24+e] = f2b(adp[(size_t)(r0+r)*80 + e]);
    }
    __syncthreads();
    for (int idx = tid; idx < 16*13; idx += 256) {
        int r = idx / 13, q = idx - r*13;
        *(uint4*)(hcat + ((size_t)(r0+r))*104 + q*8) = *(const uint4*)(&T[r][q*8]);
    }
}

// ---------------- MFMA GEMM 64-tile (R7: restored everywhere; gemm_mf2 regressed) ----------------
// 1-D grid with bijective XCD grouping (m204): column-tiles of one row-slab
// land adjacent on the SAME XCD so the A-slab is fetched from HBM once.
template<int KP>
__global__ void __launch_bounds__(256) gemm_mf(
    const bf16* __restrict__ A, int lda, int K,
    const bf16* __restrict__ Wt, const float* __restrict__ bias,
    bf16* __restrict__ C, int M, int Nc, int relu)
{
    constexpr int STR = KP + 8;
    constexpr int KPQ = KP/8;
    __shared__ bf16 As[64*STR];
    __shared__ bf16 Ws[64*STR];
    int nCol = (Nc + 63) >> 6;
    int nwg = gridDim.x;
    int bid = blockIdx.x;
    int xcd = bid & 7, kk = bid >> 3;
    int q8 = nwg >> 3, r8 = nwg & 7;
    int widx = (xcd < r8 ? xcd*(q8+1) : r8*(q8+1) + (xcd - r8)*q8) + kk;
    int mblk = widx / nCol;
    int m0 = mblk * 64;
    int c0 = (widx - mblk*nCol) * 64;
    int tid = threadIdx.x;
    const int KQ = K/8;
    uint4 z4 = {0u,0u,0u,0u};
    for (int idx = tid; idx < 64*KPQ; idx += 256) {
        int r = idx / KPQ, q = idx - r*KPQ;
        int m = m0 + r;
        uint4 v = z4;
        if (m < M && q < KQ) v = *(const uint4*)(A + (size_t)m*lda + q*8);
        *(uint4*)(&As[r*STR + q*8]) = v;
    }
    for (int idx = tid; idx < 64*KPQ; idx += 256) {
        int r = idx / KPQ, q = idx - r*KPQ;
        int n = c0 + r;
        uint4 v = z4;
        if (n < Nc) v = *(const uint4*)(Wt + (size_t)n*KP + q*8);
        *(uint4*)(&Ws[r*STR + q*8]) = v;
    }
    __syncthreads();

    int lane = tid & 63, w = tid >> 6;
    int n16 = lane & 15, quad = lane >> 4;
    constexpr int KS = KP/32;
    short8v af[KS];
    #pragma unroll
    for (int s = 0; s < KS; ++s)
        af[s] = *(const short8v*)(&As[(16*w + n16)*STR + s*32 + quad*8]);
    float4v acc[4];
    #pragma unroll
    for (int ct = 0; ct < 4; ++ct) { float4v z = {0.f,0.f,0.f,0.f}; acc[ct] = z; }
    #pragma unroll
    for (int ct = 0; ct < 4; ++ct) {
        #pragma unroll
        for (int s = 0; s < KS; ++s) {
            short8v bfr = *(const short8v*)(&Ws[(ct*16 + n16)*STR + s*32 + quad*8]);
            acc[ct] = __builtin_amdgcn_mfma_f32_16x16x32_bf16(af[s], bfr, acc[ct], 0, 0, 0);
        }
    }
    #pragma unroll
    for (int ct = 0; ct < 4; ++ct) {
        int c = c0 + ct*16 + n16;
        if (c < Nc) {
            float b = bias ? bias[c] : 0.f;
            #pragma unroll
            for (int reg = 0; reg < 4; ++reg) {
                int m = m0 + 16*w + quad*4 + reg;
                if (m < M) {
                    float v = acc[ct][reg] + b;
                    if (relu) v = fmaxf(v, 0.f);
                    C[(size_t)m*Nc + c] = f2b(v);
                }
            }
        }
    }
}

// ---------------- fused gates + LN1 ----------------
// h1 = LN(2*(h + att0*(h@pw0+b0) + 0.01*att1*(att0@pw1+b1))) in-place into h.
__global__ void __launch_bounds__(256) gate_ln1(
    bf16* __restrict__ h, const bf16* __restrict__ att0, const bf16* __restrict__ att1,
    const bf16* __restrict__ w0t, const bf16* __restrict__ w1t, const float* __restrict__ pwb,
    const float* __restrict__ gamma, const float* __restrict__ beta)
{
    constexpr int STR = 136;
    __shared__ bf16 A0s[64*STR];
    __shared__ bf16 A1s[64*STR];
    __shared__ bf16 Ws[112*STR];
    __shared__ float prm[416];     // pwb(208) | gamma(104) | beta(104)
    int m0 = blockIdx.x * 64;
    int tid = threadIdx.x;
    int lane = tid & 63, w = tid >> 6, n16 = lane & 15, quad = lane >> 4;
    uint4 z4 = {0u,0u,0u,0u};

    for (int idx = tid; idx < 64*16; idx += 256) {
        int r = idx >> 4, q = idx & 15;
        int m = m0 + r;
        uint4 v0 = z4, v1 = z4;
        if (m < TN && q < 13) {
            v0 = *(const uint4*)(h    + (size_t)m*104 + q*8);
            v1 = *(const uint4*)(att0 + (size_t)m*104 + q*8);
        }
        *(uint4*)(&A0s[r*STR + q*8]) = v0;
        *(uint4*)(&A1s[r*STR + q*8]) = v1;
    }
    for (int idx = tid; idx < 112*16; idx += 256) {
        int c = idx >> 4, q = idx & 15;
        uint4 v = z4;
        if (c < 104) v = *(const uint4*)(w0t + (size_t)c*128 + q*8);
        *(uint4*)(&Ws[c*STR + q*8]) = v;
    }
    for (int i = tid; i < 416; i += 256)
        prm[i] = (i < 208) ? pwb[i] : (i < 312 ? gamma[i-208] : beta[i-312]);
    __syncthreads();

    short8v a0f[4], a1f[4];
    #pragma unroll
    for (int s = 0; s < 4; ++s) {
        a0f[s] = *(const short8v*)(&A0s[(16*w + n16)*STR + s*32 + quad*8]);
        a1f[s] = *(const short8v*)(&A1s[(16*w + n16)*STR + s*32 + quad*8]);
    }
    float4v acc0[7], acc1[7];
    #pragma unroll
    for (int ct = 0; ct < 7; ++ct) { float4v z = {0.f,0.f,0.f,0.f}; acc0[ct] = z; acc1[ct] = z; }
    #pragma unroll
    for (int ct = 0; ct < 7; ++ct)
        #pragma unroll
        for (int s = 0; s < 4; ++s) {
            short8v bfr = *(const short8v*)(&Ws[(ct*16 + n16)*STR + s*32 + quad*8]);
            acc0[ct] = __builtin_amdgcn_mfma_f32_16x16x32_bf16(a0f[s], bfr, acc0[ct], 0, 0, 0);
        }
    __syncthreads();
    for (int idx = tid; idx < 112*16; idx += 256) {
        int c = idx >> 4, q = idx & 15;
        uint4 v = z4;
        if (c < 104) v = *(const uint4*)(w1t + (size_t)c*128 + q*8);
        *(uint4*)(&Ws[c*STR + q*8]) = v;
    }
    __syncthreads();
    #pragma unroll
    for (int ct = 0; ct < 7; ++ct)
        #pragma unroll
        for (int s = 0; s < 4; ++s) {
            short8v bfr = *(const short8v*)(&Ws[(ct*16 + n16)*STR + s*32 + quad*8]);
            acc1[ct] = __builtin_amdgcn_mfma_f32_16x16x32_bf16(a1f[s], bfr, acc1[ct], 0, 0, 0);
        }

    // epilogue: g -> LN (row distributed across the 16 n16 lanes)
    float sum[4] = {0.f,0.f,0.f,0.f};
    #pragma unroll
    for (int ct = 0; ct < 7; ++ct) {
        int c = ct*16 + n16;
        bool colok = c < 104;
        float b0 = colok ? prm[c] : 0.f;
        float b1 = colok ? prm[104 + c] : 0.f;
        #pragma unroll
        for (int reg = 0; reg < 4; ++reg) {
            int r = 16*w + quad*4 + reg;
            int m = m0 + r;
            float xv = 0.f;
            if (colok && m < TN) {
                float p0 = acc0[ct][reg] + b0;
                float p1 = acc1[ct][reg] + b1;
                float hv = b2f(A0s[r*STR + c]);
                float a0 = b2f(A1s[r*STR + c]);
                float a1 = b2f(att1[(size_t)m*104 + c]);
                xv = 2.f*(hv + a0*p0 + 0.01f*a1*p1);
            }
            acc0[ct][reg] = xv;
            sum[reg] += xv;
        }
    }
    #pragma unroll
    for (int reg = 0; reg < 4; ++reg) {
        float v = sum[reg];
        v += __shfl_xor(v,1,64); v += __shfl_xor(v,2,64);
        v += __shfl_xor(v,4,64); v += __shfl_xor(v,8,64);
        sum[reg] = v * (1.f/104.f);                     // mean
    }
    float var[4] = {0.f,0.f,0.f,0.f};
    #pragma unroll
    for (int ct = 0; ct < 7; ++ct) {
        bool colok = (ct*16 + n16) < 104;
        #pragma unroll
        for (int reg = 0; reg < 4; ++reg) {
            if (colok) {
                float d = acc0[ct][reg] - sum[reg];
                acc0[ct][reg] = d;
                var[reg] += d*d;
            }
        }
    }
    #pragma unroll
    for (int reg = 0; reg < 4; ++reg) {
        float v = var[reg];
        v += __shfl_xor(v,1,64); v += __shfl_xor(v,2,64);
        v += __shfl_xor(v,4,64); v += __shfl_xor(v,8,64);
        var[reg] = rsqrtf(v * (1.f/104.f) + 1e-5f);
    }
    #pragma unroll
    for (int ct = 0; ct < 7; ++ct) {
        int c = ct*16 + n16;
        if (c < 104) {
            float g = prm[208 + c], be = prm[312 + c];
            #pragma unroll
            for (int reg = 0; reg < 4; ++reg) {
                int m = m0 + 16*w + quad*4 + reg;
                if (m < TN)
                    h[(size_t)m*104 + c] = f2b(acc0[ct][reg]*var[reg]*g + be);
            }
        }
    }
}

// ---------------- fused fc2 + LN2: h2 = LN(h1 + hidden@fc_w2 + b) ----------------
__global__ void __launch_bounds__(256) fc2_ln2(
    const bf16* __restrict__ hidden, const bf16* __restrict__ w2t, const float* __restrict__ b2,
    const bf16* __restrict__ h1, const float* __restrict__ gamma, const float* __restrict__ beta,
    bf16* __restrict__ h2)
{
    constexpr int STRA = 232;   // 224 + 8
    constexpr int STRW = 136;   // 128 + 8 (per half)
    __shared__ bf16 As[64*STRA];
    __shared__ bf16 Ws[112*STRW];
    __shared__ float prm[312];  // b2(104) | gamma(104) | beta(104)
    int m0 = blockIdx.x * 64;
    int tid = threadIdx.x;
    int lane = tid & 63, w = tid >> 6, n16 = lane & 15, quad = lane >> 4;
    uint4 z4 = {0u,0u,0u,0u};

    for (int idx = tid; idx < 64*28; idx += 256) {
        int r = idx / 28, q = idx - r*28;
        int m = m0 + r;
        uint4 v = z4;
        if (m < TN && q < 26) v = *(const uint4*)(hidden + (size_t)m*208 + q*8);
        *(uint4*)(&As[r*STRA + q*8]) = v;
    }
    for (int idx = tid; idx < 112*16; idx += 256) {
        int c = idx >> 4, q = idx & 15;
        uint4 v = z4;
        if (c < 104) v = *(const uint4*)(w2t + (size_t)c*224 + q*8);
        *(uint4*)(&Ws[c*STRW + q*8]) = v;
    }
    for (int i = tid; i < 312; i += 256)
        prm[i] = (i < 104) ? b2[i] : (i < 208 ? gamma[i-104] : beta[i-208]);
    __syncthreads();

    short8v af[7];
    #pragma unroll
    for (int s = 0; s < 7; ++s)
        af[s] = *(const short8v*)(&As[(16*w + n16)*STRA + s*32 + quad*8]);
    float4v acc[7];
    #pragma unroll
    for (int ct = 0; ct < 7; ++ct) { float4v z = {0.f,0.f,0.f,0.f}; acc[ct] = z; }
    #pragma unroll
    for (int ct = 0; ct < 7; ++ct)
        #pragma unroll
        for (int s = 0; s < 4; ++s) {
            short8v bfr = *(const short8v*)(&Ws[(ct*16 + n16)*STRW + s*32 + quad*8]);
            acc[ct] = __builtin_amdgcn_mfma_f32_16x16x32_bf16(af[s], bfr, acc[ct], 0, 0, 0);
        }
    __syncthreads();
    for (int idx = tid; idx < 112*16; idx += 256) {   // half 2: k 128..223 (12 data uint4)
        int c = idx >> 4, q = idx & 15;
        uint4 v = z4;
        if (c < 104 && q < 12) v = *(const uint4*)(w2t + (size_t)c*224 + 128 + q*8);
        *(uint4*)(&Ws[c*STRW + q*8]) = v;
    }
    __syncthreads();
    #pragma unroll
    for (int ct = 0; ct < 7; ++ct)
        #pragma unroll
        for (int s = 4; s < 7; ++s) {
            short8v bfr = *(const short8v*)(&Ws[(ct*16 + n16)*STRW + (s-4)*32 + quad*8]);
            acc[ct] = __builtin_amdgcn_mfma_f32_16x16x32_bf16(af[s], bfr, acc[ct], 0, 0, 0);
        }

    // epilogue: x = h1 + m  -> LN
    float sum[4] = {0.f,0.f,0.f,0.f};
    #pragma unroll
    for (int ct = 0; ct < 7; ++ct) {
        int c = ct*16 + n16;
        bool colok = c < 104;
        float bb = colok ? prm[c] : 0.f;
        #pragma unroll
        for (int reg = 0; reg < 4; ++reg) {
            int m = m0 + 16*w + quad*4 + reg;
            float xv = 0.f;
            if (colok && m < TN)
                xv = b2f(h1[(size_t)m*104 + c]) + acc[ct][reg] + bb;
            acc[ct][reg] = xv;
            sum[reg] += xv;
        }
    }
    #pragma unroll
    for (int reg = 0; reg < 4; ++reg) {
        float v = sum[reg];
        v += __shfl_xor(v,1,64); v += __shfl_xor(v,2,64);
        v += __shfl_xor(v,4,64); v += __shfl_xor(v,8,64);
        sum[reg] = v * (1.f/104.f);
    }
    float var[4] = {0.f,0.f,0.f,0.f};
    #pragma unroll
    for (int ct = 0; ct < 7; ++ct) {
        bool colok = (ct*16 + n16) < 104;
        #pragma unroll
        for (int reg = 0; reg < 4; ++reg) {
            if (colok) {
                float d = acc[ct][reg] - sum[reg];
                acc[ct][reg] = d;
                var[reg] += d*d;
            }
        }
    }
    #pragma unroll
    for (int reg = 0; reg < 4; ++reg) {
        float v = var[reg];
        v += __shfl_xor(v,1,64); v += __shfl_xor(v,2,64);
        v += __shfl_xor(v,4,64); v += __shfl_xor(v,8,64);
        var[reg] = rsqrtf(v * (1.f/104.f) + 1e-5f);
    }
    #pragma unroll
    for (int ct = 0; ct < 7; ++ct) {
        int c = ct*16 + n16;
        if (c < 104) {
            float g = prm[104 + c], be = prm[208 + c];
            #pragma unroll
            for (int reg = 0; reg < 4; ++reg) {
                int m = m0 + 16*w + quad*4 + reg;
                if (m < TN)
                    h2[(size_t)m*104 + c] = f2b(acc[ct][reg]*var[reg]*g + be);
            }
        }
    }
}

// ---------------- MFMA encoder_proj ----------------
__global__ void __launch_bounds__(256) ep_mf(
    const bf16* __restrict__ h2, const bf16* __restrict__ wt, float* __restrict__ y)
{
    constexpr int STR = 136;
    __shared__ bf16 As[64*STR];
    __shared__ bf16 Ws[64*STR];
    int m0 = blockIdx.x * 64;
    int c0 = blockIdx.y * 64;
    int t0 = blockIdx.z * 8;
    int t1 = min(TT, t0 + 8);
    int tid = threadIdx.x;
    int lane = tid & 63, w = tid >> 6, n16 = lane & 15, quad = lane >> 4;
    uint4 z4 = {0u,0u,0u,0u};

    float4v acc[4];
    #pragma unroll
    for (int ct = 0; ct < 4; ++ct) { float4v z = {0.f,0.f,0.f,0.f}; acc[ct] = z; }

    for (int t = t0; t < t1; ++t) {
        for (int idx = tid; idx < 64*16; idx += 256) {
            int r = idx >> 4, q = idx & 15;
            int m = m0 + r;
            uint4 va = z4;
            if (m < NN && q < 13) va = *(const uint4*)(h2 + ((size_t)t*NN + m)*104 + q*8);
            *(uint4*)(&As[r*STR + q*8]) = va;
            int c = c0 + r;
            uint4 vw = z4;
            if (c < 104 && q < 13) vw = *(const uint4*)(wt + (size_t)c*37960 + t*104 + q*8);
            *(uint4*)(&Ws[r*STR + q*8]) = vw;
        }
        __syncthreads();
        short8v af[4];
        #pragma unroll
        for (int s = 0; s < 4; ++s)
            af[s] = *(const short8v*)(&As[(16*w + n16)*STR + s*32 + quad*8]);
        #pragma unroll
        for (int ct = 0; ct < 4; ++ct) {
            #pragma unroll
            for (int s = 0; s < 4; ++s) {
                short8v bfr = *(const short8v*)(&Ws[(ct*16 + n16)*STR + s*32 + quad*8]);
                acc[ct] = __builtin_amdgcn_mfma_f32_16x16x32_bf16(af[s], bfr, acc[ct], 0, 0, 0);
            }
        }
        __syncthreads();
    }
    #pragma unroll
    for (int ct = 0; ct < 4; ++ct) {
        int c = c0 + ct*16 + n16;
        if (c < 104) {
            #pragma unroll
            for (int reg = 0; reg < 4; ++reg) {
                int m = m0 + 16*w + quad*4 + reg;
                if (m < NN) atomicAdd(&y[(size_t)m*104 + c], acc[ct][reg]);
            }
        }
    }
}

// ---------------- MFMA z1 (R5 structure, unchanged) ----------------
static constexpr int Z1_TQ = CEILDIV(TT, 8);          // 46
static constexpr int Z1_BLOCKS = 8 * Z1_TQ * 4;       // 1472
__global__ void __launch_bounds__(512, 4) z1_mf(
    const bf16* __restrict__ adp_bf, const bf16* __restrict__ hT, bf16* __restrict__ z1)
{
    constexpr int SA  = 104;   // Asq/Bt row stride (96 data + pad), 16B-aligned
    constexpr int SH  = 72;    // Hs row stride (64 data + pad)
    constexpr int SPP = 72;    // P  row stride (64 data + pad)
    __shared__ bf16 Asq[2][64*SA];   // 26624 B: per-slab q rows (persist)
    __shared__ bf16 Bt[64*SA];       // 13312 B: shared c-rows tile
    __shared__ bf16 Hs[128*SH];      // 18432 B: shared hT tile (rows 104..127 zero)
    __shared__ bf16 P[2][64*SPP];    // 18432 B: per-slab probabilities
    __shared__ float rsb[2][2][64];  //  2048 B

    int bid = blockIdx.x;
    int xcd = bid & 7;               // all blocks of one t share an XCD/L2
    int j = bid >> 3;
    int tq = j >> 2, pair = j & 3;
    int t = tq*8 + xcd;
    if (t >= TT) return;

    int tid = threadIdx.x;
    int lane = tid & 63, w = tid >> 6;            // 8 waves
    int slab = w >> 2, wsl = w & 3;
    int qi = wsl >> 1, ci = wsl & 1;
    int n32 = lane & 31, koct = lane >> 5;
    int r0 = (pair*2 + slab)*64;                  // up to 448; masked at write

    {
        const uint4* src = (const uint4*)(adp_bf + ((size_t)t*NN + pair*128)*96);
        #pragma unroll
        for (int i = 0; i < 3; ++i) {
            int idx = tid + i*512;                // < 1536
            int s2 = idx / 768, rem = idx - s2*768;
            int r = rem / 12, q = rem - r*12;
            *(uint4*)(&Asq[s2][r*SA + q*8]) = src[idx];
        }
    }
    {
        uint4 z4v = {0u,0u,0u,0u};
        for (int idx = tid; idx < 216; idx += 512) {
            int rr = idx / 9;
            int r = 104 + rr, q = idx - rr*9;
            *(uint4*)(&Hs[r*SH + q*8]) = z4v;
        }
    }

    float16v on0, on1;
    #pragma unroll
    for (int i = 0; i < 16; ++i) { on0[i] = 0.f; on1[i] = 0.f; }
    float rs2[16];
    #pragma unroll
    for (int i = 0; i < 16; ++i) rs2[i] = 0.f;

    const bf16* hbase = hT + (size_t)t*104*448;

    uint4 preB0, preB1, preH0, preH1;
    {
        const uint4* srcB = (const uint4*)(adp_bf + (size_t)t*NN*96);
        preB0 = srcB[tid];
        if (tid < 256) preB1 = srcB[tid + 512];
        { int r = tid >> 3, q = tid & 7;
          preH0 = *(const uint4*)(hbase + (size_t)r*448 + q*8); }
        if (tid < 320) { int idx = tid + 512; int r = idx >> 3, q = idx & 7;
          preH1 = *(const uint4*)(hbase + (size_t)r*448 + q*8); }
    }

    for (int c0 = 0; c0 < NN; c0 += 64) {
        { int r = tid / 12, q = tid - (tid/12)*12;
          *(uint4*)(&Bt[r*SA + q*8]) = preB0; }
        if (tid < 256) { int idx = tid + 512; int r = idx / 12, q = idx - r*12;
          *(uint4*)(&Bt[r*SA + q*8]) = preB1; }
        { int r = tid >> 3, q = tid & 7;
          *(uint4*)(&Hs[r*SH + q*8]) = preH0; }
        if (tid < 320) { int idx = tid + 512; int r = idx >> 3, q = idx & 7;
          *(uint4*)(&Hs[r*SH + q*8]) = preH1; }
        __syncthreads();                          // barA (covers Asq on iter 0)
        int cn = c0 + 64;
        if (cn < NN) {
            const uint4* srcB = (const uint4*)(adp_bf + ((size_t)t*NN + cn)*96);
            preB0 = srcB[tid];
            if (tid < 256) preB1 = srcB[tid + 512];
            { int r = tid >> 3, q = tid & 7;
              preH0 = *(const uint4*)(hbase + (size_t)r*448 + cn + q*8); }
            if (tid < 320) { int idx = tid + 512; int r = idx >> 3, q = idx & 7;
              preH1 = *(const uint4*)(hbase + (size_t)r*448 + cn + q*8); }
        }
        float16v sc;
        #pragma unroll
        for (int i = 0; i < 16; ++i) sc[i] = 0.f;
        #pragma unroll
        for (int s = 0; s < 6; ++s) {
            short8v afq = *(const short8v*)(&Asq[slab][(qi*32 + n32)*SA + s*16 + koct*8]);
            short8v bfr = *(const short8v*)(&Bt[(ci*32 + n32)*SA + s*16 + koct*8]);
            sc = __builtin_amdgcn_mfma_f32_32x32x16_bf16(afq, bfr, sc, 0, 0, 0);
        }
        bool colok = (c0 + ci*32 + n32) < NN;
        #pragma unroll
        for (int reg = 0; reg < 16; ++reg) {
            int crow = (reg & 3) + 8*(reg >> 2) + 4*koct;
            float e = colok ? __expf(fmaxf(sc[reg], 0.f)) : 0.f;
            rs2[reg] += e;
            P[slab][(qi*32 + crow)*SPP + ci*32 + n32] = f2b(e);
        }
        __syncthreads();                          // barB: P complete (cross-wave)
        short8v pA[4];
        #pragma unroll
        for (int s = 0; s < 4; ++s)
            pA[s] = *(const short8v*)(&P[slab][(qi*32 + n32)*SPP + s*16 + koct*8]);
        #pragma unroll
        for (int s = 0; s < 4; ++s) {
            short8v hb0 = *(const short8v*)(&Hs[(ci*32 + n32)*SH + s*16 + koct*8]);
            on0 = __builtin_amdgcn_mfma_f32_32x32x16_bf16(pA[s], hb0, on0, 0, 0, 0);
        }
        #pragma unroll
        for (int s = 0; s < 4; ++s) {
            short8v hb1 = *(const short8v*)(&Hs[((ci+2)*32 + n32)*SH + s*16 + koct*8]);
            on1 = __builtin_amdgcn_mfma_f32_32x32x16_bf16(pA[s], hb1, on1, 0, 0, 0);
        }
        __syncthreads();                          // barC: reads done before restage
    }

    #pragma unroll
    for (int reg = 0; reg < 16; ++reg) {
        float v = rs2[reg];
        v += __shfl_xor(v, 1, 64);
        v += __shfl_xor(v, 2, 64);
        v += __shfl_xor(v, 4, 64);
        v += __shfl_xor(v, 8, 64);
        v += __shfl_xor(v, 16, 64);
        if (n32 == 0) {
            int crow = (reg & 3) + 8*(reg >> 2) + 4*koct;
            rsb[slab][ci][qi*32 + crow] = v;
        }
    }
    __syncthreads();

    #pragma unroll
    for (int reg = 0; reg < 16; ++reg) {
        int crow = (reg & 3) + 8*(reg >> 2) + 4*koct;
        int qrow = qi*32 + crow;
        int gq = r0 + qrow;
        if (gq < NN) {
            float inv = 1.f / (rsb[slab][0][qrow] + rsb[slab][1][qrow]);
            int d0 = ci*32 + n32;
            z1[((size_t)t*NN + gq)*104 + d0] = f2b(on0[reg] * inv);
            int d1 = (ci + 2)*32 + n32;
            if (d1 < 104)
                z1[((size_t)t*NN + gq)*104 + d1] = f2b(on1[reg] * inv);
        }
    }
}

// ---------------- MFMA KV summaries (spatial + temporal) ----------------
__global__ void __launch_bounds__(256) kvs_mf(
    const bf16* __restrict__ qkv, bf16* __restrict__ kvsb_s, bf16* __restrict__ kvsb_t)
{
    constexpr int CK = 32;          // l-chunk
    constexpr int TS = 40;          // padded row stride
    __shared__ bf16 raw[CK][216];   // 208 used (k|v span, qkv cols 104..311)
    __shared__ bf16 kTn[4][32][TS]; // per-head kn^T tile (rows 26..31 unused)
    __shared__ bf16 vT [4][32][TS]; // per-head v^T tile + ones row 26
    __shared__ float invs[CK][4];

    int bb = blockIdx.x;
    bf16* out; int L; long long strideL, base;
    if (bb < TT) { out = kvsb_s + (size_t)bb*NTILE; L = NN; base = (long long)bb*NN*312 + 104; strideL = 312; }
    else { int n = bb - TT; out = kvsb_t + (size_t)n*NTILE; L = TT; base = (long long)n*312 + 104; strideL = (long long)NN*312; }

    int tid = threadIdx.x;
    int lane = tid & 63, w = tid >> 6;       // wave = head
    int n32 = lane & 31, koct = lane >> 5;
    uint4 z4 = {0u,0u,0u,0u};

    float16v acc;
    #pragma unroll
    for (int i = 0; i < 16; ++i) acc[i] = 0.f;

    uint4 pre[4];
    #pragma unroll
    for (int j = 0; j < 4; ++j) {
        int idx = tid + j*256;
        uint4 v = z4;
        if (idx < CK*26) {
            int r = idx / 26, q = idx - r*26;
            if (r < L) v = *(const uint4*)(qkv + base + (long long)r*strideL + q*8);
        }
        pre[j] = v;
    }

    for (int l0 = 0; l0 < L; l0 += CK) {
        int lw = min(CK, L - l0);
        __syncthreads();
        #pragma unroll
        for (int j = 0; j < 4; ++j) {
            int idx = tid + j*256;
            if (idx < CK*26) {
                int r = idx / 26, q = idx - r*26;
                *(uint4*)(&raw[r][q*8]) = pre[j];
            }
        }
        __syncthreads();
        {
            int ln0 = l0 + CK;
            #pragma unroll
            for (int j = 0; j < 4; ++j) {
                int idx = tid + j*256;
                uint4 v = z4;
                if (idx < CK*26 && ln0 < L) {
                    int r = idx / 26, q = idx - r*26;
                    if (r < L - ln0) v = *(const uint4*)(qkv + base + (long long)(ln0 + r)*strideL + q*8);
                }
                pre[j] = v;
            }
        }
        if (tid < CK*4) {
            int l = tid >> 2, h = tid & 3;
            float ss = 0.f;
            #pragma unroll
            for (int m = 0; m < HD; ++m) { float v = b2f(raw[l][h*HD + m]); ss += v*v; }
            invs[l][h] = (l < lw) ? 1.f/fmaxf(sqrtf(ss), 1e-12f) : 0.f;
        }
        __syncthreads();
        for (int idx = tid; idx < 4*CK*HD; idx += 256) {
            int h = idx / (CK*HD); int rem = idx - h*CK*HD;
            int l = rem / HD; int m = rem - l*HD;
            float iv = invs[l][h];
            kTn[h][m][l] = f2b(b2f(raw[l][h*HD + m]) * iv);
            vT[h][m][l]  = raw[l][104 + h*HD + m];
        }
        if (tid < 4*CK) {
            int h = tid >> 5, l = tid & 31;
            vT[h][26][l] = f2b((l < lw) ? 1.f : 0.f);
        }
        __syncthreads();
        #pragma unroll
        for (int s = 0; s < 2; ++s) {
            short8v a = *(const short8v*)(&kTn[w][n32][s*16 + koct*8]);
            short8v b = *(const short8v*)(&vT [w][n32][s*16 + koct*8]);
            acc = __builtin_amdgcn_mfma_f32_32x32x16_bf16(a, b, acc, 0, 0, 0);
        }
    }

    int lo = w*HD;
    #pragma unroll
    for (int reg = 0; reg < 16; ++reg) {
        int m = (reg & 3) + 8*(reg >> 2) + 4*koct;
        if (m < HD) {
            if (n32 < HD)       out[(size_t)(lo + n32)*32 + m] = f2b(acc[reg]);
            else if (n32 == HD) out[(size_t)(104 + w)*32 + m] = f2b(acc[reg]);
        }
    }
}

// ---------------- MFMA linear-attention apply ----------------
__global__ void __launch_bounds__(256) attn_mm(
    bf16* __restrict__ qkv, const bf16* __restrict__ kvsb,
    int M, long long bStride, long long rowStride, float Lf, int outOff)
{
    constexpr int STR = 136;
    __shared__ bf16 As[64*STR];
    __shared__ bf16 Ws[112*STR];
    __shared__ float nsqL[64*4];
    __shared__ float denL[64*4];
    int mt = blockIdx.x, bb = blockIdx.y;
    int tid = threadIdx.x;
    int lane = tid & 63, w = tid >> 6, n16 = lane & 15, quad = lane >> 4;
    bf16* base = qkv + (size_t)bb * bStride;
    int r0 = mt*64;
    uint4 z4 = {0u,0u,0u,0u};

    for (int idx = tid; idx < 64*16; idx += 256) {
        int r = idx >> 4, q = idx & 15;
        int m = r0 + r;
        uint4 v = z4;
        if (m < M && q < 13) v = *(const uint4*)(base + (size_t)m*rowStride + q*8);
        *(uint4*)(&As[r*STR + q*8]) = v;
    }
    for (int idx = tid; idx < 112*16; idx += 256) {
        int c = idx >> 4, q = idx & 15;
        *(uint4*)(&Ws[c*STR + q*8]) = z4;
    }
    __syncthreads();
    {
        const bf16* kb = kvsb + (size_t)bb * NTILE;
        for (int idx = tid; idx < 108*13; idx += 256) {
            int c = idx / 13, qu = idx - c*13;
            int lo = (c < 104) ? (c/26)*26 : (c-104)*26;
            *(uint*)(&Ws[c*STR + lo + qu*2]) = *(const uint*)(kb + (size_t)c*32 + qu*2);
        }
    }
    __syncthreads();

    short8v af[4];
    #pragma unroll
    for (int s = 0; s < 4; ++s)
        af[s] = *(const short8v*)(&As[(16*w + n16)*STR + s*32 + quad*8]);
    float4v acc[7];
    #pragma unroll
    for (int ct = 0; ct < 7; ++ct) { float4v z = {0.f,0.f,0.f,0.f}; acc[ct] = z; }
    #pragma unroll
    for (int ct = 0; ct < 7; ++ct) {
        #pragma unroll
        for (int s = 0; s < 4; ++s) {
            short8v bfr = *(const short8v*)(&Ws[(ct*16 + n16)*STR + s*32 + quad*8]);
            acc[ct] = __builtin_amdgcn_mfma_f32_16x16x32_bf16(af[s], bfr, acc[ct], 0, 0, 0);
        }
    }
    {
        int row = tid >> 2, hh = tid & 3;
        const bf16* qr = &As[row*STR + hh*26];
        float ss = 0.f;
        #pragma unroll
        for (int m = 0; m < HD; ++m) { float v = b2f(qr[m]); ss += v*v; }
        nsqL[row*4 + hh] = ss;
    }
    if (n16 >= 8 && n16 < 12) {
        #pragma unroll
        for (int reg = 0; reg < 4; ++reg)
            denL[(16*w + quad*4 + reg)*4 + (n16 - 8)] = acc[6][reg];
    }
    __syncthreads();
    #pragma unroll
    for (int ct = 0; ct < 7; ++ct) {
        int c = ct*16 + n16;
        if (c < 104) {
            int hh = c / 26;
            #pragma unroll
            for (int reg = 0; reg < 4; ++reg) {
                int lr = 16*w + quad*4 + reg;
                int m = r0 + lr;
                if (m < M) {
                    float iq = 1.f / fmaxf(sqrtf(nsqL[lr*4 + hh]), 1e-12f);
                    float den = iq * denL[lr*4 + hh] + Lf;
                    bf16* rp = base + (size_t)m*rowStride;
                    float num = iq * acc[ct][reg] + Lf * b2f(rp[208 + c]);
                    rp[outOff + c] = f2b(num / den);
                }
            }
        }
    }
}

__global__ void __launch_bounds__(256) y_init_kernel(float* __restrict__ y, const float* __restrict__ ep_b) {
    int i = blockIdx.x*256 + threadIdx.x;
    if (i < NN*104) y[i] = ep_b[i % 104];
}

// ---------------- fused tail v2: 2 rows/block, ILP on the dot chains ----------------
// R6 post-mortem: tail at 101us, VALUBusy 2.7% -- pure L2-latency chains.
// 2 rows share each weight load (2 independent FMA chains), unroll 8 keeps
// ~8 loads in flight; out phase has up to 4 chains per thread.
__global__ void __launch_bounds__(256) tail_kernel(
    const float* __restrict__ y,
    const float* __restrict__ ew1, const float* __restrict__ eb1,
    const float* __restrict__ ew2, const float* __restrict__ eb2,
    const float* __restrict__ out_w, const float* __restrict__ out_b,
    float* __restrict__ out)
{
    int n0 = blockIdx.x * 2;               // 200 blocks x 2 rows
    int tid = threadIdx.x;
    __shared__ float yr[2][104], hid[2][208];
    if (tid < 104) {
        yr[0][tid] = y[(size_t)n0*104 + tid];
        yr[1][tid] = y[(size_t)(n0+1)*104 + tid];
    }
    __syncthreads();
    for (int i = 0; i < 3; ++i) {
        const float* w1 = ew1 + (size_t)i*104*208;
        const float* b1 = eb1 + (size_t)i*208;
        const float* w2 = ew2 + (size_t)i*208*104;
        const float* b2 = eb2 + (size_t)i*104;
        if (tid < 208) {
            float a0 = b1[tid], a1 = a0;
            #pragma unroll 8
            for (int k = 0; k < 104; ++k) {
                float w = w1[(size_t)k*208 + tid];
                a0 += yr[0][k]*w; a1 += yr[1][k]*w;
            }
            hid[0][tid] = fmaxf(a0, 0.f);
            hid[1][tid] = fmaxf(a1, 0.f);
        }
        __syncthreads();
        float y0 = 0.f, y1 = 0.f;
        if (tid < 104) {
            float a0 = b2[tid], a1 = a0;
            #pragma unroll 8
            for (int k = 0; k < 208; ++k) {
                float w = w2[(size_t)k*104 + tid];
                a0 += hid[0][k]*w; a1 += hid[1][k]*w;
            }
            y0 = yr[0][tid] + a0; y1 = yr[1][tid] + a1;
        }
        __syncthreads();
        if (tid < 104) { yr[0][tid] = y0; yr[1][tid] = y1; }
        __syncthreads();
    }
    for (int t = tid; t < TT; t += 256) {
        float a0 = out_b[t], a1 = a0;
        #pragma unroll 8
        for (int d = 0; d < 104; ++d) {
            float w = out_w[(size_t)d*TT + t];
            a0 += yr[0][d]*w; a1 += yr[1][d]*w;
        }
        out[(size_t)n0*TT + t] = a0;
        out[(size_t)(n0+1)*TT + t] = a1;
    }
}

// ---------------- launch ----------------
extern "C" void kernel_launch(void* const* d_in, const int* in_sizes, int n_in,
                              void* d_out, int out_size, void* d_ws, size_t ws_size,
                              hipStream_t stream) {
    if (ws_size < WS_NEEDED) return;

    const float* x      = (const float*)d_in[0];
    const float* W_in   = (const float*)d_in[1];
    const float* b_in   = (const float*)d_in[2];
    const float* adp    = (const float*)d_in[3];
    const float* W_tp   = (const float*)d_in[4];
    const float* b_tp   = (const float*)d_in[5];
    const float* qkv_w  = (const float*)d_in[6];
    const float* op_w   = (const float*)d_in[7];
    const float* op_b   = (const float*)d_in[8];
    const float* pw_w   = (const float*)d_in[9];
    const float* pw_b   = (const float*)d_in[10];
    const float* fc_w1  = (const float*)d_in[11];
    const float* fc_b1  = (const float*)d_in[12];
    const float* fc_w2  = (const float*)d_in[13];
    const float* fc_b2  = (const float*)d_in[14];
    const float* ln1_g  = (const float*)d_in[15];
    const float* ln1_b  = (const float*)d_in[16];
    const float* ln2_g  = (const float*)d_in[17];
    const float* ln2_b  = (const float*)d_in[18];
    const float* ep_w   = (const float*)d_in[19];
    const float* ep_b   = (const float*)d_in[20];
    const float* enc_w1 = (const float*)d_in[21];
    const float* enc_b1 = (const float*)d_in[22];
    const float* enc_w2 = (const float*)d_in[23];
    const float* enc_b2 = (const float*)d_in[24];
    const float* out_w  = (const float*)d_in[25];
    const float* out_b  = (const float*)d_in[26];

    bf16* B0 = (bf16*)d_ws;
    bf16* B1 = B0 + NB0;
    bf16* B2 = B1 + NB1;
    bf16* B3 = B2 + NB2;
    bf16* kvsb_s = B3 + NB3;
    bf16* kvsb_t = kvsb_s + NKVSB_S;
    float* ybuf  = (float*)(kvsb_t + NKVSB_T);
    bf16* wtp   = (bf16*)(ybuf + NY);
    bf16* wqkv0 = wtp + NW_TP;
    bf16* wqkv1 = wqkv0 + NW_QKV;
    bf16* wop0  = wqkv1 + NW_QKV;
    bf16* wop1  = wop0 + NW_OP;
    bf16* wpw0  = wop1 + NW_OP;
    bf16* wpw1  = wpw0 + NW_PW;
    bf16* wfc1  = wpw1 + NW_PW;
    bf16* wfc2  = wfc1 + NW_FC1;
    bf16* wept  = wfc2 + NW_FC2;
    bf16* adp_bf = B2;
    bf16* hTbuf  = B2 + NADP;

    // 0. weight prep
    prep_w<<<CEILDIV(104*128,256), 256, 0, stream>>>(W_tp, wtp, 104, 104, 128);
    prep_w<<<CEILDIV(312*128,256), 256, 0, stream>>>(qkv_w, wqkv0, 104, 312, 128);
    prep_w<<<CEILDIV(312*128,256), 256, 0, stream>>>(qkv_w + 104*312, wqkv1, 104, 312, 128);
    prep_w<<<CEILDIV(104*224,256), 256, 0, stream>>>(op_w, wop0, 208, 104, 224);
    prep_w<<<CEILDIV(104*224,256), 256, 0, stream>>>(op_w + 208*104, wop1, 208, 104, 224);
    prep_w<<<CEILDIV(104*128,256), 256, 0, stream>>>(pw_w, wpw0, 104, 104, 128);
    prep_w<<<CEILDIV(104*128,256), 256, 0, stream>>>(pw_w + 104*104, wpw1, 104, 104, 128);
    prep_w<<<CEILDIV(208*128,256), 256, 0, stream>>>(fc_w1, wfc1, 104, 208, 128);
    prep_w<<<CEILDIV(104*224,256), 256, 0, stream>>>(fc_w2, wfc2, 208, 104, 224);
    prep_wT<<<CEILDIV(37960,64), 256, 0, stream>>>(ep_w, wept);

    const int GX = CEILDIV(TN, 64);     // 2282

    // 1. hcat -> B2
    hcat_kernel<<<CEILDIV(TN,16), 256, 0, stream>>>(x, W_in, b_in, adp, B2);
    // 2. h = hcat @ W_tp + b_tp -> B0
    gemm_mf<128><<<GX*2, 256, 0, stream>>>(B2, 104, 104, wtp, b_tp, B0, TN, 104, 0);
    // 2b. z1 pre-staging into B2
    prep_adp<<<CEILDIV((int)NADP,256), 256, 0, stream>>>(adp, adp_bf);
    ht_kernel<<<dim3(7, TT), 256, 0, stream>>>(B0, hTbuf);
    // 3. z1 -> B1
    z1_mf<<<Z1_BLOCKS, 512, 0, stream>>>(adp_bf, hTbuf, B1);
    // 4. attention 0 on h
    gemm_mf<128><<<GX*5, 256, 0, stream>>>(B0, 104, 104, wqkv0, nullptr, B2, TN, 312, 0);
    kvs_mf<<<TT+NN, 256, 0, stream>>>(B2, kvsb_s, kvsb_t);
    attn_mm<<<dim3(6, NN), 256, 0, stream>>>(B2, kvsb_t, TT, 312, (long long)NN*312, (float)TT, 104);
    attn_mm<<<dim3(7, TT), 256, 0, stream>>>(B2, kvsb_s, NN, (long long)NN*312, 312, (float)NN, 0);
    gemm_mf<224><<<GX*2, 256, 0, stream>>>(B2, 312, 208, wop0, op_b, B3, TN, 104, 0);   // att0 -> B3
    // 5. attention 1 on z1
    gemm_mf<128><<<GX*5, 256, 0, stream>>>(B1, 104, 104, wqkv1, nullptr, B2, TN, 312, 0);
    kvs_mf<<<TT+NN, 256, 0, stream>>>(B2, kvsb_s, kvsb_t);
    attn_mm<<<dim3(6, NN), 256, 0, stream>>>(B2, kvsb_t, TT, 312, (long long)NN*312, (float)TT, 104);
    attn_mm<<<dim3(7, TT), 256, 0, stream>>>(B2, kvsb_s, NN, (long long)NN*312, 312, (float)NN, 0);
    gemm_mf<224><<<GX*2, 256, 0, stream>>>(B2, 312, 208, wop1, op_b + 104, B1, TN, 104, 0); // att1 -> B1
    // 6+7. fused gates + LN1 (in-place B0 -> h1)
    gate_ln1<<<GX, 256, 0, stream>>>(B0, B3, B1, wpw0, wpw1, pw_b, ln1_g, ln1_b);
    // 8. MLP: fc1 -> hidden (B2), fused fc2+LN2 -> h2 (B3)
    gemm_mf<128><<<GX*4, 256, 0, stream>>>(B0, 104, 104, wfc1, fc_b1, B2, TN, 208, 1);
    fc2_ln2<<<GX, 256, 0, stream>>>(B2, wfc2, fc_b2, B0, ln2_g, ln2_b, B3);
    // 9. encoder_proj
    y_init_kernel<<<CEILDIV(NN*104,256), 256, 0, stream>>>(ybuf, ep_b);
    ep_mf<<<dim3(CEILDIV(NN,64), 2, CEILDIV(TT,8)), 256, 0, stream>>>(B3, wept, ybuf);
    // 10+11. fused residual MLP blocks + output projection (2 rows/block)
    tail_kernel<<<NN/2, 256, 0, stream>>>(ybuf, enc_w1, enc_b1, enc_w2, enc_b2,
                                          out_w, out_b, (float*)d_out);
}

// Round 8
// 1214.772 us; speedup vs baseline: 1.1217x; 1.0319x over previous
//
#include <hip/hip_runtime.h>
#include <hip/hip_bf16.h>
#include <cstddef>

// ---------------- problem constants ----------------
#define TT   365
#define NN   400
#define TN   (TT*NN)            // 146000
#define HD   26                 // head dim
#define NH   4                  // heads

#define CEILDIV(a,b) (((a)+(b)-1)/(b))

typedef __hip_bfloat16 bf16;
typedef short short8v __attribute__((ext_vector_type(8)));
typedef float float4v __attribute__((ext_vector_type(4)));
typedef float float16v __attribute__((ext_vector_type(16)));
__device__ __forceinline__ float b2f(bf16 v){ return __bfloat162float(v); }
__device__ __forceinline__ bf16  f2b(float v){ return __float2bfloat16(v); }

// ---------------- workspace layout ----------------
static constexpr size_t NB0 = (size_t)TN*104;   // h / h1
static constexpr size_t NB1 = (size_t)TN*104;   // z1 -> att1
static constexpr size_t NB2 = (size_t)TN*312;   // hcat -> [adp_bf|hT] -> qkv+concat -> hidden
static constexpr size_t NB3 = (size_t)TN*104;   // att0 -> h2
static constexpr size_t NBF = NB0+NB1+NB2+NB3;
// compact band KV tiles: per b, 108 rows x 32 (band cols 0..25), bf16
static constexpr size_t NTILE   = (size_t)108*32;
static constexpr size_t NKVSB_S = (size_t)TT*NTILE;
static constexpr size_t NKVSB_T = (size_t)NN*NTILE;
static constexpr size_t NY      = (size_t)NN*104;
// transposed bf16 weights (Wt[n][kp], zero-padded k)
static constexpr size_t NW_TP   = 104*128;
static constexpr size_t NW_QKV  = 312*128;   // x2
static constexpr size_t NW_OP   = 104*224;   // x2
static constexpr size_t NW_PW   = 104*128;   // x2
static constexpr size_t NW_FC1  = 208*128;
static constexpr size_t NW_FC2  = 104*224;
static constexpr size_t NW_EPT  = (size_t)104*37960;   // ep_w transposed, no pad
static constexpr size_t NWT     = NW_TP + 2*NW_QKV + 2*NW_OP + 2*NW_PW + NW_FC1 + NW_FC2 + NW_EPT;
static constexpr size_t WS_NEEDED = NBF*2 + (NKVSB_S+NKVSB_T)*2 + NY*4 + NWT*2;
// z1 scratch lives inside B2 (dead between step 2 and step 4):
static constexpr size_t NADP_ROWS = (size_t)TN + 64;
static constexpr size_t NADP = NADP_ROWS*96;
static constexpr size_t NHT  = ((size_t)TT*104 + 8)*448;
static_assert(NADP + NHT <= NB2, "z1 scratch must fit in B2");

// ---------------- weight prep: Wt[n*KP+k] = bf16(W[k*Nc+n]), zero pad k>=K ----------------
__global__ void __launch_bounds__(256) prep_w(
    const float* __restrict__ W, bf16* __restrict__ Wt, int K, int Nc, int KP)
{
    int idx = blockIdx.x*256 + threadIdx.x;
    if (idx >= Nc*KP) return;
    int n = idx / KP, k = idx - n*KP;
    Wt[idx] = (k < K) ? f2b(W[(size_t)k*Nc + n]) : f2b(0.f);
}

// coalesced LDS transpose for ep weights: Wt[n][k] = bf16(W[k][n]); W is 37960x104 fp32
__global__ void __launch_bounds__(256) prep_wT(
    const float* __restrict__ W, bf16* __restrict__ Wt)
{
    __shared__ float T[64][105];
    int k0 = blockIdx.x * 64;
    int tid = threadIdx.x;
    for (int idx = tid; idx < 64*104; idx += 256) {
        int r = idx / 104, c = idx - r*104;
        int k = k0 + r;
        T[r][c] = (k < 37960) ? W[(size_t)k*104 + c] : 0.f;
    }
    __syncthreads();
    for (int idx = tid; idx < 104*32; idx += 256) {
        int n = idx >> 5, kp = idx & 31;
        int k = kp*2;
        if (k0 + k + 1 < 37960 || k0 + k < 37960) {
            if (k0 + k < 37960) {
                bf16 lo = f2b(T[k][n]);
                bf16 hi = f2b(T[k+1][n]);   // k+1 row is zero-padded if OOB of tile data
                uint v = ((uint)(*(ushort*)&hi) << 16) | (*(ushort*)&lo);
                if (k0 + k + 1 < 37960) *(uint*)(Wt + (size_t)n*37960 + k0 + k) = v;
                else Wt[(size_t)n*37960 + k0 + k] = lo;
            }
        }
    }
}

// adp_bf[row][e] = bf16(adp[row][e]) for e<80 else 0; rows >= TN are zero.
__global__ void __launch_bounds__(256) prep_adp(
    const float* __restrict__ adp, bf16* __restrict__ out)
{
    size_t i = (size_t)blockIdx.x*256 + threadIdx.x;
    if (i >= NADP) return;
    size_t row = i / 96; int e = (int)(i - row*96);
    float v = (row < TN && e < 80) ? adp[row*80 + e] : 0.f;
    out[i] = f2b(v);
}

// hT[t][d][n] = h[t][n][d], n padded to 448 with zeros
__global__ void __launch_bounds__(256) ht_kernel(
    const bf16* __restrict__ h, bf16* __restrict__ hT)
{
    __shared__ bf16 As[64*106];
    int t = blockIdx.y, n0 = blockIdx.x*64;
    int tid = threadIdx.x;
    for (int idx = tid; idx < 64*52; idx += 256) {
        int r = idx / 52, k = idx - r*52;
        int n = n0 + r;
        uint v = 0;
        if (n < NN) v = *(const uint*)(h + ((size_t)t*NN + n)*104 + k*2);
        *(uint*)(&As[r*106 + k*2]) = v;
    }
    __syncthreads();
    for (int idx = tid; idx < 104*32; idx += 256) {
        int d = idx >> 5, np = idx & 31;
        int n = np*2;
        ushort lo = *(ushort*)&As[n*106 + d];
        ushort hi = *(ushort*)&As[(n+1)*106 + d];
        uint v = ((uint)hi << 16) | lo;
        *(uint*)(hT + ((size_t)t*104 + d)*448 + n0 + n) = v;
    }
}

// ---------------- hcat (16 rows/block, LDS-staged uint4 row writes) ----------------
__global__ void __launch_bounds__(256) hcat_kernel(
    const float* __restrict__ x, const float* __restrict__ W_in,
    const float* __restrict__ b_in, const float* __restrict__ adp,
    bf16* __restrict__ hcat)
{
    __shared__ bf16 T[16][112];          // 104 used; 224B row stride (16B-aligned)
    int r0 = blockIdx.x * 16;
    int tid = threadIdx.x;
    // proj cols 0..23
    for (int idx = tid; idx < 16*24; idx += 256) {
        int r = idx / 24, c = idx - r*24;
        int row = r0 + r;
        int t = row / NN, n = row - t*NN;
        size_t xb = ((size_t)n*TT + t)*3;
        float s = b_in[c] + x[xb]*W_in[c] + x[xb+1]*W_in[24+c] + x[xb+2]*W_in[48+c];
        T[r][c] = f2b(s);
    }
    // adp cols 24..103 (coalesced f32 reads)
    for (int idx = tid; idx < 16*80; idx += 256) {
        int r = idx / 80, e = idx - r*80;
        T[r][24+e] = f2b(adp[(size_t)(r0+r)*80 + e]);
    }
    __syncthreads();
    for (int idx = tid; idx < 16*13; idx += 256) {
        int r = idx / 13, q = idx - r*13;
        *(uint4*)(hcat + ((size_t)(r0+r))*104 + q*8) = *(const uint4*)(&T[r][q*8]);
    }
}

// ---------------- MFMA GEMM 64-tile ----------------
// 1-D grid with bijective XCD grouping (m204): column-tiles of one row-slab
// land adjacent on the SAME XCD so the A-slab is fetched from HBM once.
template<int KP>
__global__ void __launch_bounds__(256) gemm_mf(
    const bf16* __restrict__ A, int lda, int K,
    const bf16* __restrict__ Wt, const float* __restrict__ bias,
    bf16* __restrict__ C, int M, int Nc, int relu)
{
    constexpr int STR = KP + 8;
    constexpr int KPQ = KP/8;
    __shared__ bf16 As[64*STR];
    __shared__ bf16 Ws[64*STR];
    int nCol = (Nc + 63) >> 6;
    int nwg = gridDim.x;
    int bid = blockIdx.x;
    int xcd = bid & 7, kk = bid >> 3;
    int q8 = nwg >> 3, r8 = nwg & 7;
    int widx = (xcd < r8 ? xcd*(q8+1) : r8*(q8+1) + (xcd - r8)*q8) + kk;
    int mblk = widx / nCol;
    int m0 = mblk * 64;
    int c0 = (widx - mblk*nCol) * 64;
    int tid = threadIdx.x;
    const int KQ = K/8;
    uint4 z4 = {0u,0u,0u,0u};
    for (int idx = tid; idx < 64*KPQ; idx += 256) {
        int r = idx / KPQ, q = idx - r*KPQ;
        int m = m0 + r;
        uint4 v = z4;
        if (m < M && q < KQ) v = *(const uint4*)(A + (size_t)m*lda + q*8);
        *(uint4*)(&As[r*STR + q*8]) = v;
    }
    for (int idx = tid; idx < 64*KPQ; idx += 256) {
        int r = idx / KPQ, q = idx - r*KPQ;
        int n = c0 + r;
        uint4 v = z4;
        if (n < Nc) v = *(const uint4*)(Wt + (size_t)n*KP + q*8);
        *(uint4*)(&Ws[r*STR + q*8]) = v;
    }
    __syncthreads();

    int lane = tid & 63, w = tid >> 6;
    int n16 = lane & 15, quad = lane >> 4;
    constexpr int KS = KP/32;
    short8v af[KS];
    #pragma unroll
    for (int s = 0; s < KS; ++s)
        af[s] = *(const short8v*)(&As[(16*w + n16)*STR + s*32 + quad*8]);
    float4v acc[4];
    #pragma unroll
    for (int ct = 0; ct < 4; ++ct) { float4v z = {0.f,0.f,0.f,0.f}; acc[ct] = z; }
    #pragma unroll
    for (int ct = 0; ct < 4; ++ct) {
        #pragma unroll
        for (int s = 0; s < KS; ++s) {
            short8v bfr = *(const short8v*)(&Ws[(ct*16 + n16)*STR + s*32 + quad*8]);
            acc[ct] = __builtin_amdgcn_mfma_f32_16x16x32_bf16(af[s], bfr, acc[ct], 0, 0, 0);
        }
    }
    #pragma unroll
    for (int ct = 0; ct < 4; ++ct) {
        int c = c0 + ct*16 + n16;
        if (c < Nc) {
            float b = bias ? bias[c] : 0.f;
            #pragma unroll
            for (int reg = 0; reg < 4; ++reg) {
                int m = m0 + 16*w + quad*4 + reg;
                if (m < M) {
                    float v = acc[ct][reg] + b;
                    if (relu) v = fmaxf(v, 0.f);
                    C[(size_t)m*Nc + c] = f2b(v);
                }
            }
        }
    }
}

// ---------------- fused gates + LN1 ----------------
// h1 = LN(2*(h + att0*(h@pw0+b0) + 0.01*att1*(att0@pw1+b1))) in-place into h.
__global__ void __launch_bounds__(256) gate_ln1(
    bf16* __restrict__ h, const bf16* __restrict__ att0, const bf16* __restrict__ att1,
    const bf16* __restrict__ w0t, const bf16* __restrict__ w1t, const float* __restrict__ pwb,
    const float* __restrict__ gamma, const float* __restrict__ beta)
{
    constexpr int STR = 136;
    __shared__ bf16 A0s[64*STR];
    __shared__ bf16 A1s[64*STR];
    __shared__ bf16 Ws[112*STR];
    __shared__ float prm[416];     // pwb(208) | gamma(104) | beta(104)
    int m0 = blockIdx.x * 64;
    int tid = threadIdx.x;
    int lane = tid & 63, w = tid >> 6, n16 = lane & 15, quad = lane >> 4;
    uint4 z4 = {0u,0u,0u,0u};

    for (int idx = tid; idx < 64*16; idx += 256) {
        int r = idx >> 4, q = idx & 15;
        int m = m0 + r;
        uint4 v0 = z4, v1 = z4;
        if (m < TN && q < 13) {
            v0 = *(const uint4*)(h    + (size_t)m*104 + q*8);
            v1 = *(const uint4*)(att0 + (size_t)m*104 + q*8);
        }
        *(uint4*)(&A0s[r*STR + q*8]) = v0;
        *(uint4*)(&A1s[r*STR + q*8]) = v1;
    }
    for (int idx = tid; idx < 112*16; idx += 256) {
        int c = idx >> 4, q = idx & 15;
        uint4 v = z4;
        if (c < 104) v = *(const uint4*)(w0t + (size_t)c*128 + q*8);
        *(uint4*)(&Ws[c*STR + q*8]) = v;
    }
    for (int i = tid; i < 416; i += 256)
        prm[i] = (i < 208) ? pwb[i] : (i < 312 ? gamma[i-208] : beta[i-312]);
    __syncthreads();

    short8v a0f[4], a1f[4];
    #pragma unroll
    for (int s = 0; s < 4; ++s) {
        a0f[s] = *(const short8v*)(&A0s[(16*w + n16)*STR + s*32 + quad*8]);
        a1f[s] = *(const short8v*)(&A1s[(16*w + n16)*STR + s*32 + quad*8]);
    }
    float4v acc0[7], acc1[7];
    #pragma unroll
    for (int ct = 0; ct < 7; ++ct) { float4v z = {0.f,0.f,0.f,0.f}; acc0[ct] = z; acc1[ct] = z; }
    #pragma unroll
    for (int ct = 0; ct < 7; ++ct)
        #pragma unroll
        for (int s = 0; s < 4; ++s) {
            short8v bfr = *(const short8v*)(&Ws[(ct*16 + n16)*STR + s*32 + quad*8]);
            acc0[ct] = __builtin_amdgcn_mfma_f32_16x16x32_bf16(a0f[s], bfr, acc0[ct], 0, 0, 0);
        }
    __syncthreads();
    for (int idx = tid; idx < 112*16; idx += 256) {
        int c = idx >> 4, q = idx & 15;
        uint4 v = z4;
        if (c < 104) v = *(const uint4*)(w1t + (size_t)c*128 + q*8);
        *(uint4*)(&Ws[c*STR + q*8]) = v;
    }
    __syncthreads();
    #pragma unroll
    for (int ct = 0; ct < 7; ++ct)
        #pragma unroll
        for (int s = 0; s < 4; ++s) {
            short8v bfr = *(const short8v*)(&Ws[(ct*16 + n16)*STR + s*32 + quad*8]);
            acc1[ct] = __builtin_amdgcn_mfma_f32_16x16x32_bf16(a1f[s], bfr, acc1[ct], 0, 0, 0);
        }

    // epilogue: g -> LN (row distributed across the 16 n16 lanes)
    float sum[4] = {0.f,0.f,0.f,0.f};
    #pragma unroll
    for (int ct = 0; ct < 7; ++ct) {
        int c = ct*16 + n16;
        bool colok = c < 104;
        float b0 = colok ? prm[c] : 0.f;
        float b1 = colok ? prm[104 + c] : 0.f;
        #pragma unroll
        for (int reg = 0; reg < 4; ++reg) {
            int r = 16*w + quad*4 + reg;
            int m = m0 + r;
            float xv = 0.f;
            if (colok && m < TN) {
                float p0 = acc0[ct][reg] + b0;
                float p1 = acc1[ct][reg] + b1;
                float hv = b2f(A0s[r*STR + c]);
                float a0 = b2f(A1s[r*STR + c]);
                float a1 = b2f(att1[(size_t)m*104 + c]);
                xv = 2.f*(hv + a0*p0 + 0.01f*a1*p1);
            }
            acc0[ct][reg] = xv;
            sum[reg] += xv;
        }
    }
    #pragma unroll
    for (int reg = 0; reg < 4; ++reg) {
        float v = sum[reg];
        v += __shfl_xor(v,1,64); v += __shfl_xor(v,2,64);
        v += __shfl_xor(v,4,64); v += __shfl_xor(v,8,64);
        sum[reg] = v * (1.f/104.f);                     // mean
    }
    float var[4] = {0.f,0.f,0.f,0.f};
    #pragma unroll
    for (int ct = 0; ct < 7; ++ct) {
        bool colok = (ct*16 + n16) < 104;
        #pragma unroll
        for (int reg = 0; reg < 4; ++reg) {
            if (colok) {
                float d = acc0[ct][reg] - sum[reg];
                acc0[ct][reg] = d;
                var[reg] += d*d;
            }
        }
    }
    #pragma unroll
    for (int reg = 0; reg < 4; ++reg) {
        float v = var[reg];
        v += __shfl_xor(v,1,64); v += __shfl_xor(v,2,64);
        v += __shfl_xor(v,4,64); v += __shfl_xor(v,8,64);
        var[reg] = rsqrtf(v * (1.f/104.f) + 1e-5f);
    }
    #pragma unroll
    for (int ct = 0; ct < 7; ++ct) {
        int c = ct*16 + n16;
        if (c < 104) {
            float g = prm[208 + c], be = prm[312 + c];
            #pragma unroll
            for (int reg = 0; reg < 4; ++reg) {
                int m = m0 + 16*w + quad*4 + reg;
                if (m < TN)
                    h[(size_t)m*104 + c] = f2b(acc0[ct][reg]*var[reg]*g + be);
            }
        }
    }
}

// ---------------- fused fc2 + LN2: h2 = LN(h1 + hidden@fc_w2 + b) ----------------
__global__ void __launch_bounds__(256) fc2_ln2(
    const bf16* __restrict__ hidden, const bf16* __restrict__ w2t, const float* __restrict__ b2,
    const bf16* __restrict__ h1, const float* __restrict__ gamma, const float* __restrict__ beta,
    bf16* __restrict__ h2)
{
    constexpr int STRA = 232;   // 224 + 8
    constexpr int STRW = 136;   // 128 + 8 (per half)
    __shared__ bf16 As[64*STRA];
    __shared__ bf16 Ws[112*STRW];
    __shared__ float prm[312];  // b2(104) | gamma(104) | beta(104)
    int m0 = blockIdx.x * 64;
    int tid = threadIdx.x;
    int lane = tid & 63, w = tid >> 6, n16 = lane & 15, quad = lane >> 4;
    uint4 z4 = {0u,0u,0u,0u};

    for (int idx = tid; idx < 64*28; idx += 256) {
        int r = idx / 28, q = idx - r*28;
        int m = m0 + r;
        uint4 v = z4;
        if (m < TN && q < 26) v = *(const uint4*)(hidden + (size_t)m*208 + q*8);
        *(uint4*)(&As[r*STRA + q*8]) = v;
    }
    for (int idx = tid; idx < 112*16; idx += 256) {
        int c = idx >> 4, q = idx & 15;
        uint4 v = z4;
        if (c < 104) v = *(const uint4*)(w2t + (size_t)c*224 + q*8);
        *(uint4*)(&Ws[c*STRW + q*8]) = v;
    }
    for (int i = tid; i < 312; i += 256)
        prm[i] = (i < 104) ? b2[i] : (i < 208 ? gamma[i-104] : beta[i-208]);
    __syncthreads();

    short8v af[7];
    #pragma unroll
    for (int s = 0; s < 7; ++s)
        af[s] = *(const short8v*)(&As[(16*w + n16)*STRA + s*32 + quad*8]);
    float4v acc[7];
    #pragma unroll
    for (int ct = 0; ct < 7; ++ct) { float4v z = {0.f,0.f,0.f,0.f}; acc[ct] = z; }
    #pragma unroll
    for (int ct = 0; ct < 7; ++ct)
        #pragma unroll
        for (int s = 0; s < 4; ++s) {
            short8v bfr = *(const short8v*)(&Ws[(ct*16 + n16)*STRW + s*32 + quad*8]);
            acc[ct] = __builtin_amdgcn_mfma_f32_16x16x32_bf16(af[s], bfr, acc[ct], 0, 0, 0);
        }
    __syncthreads();
    for (int idx = tid; idx < 112*16; idx += 256) {   // half 2: k 128..223 (12 data uint4)
        int c = idx >> 4, q = idx & 15;
        uint4 v = z4;
        if (c < 104 && q < 12) v = *(const uint4*)(w2t + (size_t)c*224 + 128 + q*8);
        *(uint4*)(&Ws[c*STRW + q*8]) = v;
    }
    __syncthreads();
    #pragma unroll
    for (int ct = 0; ct < 7; ++ct)
        #pragma unroll
        for (int s = 4; s < 7; ++s) {
            short8v bfr = *(const short8v*)(&Ws[(ct*16 + n16)*STRW + (s-4)*32 + quad*8]);
            acc[ct] = __builtin_amdgcn_mfma_f32_16x16x32_bf16(af[s], bfr, acc[ct], 0, 0, 0);
        }

    // epilogue: x = h1 + m  -> LN
    float sum[4] = {0.f,0.f,0.f,0.f};
    #pragma unroll
    for (int ct = 0; ct < 7; ++ct) {
        int c = ct*16 + n16;
        bool colok = c < 104;
        float bb = colok ? prm[c] : 0.f;
        #pragma unroll
        for (int reg = 0; reg < 4; ++reg) {
            int m = m0 + 16*w + quad*4 + reg;
            float xv = 0.f;
            if (colok && m < TN)
                xv = b2f(h1[(size_t)m*104 + c]) + acc[ct][reg] + bb;
            acc[ct][reg] = xv;
            sum[reg] += xv;
        }
    }
    #pragma unroll
    for (int reg = 0; reg < 4; ++reg) {
        float v = sum[reg];
        v += __shfl_xor(v,1,64); v += __shfl_xor(v,2,64);
        v += __shfl_xor(v,4,64); v += __shfl_xor(v,8,64);
        sum[reg] = v * (1.f/104.f);
    }
    float var[4] = {0.f,0.f,0.f,0.f};
    #pragma unroll
    for (int ct = 0; ct < 7; ++ct) {
        bool colok = (ct*16 + n16) < 104;
        #pragma unroll
        for (int reg = 0; reg < 4; ++reg) {
            if (colok) {
                float d = acc[ct][reg] - sum[reg];
                acc[ct][reg] = d;
                var[reg] += d*d;
            }
        }
    }
    #pragma unroll
    for (int reg = 0; reg < 4; ++reg) {
        float v = var[reg];
        v += __shfl_xor(v,1,64); v += __shfl_xor(v,2,64);
        v += __shfl_xor(v,4,64); v += __shfl_xor(v,8,64);
        var[reg] = rsqrtf(v * (1.f/104.f) + 1e-5f);
    }
    #pragma unroll
    for (int ct = 0; ct < 7; ++ct) {
        int c = ct*16 + n16;
        if (c < 104) {
            float g = prm[104 + c], be = prm[208 + c];
            #pragma unroll
            for (int reg = 0; reg < 4; ++reg) {
                int m = m0 + 16*w + quad*4 + reg;
                if (m < TN)
                    h2[(size_t)m*104 + c] = f2b(acc[ct][reg]*var[reg]*g + be);
            }
        }
    }
}

// ---------------- MFMA encoder_proj ----------------
__global__ void __launch_bounds__(256) ep_mf(
    const bf16* __restrict__ h2, const bf16* __restrict__ wt, float* __restrict__ y)
{
    constexpr int STR = 136;
    __shared__ bf16 As[64*STR];
    __shared__ bf16 Ws[64*STR];
    int m0 = blockIdx.x * 64;
    int c0 = blockIdx.y * 64;
    int t0 = blockIdx.z * 8;
    int t1 = min(TT, t0 + 8);
    int tid = threadIdx.x;
    int lane = tid & 63, w = tid >> 6, n16 = lane & 15, quad = lane >> 4;
    uint4 z4 = {0u,0u,0u,0u};

    float4v acc[4];
    #pragma unroll
    for (int ct = 0; ct < 4; ++ct) { float4v z = {0.f,0.f,0.f,0.f}; acc[ct] = z; }

    for (int t = t0; t < t1; ++t) {
        for (int idx = tid; idx < 64*16; idx += 256) {
            int r = idx >> 4, q = idx & 15;
            int m = m0 + r;
            uint4 va = z4;
            if (m < NN && q < 13) va = *(const uint4*)(h2 + ((size_t)t*NN + m)*104 + q*8);
            *(uint4*)(&As[r*STR + q*8]) = va;
            int c = c0 + r;
            uint4 vw = z4;
            if (c < 104 && q < 13) vw = *(const uint4*)(wt + (size_t)c*37960 + t*104 + q*8);
            *(uint4*)(&Ws[r*STR + q*8]) = vw;
        }
        __syncthreads();
        short8v af[4];
        #pragma unroll
        for (int s = 0; s < 4; ++s)
            af[s] = *(const short8v*)(&As[(16*w + n16)*STR + s*32 + quad*8]);
        #pragma unroll
        for (int ct = 0; ct < 4; ++ct) {
            #pragma unroll
            for (int s = 0; s < 4; ++s) {
                short8v bfr = *(const short8v*)(&Ws[(ct*16 + n16)*STR + s*32 + quad*8]);
                acc[ct] = __builtin_amdgcn_mfma_f32_16x16x32_bf16(af[s], bfr, acc[ct], 0, 0, 0);
            }
        }
        __syncthreads();
    }
    #pragma unroll
    for (int ct = 0; ct < 4; ++ct) {
        int c = c0 + ct*16 + n16;
        if (c < 104) {
            #pragma unroll
            for (int reg = 0; reg < 4; ++reg) {
                int m = m0 + 16*w + quad*4 + reg;
                if (m < NN) atomicAdd(&y[(size_t)m*104 + c], acc[ct][reg]);
            }
        }
    }
}

// ---------------- MFMA z1 (R5 structure, unchanged) ----------------
static constexpr int Z1_TQ = CEILDIV(TT, 8);          // 46
static constexpr int Z1_BLOCKS = 8 * Z1_TQ * 4;       // 1472
__global__ void __launch_bounds__(512, 4) z1_mf(
    const bf16* __restrict__ adp_bf, const bf16* __restrict__ hT, bf16* __restrict__ z1)
{
    constexpr int SA  = 104;   // Asq/Bt row stride (96 data + pad), 16B-aligned
    constexpr int SH  = 72;    // Hs row stride (64 data + pad)
    constexpr int SPP = 72;    // P  row stride (64 data + pad)
    __shared__ bf16 Asq[2][64*SA];   // 26624 B: per-slab q rows (persist)
    __shared__ bf16 Bt[64*SA];       // 13312 B: shared c-rows tile
    __shared__ bf16 Hs[128*SH];      // 18432 B: shared hT tile (rows 104..127 zero)
    __shared__ bf16 P[2][64*SPP];    // 18432 B: per-slab probabilities
    __shared__ float rsb[2][2][64];  //  2048 B

    int bid = blockIdx.x;
    int xcd = bid & 7;               // all blocks of one t share an XCD/L2
    int j = bid >> 3;
    int tq = j >> 2, pair = j & 3;
    int t = tq*8 + xcd;
    if (t >= TT) return;

    int tid = threadIdx.x;
    int lane = tid & 63, w = tid >> 6;            // 8 waves
    int slab = w >> 2, wsl = w & 3;
    int qi = wsl >> 1, ci = wsl & 1;
    int n32 = lane & 31, koct = lane >> 5;
    int r0 = (pair*2 + slab)*64;                  // up to 448; masked at write

    {
        const uint4* src = (const uint4*)(adp_bf + ((size_t)t*NN + pair*128)*96);
        #pragma unroll
        for (int i = 0; i < 3; ++i) {
            int idx = tid + i*512;                // < 1536
            int s2 = idx / 768, rem = idx - s2*768;
            int r = rem / 12, q = rem - r*12;
            *(uint4*)(&Asq[s2][r*SA + q*8]) = src[idx];
        }
    }
    {
        uint4 z4v = {0u,0u,0u,0u};
        for (int idx = tid; idx < 216; idx += 512) {
            int rr = idx / 9;
            int r = 104 + rr, q = idx - rr*9;
            *(uint4*)(&Hs[r*SH + q*8]) = z4v;
        }
    }

    float16v on0, on1;
    #pragma unroll
    for (int i = 0; i < 16; ++i) { on0[i] = 0.f; on1[i] = 0.f; }
    float rs2[16];
    #pragma unroll
    for (int i = 0; i < 16; ++i) rs2[i] = 0.f;

    const bf16* hbase = hT + (size_t)t*104*448;

    uint4 preB0, preB1, preH0, preH1;
    {
        const uint4* srcB = (const uint4*)(adp_bf + (size_t)t*NN*96);
        preB0 = srcB[tid];
        if (tid < 256) preB1 = srcB[tid + 512];
        { int r = tid >> 3, q = tid & 7;
          preH0 = *(const uint4*)(hbase + (size_t)r*448 + q*8); }
        if (tid < 320) { int idx = tid + 512; int r = idx >> 3, q = idx & 7;
          preH1 = *(const uint4*)(hbase + (size_t)r*448 + q*8); }
    }

    for (int c0 = 0; c0 < NN; c0 += 64) {
        { int r = tid / 12, q = tid - (tid/12)*12;
          *(uint4*)(&Bt[r*SA + q*8]) = preB0; }
        if (tid < 256) { int idx = tid + 512; int r = idx / 12, q = idx - r*12;
          *(uint4*)(&Bt[r*SA + q*8]) = preB1; }
        { int r = tid >> 3, q = tid & 7;
          *(uint4*)(&Hs[r*SH + q*8]) = preH0; }
        if (tid < 320) { int idx = tid + 512; int r = idx >> 3, q = idx & 7;
          *(uint4*)(&Hs[r*SH + q*8]) = preH1; }
        __syncthreads();                          // barA (covers Asq on iter 0)
        int cn = c0 + 64;
        if (cn < NN) {
            const uint4* srcB = (const uint4*)(adp_bf + ((size_t)t*NN + cn)*96);
            preB0 = srcB[tid];
            if (tid < 256) preB1 = srcB[tid + 512];
            { int r = tid >> 3, q = tid & 7;
              preH0 = *(const uint4*)(hbase + (size_t)r*448 + cn + q*8); }
            if (tid < 320) { int idx = tid + 512; int r = idx >> 3, q = idx & 7;
              preH1 = *(const uint4*)(hbase + (size_t)r*448 + cn + q*8); }
        }
        float16v sc;
        #pragma unroll
        for (int i = 0; i < 16; ++i) sc[i] = 0.f;
        #pragma unroll
        for (int s = 0; s < 6; ++s) {
            short8v afq = *(const short8v*)(&Asq[slab][(qi*32 + n32)*SA + s*16 + koct*8]);
            short8v bfr = *(const short8v*)(&Bt[(ci*32 + n32)*SA + s*16 + koct*8]);
            sc = __builtin_amdgcn_mfma_f32_32x32x16_bf16(afq, bfr, sc, 0, 0, 0);
        }
        bool colok = (c0 + ci*32 + n32) < NN;
        #pragma unroll
        for (int reg = 0; reg < 16; ++reg) {
            int crow = (reg & 3) + 8*(reg >> 2) + 4*koct;
            float e = colok ? __expf(fmaxf(sc[reg], 0.f)) : 0.f;
            rs2[reg] += e;
            P[slab][(qi*32 + crow)*SPP + ci*32 + n32] = f2b(e);
        }
        __syncthreads();                          // barB: P complete (cross-wave)
        short8v pA[4];
        #pragma unroll
        for (int s = 0; s < 4; ++s)
            pA[s] = *(const short8v*)(&P[slab][(qi*32 + n32)*SPP + s*16 + koct*8]);
        #pragma unroll
        for (int s = 0; s < 4; ++s) {
            short8v hb0 = *(const short8v*)(&Hs[(ci*32 + n32)*SH + s*16 + koct*8]);
            on0 = __builtin_amdgcn_mfma_f32_32x32x16_bf16(pA[s], hb0, on0, 0, 0, 0);
        }
        #pragma unroll
        for (int s = 0; s < 4; ++s) {
            short8v hb1 = *(const short8v*)(&Hs[((ci+2)*32 + n32)*SH + s*16 + koct*8]);
            on1 = __builtin_amdgcn_mfma_f32_32x32x16_bf16(pA[s], hb1, on1, 0, 0, 0);
        }
        __syncthreads();                          // barC: reads done before restage
    }

    #pragma unroll
    for (int reg = 0; reg < 16; ++reg) {
        float v = rs2[reg];
        v += __shfl_xor(v, 1, 64);
        v += __shfl_xor(v, 2, 64);
        v += __shfl_xor(v, 4, 64);
        v += __shfl_xor(v, 8, 64);
        v += __shfl_xor(v, 16, 64);
        if (n32 == 0) {
            int crow = (reg & 3) + 8*(reg >> 2) + 4*koct;
            rsb[slab][ci][qi*32 + crow] = v;
        }
    }
    __syncthreads();

    #pragma unroll
    for (int reg = 0; reg < 16; ++reg) {
        int crow = (reg & 3) + 8*(reg >> 2) + 4*koct;
        int qrow = qi*32 + crow;
        int gq = r0 + qrow;
        if (gq < NN) {
            float inv = 1.f / (rsb[slab][0][qrow] + rsb[slab][1][qrow]);
            int d0 = ci*32 + n32;
            z1[((size_t)t*NN + gq)*104 + d0] = f2b(on0[reg] * inv);
            int d1 = (ci + 2)*32 + n32;
            if (d1 < 104)
                z1[((size_t)t*NN + gq)*104 + d1] = f2b(on1[reg] * inv);
        }
    }
}

// ---------------- MFMA KV summaries (spatial + temporal) ----------------
__global__ void __launch_bounds__(256) kvs_mf(
    const bf16* __restrict__ qkv, bf16* __restrict__ kvsb_s, bf16* __restrict__ kvsb_t)
{
    constexpr int CK = 32;          // l-chunk
    constexpr int TS = 40;          // padded row stride
    __shared__ bf16 raw[CK][216];   // 208 used (k|v span, qkv cols 104..311)
    __shared__ bf16 kTn[4][32][TS]; // per-head kn^T tile (rows 26..31 unused)
    __shared__ bf16 vT [4][32][TS]; // per-head v^T tile + ones row 26
    __shared__ float invs[CK][4];

    int bb = blockIdx.x;
    bf16* out; int L; long long strideL, base;
    if (bb < TT) { out = kvsb_s + (size_t)bb*NTILE; L = NN; base = (long long)bb*NN*312 + 104; strideL = 312; }
    else { int n = bb - TT; out = kvsb_t + (size_t)n*NTILE; L = TT; base = (long long)n*312 + 104; strideL = (long long)NN*312; }

    int tid = threadIdx.x;
    int lane = tid & 63, w = tid >> 6;       // wave = head
    int n32 = lane & 31, koct = lane >> 5;
    uint4 z4 = {0u,0u,0u,0u};

    float16v acc;
    #pragma unroll
    for (int i = 0; i < 16; ++i) acc[i] = 0.f;

    uint4 pre[4];
    #pragma unroll
    for (int j = 0; j < 4; ++j) {
        int idx = tid + j*256;
        uint4 v = z4;
        if (idx < CK*26) {
            int r = idx / 26, q = idx - r*26;
            if (r < L) v = *(const uint4*)(qkv + base + (long long)r*strideL + q*8);
        }
        pre[j] = v;
    }

    for (int l0 = 0; l0 < L; l0 += CK) {
        int lw = min(CK, L - l0);
        __syncthreads();
        #pragma unroll
        for (int j = 0; j < 4; ++j) {
            int idx = tid + j*256;
            if (idx < CK*26) {
                int r = idx / 26, q = idx - r*26;
                *(uint4*)(&raw[r][q*8]) = pre[j];
            }
        }
        __syncthreads();
        {
            int ln0 = l0 + CK;
            #pragma unroll
            for (int j = 0; j < 4; ++j) {
                int idx = tid + j*256;
                uint4 v = z4;
                if (idx < CK*26 && ln0 < L) {
                    int r = idx / 26, q = idx - r*26;
                    if (r < L - ln0) v = *(const uint4*)(qkv + base + (long long)(ln0 + r)*strideL + q*8);
                }
                pre[j] = v;
            }
        }
        if (tid < CK*4) {
            int l = tid >> 2, h = tid & 3;
            float ss = 0.f;
            #pragma unroll
            for (int m = 0; m < HD; ++m) { float v = b2f(raw[l][h*HD + m]); ss += v*v; }
            invs[l][h] = (l < lw) ? 1.f/fmaxf(sqrtf(ss), 1e-12f) : 0.f;
        }
        __syncthreads();
        for (int idx = tid; idx < 4*CK*HD; idx += 256) {
            int h = idx / (CK*HD); int rem = idx - h*CK*HD;
            int l = rem / HD; int m = rem - l*HD;
            float iv = invs[l][h];
            kTn[h][m][l] = f2b(b2f(raw[l][h*HD + m]) * iv);
            vT[h][m][l]  = raw[l][104 + h*HD + m];
        }
        if (tid < 4*CK) {
            int h = tid >> 5, l = tid & 31;
            vT[h][26][l] = f2b((l < lw) ? 1.f : 0.f);
        }
        __syncthreads();
        #pragma unroll
        for (int s = 0; s < 2; ++s) {
            short8v a = *(const short8v*)(&kTn[w][n32][s*16 + koct*8]);
            short8v b = *(const short8v*)(&vT [w][n32][s*16 + koct*8]);
            acc = __builtin_amdgcn_mfma_f32_32x32x16_bf16(a, b, acc, 0, 0, 0);
        }
    }

    int lo = w*HD;
    #pragma unroll
    for (int reg = 0; reg < 16; ++reg) {
        int m = (reg & 3) + 8*(reg >> 2) + 4*koct;
        if (m < HD) {
            if (n32 < HD)       out[(size_t)(lo + n32)*32 + m] = f2b(acc[reg]);
            else if (n32 == HD) out[(size_t)(104 + w)*32 + m] = f2b(acc[reg]);
        }
    }
}

// ---------------- MFMA linear-attention apply (temporal only now) ----------------
__global__ void __launch_bounds__(256) attn_mm(
    bf16* __restrict__ qkv, const bf16* __restrict__ kvsb,
    int M, long long bStride, long long rowStride, float Lf, int outOff)
{
    constexpr int STR = 136;
    __shared__ bf16 As[64*STR];
    __shared__ bf16 Ws[112*STR];
    __shared__ float nsqL[64*4];
    __shared__ float denL[64*4];
    int mt = blockIdx.x, bb = blockIdx.y;
    int tid = threadIdx.x;
    int lane = tid & 63, w = tid >> 6, n16 = lane & 15, quad = lane >> 4;
    bf16* base = qkv + (size_t)bb * bStride;
    int r0 = mt*64;
    uint4 z4 = {0u,0u,0u,0u};

    for (int idx = tid; idx < 64*16; idx += 256) {
        int r = idx >> 4, q = idx & 15;
        int m = r0 + r;
        uint4 v = z4;
        if (m < M && q < 13) v = *(const uint4*)(base + (size_t)m*rowStride + q*8);
        *(uint4*)(&As[r*STR + q*8]) = v;
    }
    for (int idx = tid; idx < 112*16; idx += 256) {
        int c = idx >> 4, q = idx & 15;
        *(uint4*)(&Ws[c*STR + q*8]) = z4;
    }
    __syncthreads();
    {
        const bf16* kb = kvsb + (size_t)bb * NTILE;
        for (int idx = tid; idx < 108*13; idx += 256) {
            int c = idx / 13, qu = idx - c*13;
            int lo = (c < 104) ? (c/26)*26 : (c-104)*26;
            *(uint*)(&Ws[c*STR + lo + qu*2]) = *(const uint*)(kb + (size_t)c*32 + qu*2);
        }
    }
    __syncthreads();

    short8v af[4];
    #pragma unroll
    for (int s = 0; s < 4; ++s)
        af[s] = *(const short8v*)(&As[(16*w + n16)*STR + s*32 + quad*8]);
    float4v acc[7];
    #pragma unroll
    for (int ct = 0; ct < 7; ++ct) { float4v z = {0.f,0.f,0.f,0.f}; acc[ct] = z; }
    #pragma unroll
    for (int ct = 0; ct < 7; ++ct) {
        #pragma unroll
        for (int s = 0; s < 4; ++s) {
            short8v bfr = *(const short8v*)(&Ws[(ct*16 + n16)*STR + s*32 + quad*8]);
            acc[ct] = __builtin_amdgcn_mfma_f32_16x16x32_bf16(af[s], bfr, acc[ct], 0, 0, 0);
        }
    }
    {
        int row = tid >> 2, hh = tid & 3;
        const bf16* qr = &As[row*STR + hh*26];
        float ss = 0.f;
        #pragma unroll
        for (int m = 0; m < HD; ++m) { float v = b2f(qr[m]); ss += v*v; }
        nsqL[row*4 + hh] = ss;
    }
    if (n16 >= 8 && n16 < 12) {
        #pragma unroll
        for (int reg = 0; reg < 4; ++reg)
            denL[(16*w + quad*4 + reg)*4 + (n16 - 8)] = acc[6][reg];
    }
    __syncthreads();
    #pragma unroll
    for (int ct = 0; ct < 7; ++ct) {
        int c = ct*16 + n16;
        if (c < 104) {
            int hh = c / 26;
            #pragma unroll
            for (int reg = 0; reg < 4; ++reg) {
                int lr = 16*w + quad*4 + reg;
                int m = r0 + lr;
                if (m < M) {
                    float iq = 1.f / fmaxf(sqrtf(nsqL[lr*4 + hh]), 1e-12f);
                    float den = iq * denL[lr*4 + hh] + Lf;
                    bf16* rp = base + (size_t)m*rowStride;
                    float num = iq * acc[ct][reg] + Lf * b2f(rp[208 + c]);
                    rp[outOff + c] = f2b(num / den);
                }
            }
        }
    }
}

// ---------------- R8: fused spatial attn + op projection ----------------
// Per block: 64 rows of one t. Stage [q|out_t] (qkv cols 0..207, out_t written
// by the preceding temporal attn_mm). Spatial attn (Ws band rows are zero at
// k>=104 so the staged out_t cols contribute 0). Epilogue writes out_s into
// the A-tile over q; Ws restaged band -> op weights (fc2_ln2's 128/96 halves);
// then the 208-K op GEMM. Deletes the out_s global round-trip + 1 dispatch.
__global__ void __launch_bounds__(256) attn_op(
    const bf16* __restrict__ qkv, const bf16* __restrict__ kvsb,
    const bf16* __restrict__ wt, const float* __restrict__ bias,
    bf16* __restrict__ Cout, float Lf)
{
    constexpr int SA = 232;      // A stride: 208 data + 16 zero + 8 pad (16B-aligned)
    constexpr int SW = 136;
    __shared__ bf16 Acat[64*SA];     // 29696 B
    __shared__ bf16 Ws[112*SW];      // 30464 B (band, then op-W halves)
    __shared__ float nsqL[64*4];
    __shared__ float denL[64*4];
    int mt = blockIdx.x, t = blockIdx.y;
    int tid = threadIdx.x;
    int lane = tid & 63, w = tid >> 6, n16 = lane & 15, quad = lane >> 4;
    const bf16* base = qkv + (size_t)t * ((size_t)NN*312);
    int r0 = mt*64;
    uint4 z4 = {0u,0u,0u,0u};

    // stage A rows: cols 0..207 = [q|out_t]; 208..231 zero
    for (int idx = tid; idx < 64*29; idx += 256) {
        int r = idx / 29, q = idx - r*29;
        int m = r0 + r;
        uint4 v = z4;
        if (m < NN && q < 26) v = *(const uint4*)(base + (size_t)m*312 + q*8);
        *(uint4*)(&Acat[r*SA + q*8]) = v;
    }
    // stage Ws: zero cols 0..127 then scatter kvs band
    for (int idx = tid; idx < 112*16; idx += 256) {
        int c = idx >> 4, q = idx & 15;
        *(uint4*)(&Ws[c*SW + q*8]) = z4;
    }
    __syncthreads();
    {
        const bf16* kb = kvsb + (size_t)t * NTILE;
        for (int idx = tid; idx < 108*13; idx += 256) {
            int c = idx / 13, qu = idx - c*13;
            int lo = (c < 104) ? (c/26)*26 : (c-104)*26;
            *(uint*)(&Ws[c*SW + lo + qu*2]) = *(const uint*)(kb + (size_t)c*32 + qu*2);
        }
    }
    __syncthreads();

    // ---- spatial attention ----
    short8v af[4];
    #pragma unroll
    for (int s = 0; s < 4; ++s)
        af[s] = *(const short8v*)(&Acat[(16*w + n16)*SA + s*32 + quad*8]);
    float4v acc[7];
    #pragma unroll
    for (int ct = 0; ct < 7; ++ct) { float4v z = {0.f,0.f,0.f,0.f}; acc[ct] = z; }
    #pragma unroll
    for (int ct = 0; ct < 7; ++ct) {
        #pragma unroll
        for (int s = 0; s < 4; ++s) {
            short8v bfr = *(const short8v*)(&Ws[(ct*16 + n16)*SW + s*32 + quad*8]);
            acc[ct] = __builtin_amdgcn_mfma_f32_16x16x32_bf16(af[s], bfr, acc[ct], 0, 0, 0);
        }
    }
    {
        int row = tid >> 2, hh = tid & 3;
        const bf16* qr = &Acat[row*SA + hh*26];
        float ss = 0.f;
        #pragma unroll
        for (int m = 0; m < HD; ++m) { float v = b2f(qr[m]); ss += v*v; }
        nsqL[row*4 + hh] = ss;
    }
    if (n16 >= 8 && n16 < 12) {
        #pragma unroll
        for (int reg = 0; reg < 4; ++reg)
            denL[(16*w + quad*4 + reg)*4 + (n16 - 8)] = acc[6][reg];
    }
    __syncthreads();      // attn reads of Ws/Acat(q) done; denL published

    // ---- epilogue: out_s -> Acat cols 0..103 ; restage Ws <- op-W half 1 ----
    #pragma unroll
    for (int ct = 0; ct < 7; ++ct) {
        int c = ct*16 + n16;
        if (c < 104) {
            int hh = c / 26;
            #pragma unroll
            for (int reg = 0; reg < 4; ++reg) {
                int lr = 16*w + quad*4 + reg;
                int m = r0 + lr;
                if (m < NN) {
                    float iq = 1.f / fmaxf(sqrtf(nsqL[lr*4 + hh]), 1e-12f);
                    float den = iq * denL[lr*4 + hh] + Lf;
                    const bf16* rp = base + (size_t)m*312;
                    float num = iq * acc[ct][reg] + Lf * b2f(rp[208 + c]);
                    Acat[lr*SA + c] = f2b(num / den);
                }
            }
        }
    }
    for (int idx = tid; idx < 112*16; idx += 256) {   // op-W half 1: k 0..127
        int c = idx >> 4, q = idx & 15;
        uint4 v = z4;
        if (c < 104) v = *(const uint4*)(wt + (size_t)c*224 + q*8);
        *(uint4*)(&Ws[c*SW + q*8]) = v;
    }
    __syncthreads();

    // ---- op projection: C = Acat(64x208) @ W(208x104) + bias ----
    short8v af2[7];
    #pragma unroll
    for (int s = 0; s < 7; ++s)
        af2[s] = *(const short8v*)(&Acat[(16*w + n16)*SA + s*32 + quad*8]);
    float4v acc2[7];
    #pragma unroll
    for (int ct = 0; ct < 7; ++ct) { float4v z = {0.f,0.f,0.f,0.f}; acc2[ct] = z; }
    #pragma unroll
    for (int ct = 0; ct < 7; ++ct)
        #pragma unroll
        for (int s = 0; s < 4; ++s) {
            short8v bfr = *(const short8v*)(&Ws[(ct*16 + n16)*SW + s*32 + quad*8]);
            acc2[ct] = __builtin_amdgcn_mfma_f32_16x16x32_bf16(af2[s], bfr, acc2[ct], 0, 0, 0);
        }
    __syncthreads();
    for (int idx = tid; idx < 112*16; idx += 256) {   // op-W half 2: k 128..223 (12 data uint4)
        int c = idx >> 4, q = idx & 15;
        uint4 v = z4;
        if (c < 104 && q < 12) v = *(const uint4*)(wt + (size_t)c*224 + 128 + q*8);
        *(uint4*)(&Ws[c*SW + q*8]) = v;
    }
    __syncthreads();
    #pragma unroll
    for (int ct = 0; ct < 7; ++ct)
        #pragma unroll
        for (int s = 4; s < 7; ++s) {
            short8v bfr = *(const short8v*)(&Ws[(ct*16 + n16)*SW + (s-4)*32 + quad*8]);
            acc2[ct] = __builtin_amdgcn_mfma_f32_16x16x32_bf16(af2[s], bfr, acc2[ct], 0, 0, 0);
        }

    #pragma unroll
    for (int ct = 0; ct < 7; ++ct) {
        int c = ct*16 + n16;
        if (c < 104) {
            float b = bias[c];
            #pragma unroll
            for (int reg = 0; reg < 4; ++reg) {
                int m = r0 + 16*w + quad*4 + reg;
                if (m < NN)
                    Cout[((size_t)t*NN + m)*104 + c] = f2b(acc2[ct][reg] + b);
            }
        }
    }
}

__global__ void __launch_bounds__(256) y_init_kernel(float* __restrict__ y, const float* __restrict__ ep_b) {
    int i = blockIdx.x*256 + threadIdx.x;
    if (i < NN*104) y[i] = ep_b[i % 104];
}

// ---------------- fused tail: 2 rows/block, ILP on the dot chains ----------------
__global__ void __launch_bounds__(256) tail_kernel(
    const float* __restrict__ y,
    const float* __restrict__ ew1, const float* __restrict__ eb1,
    const float* __restrict__ ew2, const float* __restrict__ eb2,
    const float* __restrict__ out_w, const float* __restrict__ out_b,
    float* __restrict__ out)
{
    int n0 = blockIdx.x * 2;               // 200 blocks x 2 rows
    int tid = threadIdx.x;
    __shared__ float yr[2][104], hid[2][208];
    if (tid < 104) {
        yr[0][tid] = y[(size_t)n0*104 + tid];
        yr[1][tid] = y[(size_t)(n0+1)*104 + tid];
    }
    __syncthreads();
    for (int i = 0; i < 3; ++i) {
        const float* w1 = ew1 + (size_t)i*104*208;
        const float* b1 = eb1 + (size_t)i*208;
        const float* w2 = ew2 + (size_t)i*208*104;
        const float* b2 = eb2 + (size_t)i*104;
        if (tid < 208) {
            float a0 = b1[tid], a1 = a0;
            #pragma unroll 8
            for (int k = 0; k < 104; ++k) {
                float w = w1[(size_t)k*208 + tid];
                a0 += yr[0][k]*w; a1 += yr[1][k]*w;
            }
            hid[0][tid] = fmaxf(a0, 0.f);
            hid[1][tid] = fmaxf(a1, 0.f);
        }
        __syncthreads();
        float y0 = 0.f, y1 = 0.f;
        if (tid < 104) {
            float a0 = b2[tid], a1 = a0;
            #pragma unroll 8
            for (int k = 0; k < 208; ++k) {
                float w = w2[(size_t)k*104 + tid];
                a0 += hid[0][k]*w; a1 += hid[1][k]*w;
            }
            y0 = yr[0][tid] + a0; y1 = yr[1][tid] + a1;
        }
        __syncthreads();
        if (tid < 104) { yr[0][tid] = y0; yr[1][tid] = y1; }
        __syncthreads();
    }
    for (int t = tid; t < TT; t += 256) {
        float a0 = out_b[t], a1 = a0;
        #pragma unroll 8
        for (int d = 0; d < 104; ++d) {
            float w = out_w[(size_t)d*TT + t];
            a0 += yr[0][d]*w; a1 += yr[1][d]*w;
        }
        out[(size_t)n0*TT + t] = a0;
        out[(size_t)(n0+1)*TT + t] = a1;
    }
}

// ---------------- launch ----------------
extern "C" void kernel_launch(void* const* d_in, const int* in_sizes, int n_in,
                              void* d_out, int out_size, void* d_ws, size_t ws_size,
                              hipStream_t stream) {
    if (ws_size < WS_NEEDED) return;

    const float* x      = (const float*)d_in[0];
    const float* W_in   = (const float*)d_in[1];
    const float* b_in   = (const float*)d_in[2];
    const float* adp    = (const float*)d_in[3];
    const float* W_tp   = (const float*)d_in[4];
    const float* b_tp   = (const float*)d_in[5];
    const float* qkv_w  = (const float*)d_in[6];
    const float* op_w   = (const float*)d_in[7];
    const float* op_b   = (const float*)d_in[8];
    const float* pw_w   = (const float*)d_in[9];
    const float* pw_b   = (const float*)d_in[10];
    const float* fc_w1  = (const float*)d_in[11];
    const float* fc_b1  = (const float*)d_in[12];
    const float* fc_w2  = (const float*)d_in[13];
    const float* fc_b2  = (const float*)d_in[14];
    const float* ln1_g  = (const float*)d_in[15];
    const float* ln1_b  = (const float*)d_in[16];
    const float* ln2_g  = (const float*)d_in[17];
    const float* ln2_b  = (const float*)d_in[18];
    const float* ep_w   = (const float*)d_in[19];
    const float* ep_b   = (const float*)d_in[20];
    const float* enc_w1 = (const float*)d_in[21];
    const float* enc_b1 = (const float*)d_in[22];
    const float* enc_w2 = (const float*)d_in[23];
    const float* enc_b2 = (const float*)d_in[24];
    const float* out_w  = (const float*)d_in[25];
    const float* out_b  = (const float*)d_in[26];

    bf16* B0 = (bf16*)d_ws;
    bf16* B1 = B0 + NB0;
    bf16* B2 = B1 + NB1;
    bf16* B3 = B2 + NB2;
    bf16* kvsb_s = B3 + NB3;
    bf16* kvsb_t = kvsb_s + NKVSB_S;
    float* ybuf  = (float*)(kvsb_t + NKVSB_T);
    bf16* wtp   = (bf16*)(ybuf + NY);
    bf16* wqkv0 = wtp + NW_TP;
    bf16* wqkv1 = wqkv0 + NW_QKV;
    bf16* wop0  = wqkv1 + NW_QKV;
    bf16* wop1  = wop0 + NW_OP;
    bf16* wpw0  = wop1 + NW_OP;
    bf16* wpw1  = wpw0 + NW_PW;
    bf16* wfc1  = wpw1 + NW_PW;
    bf16* wfc2  = wfc1 + NW_FC1;
    bf16* wept  = wfc2 + NW_FC2;
    bf16* adp_bf = B2;
    bf16* hTbuf  = B2 + NADP;

    // 0. weight prep
    prep_w<<<CEILDIV(104*128,256), 256, 0, stream>>>(W_tp, wtp, 104, 104, 128);
    prep_w<<<CEILDIV(312*128,256), 256, 0, stream>>>(qkv_w, wqkv0, 104, 312, 128);
    prep_w<<<CEILDIV(312*128,256), 256, 0, stream>>>(qkv_w + 104*312, wqkv1, 104, 312, 128);
    prep_w<<<CEILDIV(104*224,256), 256, 0, stream>>>(op_w, wop0, 208, 104, 224);
    prep_w<<<CEILDIV(104*224,256), 256, 0, stream>>>(op_w + 208*104, wop1, 208, 104, 224);
    prep_w<<<CEILDIV(104*128,256), 256, 0, stream>>>(pw_w, wpw0, 104, 104, 128);
    prep_w<<<CEILDIV(104*128,256), 256, 0, stream>>>(pw_w + 104*104, wpw1, 104, 104, 128);
    prep_w<<<CEILDIV(208*128,256), 256, 0, stream>>>(fc_w1, wfc1, 104, 208, 128);
    prep_w<<<CEILDIV(104*224,256), 256, 0, stream>>>(fc_w2, wfc2, 208, 104, 224);
    prep_wT<<<CEILDIV(37960,64), 256, 0, stream>>>(ep_w, wept);

    const int GX = CEILDIV(TN, 64);     // 2282

    // 1. hcat -> B2
    hcat_kernel<<<CEILDIV(TN,16), 256, 0, stream>>>(x, W_in, b_in, adp, B2);
    // 2. h = hcat @ W_tp + b_tp -> B0
    gemm_mf<128><<<GX*2, 256, 0, stream>>>(B2, 104, 104, wtp, b_tp, B0, TN, 104, 0);
    // 2b. z1 pre-staging into B2
    prep_adp<<<CEILDIV((int)NADP,256), 256, 0, stream>>>(adp, adp_bf);
    ht_kernel<<<dim3(7, TT), 256, 0, stream>>>(B0, hTbuf);
    // 3. z1 -> B1
    z1_mf<<<Z1_BLOCKS, 512, 0, stream>>>(adp_bf, hTbuf, B1);
    // 4. attention 0 on h
    gemm_mf<128><<<GX*5, 256, 0, stream>>>(B0, 104, 104, wqkv0, nullptr, B2, TN, 312, 0);
    kvs_mf<<<TT+NN, 256, 0, stream>>>(B2, kvsb_s, kvsb_t);
    attn_mm<<<dim3(6, NN), 256, 0, stream>>>(B2, kvsb_t, TT, 312, (long long)NN*312, (float)TT, 104);
    attn_op<<<dim3(7, TT), 256, 0, stream>>>(B2, kvsb_s, wop0, op_b, B3, (float)NN);   // att0 -> B3
    // 5. attention 1 on z1
    gemm_mf<128><<<GX*5, 256, 0, stream>>>(B1, 104, 104, wqkv1, nullptr, B2, TN, 312, 0);
    kvs_mf<<<TT+NN, 256, 0, stream>>>(B2, kvsb_s, kvsb_t);
    attn_mm<<<dim3(6, NN), 256, 0, stream>>>(B2, kvsb_t, TT, 312, (long long)NN*312, (float)TT, 104);
    attn_op<<<dim3(7, TT), 256, 0, stream>>>(B2, kvsb_s, wop1, op_b + 104, B1, (float)NN); // att1 -> B1
    // 6+7. fused gates + LN1 (in-place B0 -> h1)
    gate_ln1<<<GX, 256, 0, stream>>>(B0, B3, B1, wpw0, wpw1, pw_b, ln1_g, ln1_b);
    // 8. MLP: fc1 -> hidden (B2), fused fc2+LN2 -> h2 (B3)
    gemm_mf<128><<<GX*4, 256, 0, stream>>>(B0, 104, 104, wfc1, fc_b1, B2, TN, 208, 1);
    fc2_ln2<<<GX, 256, 0, stream>>>(B2, wfc2, fc_b2, B0, ln2_g, ln2_b, B3);
    // 9. encoder_proj
    y_init_kernel<<<CEILDIV(NN*104,256), 256, 0, stream>>>(ybuf, ep_b);
    ep_mf<<<dim3(CEILDIV(NN,64), 2, CEILDIV(TT,8)), 256, 0, stream>>>(B3, wept, ybuf);
    // 10+11. fused residual MLP blocks + output projection (2 rows/block)
    tail_kernel<<<NN/2, 256, 0, stream>>>(ybuf, enc_w1, enc_b1, enc_w2, enc_b2,
                                          out_w, out_b, (float*)d_out);
}

// Round 9
// 1200.009 us; speedup vs baseline: 1.1355x; 1.0123x over previous
//
#include <hip/hip_runtime.h>
#include <hip/hip_bf16.h>
#include <cstddef>

// ---------------- problem constants ----------------
#define TT   365
#define NN   400
#define TN   (TT*NN)            // 146000
#define HD   26                 // head dim
#define NH   4                  // heads

#define CEILDIV(a,b) (((a)+(b)-1)/(b))

typedef __hip_bfloat16 bf16;
typedef short short8v __attribute__((ext_vector_type(8)));
typedef float float4v __attribute__((ext_vector_type(4)));
typedef float float16v __attribute__((ext_vector_type(16)));
__device__ __forceinline__ float b2f(bf16 v){ return __bfloat162float(v); }
__device__ __forceinline__ bf16  f2b(float v){ return __float2bfloat16(v); }

// ---------------- workspace layout ----------------
static constexpr size_t NB0 = (size_t)TN*104;   // h / h1
static constexpr size_t NB1 = (size_t)TN*104;   // z1 -> att1
static constexpr size_t NB2 = (size_t)TN*312;   // hcat -> [adp_bf|hT] -> qkv+concat -> hidden
static constexpr size_t NB3 = (size_t)TN*104;   // att0 -> h2
static constexpr size_t NBF = NB0+NB1+NB2+NB3;
// compact band KV tiles: per b, 108 rows x 32 (band cols 0..25), bf16
static constexpr size_t NTILE   = (size_t)108*32;
static constexpr size_t NKVSB_S = (size_t)TT*NTILE;
static constexpr size_t NKVSB_T = (size_t)NN*NTILE;
static constexpr size_t NY      = (size_t)NN*104;
// transposed bf16 weights (Wt[n][kp], zero-padded k)
static constexpr size_t NW_TP   = 104*128;
static constexpr size_t NW_QKV  = 312*128;   // x2
static constexpr size_t NW_OP   = 104*224;   // x2
static constexpr size_t NW_PW   = 104*128;   // x2
static constexpr size_t NW_FC1  = 208*128;
static constexpr size_t NW_FC2  = 104*224;
static constexpr size_t NW_EPT  = (size_t)104*37960;   // ep_w transposed, no pad
static constexpr size_t NWT     = NW_TP + 2*NW_QKV + 2*NW_OP + 2*NW_PW + NW_FC1 + NW_FC2 + NW_EPT;
static constexpr size_t WS_NEEDED = NBF*2 + (NKVSB_S+NKVSB_T)*2 + NY*4 + NWT*2;
// z1 scratch lives inside B2 (dead between step 2 and step 4):
static constexpr size_t NADP_ROWS = (size_t)TN + 64;
static constexpr size_t NADP = NADP_ROWS*96;
static constexpr size_t NHT  = ((size_t)TT*104 + 8)*448;
static_assert(NADP + NHT <= NB2, "z1 scratch must fit in B2");

// ---------------- weight prep: Wt[n*KP+k] = bf16(W[k*Nc+n]), zero pad k>=K ----------------
__global__ void __launch_bounds__(256) prep_w(
    const float* __restrict__ W, bf16* __restrict__ Wt, int K, int Nc, int KP)
{
    int idx = blockIdx.x*256 + threadIdx.x;
    if (idx >= Nc*KP) return;
    int n = idx / KP, k = idx - n*KP;
    Wt[idx] = (k < K) ? f2b(W[(size_t)k*Nc + n]) : f2b(0.f);
}

// coalesced LDS transpose for ep weights: Wt[n][k] = bf16(W[k][n]); W is 37960x104 fp32
__global__ void __launch_bounds__(256) prep_wT(
    const float* __restrict__ W, bf16* __restrict__ Wt)
{
    __shared__ float T[64][105];
    int k0 = blockIdx.x * 64;
    int tid = threadIdx.x;
    for (int idx = tid; idx < 64*104; idx += 256) {
        int r = idx / 104, c = idx - r*104;
        int k = k0 + r;
        T[r][c] = (k < 37960) ? W[(size_t)k*104 + c] : 0.f;
    }
    __syncthreads();
    for (int idx = tid; idx < 104*32; idx += 256) {
        int n = idx >> 5, kp = idx & 31;
        int k = kp*2;
        if (k0 + k + 1 < 37960 || k0 + k < 37960) {
            if (k0 + k < 37960) {
                bf16 lo = f2b(T[k][n]);
                bf16 hi = f2b(T[k+1][n]);   // k+1 row is zero-padded if OOB of tile data
                uint v = ((uint)(*(ushort*)&hi) << 16) | (*(ushort*)&lo);
                if (k0 + k + 1 < 37960) *(uint*)(Wt + (size_t)n*37960 + k0 + k) = v;
                else Wt[(size_t)n*37960 + k0 + k] = lo;
            }
        }
    }
}

// adp_bf[row][e] = bf16(adp[row][e]) for e<80 else 0; rows >= TN are zero.
__global__ void __launch_bounds__(256) prep_adp(
    const float* __restrict__ adp, bf16* __restrict__ out)
{
    size_t i = (size_t)blockIdx.x*256 + threadIdx.x;
    if (i >= NADP) return;
    size_t row = i / 96; int e = (int)(i - row*96);
    float v = (row < TN && e < 80) ? adp[row*80 + e] : 0.f;
    out[i] = f2b(v);
}

// hT[t][d][n] = h[t][n][d], n padded to 448 with zeros
__global__ void __launch_bounds__(256) ht_kernel(
    const bf16* __restrict__ h, bf16* __restrict__ hT)
{
    __shared__ bf16 As[64*106];
    int t = blockIdx.y, n0 = blockIdx.x*64;
    int tid = threadIdx.x;
    for (int idx = tid; idx < 64*52; idx += 256) {
        int r = idx / 52, k = idx - r*52;
        int n = n0 + r;
        uint v = 0;
        if (n < NN) v = *(const uint*)(h + ((size_t)t*NN + n)*104 + k*2);
        *(uint*)(&As[r*106 + k*2]) = v;
    }
    __syncthreads();
    for (int idx = tid; idx < 104*32; idx += 256) {
        int d = idx >> 5, np = idx & 31;
        int n = np*2;
        ushort lo = *(ushort*)&As[n*106 + d];
        ushort hi = *(ushort*)&As[(n+1)*106 + d];
        uint v = ((uint)hi << 16) | lo;
        *(uint*)(hT + ((size_t)t*104 + d)*448 + n0 + n) = v;
    }
}

// ---------------- hcat (16 rows/block, LDS-staged uint4 row writes) ----------------
__global__ void __launch_bounds__(256) hcat_kernel(
    const float* __restrict__ x, const float* __restrict__ W_in,
    const float* __restrict__ b_in, const float* __restrict__ adp,
    bf16* __restrict__ hcat)
{
    __shared__ bf16 T[16][112];          // 104 used; 224B row stride (16B-aligned)
    int r0 = blockIdx.x * 16;
    int tid = threadIdx.x;
    // proj cols 0..23
    for (int idx = tid; idx < 16*24; idx += 256) {
        int r = idx / 24, c = idx - r*24;
        int row = r0 + r;
        int t = row / NN, n = row - t*NN;
        size_t xb = ((size_t)n*TT + t)*3;
        float s = b_in[c] + x[xb]*W_in[c] + x[xb+1]*W_in[24+c] + x[xb+2]*W_in[48+c];
        T[r][c] = f2b(s);
    }
    // adp cols 24..103 (coalesced f32 reads)
    for (int idx = tid; idx < 16*80; idx += 256) {
        int r = idx / 80, e = idx - r*80;
        T[r][24+e] = f2b(adp[(size_t)(r0+r)*80 + e]);
    }
    __syncthreads();
    for (int idx = tid; idx < 16*13; idx += 256) {
        int r = idx / 13, q = idx - r*13;
        *(uint4*)(hcat + ((size_t)(r0+r))*104 + q*8) = *(const uint4*)(&T[r][q*8]);
    }
}

// ---------------- MFMA GEMM 64-tile ----------------
// 1-D grid with bijective XCD grouping (m204): column-tiles of one row-slab
// land adjacent on the SAME XCD so the A-slab is fetched from HBM once.
template<int KP>
__global__ void __launch_bounds__(256) gemm_mf(
    const bf16* __restrict__ A, int lda, int K,
    const bf16* __restrict__ Wt, const float* __restrict__ bias,
    bf16* __restrict__ C, int M, int Nc, int relu)
{
    constexpr int STR = KP + 8;
    constexpr int KPQ = KP/8;
    __shared__ bf16 As[64*STR];
    __shared__ bf16 Ws[64*STR];
    int nCol = (Nc + 63) >> 6;
    int nwg = gridDim.x;
    int bid = blockIdx.x;
    int xcd = bid & 7, kk = bid >> 3;
    int q8 = nwg >> 3, r8 = nwg & 7;
    int widx = (xcd < r8 ? xcd*(q8+1) : r8*(q8+1) + (xcd - r8)*q8) + kk;
    int mblk = widx / nCol;
    int m0 = mblk * 64;
    int c0 = (widx - mblk*nCol) * 64;
    int tid = threadIdx.x;
    const int KQ = K/8;
    uint4 z4 = {0u,0u,0u,0u};
    for (int idx = tid; idx < 64*KPQ; idx += 256) {
        int r = idx / KPQ, q = idx - r*KPQ;
        int m = m0 + r;
        uint4 v = z4;
        if (m < M && q < KQ) v = *(const uint4*)(A + (size_t)m*lda + q*8);
        *(uint4*)(&As[r*STR + q*8]) = v;
    }
    for (int idx = tid; idx < 64*KPQ; idx += 256) {
        int r = idx / KPQ, q = idx - r*KPQ;
        int n = c0 + r;
        uint4 v = z4;
        if (n < Nc) v = *(const uint4*)(Wt + (size_t)n*KP + q*8);
        *(uint4*)(&Ws[r*STR + q*8]) = v;
    }
    __syncthreads();

    int lane = tid & 63, w = tid >> 6;
    int n16 = lane & 15, quad = lane >> 4;
    constexpr int KS = KP/32;
    short8v af[KS];
    #pragma unroll
    for (int s = 0; s < KS; ++s)
        af[s] = *(const short8v*)(&As[(16*w + n16)*STR + s*32 + quad*8]);
    float4v acc[4];
    #pragma unroll
    for (int ct = 0; ct < 4; ++ct) { float4v z = {0.f,0.f,0.f,0.f}; acc[ct] = z; }
    #pragma unroll
    for (int ct = 0; ct < 4; ++ct) {
        #pragma unroll
        for (int s = 0; s < KS; ++s) {
            short8v bfr = *(const short8v*)(&Ws[(ct*16 + n16)*STR + s*32 + quad*8]);
            acc[ct] = __builtin_amdgcn_mfma_f32_16x16x32_bf16(af[s], bfr, acc[ct], 0, 0, 0);
        }
    }
    #pragma unroll
    for (int ct = 0; ct < 4; ++ct) {
        int c = c0 + ct*16 + n16;
        if (c < Nc) {
            float b = bias ? bias[c] : 0.f;
            #pragma unroll
            for (int reg = 0; reg < 4; ++reg) {
                int m = m0 + 16*w + quad*4 + reg;
                if (m < M) {
                    float v = acc[ct][reg] + b;
                    if (relu) v = fmaxf(v, 0.f);
                    C[(size_t)m*Nc + c] = f2b(v);
                }
            }
        }
    }
}

// ---------------- fused gates + LN1 ----------------
// h1 = LN(2*(h + att0*(h@pw0+b0) + 0.01*att1*(att0@pw1+b1))) in-place into h.
__global__ void __launch_bounds__(256) gate_ln1(
    bf16* __restrict__ h, const bf16* __restrict__ att0, const bf16* __restrict__ att1,
    const bf16* __restrict__ w0t, const bf16* __restrict__ w1t, const float* __restrict__ pwb,
    const float* __restrict__ gamma, const float* __restrict__ beta)
{
    constexpr int STR = 136;
    __shared__ bf16 A0s[64*STR];
    __shared__ bf16 A1s[64*STR];
    __shared__ bf16 Ws[112*STR];
    __shared__ float prm[416];     // pwb(208) | gamma(104) | beta(104)
    int m0 = blockIdx.x * 64;
    int tid = threadIdx.x;
    int lane = tid & 63, w = tid >> 6, n16 = lane & 15, quad = lane >> 4;
    uint4 z4 = {0u,0u,0u,0u};

    for (int idx = tid; idx < 64*16; idx += 256) {
        int r = idx >> 4, q = idx & 15;
        int m = m0 + r;
        uint4 v0 = z4, v1 = z4;
        if (m < TN && q < 13) {
            v0 = *(const uint4*)(h    + (size_t)m*104 + q*8);
            v1 = *(const uint4*)(att0 + (size_t)m*104 + q*8);
        }
        *(uint4*)(&A0s[r*STR + q*8]) = v0;
        *(uint4*)(&A1s[r*STR + q*8]) = v1;
    }
    for (int idx = tid; idx < 112*16; idx += 256) {
        int c = idx >> 4, q = idx & 15;
        uint4 v = z4;
        if (c < 104) v = *(const uint4*)(w0t + (size_t)c*128 + q*8);
        *(uint4*)(&Ws[c*STR + q*8]) = v;
    }
    for (int i = tid; i < 416; i += 256)
        prm[i] = (i < 208) ? pwb[i] : (i < 312 ? gamma[i-208] : beta[i-312]);
    __syncthreads();

    short8v a0f[4], a1f[4];
    #pragma unroll
    for (int s = 0; s < 4; ++s) {
        a0f[s] = *(const short8v*)(&A0s[(16*w + n16)*STR + s*32 + quad*8]);
        a1f[s] = *(const short8v*)(&A1s[(16*w + n16)*STR + s*32 + quad*8]);
    }
    float4v acc0[7], acc1[7];
    #pragma unroll
    for (int ct = 0; ct < 7; ++ct) { float4v z = {0.f,0.f,0.f,0.f}; acc0[ct] = z; acc1[ct] = z; }
    #pragma unroll
    for (int ct = 0; ct < 7; ++ct)
        #pragma unroll
        for (int s = 0; s < 4; ++s) {
            short8v bfr = *(const short8v*)(&Ws[(ct*16 + n16)*STR + s*32 + quad*8]);
            acc0[ct] = __builtin_amdgcn_mfma_f32_16x16x32_bf16(a0f[s], bfr, acc0[ct], 0, 0, 0);
        }
    __syncthreads();
    for (int idx = tid; idx < 112*16; idx += 256) {
        int c = idx >> 4, q = idx & 15;
        uint4 v = z4;
        if (c < 104) v = *(const uint4*)(w1t + (size_t)c*128 + q*8);
        *(uint4*)(&Ws[c*STR + q*8]) = v;
    }
    __syncthreads();
    #pragma unroll
    for (int ct = 0; ct < 7; ++ct)
        #pragma unroll
        for (int s = 0; s < 4; ++s) {
            short8v bfr = *(const short8v*)(&Ws[(ct*16 + n16)*STR + s*32 + quad*8]);
            acc1[ct] = __builtin_amdgcn_mfma_f32_16x16x32_bf16(a1f[s], bfr, acc1[ct], 0, 0, 0);
        }

    // epilogue: g -> LN (row distributed across the 16 n16 lanes)
    float sum[4] = {0.f,0.f,0.f,0.f};
    #pragma unroll
    for (int ct = 0; ct < 7; ++ct) {
        int c = ct*16 + n16;
        bool colok = c < 104;
        float b0 = colok ? prm[c] : 0.f;
        float b1 = colok ? prm[104 + c] : 0.f;
        #pragma unroll
        for (int reg = 0; reg < 4; ++reg) {
            int r = 16*w + quad*4 + reg;
            int m = m0 + r;
            float xv = 0.f;
            if (colok && m < TN) {
                float p0 = acc0[ct][reg] + b0;
                float p1 = acc1[ct][reg] + b1;
                float hv = b2f(A0s[r*STR + c]);
                float a0 = b2f(A1s[r*STR + c]);
                float a1 = b2f(att1[(size_t)m*104 + c]);
                xv = 2.f*(hv + a0*p0 + 0.01f*a1*p1);
            }
            acc0[ct][reg] = xv;
            sum[reg] += xv;
        }
    }
    #pragma unroll
    for (int reg = 0; reg < 4; ++reg) {
        float v = sum[reg];
        v += __shfl_xor(v,1,64); v += __shfl_xor(v,2,64);
        v += __shfl_xor(v,4,64); v += __shfl_xor(v,8,64);
        sum[reg] = v * (1.f/104.f);                     // mean
    }
    float var[4] = {0.f,0.f,0.f,0.f};
    #pragma unroll
    for (int ct = 0; ct < 7; ++ct) {
        bool colok = (ct*16 + n16) < 104;
        #pragma unroll
        for (int reg = 0; reg < 4; ++reg) {
            if (colok) {
                float d = acc0[ct][reg] - sum[reg];
                acc0[ct][reg] = d;
                var[reg] += d*d;
            }
        }
    }
    #pragma unroll
    for (int reg = 0; reg < 4; ++reg) {
        float v = var[reg];
        v += __shfl_xor(v,1,64); v += __shfl_xor(v,2,64);
        v += __shfl_xor(v,4,64); v += __shfl_xor(v,8,64);
        var[reg] = rsqrtf(v * (1.f/104.f) + 1e-5f);
    }
    #pragma unroll
    for (int ct = 0; ct < 7; ++ct) {
        int c = ct*16 + n16;
        if (c < 104) {
            float g = prm[208 + c], be = prm[312 + c];
            #pragma unroll
            for (int reg = 0; reg < 4; ++reg) {
                int m = m0 + 16*w + quad*4 + reg;
                if (m < TN)
                    h[(size_t)m*104 + c] = f2b(acc0[ct][reg]*var[reg]*g + be);
            }
        }
    }
}

// ---------------- fused fc2 + LN2: h2 = LN(h1 + hidden@fc_w2 + b) ----------------
__global__ void __launch_bounds__(256) fc2_ln2(
    const bf16* __restrict__ hidden, const bf16* __restrict__ w2t, const float* __restrict__ b2,
    const bf16* __restrict__ h1, const float* __restrict__ gamma, const float* __restrict__ beta,
    bf16* __restrict__ h2)
{
    constexpr int STRA = 232;   // 224 + 8
    constexpr int STRW = 136;   // 128 + 8 (per half)
    __shared__ bf16 As[64*STRA];
    __shared__ bf16 Ws[112*STRW];
    __shared__ float prm[312];  // b2(104) | gamma(104) | beta(104)
    int m0 = blockIdx.x * 64;
    int tid = threadIdx.x;
    int lane = tid & 63, w = tid >> 6, n16 = lane & 15, quad = lane >> 4;
    uint4 z4 = {0u,0u,0u,0u};

    for (int idx = tid; idx < 64*28; idx += 256) {
        int r = idx / 28, q = idx - r*28;
        int m = m0 + r;
        uint4 v = z4;
        if (m < TN && q < 26) v = *(const uint4*)(hidden + (size_t)m*208 + q*8);
        *(uint4*)(&As[r*STRA + q*8]) = v;
    }
    for (int idx = tid; idx < 112*16; idx += 256) {
        int c = idx >> 4, q = idx & 15;
        uint4 v = z4;
        if (c < 104) v = *(const uint4*)(w2t + (size_t)c*224 + q*8);
        *(uint4*)(&Ws[c*STRW + q*8]) = v;
    }
    for (int i = tid; i < 312; i += 256)
        prm[i] = (i < 104) ? b2[i] : (i < 208 ? gamma[i-104] : beta[i-208]);
    __syncthreads();

    short8v af[7];
    #pragma unroll
    for (int s = 0; s < 7; ++s)
        af[s] = *(const short8v*)(&As[(16*w + n16)*STRA + s*32 + quad*8]);
    float4v acc[7];
    #pragma unroll
    for (int ct = 0; ct < 7; ++ct) { float4v z = {0.f,0.f,0.f,0.f}; acc[ct] = z; }
    #pragma unroll
    for (int ct = 0; ct < 7; ++ct)
        #pragma unroll
        for (int s = 0; s < 4; ++s) {
            short8v bfr = *(const short8v*)(&Ws[(ct*16 + n16)*STRW + s*32 + quad*8]);
            acc[ct] = __builtin_amdgcn_mfma_f32_16x16x32_bf16(af[s], bfr, acc[ct], 0, 0, 0);
        }
    __syncthreads();
    for (int idx = tid; idx < 112*16; idx += 256) {   // half 2: k 128..223 (12 data uint4)
        int c = idx >> 4, q = idx & 15;
        uint4 v = z4;
        if (c < 104 && q < 12) v = *(const uint4*)(w2t + (size_t)c*224 + 128 + q*8);
        *(uint4*)(&Ws[c*STRW + q*8]) = v;
    }
    __syncthreads();
    #pragma unroll
    for (int ct = 0; ct < 7; ++ct)
        #pragma unroll
        for (int s = 4; s < 7; ++s) {
            short8v bfr = *(const short8v*)(&Ws[(ct*16 + n16)*STRW + (s-4)*32 + quad*8]);
            acc[ct] = __builtin_amdgcn_mfma_f32_16x16x32_bf16(af[s], bfr, acc[ct], 0, 0, 0);
        }

    // epilogue: x = h1 + m  -> LN
    float sum[4] = {0.f,0.f,0.f,0.f};
    #pragma unroll
    for (int ct = 0; ct < 7; ++ct) {
        int c = ct*16 + n16;
        bool colok = c < 104;
        float bb = colok ? prm[c] : 0.f;
        #pragma unroll
        for (int reg = 0; reg < 4; ++reg) {
            int m = m0 + 16*w + quad*4 + reg;
            float xv = 0.f;
            if (colok && m < TN)
                xv = b2f(h1[(size_t)m*104 + c]) + acc[ct][reg] + bb;
            acc[ct][reg] = xv;
            sum[reg] += xv;
        }
    }
    #pragma unroll
    for (int reg = 0; reg < 4; ++reg) {
        float v = sum[reg];
        v += __shfl_xor(v,1,64); v += __shfl_xor(v,2,64);
        v += __shfl_xor(v,4,64); v += __shfl_xor(v,8,64);
        sum[reg] = v * (1.f/104.f);
    }
    float var[4] = {0.f,0.f,0.f,0.f};
    #pragma unroll
    for (int ct = 0; ct < 7; ++ct) {
        bool colok = (ct*16 + n16) < 104;
        #pragma unroll
        for (int reg = 0; reg < 4; ++reg) {
            if (colok) {
                float d = acc[ct][reg] - sum[reg];
                acc[ct][reg] = d;
                var[reg] += d*d;
            }
        }
    }
    #pragma unroll
    for (int reg = 0; reg < 4; ++reg) {
        float v = var[reg];
        v += __shfl_xor(v,1,64); v += __shfl_xor(v,2,64);
        v += __shfl_xor(v,4,64); v += __shfl_xor(v,8,64);
        var[reg] = rsqrtf(v * (1.f/104.f) + 1e-5f);
    }
    #pragma unroll
    for (int ct = 0; ct < 7; ++ct) {
        int c = ct*16 + n16;
        if (c < 104) {
            float g = prm[104 + c], be = prm[208 + c];
            #pragma unroll
            for (int reg = 0; reg < 4; ++reg) {
                int m = m0 + 16*w + quad*4 + reg;
                if (m < TN)
                    h2[(size_t)m*104 + c] = f2b(acc[ct][reg]*var[reg]*g + be);
            }
        }
    }
}

// ---------------- MFMA encoder_proj ----------------
__global__ void __launch_bounds__(256) ep_mf(
    const bf16* __restrict__ h2, const bf16* __restrict__ wt, float* __restrict__ y)
{
    constexpr int STR = 136;
    __shared__ bf16 As[64*STR];
    __shared__ bf16 Ws[64*STR];
    int m0 = blockIdx.x * 64;
    int c0 = blockIdx.y * 64;
    int t0 = blockIdx.z * 8;
    int t1 = min(TT, t0 + 8);
    int tid = threadIdx.x;
    int lane = tid & 63, w = tid >> 6, n16 = lane & 15, quad = lane >> 4;
    uint4 z4 = {0u,0u,0u,0u};

    float4v acc[4];
    #pragma unroll
    for (int ct = 0; ct < 4; ++ct) { float4v z = {0.f,0.f,0.f,0.f}; acc[ct] = z; }

    for (int t = t0; t < t1; ++t) {
        for (int idx = tid; idx < 64*16; idx += 256) {
            int r = idx >> 4, q = idx & 15;
            int m = m0 + r;
            uint4 va = z4;
            if (m < NN && q < 13) va = *(const uint4*)(h2 + ((size_t)t*NN + m)*104 + q*8);
            *(uint4*)(&As[r*STR + q*8]) = va;
            int c = c0 + r;
            uint4 vw = z4;
            if (c < 104 && q < 13) vw = *(const uint4*)(wt + (size_t)c*37960 + t*104 + q*8);
            *(uint4*)(&Ws[r*STR + q*8]) = vw;
        }
        __syncthreads();
        short8v af[4];
        #pragma unroll
        for (int s = 0; s < 4; ++s)
            af[s] = *(const short8v*)(&As[(16*w + n16)*STR + s*32 + quad*8]);
        #pragma unroll
        for (int ct = 0; ct < 4; ++ct) {
            #pragma unroll
            for (int s = 0; s < 4; ++s) {
                short8v bfr = *(const short8v*)(&Ws[(ct*16 + n16)*STR + s*32 + quad*8]);
                acc[ct] = __builtin_amdgcn_mfma_f32_16x16x32_bf16(af[s], bfr, acc[ct], 0, 0, 0);
            }
        }
        __syncthreads();
    }
    #pragma unroll
    for (int ct = 0; ct < 4; ++ct) {
        int c = c0 + ct*16 + n16;
        if (c < 104) {
            #pragma unroll
            for (int reg = 0; reg < 4; ++reg) {
                int m = m0 + 16*w + quad*4 + reg;
                if (m < NN) atomicAdd(&y[(size_t)m*104 + c], acc[ct][reg]);
            }
        }
    }
}

// ---------------- MFMA z1 (R5 structure, unchanged) ----------------
static constexpr int Z1_TQ = CEILDIV(TT, 8);          // 46
static constexpr int Z1_BLOCKS = 8 * Z1_TQ * 4;       // 1472
__global__ void __launch_bounds__(512, 4) z1_mf(
    const bf16* __restrict__ adp_bf, const bf16* __restrict__ hT, bf16* __restrict__ z1)
{
    constexpr int SA  = 104;   // Asq/Bt row stride (96 data + pad), 16B-aligned
    constexpr int SH  = 72;    // Hs row stride (64 data + pad)
    constexpr int SPP = 72;    // P  row stride (64 data + pad)
    __shared__ bf16 Asq[2][64*SA];   // 26624 B: per-slab q rows (persist)
    __shared__ bf16 Bt[64*SA];       // 13312 B: shared c-rows tile
    __shared__ bf16 Hs[128*SH];      // 18432 B: shared hT tile (rows 104..127 zero)
    __shared__ bf16 P[2][64*SPP];    // 18432 B: per-slab probabilities
    __shared__ float rsb[2][2][64];  //  2048 B

    int bid = blockIdx.x;
    int xcd = bid & 7;               // all blocks of one t share an XCD/L2
    int j = bid >> 3;
    int tq = j >> 2, pair = j & 3;
    int t = tq*8 + xcd;
    if (t >= TT) return;

    int tid = threadIdx.x;
    int lane = tid & 63, w = tid >> 6;            // 8 waves
    int slab = w >> 2, wsl = w & 3;
    int qi = wsl >> 1, ci = wsl & 1;
    int n32 = lane & 31, koct = lane >> 5;
    int r0 = (pair*2 + slab)*64;                  // up to 448; masked at write

    {
        const uint4* src = (const uint4*)(adp_bf + ((size_t)t*NN + pair*128)*96);
        #pragma unroll
        for (int i = 0; i < 3; ++i) {
            int idx = tid + i*512;                // < 1536
            int s2 = idx / 768, rem = idx - s2*768;
            int r = rem / 12, q = rem - r*12;
            *(uint4*)(&Asq[s2][r*SA + q*8]) = src[idx];
        }
    }
    {
        uint4 z4v = {0u,0u,0u,0u};
        for (int idx = tid; idx < 216; idx += 512) {
            int rr = idx / 9;
            int r = 104 + rr, q = idx - rr*9;
            *(uint4*)(&Hs[r*SH + q*8]) = z4v;
        }
    }

    float16v on0, on1;
    #pragma unroll
    for (int i = 0; i < 16; ++i) { on0[i] = 0.f; on1[i] = 0.f; }
    float rs2[16];
    #pragma unroll
    for (int i = 0; i < 16; ++i) rs2[i] = 0.f;

    const bf16* hbase = hT + (size_t)t*104*448;

    uint4 preB0, preB1, preH0, preH1;
    {
        const uint4* srcB = (const uint4*)(adp_bf + (size_t)t*NN*96);
        preB0 = srcB[tid];
        if (tid < 256) preB1 = srcB[tid + 512];
        { int r = tid >> 3, q = tid & 7;
          preH0 = *(const uint4*)(hbase + (size_t)r*448 + q*8); }
        if (tid < 320) { int idx = tid + 512; int r = idx >> 3, q = idx & 7;
          preH1 = *(const uint4*)(hbase + (size_t)r*448 + q*8); }
    }

    for (int c0 = 0; c0 < NN; c0 += 64) {
        { int r = tid / 12, q = tid - (tid/12)*12;
          *(uint4*)(&Bt[r*SA + q*8]) = preB0; }
        if (tid < 256) { int idx = tid + 512; int r = idx / 12, q = idx - r*12;
          *(uint4*)(&Bt[r*SA + q*8]) = preB1; }
        { int r = tid >> 3, q = tid & 7;
          *(uint4*)(&Hs[r*SH + q*8]) = preH0; }
        if (tid < 320) { int idx = tid + 512; int r = idx >> 3, q = idx & 7;
          *(uint4*)(&Hs[r*SH + q*8]) = preH1; }
        __syncthreads();                          // barA (covers Asq on iter 0)
        int cn = c0 + 64;
        if (cn < NN) {
            const uint4* srcB = (const uint4*)(adp_bf + ((size_t)t*NN + cn)*96);
            preB0 = srcB[tid];
            if (tid < 256) preB1 = srcB[tid + 512];
            { int r = tid >> 3, q = tid & 7;
              preH0 = *(const uint4*)(hbase + (size_t)r*448 + cn + q*8); }
            if (tid < 320) { int idx = tid + 512; int r = idx >> 3, q = idx & 7;
              preH1 = *(const uint4*)(hbase + (size_t)r*448 + cn + q*8); }
        }
        float16v sc;
        #pragma unroll
        for (int i = 0; i < 16; ++i) sc[i] = 0.f;
        #pragma unroll
        for (int s = 0; s < 6; ++s) {
            short8v afq = *(const short8v*)(&Asq[slab][(qi*32 + n32)*SA + s*16 + koct*8]);
            short8v bfr = *(const short8v*)(&Bt[(ci*32 + n32)*SA + s*16 + koct*8]);
            sc = __builtin_amdgcn_mfma_f32_32x32x16_bf16(afq, bfr, sc, 0, 0, 0);
        }
        bool colok = (c0 + ci*32 + n32) < NN;
        #pragma unroll
        for (int reg = 0; reg < 16; ++reg) {
            int crow = (reg & 3) + 8*(reg >> 2) + 4*koct;
            float e = colok ? __expf(fmaxf(sc[reg], 0.f)) : 0.f;
            rs2[reg] += e;
            P[slab][(qi*32 + crow)*SPP + ci*32 + n32] = f2b(e);
        }
        __syncthreads();                          // barB: P complete (cross-wave)
        short8v pA[4];
        #pragma unroll
        for (int s = 0; s < 4; ++s)
            pA[s] = *(const short8v*)(&P[slab][(qi*32 + n32)*SPP + s*16 + koct*8]);
        #pragma unroll
        for (int s = 0; s < 4; ++s) {
            short8v hb0 = *(const short8v*)(&Hs[(ci*32 + n32)*SH + s*16 + koct*8]);
            on0 = __builtin_amdgcn_mfma_f32_32x32x16_bf16(pA[s], hb0, on0, 0, 0, 0);
        }
        #pragma unroll
        for (int s = 0; s < 4; ++s) {
            short8v hb1 = *(const short8v*)(&Hs[((ci+2)*32 + n32)*SH + s*16 + koct*8]);
            on1 = __builtin_amdgcn_mfma_f32_32x32x16_bf16(pA[s], hb1, on1, 0, 0, 0);
        }
        __syncthreads();                          // barC: reads done before restage
    }

    #pragma unroll
    for (int reg = 0; reg < 16; ++reg) {
        float v = rs2[reg];
        v += __shfl_xor(v, 1, 64);
        v += __shfl_xor(v, 2, 64);
        v += __shfl_xor(v, 4, 64);
        v += __shfl_xor(v, 8, 64);
        v += __shfl_xor(v, 16, 64);
        if (n32 == 0) {
            int crow = (reg & 3) + 8*(reg >> 2) + 4*koct;
            rsb[slab][ci][qi*32 + crow] = v;
        }
    }
    __syncthreads();

    #pragma unroll
    for (int reg = 0; reg < 16; ++reg) {
        int crow = (reg & 3) + 8*(reg >> 2) + 4*koct;
        int qrow = qi*32 + crow;
        int gq = r0 + qrow;
        if (gq < NN) {
            float inv = 1.f / (rsb[slab][0][qrow] + rsb[slab][1][qrow]);
            int d0 = ci*32 + n32;
            z1[((size_t)t*NN + gq)*104 + d0] = f2b(on0[reg] * inv);
            int d1 = (ci + 2)*32 + n32;
            if (d1 < 104)
                z1[((size_t)t*NN + gq)*104 + d1] = f2b(on1[reg] * inv);
        }
    }
}

// ---------------- MFMA KV summaries (spatial + temporal) ----------------
__global__ void __launch_bounds__(256) kvs_mf(
    const bf16* __restrict__ qkv, bf16* __restrict__ kvsb_s, bf16* __restrict__ kvsb_t)
{
    constexpr int CK = 32;          // l-chunk
    constexpr int TS = 40;          // padded row stride
    __shared__ bf16 raw[CK][216];   // 208 used (k|v span, qkv cols 104..311)
    __shared__ bf16 kTn[4][32][TS]; // per-head kn^T tile (rows 26..31 unused)
    __shared__ bf16 vT [4][32][TS]; // per-head v^T tile + ones row 26
    __shared__ float invs[CK][4];

    int bb = blockIdx.x;
    bf16* out; int L; long long strideL, base;
    if (bb < TT) { out = kvsb_s + (size_t)bb*NTILE; L = NN; base = (long long)bb*NN*312 + 104; strideL = 312; }
    else { int n = bb - TT; out = kvsb_t + (size_t)n*NTILE; L = TT; base = (long long)n*312 + 104; strideL = (long long)NN*312; }

    int tid = threadIdx.x;
    int lane = tid & 63, w = tid >> 6;       // wave = head
    int n32 = lane & 31, koct = lane >> 5;
    uint4 z4 = {0u,0u,0u,0u};

    float16v acc;
    #pragma unroll
    for (int i = 0; i < 16; ++i) acc[i] = 0.f;

    uint4 pre[4];
    #pragma unroll
    for (int j = 0; j < 4; ++j) {
        int idx = tid + j*256;
        uint4 v = z4;
        if (idx < CK*26) {
            int r = idx / 26, q = idx - r*26;
            if (r < L) v = *(const uint4*)(qkv + base + (long long)r*strideL + q*8);
        }
        pre[j] = v;
    }

    for (int l0 = 0; l0 < L; l0 += CK) {
        int lw = min(CK, L - l0);
        __syncthreads();
        #pragma unroll
        for (int j = 0; j < 4; ++j) {
            int idx = tid + j*256;
            if (idx < CK*26) {
                int r = idx / 26, q = idx - r*26;
                *(uint4*)(&raw[r][q*8]) = pre[j];
            }
        }
        __syncthreads();
        {
            int ln0 = l0 + CK;
            #pragma unroll
            for (int j = 0; j < 4; ++j) {
                int idx = tid + j*256;
                uint4 v = z4;
                if (idx < CK*26 && ln0 < L) {
                    int r = idx / 26, q = idx - r*26;
                    if (r < L - ln0) v = *(const uint4*)(qkv + base + (long long)(ln0 + r)*strideL + q*8);
                }
                pre[j] = v;
            }
        }
        if (tid < CK*4) {
            int l = tid >> 2, h = tid & 3;
            float ss = 0.f;
            #pragma unroll
            for (int m = 0; m < HD; ++m) { float v = b2f(raw[l][h*HD + m]); ss += v*v; }
            invs[l][h] = (l < lw) ? 1.f/fmaxf(sqrtf(ss), 1e-12f) : 0.f;
        }
        __syncthreads();
        for (int idx = tid; idx < 4*CK*HD; idx += 256) {
            int h = idx / (CK*HD); int rem = idx - h*CK*HD;
            int l = rem / HD; int m = rem - l*HD;
            float iv = invs[l][h];
            kTn[h][m][l] = f2b(b2f(raw[l][h*HD + m]) * iv);
            vT[h][m][l]  = raw[l][104 + h*HD + m];
        }
        if (tid < 4*CK) {
            int h = tid >> 5, l = tid & 31;
            vT[h][26][l] = f2b((l < lw) ? 1.f : 0.f);
        }
        __syncthreads();
        #pragma unroll
        for (int s = 0; s < 2; ++s) {
            short8v a = *(const short8v*)(&kTn[w][n32][s*16 + koct*8]);
            short8v b = *(const short8v*)(&vT [w][n32][s*16 + koct*8]);
            acc = __builtin_amdgcn_mfma_f32_32x32x16_bf16(a, b, acc, 0, 0, 0);
        }
    }

    int lo = w*HD;
    #pragma unroll
    for (int reg = 0; reg < 16; ++reg) {
        int m = (reg & 3) + 8*(reg >> 2) + 4*koct;
        if (m < HD) {
            if (n32 < HD)       out[(size_t)(lo + n32)*32 + m] = f2b(acc[reg]);
            else if (n32 == HD) out[(size_t)(104 + w)*32 + m] = f2b(acc[reg]);
        }
    }
}

// ---------------- MFMA linear-attention apply (temporal only now) ----------------
__global__ void __launch_bounds__(256) attn_mm(
    bf16* __restrict__ qkv, const bf16* __restrict__ kvsb,
    int M, long long bStride, long long rowStride, float Lf, int outOff)
{
    constexpr int STR = 136;
    __shared__ bf16 As[64*STR];
    __shared__ bf16 Ws[112*STR];
    __shared__ float nsqL[64*4];
    __shared__ float denL[64*4];
    int mt = blockIdx.x, bb = blockIdx.y;
    int tid = threadIdx.x;
    int lane = tid & 63, w = tid >> 6, n16 = lane & 15, quad = lane >> 4;
    bf16* base = qkv + (size_t)bb * bStride;
    int r0 = mt*64;
    uint4 z4 = {0u,0u,0u,0u};

    for (int idx = tid; idx < 64*16; idx += 256) {
        int r = idx >> 4, q = idx & 15;
        int m = r0 + r;
        uint4 v = z4;
        if (m < M && q < 13) v = *(const uint4*)(base + (size_t)m*rowStride + q*8);
        *(uint4*)(&As[r*STR + q*8]) = v;
    }
    for (int idx = tid; idx < 112*16; idx += 256) {
        int c = idx >> 4, q = idx & 15;
        *(uint4*)(&Ws[c*STR + q*8]) = z4;
    }
    __syncthreads();
    {
        const bf16* kb = kvsb + (size_t)bb * NTILE;
        for (int idx = tid; idx < 108*13; idx += 256) {
            int c = idx / 13, qu = idx - c*13;
            int lo = (c < 104) ? (c/26)*26 : (c-104)*26;
            *(uint*)(&Ws[c*STR + lo + qu*2]) = *(const uint*)(kb + (size_t)c*32 + qu*2);
        }
    }
    __syncthreads();

    short8v af[4];
    #pragma unroll
    for (int s = 0; s < 4; ++s)
        af[s] = *(const short8v*)(&As[(16*w + n16)*STR + s*32 + quad*8]);
    float4v acc[7];
    #pragma unroll
    for (int ct = 0; ct < 7; ++ct) { float4v z = {0.f,0.f,0.f,0.f}; acc[ct] = z; }
    #pragma unroll
    for (int ct = 0; ct < 7; ++ct) {
        #pragma unroll
        for (int s = 0; s < 4; ++s) {
            short8v bfr = *(const short8v*)(&Ws[(ct*16 + n16)*STR + s*32 + quad*8]);
            acc[ct] = __builtin_amdgcn_mfma_f32_16x16x32_bf16(af[s], bfr, acc[ct], 0, 0, 0);
        }
    }
    {
        int row = tid >> 2, hh = tid & 3;
        const bf16* qr = &As[row*STR + hh*26];
        float ss = 0.f;
        #pragma unroll
        for (int m = 0; m < HD; ++m) { float v = b2f(qr[m]); ss += v*v; }
        nsqL[row*4 + hh] = ss;
    }
    if (n16 >= 8 && n16 < 12) {
        #pragma unroll
        for (int reg = 0; reg < 4; ++reg)
            denL[(16*w + quad*4 + reg)*4 + (n16 - 8)] = acc[6][reg];
    }
    __syncthreads();
    #pragma unroll
    for (int ct = 0; ct < 7; ++ct) {
        int c = ct*16 + n16;
        if (c < 104) {
            int hh = c / 26;
            #pragma unroll
            for (int reg = 0; reg < 4; ++reg) {
                int lr = 16*w + quad*4 + reg;
                int m = r0 + lr;
                if (m < M) {
                    float iq = 1.f / fmaxf(sqrtf(nsqL[lr*4 + hh]), 1e-12f);
                    float den = iq * denL[lr*4 + hh] + Lf;
                    bf16* rp = base + (size_t)m*rowStride;
                    float num = iq * acc[ct][reg] + Lf * b2f(rp[208 + c]);
                    rp[outOff + c] = f2b(num / den);
                }
            }
        }
    }
}

// ---------------- R8/R9: fused spatial attn + op projection ----------------
// R9: T14 register-prefetch of both op-W halves — half 1 issued at kernel
// entry (waitcnt lands at the epilogue commit, overlapping staging+attn),
// half 2 issued right after half 1's commit (overlaps the half-1 MFMAs).
// Removes the two fully-exposed W-restage stalls diagnosed in R8 (117us,
// MfmaUtil 4%, 2 blocks/CU latency-bound).
__global__ void __launch_bounds__(256) attn_op(
    const bf16* __restrict__ qkv, const bf16* __restrict__ kvsb,
    const bf16* __restrict__ wt, const float* __restrict__ bias,
    bf16* __restrict__ Cout, float Lf)
{
    constexpr int SA = 232;      // A stride: 208 data + 16 zero + 8 pad (16B-aligned)
    constexpr int SW = 136;
    __shared__ bf16 Acat[64*SA];     // 29696 B
    __shared__ bf16 Ws[112*SW];      // 30464 B (band, then op-W halves)
    __shared__ float nsqL[64*4];
    __shared__ float denL[64*4];
    int mt = blockIdx.x, t = blockIdx.y;
    int tid = threadIdx.x;
    int lane = tid & 63, w = tid >> 6, n16 = lane & 15, quad = lane >> 4;
    const bf16* base = qkv + (size_t)t * ((size_t)NN*312);
    int r0 = mt*64;
    uint4 z4 = {0u,0u,0u,0u};

    // T14: issue op-W half-1 loads NOW; consumed at the epilogue commit.
    uint4 preW[7];
    #pragma unroll
    for (int j = 0; j < 7; ++j) {
        int idx = tid + j*256;               // 112*16 = 1792 slots
        int c = idx >> 4, q = idx & 15;
        uint4 v = z4;
        if (c < 104) v = *(const uint4*)(wt + (size_t)c*224 + q*8);
        preW[j] = v;
    }

    // stage A rows: cols 0..207 = [q|out_t]; 208..231 zero
    for (int idx = tid; idx < 64*29; idx += 256) {
        int r = idx / 29, q = idx - r*29;
        int m = r0 + r;
        uint4 v = z4;
        if (m < NN && q < 26) v = *(const uint4*)(base + (size_t)m*312 + q*8);
        *(uint4*)(&Acat[r*SA + q*8]) = v;
    }
    // stage Ws: zero cols 0..127 then scatter kvs band
    for (int idx = tid; idx < 112*16; idx += 256) {
        int c = idx >> 4, q = idx & 15;
        *(uint4*)(&Ws[c*SW + q*8]) = z4;
    }
    __syncthreads();
    {
        const bf16* kb = kvsb + (size_t)t * NTILE;
        for (int idx = tid; idx < 108*13; idx += 256) {
            int c = idx / 13, qu = idx - c*13;
            int lo = (c < 104) ? (c/26)*26 : (c-104)*26;
            *(uint*)(&Ws[c*SW + lo + qu*2]) = *(const uint*)(kb + (size_t)c*32 + qu*2);
        }
    }
    __syncthreads();

    // ---- spatial attention ----
    short8v af[4];
    #pragma unroll
    for (int s = 0; s < 4; ++s)
        af[s] = *(const short8v*)(&Acat[(16*w + n16)*SA + s*32 + quad*8]);
    float4v acc[7];
    #pragma unroll
    for (int ct = 0; ct < 7; ++ct) { float4v z = {0.f,0.f,0.f,0.f}; acc[ct] = z; }
    #pragma unroll
    for (int ct = 0; ct < 7; ++ct) {
        #pragma unroll
        for (int s = 0; s < 4; ++s) {
            short8v bfr = *(const short8v*)(&Ws[(ct*16 + n16)*SW + s*32 + quad*8]);
            acc[ct] = __builtin_amdgcn_mfma_f32_16x16x32_bf16(af[s], bfr, acc[ct], 0, 0, 0);
        }
    }
    {
        int row = tid >> 2, hh = tid & 3;
        const bf16* qr = &Acat[row*SA + hh*26];
        float ss = 0.f;
        #pragma unroll
        for (int m = 0; m < HD; ++m) { float v = b2f(qr[m]); ss += v*v; }
        nsqL[row*4 + hh] = ss;
    }
    if (n16 >= 8 && n16 < 12) {
        #pragma unroll
        for (int reg = 0; reg < 4; ++reg)
            denL[(16*w + quad*4 + reg)*4 + (n16 - 8)] = acc[6][reg];
    }
    __syncthreads();      // attn reads of Ws/Acat(q) done; denL published

    // ---- epilogue: out_s -> Acat cols 0..103 ; commit preW1 ; issue preW2 ----
    #pragma unroll
    for (int ct = 0; ct < 7; ++ct) {
        int c = ct*16 + n16;
        if (c < 104) {
            int hh = c / 26;
            #pragma unroll
            for (int reg = 0; reg < 4; ++reg) {
                int lr = 16*w + quad*4 + reg;
                int m = r0 + lr;
                if (m < NN) {
                    float iq = 1.f / fmaxf(sqrtf(nsqL[lr*4 + hh]), 1e-12f);
                    float den = iq * denL[lr*4 + hh] + Lf;
                    const bf16* rp = base + (size_t)m*312;
                    float num = iq * acc[ct][reg] + Lf * b2f(rp[208 + c]);
                    Acat[lr*SA + c] = f2b(num / den);
                }
            }
        }
    }
    #pragma unroll
    for (int j = 0; j < 7; ++j) {        // commit half 1 (waitcnt for entry loads)
        int idx = tid + j*256;
        int c = idx >> 4, q = idx & 15;
        *(uint4*)(&Ws[c*SW + q*8]) = preW[j];
    }
    #pragma unroll
    for (int j = 0; j < 7; ++j) {        // issue half 2; overlaps half-1 MFMAs
        int idx = tid + j*256;
        int c = idx >> 4, q = idx & 15;
        uint4 v = z4;
        if (c < 104 && q < 12) v = *(const uint4*)(wt + (size_t)c*224 + 128 + q*8);
        preW[j] = v;
    }
    __syncthreads();

    // ---- op projection: C = Acat(64x208) @ W(208x104) + bias ----
    short8v af2[7];
    #pragma unroll
    for (int s = 0; s < 7; ++s)
        af2[s] = *(const short8v*)(&Acat[(16*w + n16)*SA + s*32 + quad*8]);
    float4v acc2[7];
    #pragma unroll
    for (int ct = 0; ct < 7; ++ct) { float4v z = {0.f,0.f,0.f,0.f}; acc2[ct] = z; }
    #pragma unroll
    for (int ct = 0; ct < 7; ++ct)
        #pragma unroll
        for (int s = 0; s < 4; ++s) {
            short8v bfr = *(const short8v*)(&Ws[(ct*16 + n16)*SW + s*32 + quad*8]);
            acc2[ct] = __builtin_amdgcn_mfma_f32_16x16x32_bf16(af2[s], bfr, acc2[ct], 0, 0, 0);
        }
    __syncthreads();
    #pragma unroll
    for (int j = 0; j < 7; ++j) {        // commit half 2
        int idx = tid + j*256;
        int c = idx >> 4, q = idx & 15;
        *(uint4*)(&Ws[c*SW + q*8]) = preW[j];
    }
    __syncthreads();
    #pragma unroll
    for (int ct = 0; ct < 7; ++ct)
        #pragma unroll
        for (int s = 4; s < 7; ++s) {
            short8v bfr = *(const short8v*)(&Ws[(ct*16 + n16)*SW + (s-4)*32 + quad*8]);
            acc2[ct] = __builtin_amdgcn_mfma_f32_16x16x32_bf16(af2[s], bfr, acc2[ct], 0, 0, 0);
        }

    #pragma unroll
    for (int ct = 0; ct < 7; ++ct) {
        int c = ct*16 + n16;
        if (c < 104) {
            float b = bias[c];
            #pragma unroll
            for (int reg = 0; reg < 4; ++reg) {
                int m = r0 + 16*w + quad*4 + reg;
                if (m < NN)
                    Cout[((size_t)t*NN + m)*104 + c] = f2b(acc2[ct][reg] + b);
            }
        }
    }
}

__global__ void __launch_bounds__(256) y_init_kernel(float* __restrict__ y, const float* __restrict__ ep_b) {
    int i = blockIdx.x*256 + threadIdx.x;
    if (i < NN*104) y[i] = ep_b[i % 104];
}

// ---------------- fused tail: 2 rows/block, ILP on the dot chains ----------------
__global__ void __launch_bounds__(256) tail_kernel(
    const float* __restrict__ y,
    const float* __restrict__ ew1, const float* __restrict__ eb1,
    const float* __restrict__ ew2, const float* __restrict__ eb2,
    const float* __restrict__ out_w, const float* __restrict__ out_b,
    float* __restrict__ out)
{
    int n0 = blockIdx.x * 2;               // 200 blocks x 2 rows
    int tid = threadIdx.x;
    __shared__ float yr[2][104], hid[2][208];
    if (tid < 104) {
        yr[0][tid] = y[(size_t)n0*104 + tid];
        yr[1][tid] = y[(size_t)(n0+1)*104 + tid];
    }
    __syncthreads();
    for (int i = 0; i < 3; ++i) {
        const float* w1 = ew1 + (size_t)i*104*208;
        const float* b1 = eb1 + (size_t)i*208;
        const float* w2 = ew2 + (size_t)i*208*104;
        const float* b2 = eb2 + (size_t)i*104;
        if (tid < 208) {
            float a0 = b1[tid], a1 = a0;
            #pragma unroll 8
            for (int k = 0; k < 104; ++k) {
                float w = w1[(size_t)k*208 + tid];
                a0 += yr[0][k]*w; a1 += yr[1][k]*w;
            }
            hid[0][tid] = fmaxf(a0, 0.f);
            hid[1][tid] = fmaxf(a1, 0.f);
        }
        __syncthreads();
        float y0 = 0.f, y1 = 0.f;
        if (tid < 104) {
            float a0 = b2[tid], a1 = a0;
            #pragma unroll 8
            for (int k = 0; k < 208; ++k) {
                float w = w2[(size_t)k*104 + tid];
                a0 += hid[0][k]*w; a1 += hid[1][k]*w;
            }
            y0 = yr[0][tid] + a0; y1 = yr[1][tid] + a1;
        }
        __syncthreads();
        if (tid < 104) { yr[0][tid] = y0; yr[1][tid] = y1; }
        __syncthreads();
    }
    for (int t = tid; t < TT; t += 256) {
        float a0 = out_b[t], a1 = a0;
        #pragma unroll 8
        for (int d = 0; d < 104; ++d) {
            float w = out_w[(size_t)d*TT + t];
            a0 += yr[0][d]*w; a1 += yr[1][d]*w;
        }
        out[(size_t)n0*TT + t] = a0;
        out[(size_t)(n0+1)*TT + t] = a1;
    }
}

// ---------------- launch ----------------
extern "C" void kernel_launch(void* const* d_in, const int* in_sizes, int n_in,
                              void* d_out, int out_size, void* d_ws, size_t ws_size,
                              hipStream_t stream) {
    if (ws_size < WS_NEEDED) return;

    const float* x      = (const float*)d_in[0];
    const float* W_in   = (const float*)d_in[1];
    const float* b_in   = (const float*)d_in[2];
    const float* adp    = (const float*)d_in[3];
    const float* W_tp   = (const float*)d_in[4];
    const float* b_tp   = (const float*)d_in[5];
    const float* qkv_w  = (const float*)d_in[6];
    const float* op_w   = (const float*)d_in[7];
    const float* op_b   = (const float*)d_in[8];
    const float* pw_w   = (const float*)d_in[9];
    const float* pw_b   = (const float*)d_in[10];
    const float* fc_w1  = (const float*)d_in[11];
    const float* fc_b1  = (const float*)d_in[12];
    const float* fc_w2  = (const float*)d_in[13];
    const float* fc_b2  = (const float*)d_in[14];
    const float* ln1_g  = (const float*)d_in[15];
    const float* ln1_b  = (const float*)d_in[16];
    const float* ln2_g  = (const float*)d_in[17];
    const float* ln2_b  = (const float*)d_in[18];
    const float* ep_w   = (const float*)d_in[19];
    const float* ep_b   = (const float*)d_in[20];
    const float* enc_w1 = (const float*)d_in[21];
    const float* enc_b1 = (const float*)d_in[22];
    const float* enc_w2 = (const float*)d_in[23];
    const float* enc_b2 = (const float*)d_in[24];
    const float* out_w  = (const float*)d_in[25];
    const float* out_b  = (const float*)d_in[26];

    bf16* B0 = (bf16*)d_ws;
    bf16* B1 = B0 + NB0;
    bf16* B2 = B1 + NB1;
    bf16* B3 = B2 + NB2;
    bf16* kvsb_s = B3 + NB3;
    bf16* kvsb_t = kvsb_s + NKVSB_S;
    float* ybuf  = (float*)(kvsb_t + NKVSB_T);
    bf16* wtp   = (bf16*)(ybuf + NY);
    bf16* wqkv0 = wtp + NW_TP;
    bf16* wqkv1 = wqkv0 + NW_QKV;
    bf16* wop0  = wqkv1 + NW_QKV;
    bf16* wop1  = wop0 + NW_OP;
    bf16* wpw0  = wop1 + NW_OP;
    bf16* wpw1  = wpw0 + NW_PW;
    bf16* wfc1  = wpw1 + NW_PW;
    bf16* wfc2  = wfc1 + NW_FC1;
    bf16* wept  = wfc2 + NW_FC2;
    bf16* adp_bf = B2;
    bf16* hTbuf  = B2 + NADP;

    // 0. weight prep
    prep_w<<<CEILDIV(104*128,256), 256, 0, stream>>>(W_tp, wtp, 104, 104, 128);
    prep_w<<<CEILDIV(312*128,256), 256, 0, stream>>>(qkv_w, wqkv0, 104, 312, 128);
    prep_w<<<CEILDIV(312*128,256), 256, 0, stream>>>(qkv_w + 104*312, wqkv1, 104, 312, 128);
    prep_w<<<CEILDIV(104*224,256), 256, 0, stream>>>(op_w, wop0, 208, 104, 224);
    prep_w<<<CEILDIV(104*224,256), 256, 0, stream>>>(op_w + 208*104, wop1, 208, 104, 224);
    prep_w<<<CEILDIV(104*128,256), 256, 0, stream>>>(pw_w, wpw0, 104, 104, 128);
    prep_w<<<CEILDIV(104*128,256), 256, 0, stream>>>(pw_w + 104*104, wpw1, 104, 104, 128);
    prep_w<<<CEILDIV(208*128,256), 256, 0, stream>>>(fc_w1, wfc1, 104, 208, 128);
    prep_w<<<CEILDIV(104*224,256), 256, 0, stream>>>(fc_w2, wfc2, 208, 104, 224);
    prep_wT<<<CEILDIV(37960,64), 256, 0, stream>>>(ep_w, wept);

    const int GX = CEILDIV(TN, 64);     // 2282

    // 1. hcat -> B2
    hcat_kernel<<<CEILDIV(TN,16), 256, 0, stream>>>(x, W_in, b_in, adp, B2);
    // 2. h = hcat @ W_tp + b_tp -> B0
    gemm_mf<128><<<GX*2, 256, 0, stream>>>(B2, 104, 104, wtp, b_tp, B0, TN, 104, 0);
    // 2b. z1 pre-staging into B2
    prep_adp<<<CEILDIV((int)NADP,256), 256, 0, stream>>>(adp, adp_bf);
    ht_kernel<<<dim3(7, TT), 256, 0, stream>>>(B0, hTbuf);
    // 3. z1 -> B1
    z1_mf<<<Z1_BLOCKS, 512, 0, stream>>>(adp_bf, hTbuf, B1);
    // 4. attention 0 on h
    gemm_mf<128><<<GX*5, 256, 0, stream>>>(B0, 104, 104, wqkv0, nullptr, B2, TN, 312, 0);
    kvs_mf<<<TT+NN, 256, 0, stream>>>(B2, kvsb_s, kvsb_t);
    attn_mm<<<dim3(6, NN), 256, 0, stream>>>(B2, kvsb_t, TT, 312, (long long)NN*312, (float)TT, 104);
    attn_op<<<dim3(7, TT), 256, 0, stream>>>(B2, kvsb_s, wop0, op_b, B3, (float)NN);   // att0 -> B3
    // 5. attention 1 on z1
    gemm_mf<128><<<GX*5, 256, 0, stream>>>(B1, 104, 104, wqkv1, nullptr, B2, TN, 312, 0);
    kvs_mf<<<TT+NN, 256, 0, stream>>>(B2, kvsb_s, kvsb_t);
    attn_mm<<<dim3(6, NN), 256, 0, stream>>>(B2, kvsb_t, TT, 312, (long long)NN*312, (float)TT, 104);
    attn_op<<<dim3(7, TT), 256, 0, stream>>>(B2, kvsb_s, wop1, op_b + 104, B1, (float)NN); // att1 -> B1
    // 6+7. fused gates + LN1 (in-place B0 -> h1)
    gate_ln1<<<GX, 256, 0, stream>>>(B0, B3, B1, wpw0, wpw1, pw_b, ln1_g, ln1_b);
    // 8. MLP: fc1 -> hidden (B2), fused fc2+LN2 -> h2 (B3)
    gemm_mf<128><<<GX*4, 256, 0, stream>>>(B0, 104, 104, wfc1, fc_b1, B2, TN, 208, 1);
    fc2_ln2<<<GX, 256, 0, stream>>>(B2, wfc2, fc_b2, B0, ln2_g, ln2_b, B3);
    // 9. encoder_proj
    y_init_kernel<<<CEILDIV(NN*104,256), 256, 0, stream>>>(ybuf, ep_b);
    ep_mf<<<dim3(CEILDIV(NN,64), 2, CEILDIV(TT,8)), 256, 0, stream>>>(B3, wept, ybuf);
    // 10+11. fused residual MLP blocks + output projection (2 rows/block)
    tail_kernel<<<NN/2, 256, 0, stream>>>(ybuf, enc_w1, enc_b1, enc_w2, enc_b2,
                                          out_w, out_b, (float*)d_out);
}

// Round 10
// 1181.364 us; speedup vs baseline: 1.1534x; 1.0158x over previous
//
#include <hip/hip_runtime.h>
#include <hip/hip_bf16.h>
#include <cstddef>

// ---------------- problem constants ----------------
#define TT   365
#define NN   400
#define TN   (TT*NN)            // 146000
#define HD   26                 // head dim
#define NH   4                  // heads

#define CEILDIV(a,b) (((a)+(b)-1)/(b))

typedef __hip_bfloat16 bf16;
typedef short short8v __attribute__((ext_vector_type(8)));
typedef float float4v __attribute__((ext_vector_type(4)));
typedef float float16v __attribute__((ext_vector_type(16)));
__device__ __forceinline__ float b2f(bf16 v){ return __bfloat162float(v); }
__device__ __forceinline__ bf16  f2b(float v){ return __float2bfloat16(v); }

// ---------------- workspace layout ----------------
static constexpr size_t NB0 = (size_t)TN*104;   // h / h1
static constexpr size_t NB1 = (size_t)TN*104;   // z1 -> att1
static constexpr size_t NB2 = (size_t)TN*312;   // hcat -> [adp_bf|hT] -> qkv+concat -> hidden
static constexpr size_t NB3 = (size_t)TN*104;   // att0 -> h2
static constexpr size_t NBF = NB0+NB1+NB2+NB3;
// compact band KV tiles: per b, 108 rows x 32 (band cols 0..25), bf16
static constexpr size_t NTILE   = (size_t)108*32;
static constexpr size_t NKVSB_S = (size_t)TT*NTILE;
static constexpr size_t NKVSB_T = (size_t)NN*NTILE;
static constexpr size_t NY      = (size_t)NN*104;
// transposed bf16 weights (Wt[n][kp], zero-padded k)
static constexpr size_t NW_TP   = 104*128;
static constexpr size_t NW_QKV  = 312*128;   // x2
static constexpr size_t NW_OP   = 104*224;   // x2
static constexpr size_t NW_PW   = 104*128;   // x2
static constexpr size_t NW_FC1  = 208*128;
static constexpr size_t NW_FC2  = 104*224;
static constexpr size_t NW_EPT  = (size_t)104*37960;   // ep_w transposed, no pad
static constexpr size_t NWT     = NW_TP + 2*NW_QKV + 2*NW_OP + 2*NW_PW + NW_FC1 + NW_FC2 + NW_EPT;
static constexpr size_t WS_NEEDED = NBF*2 + (NKVSB_S+NKVSB_T)*2 + NY*4 + NWT*2;
// z1 scratch lives inside B2 (dead between step 2 and step 4):
static constexpr size_t NADP_ROWS = (size_t)TN + 64;
static constexpr size_t NADP = NADP_ROWS*96;
static constexpr size_t NHT  = ((size_t)TT*104 + 8)*448;
static_assert(NADP + NHT <= NB2, "z1 scratch must fit in B2");

// ---------------- weight prep: Wt[n*KP+k] = bf16(W[k*Nc+n]), zero pad k>=K ----------------
__global__ void __launch_bounds__(256) prep_w(
    const float* __restrict__ W, bf16* __restrict__ Wt, int K, int Nc, int KP)
{
    int idx = blockIdx.x*256 + threadIdx.x;
    if (idx >= Nc*KP) return;
    int n = idx / KP, k = idx - n*KP;
    Wt[idx] = (k < K) ? f2b(W[(size_t)k*Nc + n]) : f2b(0.f);
}

// coalesced LDS transpose for ep weights: Wt[n][k] = bf16(W[k][n]); W is 37960x104 fp32
__global__ void __launch_bounds__(256) prep_wT(
    const float* __restrict__ W, bf16* __restrict__ Wt)
{
    __shared__ float T[64][105];
    int k0 = blockIdx.x * 64;
    int tid = threadIdx.x;
    for (int idx = tid; idx < 64*104; idx += 256) {
        int r = idx / 104, c = idx - r*104;
        int k = k0 + r;
        T[r][c] = (k < 37960) ? W[(size_t)k*104 + c] : 0.f;
    }
    __syncthreads();
    for (int idx = tid; idx < 104*32; idx += 256) {
        int n = idx >> 5, kp = idx & 31;
        int k = kp*2;
        if (k0 + k + 1 < 37960 || k0 + k < 37960) {
            if (k0 + k < 37960) {
                bf16 lo = f2b(T[k][n]);
                bf16 hi = f2b(T[k+1][n]);   // k+1 row is zero-padded if OOB of tile data
                uint v = ((uint)(*(ushort*)&hi) << 16) | (*(ushort*)&lo);
                if (k0 + k + 1 < 37960) *(uint*)(Wt + (size_t)n*37960 + k0 + k) = v;
                else Wt[(size_t)n*37960 + k0 + k] = lo;
            }
        }
    }
}

// adp_bf[row][e] = bf16(adp[row][e]) for e<80 else 0; rows >= TN are zero.
__global__ void __launch_bounds__(256) prep_adp(
    const float* __restrict__ adp, bf16* __restrict__ out)
{
    size_t i = (size_t)blockIdx.x*256 + threadIdx.x;
    if (i >= NADP) return;
    size_t row = i / 96; int e = (int)(i - row*96);
    float v = (row < TN && e < 80) ? adp[row*80 + e] : 0.f;
    out[i] = f2b(v);
}

// hT[t][d][n] = h[t][n][d], n padded to 448 with zeros
__global__ void __launch_bounds__(256) ht_kernel(
    const bf16* __restrict__ h, bf16* __restrict__ hT)
{
    __shared__ bf16 As[64*106];
    int t = blockIdx.y, n0 = blockIdx.x*64;
    int tid = threadIdx.x;
    for (int idx = tid; idx < 64*52; idx += 256) {
        int r = idx / 52, k = idx - r*52;
        int n = n0 + r;
        uint v = 0;
        if (n < NN) v = *(const uint*)(h + ((size_t)t*NN + n)*104 + k*2);
        *(uint*)(&As[r*106 + k*2]) = v;
    }
    __syncthreads();
    for (int idx = tid; idx < 104*32; idx += 256) {
        int d = idx >> 5, np = idx & 31;
        int n = np*2;
        ushort lo = *(ushort*)&As[n*106 + d];
        ushort hi = *(ushort*)&As[(n+1)*106 + d];
        uint v = ((uint)hi << 16) | lo;
        *(uint*)(hT + ((size_t)t*104 + d)*448 + n0 + n) = v;
    }
}

// ---------------- hcat (16 rows/block, LDS-staged uint4 row writes) ----------------
__global__ void __launch_bounds__(256) hcat_kernel(
    const float* __restrict__ x, const float* __restrict__ W_in,
    const float* __restrict__ b_in, const float* __restrict__ adp,
    bf16* __restrict__ hcat)
{
    __shared__ bf16 T[16][112];          // 104 used; 224B row stride (16B-aligned)
    int r0 = blockIdx.x * 16;
    int tid = threadIdx.x;
    // proj cols 0..23
    for (int idx = tid; idx < 16*24; idx += 256) {
        int r = idx / 24, c = idx - r*24;
        int row = r0 + r;
        int t = row / NN, n = row - t*NN;
        size_t xb = ((size_t)n*TT + t)*3;
        float s = b_in[c] + x[xb]*W_in[c] + x[xb+1]*W_in[24+c] + x[xb+2]*W_in[48+c];
        T[r][c] = f2b(s);
    }
    // adp cols 24..103 (coalesced f32 reads)
    for (int idx = tid; idx < 16*80; idx += 256) {
        int r = idx / 80, e = idx - r*80;
        T[r][24+e] = f2b(adp[(size_t)(r0+r)*80 + e]);
    }
    __syncthreads();
    for (int idx = tid; idx < 16*13; idx += 256) {
        int r = idx / 13, q = idx - r*13;
        *(uint4*)(hcat + ((size_t)(r0+r))*104 + q*8) = *(const uint4*)(&T[r][q*8]);
    }
}

// ---------------- MFMA GEMM 64-tile ----------------
// 1-D grid with bijective XCD grouping (m204): column-tiles of one row-slab
// land adjacent on the SAME XCD so the A-slab is fetched from HBM once.
template<int KP>
__global__ void __launch_bounds__(256) gemm_mf(
    const bf16* __restrict__ A, int lda, int K,
    const bf16* __restrict__ Wt, const float* __restrict__ bias,
    bf16* __restrict__ C, int M, int Nc, int relu)
{
    constexpr int STR = KP + 8;
    constexpr int KPQ = KP/8;
    __shared__ bf16 As[64*STR];
    __shared__ bf16 Ws[64*STR];
    int nCol = (Nc + 63) >> 6;
    int nwg = gridDim.x;
    int bid = blockIdx.x;
    int xcd = bid & 7, kk = bid >> 3;
    int q8 = nwg >> 3, r8 = nwg & 7;
    int widx = (xcd < r8 ? xcd*(q8+1) : r8*(q8+1) + (xcd - r8)*q8) + kk;
    int mblk = widx / nCol;
    int m0 = mblk * 64;
    int c0 = (widx - mblk*nCol) * 64;
    int tid = threadIdx.x;
    const int KQ = K/8;
    uint4 z4 = {0u,0u,0u,0u};
    for (int idx = tid; idx < 64*KPQ; idx += 256) {
        int r = idx / KPQ, q = idx - r*KPQ;
        int m = m0 + r;
        uint4 v = z4;
        if (m < M && q < KQ) v = *(const uint4*)(A + (size_t)m*lda + q*8);
        *(uint4*)(&As[r*STR + q*8]) = v;
    }
    for (int idx = tid; idx < 64*KPQ; idx += 256) {
        int r = idx / KPQ, q = idx - r*KPQ;
        int n = c0 + r;
        uint4 v = z4;
        if (n < Nc) v = *(const uint4*)(Wt + (size_t)n*KP + q*8);
        *(uint4*)(&Ws[r*STR + q*8]) = v;
    }
    __syncthreads();

    int lane = tid & 63, w = tid >> 6;
    int n16 = lane & 15, quad = lane >> 4;
    constexpr int KS = KP/32;
    short8v af[KS];
    #pragma unroll
    for (int s = 0; s < KS; ++s)
        af[s] = *(const short8v*)(&As[(16*w + n16)*STR + s*32 + quad*8]);
    float4v acc[4];
    #pragma unroll
    for (int ct = 0; ct < 4; ++ct) { float4v z = {0.f,0.f,0.f,0.f}; acc[ct] = z; }
    #pragma unroll
    for (int ct = 0; ct < 4; ++ct) {
        #pragma unroll
        for (int s = 0; s < KS; ++s) {
            short8v bfr = *(const short8v*)(&Ws[(ct*16 + n16)*STR + s*32 + quad*8]);
            acc[ct] = __builtin_amdgcn_mfma_f32_16x16x32_bf16(af[s], bfr, acc[ct], 0, 0, 0);
        }
    }
    #pragma unroll
    for (int ct = 0; ct < 4; ++ct) {
        int c = c0 + ct*16 + n16;
        if (c < Nc) {
            float b = bias ? bias[c] : 0.f;
            #pragma unroll
            for (int reg = 0; reg < 4; ++reg) {
                int m = m0 + 16*w + quad*4 + reg;
                if (m < M) {
                    float v = acc[ct][reg] + b;
                    if (relu) v = fmaxf(v, 0.f);
                    C[(size_t)m*Nc + c] = f2b(v);
                }
            }
        }
    }
}

// ---------------- fused gates + LN1 ----------------
// h1 = LN(2*(h + att0*(h@pw0+b0) + 0.01*att1*(att0@pw1+b1))) in-place into h.
__global__ void __launch_bounds__(256) gate_ln1(
    bf16* __restrict__ h, const bf16* __restrict__ att0, const bf16* __restrict__ att1,
    const bf16* __restrict__ w0t, const bf16* __restrict__ w1t, const float* __restrict__ pwb,
    const float* __restrict__ gamma, const float* __restrict__ beta)
{
    constexpr int STR = 136;
    __shared__ bf16 A0s[64*STR];
    __shared__ bf16 A1s[64*STR];
    __shared__ bf16 Ws[112*STR];
    __shared__ float prm[416];     // pwb(208) | gamma(104) | beta(104)
    int m0 = blockIdx.x * 64;
    int tid = threadIdx.x;
    int lane = tid & 63, w = tid >> 6, n16 = lane & 15, quad = lane >> 4;
    uint4 z4 = {0u,0u,0u,0u};

    for (int idx = tid; idx < 64*16; idx += 256) {
        int r = idx >> 4, q = idx & 15;
        int m = m0 + r;
        uint4 v0 = z4, v1 = z4;
        if (m < TN && q < 13) {
            v0 = *(const uint4*)(h    + (size_t)m*104 + q*8);
            v1 = *(const uint4*)(att0 + (size_t)m*104 + q*8);
        }
        *(uint4*)(&A0s[r*STR + q*8]) = v0;
        *(uint4*)(&A1s[r*STR + q*8]) = v1;
    }
    for (int idx = tid; idx < 112*16; idx += 256) {
        int c = idx >> 4, q = idx & 15;
        uint4 v = z4;
        if (c < 104) v = *(const uint4*)(w0t + (size_t)c*128 + q*8);
        *(uint4*)(&Ws[c*STR + q*8]) = v;
    }
    for (int i = tid; i < 416; i += 256)
        prm[i] = (i < 208) ? pwb[i] : (i < 312 ? gamma[i-208] : beta[i-312]);
    __syncthreads();

    short8v a0f[4], a1f[4];
    #pragma unroll
    for (int s = 0; s < 4; ++s) {
        a0f[s] = *(const short8v*)(&A0s[(16*w + n16)*STR + s*32 + quad*8]);
        a1f[s] = *(const short8v*)(&A1s[(16*w + n16)*STR + s*32 + quad*8]);
    }
    float4v acc0[7], acc1[7];
    #pragma unroll
    for (int ct = 0; ct < 7; ++ct) { float4v z = {0.f,0.f,0.f,0.f}; acc0[ct] = z; acc1[ct] = z; }
    #pragma unroll
    for (int ct = 0; ct < 7; ++ct)
        #pragma unroll
        for (int s = 0; s < 4; ++s) {
            short8v bfr = *(const short8v*)(&Ws[(ct*16 + n16)*STR + s*32 + quad*8]);
            acc0[ct] = __builtin_amdgcn_mfma_f32_16x16x32_bf16(a0f[s], bfr, acc0[ct], 0, 0, 0);
        }
    __syncthreads();
    for (int idx = tid; idx < 112*16; idx += 256) {
        int c = idx >> 4, q = idx & 15;
        uint4 v = z4;
        if (c < 104) v = *(const uint4*)(w1t + (size_t)c*128 + q*8);
        *(uint4*)(&Ws[c*STR + q*8]) = v;
    }
    __syncthreads();
    #pragma unroll
    for (int ct = 0; ct < 7; ++ct)
        #pragma unroll
        for (int s = 0; s < 4; ++s) {
            short8v bfr = *(const short8v*)(&Ws[(ct*16 + n16)*STR + s*32 + quad*8]);
            acc1[ct] = __builtin_amdgcn_mfma_f32_16x16x32_bf16(a1f[s], bfr, acc1[ct], 0, 0, 0);
        }

    // epilogue: g -> LN (row distributed across the 16 n16 lanes)
    float sum[4] = {0.f,0.f,0.f,0.f};
    #pragma unroll
    for (int ct = 0; ct < 7; ++ct) {
        int c = ct*16 + n16;
        bool colok = c < 104;
        float b0 = colok ? prm[c] : 0.f;
        float b1 = colok ? prm[104 + c] : 0.f;
        #pragma unroll
        for (int reg = 0; reg < 4; ++reg) {
            int r = 16*w + quad*4 + reg;
            int m = m0 + r;
            float xv = 0.f;
            if (colok && m < TN) {
                float p0 = acc0[ct][reg] + b0;
                float p1 = acc1[ct][reg] + b1;
                float hv = b2f(A0s[r*STR + c]);
                float a0 = b2f(A1s[r*STR + c]);
                float a1 = b2f(att1[(size_t)m*104 + c]);
                xv = 2.f*(hv + a0*p0 + 0.01f*a1*p1);
            }
            acc0[ct][reg] = xv;
            sum[reg] += xv;
        }
    }
    #pragma unroll
    for (int reg = 0; reg < 4; ++reg) {
        float v = sum[reg];
        v += __shfl_xor(v,1,64); v += __shfl_xor(v,2,64);
        v += __shfl_xor(v,4,64); v += __shfl_xor(v,8,64);
        sum[reg] = v * (1.f/104.f);                     // mean
    }
    float var[4] = {0.f,0.f,0.f,0.f};
    #pragma unroll
    for (int ct = 0; ct < 7; ++ct) {
        bool colok = (ct*16 + n16) < 104;
        #pragma unroll
        for (int reg = 0; reg < 4; ++reg) {
            if (colok) {
                float d = acc0[ct][reg] - sum[reg];
                acc0[ct][reg] = d;
                var[reg] += d*d;
            }
        }
    }
    #pragma unroll
    for (int reg = 0; reg < 4; ++reg) {
        float v = var[reg];
        v += __shfl_xor(v,1,64); v += __shfl_xor(v,2,64);
        v += __shfl_xor(v,4,64); v += __shfl_xor(v,8,64);
        var[reg] = rsqrtf(v * (1.f/104.f) + 1e-5f);
    }
    #pragma unroll
    for (int ct = 0; ct < 7; ++ct) {
        int c = ct*16 + n16;
        if (c < 104) {
            float g = prm[208 + c], be = prm[312 + c];
            #pragma unroll
            for (int reg = 0; reg < 4; ++reg) {
                int m = m0 + 16*w + quad*4 + reg;
                if (m < TN)
                    h[(size_t)m*104 + c] = f2b(acc0[ct][reg]*var[reg]*g + be);
            }
        }
    }
}

// ---------------- fused fc2 + LN2: h2 = LN(h1 + hidden@fc_w2 + b) ----------------
__global__ void __launch_bounds__(256) fc2_ln2(
    const bf16* __restrict__ hidden, const bf16* __restrict__ w2t, const float* __restrict__ b2,
    const bf16* __restrict__ h1, const float* __restrict__ gamma, const float* __restrict__ beta,
    bf16* __restrict__ h2)
{
    constexpr int STRA = 232;   // 224 + 8
    constexpr int STRW = 136;   // 128 + 8 (per half)
    __shared__ bf16 As[64*STRA];
    __shared__ bf16 Ws[112*STRW];
    __shared__ float prm[312];  // b2(104) | gamma(104) | beta(104)
    int m0 = blockIdx.x * 64;
    int tid = threadIdx.x;
    int lane = tid & 63, w = tid >> 6, n16 = lane & 15, quad = lane >> 4;
    uint4 z4 = {0u,0u,0u,0u};

    for (int idx = tid; idx < 64*28; idx += 256) {
        int r = idx / 28, q = idx - r*28;
        int m = m0 + r;
        uint4 v = z4;
        if (m < TN && q < 26) v = *(const uint4*)(hidden + (size_t)m*208 + q*8);
        *(uint4*)(&As[r*STRA + q*8]) = v;
    }
    for (int idx = tid; idx < 112*16; idx += 256) {
        int c = idx >> 4, q = idx & 15;
        uint4 v = z4;
        if (c < 104) v = *(const uint4*)(w2t + (size_t)c*224 + q*8);
        *(uint4*)(&Ws[c*STRW + q*8]) = v;
    }
    for (int i = tid; i < 312; i += 256)
        prm[i] = (i < 104) ? b2[i] : (i < 208 ? gamma[i-104] : beta[i-208]);
    __syncthreads();

    short8v af[7];
    #pragma unroll
    for (int s = 0; s < 7; ++s)
        af[s] = *(const short8v*)(&As[(16*w + n16)*STRA + s*32 + quad*8]);
    float4v acc[7];
    #pragma unroll
    for (int ct = 0; ct < 7; ++ct) { float4v z = {0.f,0.f,0.f,0.f}; acc[ct] = z; }
    #pragma unroll
    for (int ct = 0; ct < 7; ++ct)
        #pragma unroll
        for (int s = 0; s < 4; ++s) {
            short8v bfr = *(const short8v*)(&Ws[(ct*16 + n16)*STRW + s*32 + quad*8]);
            acc[ct] = __builtin_amdgcn_mfma_f32_16x16x32_bf16(af[s], bfr, acc[ct], 0, 0, 0);
        }
    __syncthreads();
    for (int idx = tid; idx < 112*16; idx += 256) {   // half 2: k 128..223 (12 data uint4)
        int c = idx >> 4, q = idx & 15;
        uint4 v = z4;
        if (c < 104 && q < 12) v = *(const uint4*)(w2t + (size_t)c*224 + 128 + q*8);
        *(uint4*)(&Ws[c*STRW + q*8]) = v;
    }
    __syncthreads();
    #pragma unroll
    for (int ct = 0; ct < 7; ++ct)
        #pragma unroll
        for (int s = 4; s < 7; ++s) {
            short8v bfr = *(const short8v*)(&Ws[(ct*16 + n16)*STRW + (s-4)*32 + quad*8]);
            acc[ct] = __builtin_amdgcn_mfma_f32_16x16x32_bf16(af[s], bfr, acc[ct], 0, 0, 0);
        }

    // epilogue: x = h1 + m  -> LN
    float sum[4] = {0.f,0.f,0.f,0.f};
    #pragma unroll
    for (int ct = 0; ct < 7; ++ct) {
        int c = ct*16 + n16;
        bool colok = c < 104;
        float bb = colok ? prm[c] : 0.f;
        #pragma unroll
        for (int reg = 0; reg < 4; ++reg) {
            int m = m0 + 16*w + quad*4 + reg;
            float xv = 0.f;
            if (colok && m < TN)
                xv = b2f(h1[(size_t)m*104 + c]) + acc[ct][reg] + bb;
            acc[ct][reg] = xv;
            sum[reg] += xv;
        }
    }
    #pragma unroll
    for (int reg = 0; reg < 4; ++reg) {
        float v = sum[reg];
        v += __shfl_xor(v,1,64); v += __shfl_xor(v,2,64);
        v += __shfl_xor(v,4,64); v += __shfl_xor(v,8,64);
        sum[reg] = v * (1.f/104.f);
    }
    float var[4] = {0.f,0.f,0.f,0.f};
    #pragma unroll
    for (int ct = 0; ct < 7; ++ct) {
        bool colok = (ct*16 + n16) < 104;
        #pragma unroll
        for (int reg = 0; reg < 4; ++reg) {
            if (colok) {
                float d = acc[ct][reg] - sum[reg];
                acc[ct][reg] = d;
                var[reg] += d*d;
            }
        }
    }
    #pragma unroll
    for (int reg = 0; reg < 4; ++reg) {
        float v = var[reg];
        v += __shfl_xor(v,1,64); v += __shfl_xor(v,2,64);
        v += __shfl_xor(v,4,64); v += __shfl_xor(v,8,64);
        var[reg] = rsqrtf(v * (1.f/104.f) + 1e-5f);
    }
    #pragma unroll
    for (int ct = 0; ct < 7; ++ct) {
        int c = ct*16 + n16;
        if (c < 104) {
            float g = prm[104 + c], be = prm[208 + c];
            #pragma unroll
            for (int reg = 0; reg < 4; ++reg) {
                int m = m0 + 16*w + quad*4 + reg;
                if (m < TN)
                    h2[(size_t)m*104 + c] = f2b(acc[ct][reg]*var[reg]*g + be);
            }
        }
    }
}

// ---------------- MFMA encoder_proj ----------------
__global__ void __launch_bounds__(256) ep_mf(
    const bf16* __restrict__ h2, const bf16* __restrict__ wt, float* __restrict__ y)
{
    constexpr int STR = 136;
    __shared__ bf16 As[64*STR];
    __shared__ bf16 Ws[64*STR];
    int m0 = blockIdx.x * 64;
    int c0 = blockIdx.y * 64;
    int t0 = blockIdx.z * 8;
    int t1 = min(TT, t0 + 8);
    int tid = threadIdx.x;
    int lane = tid & 63, w = tid >> 6, n16 = lane & 15, quad = lane >> 4;
    uint4 z4 = {0u,0u,0u,0u};

    float4v acc[4];
    #pragma unroll
    for (int ct = 0; ct < 4; ++ct) { float4v z = {0.f,0.f,0.f,0.f}; acc[ct] = z; }

    for (int t = t0; t < t1; ++t) {
        for (int idx = tid; idx < 64*16; idx += 256) {
            int r = idx >> 4, q = idx & 15;
            int m = m0 + r;
            uint4 va = z4;
            if (m < NN && q < 13) va = *(const uint4*)(h2 + ((size_t)t*NN + m)*104 + q*8);
            *(uint4*)(&As[r*STR + q*8]) = va;
            int c = c0 + r;
            uint4 vw = z4;
            if (c < 104 && q < 13) vw = *(const uint4*)(wt + (size_t)c*37960 + t*104 + q*8);
            *(uint4*)(&Ws[r*STR + q*8]) = vw;
        }
        __syncthreads();
        short8v af[4];
        #pragma unroll
        for (int s = 0; s < 4; ++s)
            af[s] = *(const short8v*)(&As[(16*w + n16)*STR + s*32 + quad*8]);
        #pragma unroll
        for (int ct = 0; ct < 4; ++ct) {
            #pragma unroll
            for (int s = 0; s < 4; ++s) {
                short8v bfr = *(const short8v*)(&Ws[(ct*16 + n16)*STR + s*32 + quad*8]);
                acc[ct] = __builtin_amdgcn_mfma_f32_16x16x32_bf16(af[s], bfr, acc[ct], 0, 0, 0);
            }
        }
        __syncthreads();
    }
    #pragma unroll
    for (int ct = 0; ct < 4; ++ct) {
        int c = c0 + ct*16 + n16;
        if (c < 104) {
            #pragma unroll
            for (int reg = 0; reg < 4; ++reg) {
                int m = m0 + 16*w + quad*4 + reg;
                if (m < NN) atomicAdd(&y[(size_t)m*104 + c], acc[ct][reg]);
            }
        }
    }
}

// ---------------- MFMA z1 (R5 structure, unchanged) ----------------
static constexpr int Z1_TQ = CEILDIV(TT, 8);          // 46
static constexpr int Z1_BLOCKS = 8 * Z1_TQ * 4;       // 1472
__global__ void __launch_bounds__(512, 4) z1_mf(
    const bf16* __restrict__ adp_bf, const bf16* __restrict__ hT, bf16* __restrict__ z1)
{
    constexpr int SA  = 104;   // Asq/Bt row stride (96 data + pad), 16B-aligned
    constexpr int SH  = 72;    // Hs row stride (64 data + pad)
    constexpr int SPP = 72;    // P  row stride (64 data + pad)
    __shared__ bf16 Asq[2][64*SA];   // 26624 B: per-slab q rows (persist)
    __shared__ bf16 Bt[64*SA];       // 13312 B: shared c-rows tile
    __shared__ bf16 Hs[128*SH];      // 18432 B: shared hT tile (rows 104..127 zero)
    __shared__ bf16 P[2][64*SPP];    // 18432 B: per-slab probabilities
    __shared__ float rsb[2][2][64];  //  2048 B

    int bid = blockIdx.x;
    int xcd = bid & 7;               // all blocks of one t share an XCD/L2
    int j = bid >> 3;
    int tq = j >> 2, pair = j & 3;
    int t = tq*8 + xcd;
    if (t >= TT) return;

    int tid = threadIdx.x;
    int lane = tid & 63, w = tid >> 6;            // 8 waves
    int slab = w >> 2, wsl = w & 3;
    int qi = wsl >> 1, ci = wsl & 1;
    int n32 = lane & 31, koct = lane >> 5;
    int r0 = (pair*2 + slab)*64;                  // up to 448; masked at write

    {
        const uint4* src = (const uint4*)(adp_bf + ((size_t)t*NN + pair*128)*96);
        #pragma unroll
        for (int i = 0; i < 3; ++i) {
            int idx = tid + i*512;                // < 1536
            int s2 = idx / 768, rem = idx - s2*768;
            int r = rem / 12, q = rem - r*12;
            *(uint4*)(&Asq[s2][r*SA + q*8]) = src[idx];
        }
    }
    {
        uint4 z4v = {0u,0u,0u,0u};
        for (int idx = tid; idx < 216; idx += 512) {
            int rr = idx / 9;
            int r = 104 + rr, q = idx - rr*9;
            *(uint4*)(&Hs[r*SH + q*8]) = z4v;
        }
    }

    float16v on0, on1;
    #pragma unroll
    for (int i = 0; i < 16; ++i) { on0[i] = 0.f; on1[i] = 0.f; }
    float rs2[16];
    #pragma unroll
    for (int i = 0; i < 16; ++i) rs2[i] = 0.f;

    const bf16* hbase = hT + (size_t)t*104*448;

    uint4 preB0, preB1, preH0, preH1;
    {
        const uint4* srcB = (const uint4*)(adp_bf + (size_t)t*NN*96);
        preB0 = srcB[tid];
        if (tid < 256) preB1 = srcB[tid + 512];
        { int r = tid >> 3, q = tid & 7;
          preH0 = *(const uint4*)(hbase + (size_t)r*448 + q*8); }
        if (tid < 320) { int idx = tid + 512; int r = idx >> 3, q = idx & 7;
          preH1 = *(const uint4*)(hbase + (size_t)r*448 + q*8); }
    }

    for (int c0 = 0; c0 < NN; c0 += 64) {
        { int r = tid / 12, q = tid - (tid/12)*12;
          *(uint4*)(&Bt[r*SA + q*8]) = preB0; }
        if (tid < 256) { int idx = tid + 512; int r = idx / 12, q = idx - r*12;
          *(uint4*)(&Bt[r*SA + q*8]) = preB1; }
        { int r = tid >> 3, q = tid & 7;
          *(uint4*)(&Hs[r*SH + q*8]) = preH0; }
        if (tid < 320) { int idx = tid + 512; int r = idx >> 3, q = idx & 7;
          *(uint4*)(&Hs[r*SH + q*8]) = preH1; }
        __syncthreads();                          // barA (covers Asq on iter 0)
        int cn = c0 + 64;
        if (cn < NN) {
            const uint4* srcB = (const uint4*)(adp_bf + ((size_t)t*NN + cn)*96);
            preB0 = srcB[tid];
            if (tid < 256) preB1 = srcB[tid + 512];
            { int r = tid >> 3, q = tid & 7;
              preH0 = *(const uint4*)(hbase + (size_t)r*448 + cn + q*8); }
            if (tid < 320) { int idx = tid + 512; int r = idx >> 3, q = idx & 7;
              preH1 = *(const uint4*)(hbase + (size_t)r*448 + cn + q*8); }
        }
        float16v sc;
        #pragma unroll
        for (int i = 0; i < 16; ++i) sc[i] = 0.f;
        #pragma unroll
        for (int s = 0; s < 6; ++s) {
            short8v afq = *(const short8v*)(&Asq[slab][(qi*32 + n32)*SA + s*16 + koct*8]);
            short8v bfr = *(const short8v*)(&Bt[(ci*32 + n32)*SA + s*16 + koct*8]);
            sc = __builtin_amdgcn_mfma_f32_32x32x16_bf16(afq, bfr, sc, 0, 0, 0);
        }
        bool colok = (c0 + ci*32 + n32) < NN;
        #pragma unroll
        for (int reg = 0; reg < 16; ++reg) {
            int crow = (reg & 3) + 8*(reg >> 2) + 4*koct;
            float e = colok ? __expf(fmaxf(sc[reg], 0.f)) : 0.f;
            rs2[reg] += e;
            P[slab][(qi*32 + crow)*SPP + ci*32 + n32] = f2b(e);
        }
        __syncthreads();                          // barB: P complete (cross-wave)
        short8v pA[4];
        #pragma unroll
        for (int s = 0; s < 4; ++s)
            pA[s] = *(const short8v*)(&P[slab][(qi*32 + n32)*SPP + s*16 + koct*8]);
        #pragma unroll
        for (int s = 0; s < 4; ++s) {
            short8v hb0 = *(const short8v*)(&Hs[(ci*32 + n32)*SH + s*16 + koct*8]);
            on0 = __builtin_amdgcn_mfma_f32_32x32x16_bf16(pA[s], hb0, on0, 0, 0, 0);
        }
        #pragma unroll
        for (int s = 0; s < 4; ++s) {
            short8v hb1 = *(const short8v*)(&Hs[((ci+2)*32 + n32)*SH + s*16 + koct*8]);
            on1 = __builtin_amdgcn_mfma_f32_32x32x16_bf16(pA[s], hb1, on1, 0, 0, 0);
        }
        __syncthreads();                          // barC: reads done before restage
    }

    #pragma unroll
    for (int reg = 0; reg < 16; ++reg) {
        float v = rs2[reg];
        v += __shfl_xor(v, 1, 64);
        v += __shfl_xor(v, 2, 64);
        v += __shfl_xor(v, 4, 64);
        v += __shfl_xor(v, 8, 64);
        v += __shfl_xor(v, 16, 64);
        if (n32 == 0) {
            int crow = (reg & 3) + 8*(reg >> 2) + 4*koct;
            rsb[slab][ci][qi*32 + crow] = v;
        }
    }
    __syncthreads();

    #pragma unroll
    for (int reg = 0; reg < 16; ++reg) {
        int crow = (reg & 3) + 8*(reg >> 2) + 4*koct;
        int qrow = qi*32 + crow;
        int gq = r0 + qrow;
        if (gq < NN) {
            float inv = 1.f / (rsb[slab][0][qrow] + rsb[slab][1][qrow]);
            int d0 = ci*32 + n32;
            z1[((size_t)t*NN + gq)*104 + d0] = f2b(on0[reg] * inv);
            int d1 = (ci + 2)*32 + n32;
            if (d1 < 104)
                z1[((size_t)t*NN + gq)*104 + d1] = f2b(on1[reg] * inv);
        }
    }
}

// ---------------- MFMA KV summaries (spatial + temporal) ----------------
__global__ void __launch_bounds__(256) kvs_mf(
    const bf16* __restrict__ qkv, bf16* __restrict__ kvsb_s, bf16* __restrict__ kvsb_t)
{
    constexpr int CK = 32;          // l-chunk
    constexpr int TS = 40;          // padded row stride
    __shared__ bf16 raw[CK][216];   // 208 used (k|v span, qkv cols 104..311)
    __shared__ bf16 kTn[4][32][TS]; // per-head kn^T tile (rows 26..31 unused)
    __shared__ bf16 vT [4][32][TS]; // per-head v^T tile + ones row 26
    __shared__ float invs[CK][4];

    int bb = blockIdx.x;
    bf16* out; int L; long long strideL, base;
    if (bb < TT) { out = kvsb_s + (size_t)bb*NTILE; L = NN; base = (long long)bb*NN*312 + 104; strideL = 312; }
    else { int n = bb - TT; out = kvsb_t + (size_t)n*NTILE; L = TT; base = (long long)n*312 + 104; strideL = (long long)NN*312; }

    int tid = threadIdx.x;
    int lane = tid & 63, w = tid >> 6;       // wave = head
    int n32 = lane & 31, koct = lane >> 5;
    uint4 z4 = {0u,0u,0u,0u};

    float16v acc;
    #pragma unroll
    for (int i = 0; i < 16; ++i) acc[i] = 0.f;

    uint4 pre[4];
    #pragma unroll
    for (int j = 0; j < 4; ++j) {
        int idx = tid + j*256;
        uint4 v = z4;
        if (idx < CK*26) {
            int r = idx / 26, q = idx - r*26;
            if (r < L) v = *(const uint4*)(qkv + base + (long long)r*strideL + q*8);
        }
        pre[j] = v;
    }

    for (int l0 = 0; l0 < L; l0 += CK) {
        int lw = min(CK, L - l0);
        __syncthreads();
        #pragma unroll
        for (int j = 0; j < 4; ++j) {
            int idx = tid + j*256;
            if (idx < CK*26) {
                int r = idx / 26, q = idx - r*26;
                *(uint4*)(&raw[r][q*8]) = pre[j];
            }
        }
        __syncthreads();
        {
            int ln0 = l0 + CK;
            #pragma unroll
            for (int j = 0; j < 4; ++j) {
                int idx = tid + j*256;
                uint4 v = z4;
                if (idx < CK*26 && ln0 < L) {
                    int r = idx / 26, q = idx - r*26;
                    if (r < L - ln0) v = *(const uint4*)(qkv + base + (long long)(ln0 + r)*strideL + q*8);
                }
                pre[j] = v;
            }
        }
        if (tid < CK*4) {
            int l = tid >> 2, h = tid & 3;
            float ss = 0.f;
            #pragma unroll
            for (int m = 0; m < HD; ++m) { float v = b2f(raw[l][h*HD + m]); ss += v*v; }
            invs[l][h] = (l < lw) ? 1.f/fmaxf(sqrtf(ss), 1e-12f) : 0.f;
        }
        __syncthreads();
        for (int idx = tid; idx < 4*CK*HD; idx += 256) {
            int h = idx / (CK*HD); int rem = idx - h*CK*HD;
            int l = rem / HD; int m = rem - l*HD;
            float iv = invs[l][h];
            kTn[h][m][l] = f2b(b2f(raw[l][h*HD + m]) * iv);
            vT[h][m][l]  = raw[l][104 + h*HD + m];
        }
        if (tid < 4*CK) {
            int h = tid >> 5, l = tid & 31;
            vT[h][26][l] = f2b((l < lw) ? 1.f : 0.f);
        }
        __syncthreads();
        #pragma unroll
        for (int s = 0; s < 2; ++s) {
            short8v a = *(const short8v*)(&kTn[w][n32][s*16 + koct*8]);
            short8v b = *(const short8v*)(&vT [w][n32][s*16 + koct*8]);
            acc = __builtin_amdgcn_mfma_f32_32x32x16_bf16(a, b, acc, 0, 0, 0);
        }
    }

    int lo = w*HD;
    #pragma unroll
    for (int reg = 0; reg < 16; ++reg) {
        int m = (reg & 3) + 8*(reg >> 2) + 4*koct;
        if (m < HD) {
            if (n32 < HD)       out[(size_t)(lo + n32)*32 + m] = f2b(acc[reg]);
            else if (n32 == HD) out[(size_t)(104 + w)*32 + m] = f2b(acc[reg]);
        }
    }
}

// ---------------- MFMA linear-attention apply (temporal only now) ----------------
__global__ void __launch_bounds__(256) attn_mm(
    bf16* __restrict__ qkv, const bf16* __restrict__ kvsb,
    int M, long long bStride, long long rowStride, float Lf, int outOff)
{
    constexpr int STR = 136;
    __shared__ bf16 As[64*STR];
    __shared__ bf16 Ws[112*STR];
    __shared__ float nsqL[64*4];
    __shared__ float denL[64*4];
    int mt = blockIdx.x, bb = blockIdx.y;
    int tid = threadIdx.x;
    int lane = tid & 63, w = tid >> 6, n16 = lane & 15, quad = lane >> 4;
    bf16* base = qkv + (size_t)bb * bStride;
    int r0 = mt*64;
    uint4 z4 = {0u,0u,0u,0u};

    for (int idx = tid; idx < 64*16; idx += 256) {
        int r = idx >> 4, q = idx & 15;
        int m = r0 + r;
        uint4 v = z4;
        if (m < M && q < 13) v = *(const uint4*)(base + (size_t)m*rowStride + q*8);
        *(uint4*)(&As[r*STR + q*8]) = v;
    }
    for (int idx = tid; idx < 112*16; idx += 256) {
        int c = idx >> 4, q = idx & 15;
        *(uint4*)(&Ws[c*STR + q*8]) = z4;
    }
    __syncthreads();
    {
        const bf16* kb = kvsb + (size_t)bb * NTILE;
        for (int idx = tid; idx < 108*13; idx += 256) {
            int c = idx / 13, qu = idx - c*13;
            int lo = (c < 104) ? (c/26)*26 : (c-104)*26;
            *(uint*)(&Ws[c*STR + lo + qu*2]) = *(const uint*)(kb + (size_t)c*32 + qu*2);
        }
    }
    __syncthreads();

    short8v af[4];
    #pragma unroll
    for (int s = 0; s < 4; ++s)
        af[s] = *(const short8v*)(&As[(16*w + n16)*STR + s*32 + quad*8]);
    float4v acc[7];
    #pragma unroll
    for (int ct = 0; ct < 7; ++ct) { float4v z = {0.f,0.f,0.f,0.f}; acc[ct] = z; }
    #pragma unroll
    for (int ct = 0; ct < 7; ++ct) {
        #pragma unroll
        for (int s = 0; s < 4; ++s) {
            short8v bfr = *(const short8v*)(&Ws[(ct*16 + n16)*STR + s*32 + quad*8]);
            acc[ct] = __builtin_amdgcn_mfma_f32_16x16x32_bf16(af[s], bfr, acc[ct], 0, 0, 0);
        }
    }
    {
        int row = tid >> 2, hh = tid & 3;
        const bf16* qr = &As[row*STR + hh*26];
        float ss = 0.f;
        #pragma unroll
        for (int m = 0; m < HD; ++m) { float v = b2f(qr[m]); ss += v*v; }
        nsqL[row*4 + hh] = ss;
    }
    if (n16 >= 8 && n16 < 12) {
        #pragma unroll
        for (int reg = 0; reg < 4; ++reg)
            denL[(16*w + quad*4 + reg)*4 + (n16 - 8)] = acc[6][reg];
    }
    __syncthreads();
    #pragma unroll
    for (int ct = 0; ct < 7; ++ct) {
        int c = ct*16 + n16;
        if (c < 104) {
            int hh = c / 26;
            #pragma unroll
            for (int reg = 0; reg < 4; ++reg) {
                int lr = 16*w + quad*4 + reg;
                int m = r0 + lr;
                if (m < M) {
                    float iq = 1.f / fmaxf(sqrtf(nsqL[lr*4 + hh]), 1e-12f);
                    float den = iq * denL[lr*4 + hh] + Lf;
                    bf16* rp = base + (size_t)m*rowStride;
                    float num = iq * acc[ct][reg] + Lf * b2f(rp[208 + c]);
                    rp[outOff + c] = f2b(num / den);
                }
            }
        }
    }
}

// ---------------- R8-R10: fused spatial attn + op projection ----------------
// R10: v (qkv cols 208..311) staged into Acat with the row stage (full 312-col
// rows, coalesced) so the epilogue's 28 scattered scalar global v-loads per
// thread become LDS reads. SA=328 (164 dwords = 4 mod 32 -> 2-way-free bank
// pattern; SA=320 would be 16-way). op-W k>=208 is zero-padded so the staged
// v cols contribute 0 to the projection MFMAs.
__global__ void __launch_bounds__(256) attn_op(
    const bf16* __restrict__ qkv, const bf16* __restrict__ kvsb,
    const bf16* __restrict__ wt, const float* __restrict__ bias,
    bf16* __restrict__ Cout, float Lf)
{
    constexpr int SA = 328;      // 312 data + 16 pad (16B-aligned)
    constexpr int SW = 136;
    __shared__ bf16 Acat[64*SA];     // 41984 B
    __shared__ bf16 Ws[112*SW];      // 30464 B (band, then op-W halves)
    __shared__ float nsqL[64*4];
    __shared__ float denL[64*4];
    int mt = blockIdx.x, t = blockIdx.y;
    int tid = threadIdx.x;
    int lane = tid & 63, w = tid >> 6, n16 = lane & 15, quad = lane >> 4;
    const bf16* base = qkv + (size_t)t * ((size_t)NN*312);
    int r0 = mt*64;
    uint4 z4 = {0u,0u,0u,0u};

    // T14: issue op-W half-1 loads NOW; consumed at the epilogue commit.
    uint4 preW[7];
    #pragma unroll
    for (int j = 0; j < 7; ++j) {
        int idx = tid + j*256;               // 112*16 = 1792 slots
        int c = idx >> 4, q = idx & 15;
        uint4 v = z4;
        if (c < 104) v = *(const uint4*)(wt + (size_t)c*224 + q*8);
        preW[j] = v;
    }

    // stage A rows: full qkv rows, cols 0..311 = [q|out_t|v]
    for (int idx = tid; idx < 64*39; idx += 256) {
        int r = idx / 39, q = idx - r*39;
        int m = r0 + r;
        uint4 v = z4;
        if (m < NN) v = *(const uint4*)(base + (size_t)m*312 + q*8);
        *(uint4*)(&Acat[r*SA + q*8]) = v;
    }
    // stage Ws: zero cols 0..127 then scatter kvs band
    for (int idx = tid; idx < 112*16; idx += 256) {
        int c = idx >> 4, q = idx & 15;
        *(uint4*)(&Ws[c*SW + q*8]) = z4;
    }
    __syncthreads();
    {
        const bf16* kb = kvsb + (size_t)t * NTILE;
        for (int idx = tid; idx < 108*13; idx += 256) {
            int c = idx / 13, qu = idx - c*13;
            int lo = (c < 104) ? (c/26)*26 : (c-104)*26;
            *(uint*)(&Ws[c*SW + lo + qu*2]) = *(const uint*)(kb + (size_t)c*32 + qu*2);
        }
    }
    __syncthreads();

    // ---- spatial attention ----
    short8v af[4];
    #pragma unroll
    for (int s = 0; s < 4; ++s)
        af[s] = *(const short8v*)(&Acat[(16*w + n16)*SA + s*32 + quad*8]);
    float4v acc[7];
    #pragma unroll
    for (int ct = 0; ct < 7; ++ct) { float4v z = {0.f,0.f,0.f,0.f}; acc[ct] = z; }
    #pragma unroll
    for (int ct = 0; ct < 7; ++ct) {
        #pragma unroll
        for (int s = 0; s < 4; ++s) {
            short8v bfr = *(const short8v*)(&Ws[(ct*16 + n16)*SW + s*32 + quad*8]);
            acc[ct] = __builtin_amdgcn_mfma_f32_16x16x32_bf16(af[s], bfr, acc[ct], 0, 0, 0);
        }
    }
    {
        int row = tid >> 2, hh = tid & 3;
        const bf16* qr = &Acat[row*SA + hh*26];
        float ss = 0.f;
        #pragma unroll
        for (int m = 0; m < HD; ++m) { float v = b2f(qr[m]); ss += v*v; }
        nsqL[row*4 + hh] = ss;
    }
    if (n16 >= 8 && n16 < 12) {
        #pragma unroll
        for (int reg = 0; reg < 4; ++reg)
            denL[(16*w + quad*4 + reg)*4 + (n16 - 8)] = acc[6][reg];
    }
    __syncthreads();      // attn reads of Ws/Acat(q) done; denL published

    // ---- epilogue: out_s -> Acat cols 0..103 (v from LDS); commit preW1; issue preW2 ----
    #pragma unroll
    for (int ct = 0; ct < 7; ++ct) {
        int c = ct*16 + n16;
        if (c < 104) {
            int hh = c / 26;
            #pragma unroll
            for (int reg = 0; reg < 4; ++reg) {
                int lr = 16*w + quad*4 + reg;
                int m = r0 + lr;
                if (m < NN) {
                    float iq = 1.f / fmaxf(sqrtf(nsqL[lr*4 + hh]), 1e-12f);
                    float den = iq * denL[lr*4 + hh] + Lf;
                    float num = iq * acc[ct][reg] + Lf * b2f(Acat[lr*SA + 208 + c]);
                    Acat[lr*SA + c] = f2b(num / den);
                }
            }
        }
    }
    #pragma unroll
    for (int j = 0; j < 7; ++j) {        // commit half 1 (waitcnt for entry loads)
        int idx = tid + j*256;
        int c = idx >> 4, q = idx & 15;
        *(uint4*)(&Ws[c*SW + q*8]) = preW[j];
    }
    #pragma unroll
    for (int j = 0; j < 7; ++j) {        // issue half 2; overlaps half-1 MFMAs
        int idx = tid + j*256;
        int c = idx >> 4, q = idx & 15;
        uint4 v = z4;
        if (c < 104 && q < 12) v = *(const uint4*)(wt + (size_t)c*224 + 128 + q*8);
        preW[j] = v;
    }
    __syncthreads();

    // ---- op projection: C = Acat(64x208) @ W(208x104) + bias ----
    short8v af2[7];
    #pragma unroll
    for (int s = 0; s < 7; ++s)
        af2[s] = *(const short8v*)(&Acat[(16*w + n16)*SA + s*32 + quad*8]);
    float4v acc2[7];
    #pragma unroll
    for (int ct = 0; ct < 7; ++ct) { float4v z = {0.f,0.f,0.f,0.f}; acc2[ct] = z; }
    #pragma unroll
    for (int ct = 0; ct < 7; ++ct)
        #pragma unroll
        for (int s = 0; s < 4; ++s) {
            short8v bfr = *(const short8v*)(&Ws[(ct*16 + n16)*SW + s*32 + quad*8]);
            acc2[ct] = __builtin_amdgcn_mfma_f32_16x16x32_bf16(af2[s], bfr, acc2[ct], 0, 0, 0);
        }
    __syncthreads();
    #pragma unroll
    for (int j = 0; j < 7; ++j) {        // commit half 2
        int idx = tid + j*256;
        int c = idx >> 4, q = idx & 15;
        *(uint4*)(&Ws[c*SW + q*8]) = preW[j];
    }
    __syncthreads();
    #pragma unroll
    for (int ct = 0; ct < 7; ++ct)
        #pragma unroll
        for (int s = 4; s < 7; ++s) {
            short8v bfr = *(const short8v*)(&Ws[(ct*16 + n16)*SW + (s-4)*32 + quad*8]);
            acc2[ct] = __builtin_amdgcn_mfma_f32_16x16x32_bf16(af2[s], bfr, acc2[ct], 0, 0, 0);
        }

    #pragma unroll
    for (int ct = 0; ct < 7; ++ct) {
        int c = ct*16 + n16;
        if (c < 104) {
            float b = bias[c];
            #pragma unroll
            for (int reg = 0; reg < 4; ++reg) {
                int m = r0 + 16*w + quad*4 + reg;
                if (m < NN)
                    Cout[((size_t)t*NN + m)*104 + c] = f2b(acc2[ct][reg] + b);
            }
        }
    }
}

__global__ void __launch_bounds__(256) y_init_kernel(float* __restrict__ y, const float* __restrict__ ep_b) {
    int i = blockIdx.x*256 + threadIdx.x;
    if (i < NN*104) y[i] = ep_b[i % 104];
}

// ---------------- fused tail: 2 rows/block, ILP on the dot chains ----------------
__global__ void __launch_bounds__(256) tail_kernel(
    const float* __restrict__ y,
    const float* __restrict__ ew1, const float* __restrict__ eb1,
    const float* __restrict__ ew2, const float* __restrict__ eb2,
    const float* __restrict__ out_w, const float* __restrict__ out_b,
    float* __restrict__ out)
{
    int n0 = blockIdx.x * 2;               // 200 blocks x 2 rows
    int tid = threadIdx.x;
    __shared__ float yr[2][104], hid[2][208];
    if (tid < 104) {
        yr[0][tid] = y[(size_t)n0*104 + tid];
        yr[1][tid] = y[(size_t)(n0+1)*104 + tid];
    }
    __syncthreads();
    for (int i = 0; i < 3; ++i) {
        const float* w1 = ew1 + (size_t)i*104*208;
        const float* b1 = eb1 + (size_t)i*208;
        const float* w2 = ew2 + (size_t)i*208*104;
        const float* b2 = eb2 + (size_t)i*104;
        if (tid < 208) {
            float a0 = b1[tid], a1 = a0;
            #pragma unroll 8
            for (int k = 0; k < 104; ++k) {
                float w = w1[(size_t)k*208 + tid];
                a0 += yr[0][k]*w; a1 += yr[1][k]*w;
            }
            hid[0][tid] = fmaxf(a0, 0.f);
            hid[1][tid] = fmaxf(a1, 0.f);
        }
        __syncthreads();
        float y0 = 0.f, y1 = 0.f;
        if (tid < 104) {
            float a0 = b2[tid], a1 = a0;
            #pragma unroll 8
            for (int k = 0; k < 208; ++k) {
                float w = w2[(size_t)k*104 + tid];
                a0 += hid[0][k]*w; a1 += hid[1][k]*w;
            }
            y0 = yr[0][tid] + a0; y1 = yr[1][tid] + a1;
        }
        __syncthreads();
        if (tid < 104) { yr[0][tid] = y0; yr[1][tid] = y1; }
        __syncthreads();
    }
    for (int t = tid; t < TT; t += 256) {
        float a0 = out_b[t], a1 = a0;
        #pragma unroll 8
        for (int d = 0; d < 104; ++d) {
            float w = out_w[(size_t)d*TT + t];
            a0 += yr[0][d]*w; a1 += yr[1][d]*w;
        }
        out[(size_t)n0*TT + t] = a0;
        out[(size_t)(n0+1)*TT + t] = a1;
    }
}

// ---------------- launch ----------------
extern "C" void kernel_launch(void* const* d_in, const int* in_sizes, int n_in,
                              void* d_out, int out_size, void* d_ws, size_t ws_size,
                              hipStream_t stream) {
    if (ws_size < WS_NEEDED) return;

    const float* x      = (const float*)d_in[0];
    const float* W_in   = (const float*)d_in[1];
    const float* b_in   = (const float*)d_in[2];
    const float* adp    = (const float*)d_in[3];
    const float* W_tp   = (const float*)d_in[4];
    const float* b_tp   = (const float*)d_in[5];
    const float* qkv_w  = (const float*)d_in[6];
    const float* op_w   = (const float*)d_in[7];
    const float* op_b   = (const float*)d_in[8];
    const float* pw_w   = (const float*)d_in[9];
    const float* pw_b   = (const float*)d_in[10];
    const float* fc_w1  = (const float*)d_in[11];
    const float* fc_b1  = (const float*)d_in[12];
    const float* fc_w2  = (const float*)d_in[13];
    const float* fc_b2  = (const float*)d_in[14];
    const float* ln1_g  = (const float*)d_in[15];
    const float* ln1_b  = (const float*)d_in[16];
    const float* ln2_g  = (const float*)d_in[17];
    const float* ln2_b  = (const float*)d_in[18];
    const float* ep_w   = (const float*)d_in[19];
    const float* ep_b   = (const float*)d_in[20];
    const float* enc_w1 = (const float*)d_in[21];
    const float* enc_b1 = (const float*)d_in[22];
    const float* enc_w2 = (const float*)d_in[23];
    const float* enc_b2 = (const float*)d_in[24];
    const float* out_w  = (const float*)d_in[25];
    const float* out_b  = (const float*)d_in[26];

    bf16* B0 = (bf16*)d_ws;
    bf16* B1 = B0 + NB0;
    bf16* B2 = B1 + NB1;
    bf16* B3 = B2 + NB2;
    bf16* kvsb_s = B3 + NB3;
    bf16* kvsb_t = kvsb_s + NKVSB_S;
    float* ybuf  = (float*)(kvsb_t + NKVSB_T);
    bf16* wtp   = (bf16*)(ybuf + NY);
    bf16* wqkv0 = wtp + NW_TP;
    bf16* wqkv1 = wqkv0 + NW_QKV;
    bf16* wop0  = wqkv1 + NW_QKV;
    bf16* wop1  = wop0 + NW_OP;
    bf16* wpw0  = wop1 + NW_OP;
    bf16* wpw1  = wpw0 + NW_PW;
    bf16* wfc1  = wpw1 + NW_PW;
    bf16* wfc2  = wfc1 + NW_FC1;
    bf16* wept  = wfc2 + NW_FC2;
    bf16* adp_bf = B2;
    bf16* hTbuf  = B2 + NADP;

    // 0. weight prep
    prep_w<<<CEILDIV(104*128,256), 256, 0, stream>>>(W_tp, wtp, 104, 104, 128);
    prep_w<<<CEILDIV(312*128,256), 256, 0, stream>>>(qkv_w, wqkv0, 104, 312, 128);
    prep_w<<<CEILDIV(312*128,256), 256, 0, stream>>>(qkv_w + 104*312, wqkv1, 104, 312, 128);
    prep_w<<<CEILDIV(104*224,256), 256, 0, stream>>>(op_w, wop0, 208, 104, 224);
    prep_w<<<CEILDIV(104*224,256), 256, 0, stream>>>(op_w + 208*104, wop1, 208, 104, 224);
    prep_w<<<CEILDIV(104*128,256), 256, 0, stream>>>(pw_w, wpw0, 104, 104, 128);
    prep_w<<<CEILDIV(104*128,256), 256, 0, stream>>>(pw_w + 104*104, wpw1, 104, 104, 128);
    prep_w<<<CEILDIV(208*128,256), 256, 0, stream>>>(fc_w1, wfc1, 104, 208, 128);
    prep_w<<<CEILDIV(104*224,256), 256, 0, stream>>>(fc_w2, wfc2, 208, 104, 224);
    prep_wT<<<CEILDIV(37960,64), 256, 0, stream>>>(ep_w, wept);

    const int GX = CEILDIV(TN, 64);     // 2282

    // 1. hcat -> B2
    hcat_kernel<<<CEILDIV(TN,16), 256, 0, stream>>>(x, W_in, b_in, adp, B2);
    // 2. h = hcat @ W_tp + b_tp -> B0
    gemm_mf<128><<<GX*2, 256, 0, stream>>>(B2, 104, 104, wtp, b_tp, B0, TN, 104, 0);
    // 2b. z1 pre-staging into B2
    prep_adp<<<CEILDIV((int)NADP,256), 256, 0, stream>>>(adp, adp_bf);
    ht_kernel<<<dim3(7, TT), 256, 0, stream>>>(B0, hTbuf);
    // 3. z1 -> B1
    z1_mf<<<Z1_BLOCKS, 512, 0, stream>>>(adp_bf, hTbuf, B1);
    // 4. attention 0 on h
    gemm_mf<128><<<GX*5, 256, 0, stream>>>(B0, 104, 104, wqkv0, nullptr, B2, TN, 312, 0);
    kvs_mf<<<TT+NN, 256, 0, stream>>>(B2, kvsb_s, kvsb_t);
    attn_mm<<<dim3(6, NN), 256, 0, stream>>>(B2, kvsb_t, TT, 312, (long long)NN*312, (float)TT, 104);
    attn_op<<<dim3(7, TT), 256, 0, stream>>>(B2, kvsb_s, wop0, op_b, B3, (float)NN);   // att0 -> B3
    // 5. attention 1 on z1
    gemm_mf<128><<<GX*5, 256, 0, stream>>>(B1, 104, 104, wqkv1, nullptr, B2, TN, 312, 0);
    kvs_mf<<<TT+NN, 256, 0, stream>>>(B2, kvsb_s, kvsb_t);
    attn_mm<<<dim3(6, NN), 256, 0, stream>>>(B2, kvsb_t, TT, 312, (long long)NN*312, (float)TT, 104);
    attn_op<<<dim3(7, TT), 256, 0, stream>>>(B2, kvsb_s, wop1, op_b + 104, B1, (float)NN); // att1 -> B1
    // 6+7. fused gates + LN1 (in-place B0 -> h1)
    gate_ln1<<<GX, 256, 0, stream>>>(B0, B3, B1, wpw0, wpw1, pw_b, ln1_g, ln1_b);
    // 8. MLP: fc1 -> hidden (B2), fused fc2+LN2 -> h2 (B3)
    gemm_mf<128><<<GX*4, 256, 0, stream>>>(B0, 104, 104, wfc1, fc_b1, B2, TN, 208, 1);
    fc2_ln2<<<GX, 256, 0, stream>>>(B2, wfc2, fc_b2, B0, ln2_g, ln2_b, B3);
    // 9. encoder_proj
    y_init_kernel<<<CEILDIV(NN*104,256), 256, 0, stream>>>(ybuf, ep_b);
    ep_mf<<<dim3(CEILDIV(NN,64), 2, CEILDIV(TT,8)), 256, 0, stream>>>(B3, wept, ybuf);
    // 10+11. fused residual MLP blocks + output projection (2 rows/block)
    tail_kernel<<<NN/2, 256, 0, stream>>>(ybuf, enc_w1, enc_b1, enc_w2, enc_b2,
                                          out_w, out_b, (float*)d_out);
}

// Round 11
// 1132.689 us; speedup vs baseline: 1.2029x; 1.0430x over previous
//
#include <hip/hip_runtime.h>
#include <hip/hip_bf16.h>
#include <cstddef>

// ---------------- problem constants ----------------
#define TT   365
#define NN   400
#define TN   (TT*NN)            // 146000
#define HD   26                 // head dim
#define NH   4                  // heads

#define CEILDIV(a,b) (((a)+(b)-1)/(b))

typedef __hip_bfloat16 bf16;
typedef short short8v __attribute__((ext_vector_type(8)));
typedef float float4v __attribute__((ext_vector_type(4)));
typedef float float16v __attribute__((ext_vector_type(16)));
__device__ __forceinline__ float b2f(bf16 v){ return __bfloat162float(v); }
__device__ __forceinline__ bf16  f2b(float v){ return __float2bfloat16(v); }

// ---------------- workspace layout ----------------
static constexpr size_t NB0 = (size_t)TN*104;   // h / h1
static constexpr size_t NB1 = (size_t)TN*104;   // z1 -> att1
static constexpr size_t NB2 = (size_t)TN*312;   // hcat -> [adp_bf|hT] -> qkv+concat -> hidden
static constexpr size_t NB3 = (size_t)TN*104;   // att0 -> h2
static constexpr size_t NBF = NB0+NB1+NB2+NB3;
// compact band KV tiles: per b, 108 rows x 32 (band cols 0..25), bf16
static constexpr size_t NTILE   = (size_t)108*32;
static constexpr size_t NKVSB_S = (size_t)TT*NTILE;
static constexpr size_t NKVSB_T = (size_t)NN*NTILE;
static constexpr size_t NY      = (size_t)NN*104;
// transposed bf16 weights (Wt[n][kp], zero-padded k)
static constexpr size_t NW_TP   = 104*128;
static constexpr size_t NW_QKV  = 312*128;   // x2
static constexpr size_t NW_OP   = 104*224;   // x2
static constexpr size_t NW_PW   = 104*128;   // x2
static constexpr size_t NW_FC1  = 208*128;
static constexpr size_t NW_FC2  = 104*224;
static constexpr size_t NW_EPT  = (size_t)104*37960;   // ep_w transposed, no pad
static constexpr size_t NWT     = NW_TP + 2*NW_QKV + 2*NW_OP + 2*NW_PW + NW_FC1 + NW_FC2 + NW_EPT;
static constexpr size_t WS_NEEDED = NBF*2 + (NKVSB_S+NKVSB_T)*2 + NY*4 + NWT*2;
// z1 scratch lives inside B2 (dead between step 2 and step 4):
static constexpr size_t NADP_ROWS = (size_t)TN + 64;
static constexpr size_t NADP = NADP_ROWS*96;
static constexpr size_t NHT  = ((size_t)TT*104 + 8)*448;
static_assert(NADP + NHT <= NB2, "z1 scratch must fit in B2");

// ---------------- weight prep: Wt[n*KP+k] = bf16(W[k*Nc+n]), zero pad k>=K ----------------
__global__ void __launch_bounds__(256) prep_w(
    const float* __restrict__ W, bf16* __restrict__ Wt, int K, int Nc, int KP)
{
    int idx = blockIdx.x*256 + threadIdx.x;
    if (idx >= Nc*KP) return;
    int n = idx / KP, k = idx - n*KP;
    Wt[idx] = (k < K) ? f2b(W[(size_t)k*Nc + n]) : f2b(0.f);
}

// coalesced LDS transpose for ep weights: Wt[n][k] = bf16(W[k][n]); W is 37960x104 fp32
__global__ void __launch_bounds__(256) prep_wT(
    const float* __restrict__ W, bf16* __restrict__ Wt)
{
    __shared__ float T[64][105];
    int k0 = blockIdx.x * 64;
    int tid = threadIdx.x;
    for (int idx = tid; idx < 64*104; idx += 256) {
        int r = idx / 104, c = idx - r*104;
        int k = k0 + r;
        T[r][c] = (k < 37960) ? W[(size_t)k*104 + c] : 0.f;
    }
    __syncthreads();
    for (int idx = tid; idx < 104*32; idx += 256) {
        int n = idx >> 5, kp = idx & 31;
        int k = kp*2;
        if (k0 + k + 1 < 37960 || k0 + k < 37960) {
            if (k0 + k < 37960) {
                bf16 lo = f2b(T[k][n]);
                bf16 hi = f2b(T[k+1][n]);   // k+1 row is zero-padded if OOB of tile data
                uint v = ((uint)(*(ushort*)&hi) << 16) | (*(ushort*)&lo);
                if (k0 + k + 1 < 37960) *(uint*)(Wt + (size_t)n*37960 + k0 + k) = v;
                else Wt[(size_t)n*37960 + k0 + k] = lo;
            }
        }
    }
}

// adp_bf[row][e] = bf16(adp[row][e]) for e<80 else 0; rows >= TN are zero.
__global__ void __launch_bounds__(256) prep_adp(
    const float* __restrict__ adp, bf16* __restrict__ out)
{
    size_t i = (size_t)blockIdx.x*256 + threadIdx.x;
    if (i >= NADP) return;
    size_t row = i / 96; int e = (int)(i - row*96);
    float v = (row < TN && e < 80) ? adp[row*80 + e] : 0.f;
    out[i] = f2b(v);
}

// hT[t][d][n] = h[t][n][d], n padded to 448 with zeros
__global__ void __launch_bounds__(256) ht_kernel(
    const bf16* __restrict__ h, bf16* __restrict__ hT)
{
    __shared__ bf16 As[64*106];
    int t = blockIdx.y, n0 = blockIdx.x*64;
    int tid = threadIdx.x;
    for (int idx = tid; idx < 64*52; idx += 256) {
        int r = idx / 52, k = idx - r*52;
        int n = n0 + r;
        uint v = 0;
        if (n < NN) v = *(const uint*)(h + ((size_t)t*NN + n)*104 + k*2);
        *(uint*)(&As[r*106 + k*2]) = v;
    }
    __syncthreads();
    for (int idx = tid; idx < 104*32; idx += 256) {
        int d = idx >> 5, np = idx & 31;
        int n = np*2;
        ushort lo = *(ushort*)&As[n*106 + d];
        ushort hi = *(ushort*)&As[(n+1)*106 + d];
        uint v = ((uint)hi << 16) | lo;
        *(uint*)(hT + ((size_t)t*104 + d)*448 + n0 + n) = v;
    }
}

// ---------------- hcat (16 rows/block, LDS-staged uint4 row writes) ----------------
__global__ void __launch_bounds__(256) hcat_kernel(
    const float* __restrict__ x, const float* __restrict__ W_in,
    const float* __restrict__ b_in, const float* __restrict__ adp,
    bf16* __restrict__ hcat)
{
    __shared__ bf16 T[16][112];          // 104 used; 224B row stride (16B-aligned)
    int r0 = blockIdx.x * 16;
    int tid = threadIdx.x;
    // proj cols 0..23
    for (int idx = tid; idx < 16*24; idx += 256) {
        int r = idx / 24, c = idx - r*24;
        int row = r0 + r;
        int t = row / NN, n = row - t*NN;
        size_t xb = ((size_t)n*TT + t)*3;
        float s = b_in[c] + x[xb]*W_in[c] + x[xb+1]*W_in[24+c] + x[xb+2]*W_in[48+c];
        T[r][c] = f2b(s);
    }
    // adp cols 24..103 (coalesced f32 reads)
    for (int idx = tid; idx < 16*80; idx += 256) {
        int r = idx / 80, e = idx - r*80;
        T[r][24+e] = f2b(adp[(size_t)(r0+r)*80 + e]);
    }
    __syncthreads();
    for (int idx = tid; idx < 16*13; idx += 256) {
        int r = idx / 13, q = idx - r*13;
        *(uint4*)(hcat + ((size_t)(r0+r))*104 + q*8) = *(const uint4*)(&T[r][q*8]);
    }
}

// ---------------- MFMA GEMM 64-tile ----------------
// 1-D grid with bijective XCD grouping (m204): column-tiles of one row-slab
// land adjacent on the SAME XCD so the A-slab is fetched from HBM once.
template<int KP>
__global__ void __launch_bounds__(256) gemm_mf(
    const bf16* __restrict__ A, int lda, int K,
    const bf16* __restrict__ Wt, const float* __restrict__ bias,
    bf16* __restrict__ C, int M, int Nc, int relu)
{
    constexpr int STR = KP + 8;
    constexpr int KPQ = KP/8;
    __shared__ bf16 As[64*STR];
    __shared__ bf16 Ws[64*STR];
    int nCol = (Nc + 63) >> 6;
    int nwg = gridDim.x;
    int bid = blockIdx.x;
    int xcd = bid & 7, kk = bid >> 3;
    int q8 = nwg >> 3, r8 = nwg & 7;
    int widx = (xcd < r8 ? xcd*(q8+1) : r8*(q8+1) + (xcd - r8)*q8) + kk;
    int mblk = widx / nCol;
    int m0 = mblk * 64;
    int c0 = (widx - mblk*nCol) * 64;
    int tid = threadIdx.x;
    const int KQ = K/8;
    uint4 z4 = {0u,0u,0u,0u};
    for (int idx = tid; idx < 64*KPQ; idx += 256) {
        int r = idx / KPQ, q = idx - r*KPQ;
        int m = m0 + r;
        uint4 v = z4;
        if (m < M && q < KQ) v = *(const uint4*)(A + (size_t)m*lda + q*8);
        *(uint4*)(&As[r*STR + q*8]) = v;
    }
    for (int idx = tid; idx < 64*KPQ; idx += 256) {
        int r = idx / KPQ, q = idx - r*KPQ;
        int n = c0 + r;
        uint4 v = z4;
        if (n < Nc) v = *(const uint4*)(Wt + (size_t)n*KP + q*8);
        *(uint4*)(&Ws[r*STR + q*8]) = v;
    }
    __syncthreads();

    int lane = tid & 63, w = tid >> 6;
    int n16 = lane & 15, quad = lane >> 4;
    constexpr int KS = KP/32;
    short8v af[KS];
    #pragma unroll
    for (int s = 0; s < KS; ++s)
        af[s] = *(const short8v*)(&As[(16*w + n16)*STR + s*32 + quad*8]);
    float4v acc[4];
    #pragma unroll
    for (int ct = 0; ct < 4; ++ct) { float4v z = {0.f,0.f,0.f,0.f}; acc[ct] = z; }
    #pragma unroll
    for (int ct = 0; ct < 4; ++ct) {
        #pragma unroll
        for (int s = 0; s < KS; ++s) {
            short8v bfr = *(const short8v*)(&Ws[(ct*16 + n16)*STR + s*32 + quad*8]);
            acc[ct] = __builtin_amdgcn_mfma_f32_16x16x32_bf16(af[s], bfr, acc[ct], 0, 0, 0);
        }
    }
    #pragma unroll
    for (int ct = 0; ct < 4; ++ct) {
        int c = c0 + ct*16 + n16;
        if (c < Nc) {
            float b = bias ? bias[c] : 0.f;
            #pragma unroll
            for (int reg = 0; reg < 4; ++reg) {
                int m = m0 + 16*w + quad*4 + reg;
                if (m < M) {
                    float v = acc[ct][reg] + b;
                    if (relu) v = fmaxf(v, 0.f);
                    C[(size_t)m*Nc + c] = f2b(v);
                }
            }
        }
    }
}

// ---------------- fused gates + LN1 ----------------
// h1 = LN(2*(h + att0*(h@pw0+b0) + 0.01*att1*(att0@pw1+b1))) in-place into h.
__global__ void __launch_bounds__(256) gate_ln1(
    bf16* __restrict__ h, const bf16* __restrict__ att0, const bf16* __restrict__ att1,
    const bf16* __restrict__ w0t, const bf16* __restrict__ w1t, const float* __restrict__ pwb,
    const float* __restrict__ gamma, const float* __restrict__ beta)
{
    constexpr int STR = 136;
    __shared__ bf16 A0s[64*STR];
    __shared__ bf16 A1s[64*STR];
    __shared__ bf16 Ws[112*STR];
    __shared__ float prm[416];     // pwb(208) | gamma(104) | beta(104)
    int m0 = blockIdx.x * 64;
    int tid = threadIdx.x;
    int lane = tid & 63, w = tid >> 6, n16 = lane & 15, quad = lane >> 4;
    uint4 z4 = {0u,0u,0u,0u};

    for (int idx = tid; idx < 64*16; idx += 256) {
        int r = idx >> 4, q = idx & 15;
        int m = m0 + r;
        uint4 v0 = z4, v1 = z4;
        if (m < TN && q < 13) {
            v0 = *(const uint4*)(h    + (size_t)m*104 + q*8);
            v1 = *(const uint4*)(att0 + (size_t)m*104 + q*8);
        }
        *(uint4*)(&A0s[r*STR + q*8]) = v0;
        *(uint4*)(&A1s[r*STR + q*8]) = v1;
    }
    for (int idx = tid; idx < 112*16; idx += 256) {
        int c = idx >> 4, q = idx & 15;
        uint4 v = z4;
        if (c < 104) v = *(const uint4*)(w0t + (size_t)c*128 + q*8);
        *(uint4*)(&Ws[c*STR + q*8]) = v;
    }
    for (int i = tid; i < 416; i += 256)
        prm[i] = (i < 208) ? pwb[i] : (i < 312 ? gamma[i-208] : beta[i-312]);
    __syncthreads();

    short8v a0f[4], a1f[4];
    #pragma unroll
    for (int s = 0; s < 4; ++s) {
        a0f[s] = *(const short8v*)(&A0s[(16*w + n16)*STR + s*32 + quad*8]);
        a1f[s] = *(const short8v*)(&A1s[(16*w + n16)*STR + s*32 + quad*8]);
    }
    float4v acc0[7], acc1[7];
    #pragma unroll
    for (int ct = 0; ct < 7; ++ct) { float4v z = {0.f,0.f,0.f,0.f}; acc0[ct] = z; acc1[ct] = z; }
    #pragma unroll
    for (int ct = 0; ct < 7; ++ct)
        #pragma unroll
        for (int s = 0; s < 4; ++s) {
            short8v bfr = *(const short8v*)(&Ws[(ct*16 + n16)*STR + s*32 + quad*8]);
            acc0[ct] = __builtin_amdgcn_mfma_f32_16x16x32_bf16(a0f[s], bfr, acc0[ct], 0, 0, 0);
        }
    __syncthreads();
    for (int idx = tid; idx < 112*16; idx += 256) {
        int c = idx >> 4, q = idx & 15;
        uint4 v = z4;
        if (c < 104) v = *(const uint4*)(w1t + (size_t)c*128 + q*8);
        *(uint4*)(&Ws[c*STR + q*8]) = v;
    }
    __syncthreads();
    #pragma unroll
    for (int ct = 0; ct < 7; ++ct)
        #pragma unroll
        for (int s = 0; s < 4; ++s) {
            short8v bfr = *(const short8v*)(&Ws[(ct*16 + n16)*STR + s*32 + quad*8]);
            acc1[ct] = __builtin_amdgcn_mfma_f32_16x16x32_bf16(a1f[s], bfr, acc1[ct], 0, 0, 0);
        }

    // epilogue: g -> LN (row distributed across the 16 n16 lanes)
    float sum[4] = {0.f,0.f,0.f,0.f};
    #pragma unroll
    for (int ct = 0; ct < 7; ++ct) {
        int c = ct*16 + n16;
        bool colok = c < 104;
        float b0 = colok ? prm[c] : 0.f;
        float b1 = colok ? prm[104 + c] : 0.f;
        #pragma unroll
        for (int reg = 0; reg < 4; ++reg) {
            int r = 16*w + quad*4 + reg;
            int m = m0 + r;
            float xv = 0.f;
            if (colok && m < TN) {
                float p0 = acc0[ct][reg] + b0;
                float p1 = acc1[ct][reg] + b1;
                float hv = b2f(A0s[r*STR + c]);
                float a0 = b2f(A1s[r*STR + c]);
                float a1 = b2f(att1[(size_t)m*104 + c]);
                xv = 2.f*(hv + a0*p0 + 0.01f*a1*p1);
            }
            acc0[ct][reg] = xv;
            sum[reg] += xv;
        }
    }
    #pragma unroll
    for (int reg = 0; reg < 4; ++reg) {
        float v = sum[reg];
        v += __shfl_xor(v,1,64); v += __shfl_xor(v,2,64);
        v += __shfl_xor(v,4,64); v += __shfl_xor(v,8,64);
        sum[reg] = v * (1.f/104.f);                     // mean
    }
    float var[4] = {0.f,0.f,0.f,0.f};
    #pragma unroll
    for (int ct = 0; ct < 7; ++ct) {
        bool colok = (ct*16 + n16) < 104;
        #pragma unroll
        for (int reg = 0; reg < 4; ++reg) {
            if (colok) {
                float d = acc0[ct][reg] - sum[reg];
                acc0[ct][reg] = d;
                var[reg] += d*d;
            }
        }
    }
    #pragma unroll
    for (int reg = 0; reg < 4; ++reg) {
        float v = var[reg];
        v += __shfl_xor(v,1,64); v += __shfl_xor(v,2,64);
        v += __shfl_xor(v,4,64); v += __shfl_xor(v,8,64);
        var[reg] = rsqrtf(v * (1.f/104.f) + 1e-5f);
    }
    #pragma unroll
    for (int ct = 0; ct < 7; ++ct) {
        int c = ct*16 + n16;
        if (c < 104) {
            float g = prm[208 + c], be = prm[312 + c];
            #pragma unroll
            for (int reg = 0; reg < 4; ++reg) {
                int m = m0 + 16*w + quad*4 + reg;
                if (m < TN)
                    h[(size_t)m*104 + c] = f2b(acc0[ct][reg]*var[reg]*g + be);
            }
        }
    }
}

// ---------------- fused fc2 + LN2: h2 = LN(h1 + hidden@fc_w2 + b) ----------------
__global__ void __launch_bounds__(256) fc2_ln2(
    const bf16* __restrict__ hidden, const bf16* __restrict__ w2t, const float* __restrict__ b2,
    const bf16* __restrict__ h1, const float* __restrict__ gamma, const float* __restrict__ beta,
    bf16* __restrict__ h2)
{
    constexpr int STRA = 232;   // 224 + 8
    constexpr int STRW = 136;   // 128 + 8 (per half)
    __shared__ bf16 As[64*STRA];
    __shared__ bf16 Ws[112*STRW];
    __shared__ float prm[312];  // b2(104) | gamma(104) | beta(104)
    int m0 = blockIdx.x * 64;
    int tid = threadIdx.x;
    int lane = tid & 63, w = tid >> 6, n16 = lane & 15, quad = lane >> 4;
    uint4 z4 = {0u,0u,0u,0u};

    for (int idx = tid; idx < 64*28; idx += 256) {
        int r = idx / 28, q = idx - r*28;
        int m = m0 + r;
        uint4 v = z4;
        if (m < TN && q < 26) v = *(const uint4*)(hidden + (size_t)m*208 + q*8);
        *(uint4*)(&As[r*STRA + q*8]) = v;
    }
    for (int idx = tid; idx < 112*16; idx += 256) {
        int c = idx >> 4, q = idx & 15;
        uint4 v = z4;
        if (c < 104) v = *(const uint4*)(w2t + (size_t)c*224 + q*8);
        *(uint4*)(&Ws[c*STRW + q*8]) = v;
    }
    for (int i = tid; i < 312; i += 256)
        prm[i] = (i < 104) ? b2[i] : (i < 208 ? gamma[i-104] : beta[i-208]);
    __syncthreads();

    short8v af[7];
    #pragma unroll
    for (int s = 0; s < 7; ++s)
        af[s] = *(const short8v*)(&As[(16*w + n16)*STRA + s*32 + quad*8]);
    float4v acc[7];
    #pragma unroll
    for (int ct = 0; ct < 7; ++ct) { float4v z = {0.f,0.f,0.f,0.f}; acc[ct] = z; }
    #pragma unroll
    for (int ct = 0; ct < 7; ++ct)
        #pragma unroll
        for (int s = 0; s < 4; ++s) {
            short8v bfr = *(const short8v*)(&Ws[(ct*16 + n16)*STRW + s*32 + quad*8]);
            acc[ct] = __builtin_amdgcn_mfma_f32_16x16x32_bf16(af[s], bfr, acc[ct], 0, 0, 0);
        }
    __syncthreads();
    for (int idx = tid; idx < 112*16; idx += 256) {   // half 2: k 128..223 (12 data uint4)
        int c = idx >> 4, q = idx & 15;
        uint4 v = z4;
        if (c < 104 && q < 12) v = *(const uint4*)(w2t + (size_t)c*224 + 128 + q*8);
        *(uint4*)(&Ws[c*STRW + q*8]) = v;
    }
    __syncthreads();
    #pragma unroll
    for (int ct = 0; ct < 7; ++ct)
        #pragma unroll
        for (int s = 4; s < 7; ++s) {
            short8v bfr = *(const short8v*)(&Ws[(ct*16 + n16)*STRW + (s-4)*32 + quad*8]);
            acc[ct] = __builtin_amdgcn_mfma_f32_16x16x32_bf16(af[s], bfr, acc[ct], 0, 0, 0);
        }

    // epilogue: x = h1 + m  -> LN
    float sum[4] = {0.f,0.f,0.f,0.f};
    #pragma unroll
    for (int ct = 0; ct < 7; ++ct) {
        int c = ct*16 + n16;
        bool colok = c < 104;
        float bb = colok ? prm[c] : 0.f;
        #pragma unroll
        for (int reg = 0; reg < 4; ++reg) {
            int m = m0 + 16*w + quad*4 + reg;
            float xv = 0.f;
            if (colok && m < TN)
                xv = b2f(h1[(size_t)m*104 + c]) + acc[ct][reg] + bb;
            acc[ct][reg] = xv;
            sum[reg] += xv;
        }
    }
    #pragma unroll
    for (int reg = 0; reg < 4; ++reg) {
        float v = sum[reg];
        v += __shfl_xor(v,1,64); v += __shfl_xor(v,2,64);
        v += __shfl_xor(v,4,64); v += __shfl_xor(v,8,64);
        sum[reg] = v * (1.f/104.f);
    }
    float var[4] = {0.f,0.f,0.f,0.f};
    #pragma unroll
    for (int ct = 0; ct < 7; ++ct) {
        bool colok = (ct*16 + n16) < 104;
        #pragma unroll
        for (int reg = 0; reg < 4; ++reg) {
            if (colok) {
                float d = acc[ct][reg] - sum[reg];
                acc[ct][reg] = d;
                var[reg] += d*d;
            }
        }
    }
    #pragma unroll
    for (int reg = 0; reg < 4; ++reg) {
        float v = var[reg];
        v += __shfl_xor(v,1,64); v += __shfl_xor(v,2,64);
        v += __shfl_xor(v,4,64); v += __shfl_xor(v,8,64);
        var[reg] = rsqrtf(v * (1.f/104.f) + 1e-5f);
    }
    #pragma unroll
    for (int ct = 0; ct < 7; ++ct) {
        int c = ct*16 + n16;
        if (c < 104) {
            float g = prm[104 + c], be = prm[208 + c];
            #pragma unroll
            for (int reg = 0; reg < 4; ++reg) {
                int m = m0 + 16*w + quad*4 + reg;
                if (m < TN)
                    h2[(size_t)m*104 + c] = f2b(acc[ct][reg]*var[reg]*g + be);
            }
        }
    }
}

// ---------------- MFMA encoder_proj ----------------
__global__ void __launch_bounds__(256) ep_mf(
    const bf16* __restrict__ h2, const bf16* __restrict__ wt, float* __restrict__ y)
{
    constexpr int STR = 136;
    __shared__ bf16 As[64*STR];
    __shared__ bf16 Ws[64*STR];
    int m0 = blockIdx.x * 64;
    int c0 = blockIdx.y * 64;
    int t0 = blockIdx.z * 8;
    int t1 = min(TT, t0 + 8);
    int tid = threadIdx.x;
    int lane = tid & 63, w = tid >> 6, n16 = lane & 15, quad = lane >> 4;
    uint4 z4 = {0u,0u,0u,0u};

    float4v acc[4];
    #pragma unroll
    for (int ct = 0; ct < 4; ++ct) { float4v z = {0.f,0.f,0.f,0.f}; acc[ct] = z; }

    for (int t = t0; t < t1; ++t) {
        for (int idx = tid; idx < 64*16; idx += 256) {
            int r = idx >> 4, q = idx & 15;
            int m = m0 + r;
            uint4 va = z4;
            if (m < NN && q < 13) va = *(const uint4*)(h2 + ((size_t)t*NN + m)*104 + q*8);
            *(uint4*)(&As[r*STR + q*8]) = va;
            int c = c0 + r;
            uint4 vw = z4;
            if (c < 104 && q < 13) vw = *(const uint4*)(wt + (size_t)c*37960 + t*104 + q*8);
            *(uint4*)(&Ws[r*STR + q*8]) = vw;
        }
        __syncthreads();
        short8v af[4];
        #pragma unroll
        for (int s = 0; s < 4; ++s)
            af[s] = *(const short8v*)(&As[(16*w + n16)*STR + s*32 + quad*8]);
        #pragma unroll
        for (int ct = 0; ct < 4; ++ct) {
            #pragma unroll
            for (int s = 0; s < 4; ++s) {
                short8v bfr = *(const short8v*)(&Ws[(ct*16 + n16)*STR + s*32 + quad*8]);
                acc[ct] = __builtin_amdgcn_mfma_f32_16x16x32_bf16(af[s], bfr, acc[ct], 0, 0, 0);
            }
        }
        __syncthreads();
    }
    #pragma unroll
    for (int ct = 0; ct < 4; ++ct) {
        int c = c0 + ct*16 + n16;
        if (c < 104) {
            #pragma unroll
            for (int reg = 0; reg < 4; ++reg) {
                int m = m0 + 16*w + quad*4 + reg;
                if (m < NN) atomicAdd(&y[(size_t)m*104 + c], acc[ct][reg]);
            }
        }
    }
}

// ---------------- MFMA z1 (R5 structure, unchanged) ----------------
static constexpr int Z1_TQ = CEILDIV(TT, 8);          // 46
static constexpr int Z1_BLOCKS = 8 * Z1_TQ * 4;       // 1472
__global__ void __launch_bounds__(512, 4) z1_mf(
    const bf16* __restrict__ adp_bf, const bf16* __restrict__ hT, bf16* __restrict__ z1)
{
    constexpr int SA  = 104;   // Asq/Bt row stride (96 data + pad), 16B-aligned
    constexpr int SH  = 72;    // Hs row stride (64 data + pad)
    constexpr int SPP = 72;    // P  row stride (64 data + pad)
    __shared__ bf16 Asq[2][64*SA];   // 26624 B: per-slab q rows (persist)
    __shared__ bf16 Bt[64*SA];       // 13312 B: shared c-rows tile
    __shared__ bf16 Hs[128*SH];      // 18432 B: shared hT tile (rows 104..127 zero)
    __shared__ bf16 P[2][64*SPP];    // 18432 B: per-slab probabilities
    __shared__ float rsb[2][2][64];  //  2048 B

    int bid = blockIdx.x;
    int xcd = bid & 7;               // all blocks of one t share an XCD/L2
    int j = bid >> 3;
    int tq = j >> 2, pair = j & 3;
    int t = tq*8 + xcd;
    if (t >= TT) return;

    int tid = threadIdx.x;
    int lane = tid & 63, w = tid >> 6;            // 8 waves
    int slab = w >> 2, wsl = w & 3;
    int qi = wsl >> 1, ci = wsl & 1;
    int n32 = lane & 31, koct = lane >> 5;
    int r0 = (pair*2 + slab)*64;                  // up to 448; masked at write

    {
        const uint4* src = (const uint4*)(adp_bf + ((size_t)t*NN + pair*128)*96);
        #pragma unroll
        for (int i = 0; i < 3; ++i) {
            int idx = tid + i*512;                // < 1536
            int s2 = idx / 768, rem = idx - s2*768;
            int r = rem / 12, q = rem - r*12;
            *(uint4*)(&Asq[s2][r*SA + q*8]) = src[idx];
        }
    }
    {
        uint4 z4v = {0u,0u,0u,0u};
        for (int idx = tid; idx < 216; idx += 512) {
            int rr = idx / 9;
            int r = 104 + rr, q = idx - rr*9;
            *(uint4*)(&Hs[r*SH + q*8]) = z4v;
        }
    }

    float16v on0, on1;
    #pragma unroll
    for (int i = 0; i < 16; ++i) { on0[i] = 0.f; on1[i] = 0.f; }
    float rs2[16];
    #pragma unroll
    for (int i = 0; i < 16; ++i) rs2[i] = 0.f;

    const bf16* hbase = hT + (size_t)t*104*448;

    uint4 preB0, preB1, preH0, preH1;
    {
        const uint4* srcB = (const uint4*)(adp_bf + (size_t)t*NN*96);
        preB0 = srcB[tid];
        if (tid < 256) preB1 = srcB[tid + 512];
        { int r = tid >> 3, q = tid & 7;
          preH0 = *(const uint4*)(hbase + (size_t)r*448 + q*8); }
        if (tid < 320) { int idx = tid + 512; int r = idx >> 3, q = idx & 7;
          preH1 = *(const uint4*)(hbase + (size_t)r*448 + q*8); }
    }

    for (int c0 = 0; c0 < NN; c0 += 64) {
        { int r = tid / 12, q = tid - (tid/12)*12;
          *(uint4*)(&Bt[r*SA + q*8]) = preB0; }
        if (tid < 256) { int idx = tid + 512; int r = idx / 12, q = idx - r*12;
          *(uint4*)(&Bt[r*SA + q*8]) = preB1; }
        { int r = tid >> 3, q = tid & 7;
          *(uint4*)(&Hs[r*SH + q*8]) = preH0; }
        if (tid < 320) { int idx = tid + 512; int r = idx >> 3, q = idx & 7;
          *(uint4*)(&Hs[r*SH + q*8]) = preH1; }
        __syncthreads();                          // barA (covers Asq on iter 0)
        int cn = c0 + 64;
        if (cn < NN) {
            const uint4* srcB = (const uint4*)(adp_bf + ((size_t)t*NN + cn)*96);
            preB0 = srcB[tid];
            if (tid < 256) preB1 = srcB[tid + 512];
            { int r = tid >> 3, q = tid & 7;
              preH0 = *(const uint4*)(hbase + (size_t)r*448 + cn + q*8); }
            if (tid < 320) { int idx = tid + 512; int r = idx >> 3, q = idx & 7;
              preH1 = *(const uint4*)(hbase + (size_t)r*448 + cn + q*8); }
        }
        float16v sc;
        #pragma unroll
        for (int i = 0; i < 16; ++i) sc[i] = 0.f;
        #pragma unroll
        for (int s = 0; s < 6; ++s) {
            short8v afq = *(const short8v*)(&Asq[slab][(qi*32 + n32)*SA + s*16 + koct*8]);
            short8v bfr = *(const short8v*)(&Bt[(ci*32 + n32)*SA + s*16 + koct*8]);
            sc = __builtin_amdgcn_mfma_f32_32x32x16_bf16(afq, bfr, sc, 0, 0, 0);
        }
        bool colok = (c0 + ci*32 + n32) < NN;
        #pragma unroll
        for (int reg = 0; reg < 16; ++reg) {
            int crow = (reg & 3) + 8*(reg >> 2) + 4*koct;
            float e = colok ? __expf(fmaxf(sc[reg], 0.f)) : 0.f;
            rs2[reg] += e;
            P[slab][(qi*32 + crow)*SPP + ci*32 + n32] = f2b(e);
        }
        __syncthreads();                          // barB: P complete (cross-wave)
        short8v pA[4];
        #pragma unroll
        for (int s = 0; s < 4; ++s)
            pA[s] = *(const short8v*)(&P[slab][(qi*32 + n32)*SPP + s*16 + koct*8]);
        #pragma unroll
        for (int s = 0; s < 4; ++s) {
            short8v hb0 = *(const short8v*)(&Hs[(ci*32 + n32)*SH + s*16 + koct*8]);
            on0 = __builtin_amdgcn_mfma_f32_32x32x16_bf16(pA[s], hb0, on0, 0, 0, 0);
        }
        #pragma unroll
        for (int s = 0; s < 4; ++s) {
            short8v hb1 = *(const short8v*)(&Hs[((ci+2)*32 + n32)*SH + s*16 + koct*8]);
            on1 = __builtin_amdgcn_mfma_f32_32x32x16_bf16(pA[s], hb1, on1, 0, 0, 0);
        }
        __syncthreads();                          // barC: reads done before restage
    }

    #pragma unroll
    for (int reg = 0; reg < 16; ++reg) {
        float v = rs2[reg];
        v += __shfl_xor(v, 1, 64);
        v += __shfl_xor(v, 2, 64);
        v += __shfl_xor(v, 4, 64);
        v += __shfl_xor(v, 8, 64);
        v += __shfl_xor(v, 16, 64);
        if (n32 == 0) {
            int crow = (reg & 3) + 8*(reg >> 2) + 4*koct;
            rsb[slab][ci][qi*32 + crow] = v;
        }
    }
    __syncthreads();

    #pragma unroll
    for (int reg = 0; reg < 16; ++reg) {
        int crow = (reg & 3) + 8*(reg >> 2) + 4*koct;
        int qrow = qi*32 + crow;
        int gq = r0 + qrow;
        if (gq < NN) {
            float inv = 1.f / (rsb[slab][0][qrow] + rsb[slab][1][qrow]);
            int d0 = ci*32 + n32;
            z1[((size_t)t*NN + gq)*104 + d0] = f2b(on0[reg] * inv);
            int d1 = (ci + 2)*32 + n32;
            if (d1 < 104)
                z1[((size_t)t*NN + gq)*104 + d1] = f2b(on1[reg] * inv);
        }
    }
}

// ---------------- MFMA KV summaries (spatial + temporal) ----------------
__global__ void __launch_bounds__(256) kvs_mf(
    const bf16* __restrict__ qkv, bf16* __restrict__ kvsb_s, bf16* __restrict__ kvsb_t)
{
    constexpr int CK = 32;          // l-chunk
    constexpr int TS = 40;          // padded row stride
    __shared__ bf16 raw[CK][216];   // 208 used (k|v span, qkv cols 104..311)
    __shared__ bf16 kTn[4][32][TS]; // per-head kn^T tile (rows 26..31 unused)
    __shared__ bf16 vT [4][32][TS]; // per-head v^T tile + ones row 26
    __shared__ float invs[CK][4];

    int bb = blockIdx.x;
    bf16* out; int L; long long strideL, base;
    if (bb < TT) { out = kvsb_s + (size_t)bb*NTILE; L = NN; base = (long long)bb*NN*312 + 104; strideL = 312; }
    else { int n = bb - TT; out = kvsb_t + (size_t)n*NTILE; L = TT; base = (long long)n*312 + 104; strideL = (long long)NN*312; }

    int tid = threadIdx.x;
    int lane = tid & 63, w = tid >> 6;       // wave = head
    int n32 = lane & 31, koct = lane >> 5;
    uint4 z4 = {0u,0u,0u,0u};

    float16v acc;
    #pragma unroll
    for (int i = 0; i < 16; ++i) acc[i] = 0.f;

    uint4 pre[4];
    #pragma unroll
    for (int j = 0; j < 4; ++j) {
        int idx = tid + j*256;
        uint4 v = z4;
        if (idx < CK*26) {
            int r = idx / 26, q = idx - r*26;
            if (r < L) v = *(const uint4*)(qkv + base + (long long)r*strideL + q*8);
        }
        pre[j] = v;
    }

    for (int l0 = 0; l0 < L; l0 += CK) {
        int lw = min(CK, L - l0);
        __syncthreads();
        #pragma unroll
        for (int j = 0; j < 4; ++j) {
            int idx = tid + j*256;
            if (idx < CK*26) {
                int r = idx / 26, q = idx - r*26;
                *(uint4*)(&raw[r][q*8]) = pre[j];
            }
        }
        __syncthreads();
        {
            int ln0 = l0 + CK;
            #pragma unroll
            for (int j = 0; j < 4; ++j) {
                int idx = tid + j*256;
                uint4 v = z4;
                if (idx < CK*26 && ln0 < L) {
                    int r = idx / 26, q = idx - r*26;
                    if (r < L - ln0) v = *(const uint4*)(qkv + base + (long long)(ln0 + r)*strideL + q*8);
                }
                pre[j] = v;
            }
        }
        if (tid < CK*4) {
            int l = tid >> 2, h = tid & 3;
            float ss = 0.f;
            #pragma unroll
            for (int m = 0; m < HD; ++m) { float v = b2f(raw[l][h*HD + m]); ss += v*v; }
            invs[l][h] = (l < lw) ? 1.f/fmaxf(sqrtf(ss), 1e-12f) : 0.f;
        }
        __syncthreads();
        for (int idx = tid; idx < 4*CK*HD; idx += 256) {
            int h = idx / (CK*HD); int rem = idx - h*CK*HD;
            int l = rem / HD; int m = rem - l*HD;
            float iv = invs[l][h];
            kTn[h][m][l] = f2b(b2f(raw[l][h*HD + m]) * iv);
            vT[h][m][l]  = raw[l][104 + h*HD + m];
        }
        if (tid < 4*CK) {
            int h = tid >> 5, l = tid & 31;
            vT[h][26][l] = f2b((l < lw) ? 1.f : 0.f);
        }
        __syncthreads();
        #pragma unroll
        for (int s = 0; s < 2; ++s) {
            short8v a = *(const short8v*)(&kTn[w][n32][s*16 + koct*8]);
            short8v b = *(const short8v*)(&vT [w][n32][s*16 + koct*8]);
            acc = __builtin_amdgcn_mfma_f32_32x32x16_bf16(a, b, acc, 0, 0, 0);
        }
    }

    int lo = w*HD;
    #pragma unroll
    for (int reg = 0; reg < 16; ++reg) {
        int m = (reg & 3) + 8*(reg >> 2) + 4*koct;
        if (m < HD) {
            if (n32 < HD)       out[(size_t)(lo + n32)*32 + m] = f2b(acc[reg]);
            else if (n32 == HD) out[(size_t)(104 + w)*32 + m] = f2b(acc[reg]);
        }
    }
}

// ---------------- MFMA linear-attention apply (temporal only) ----------------
// R11: per-slot iq/rden transform — one rsqrt+div per THREAD replaces
// ~56 transcendentals/thread in the epilogue.
__global__ void __launch_bounds__(256) attn_mm(
    bf16* __restrict__ qkv, const bf16* __restrict__ kvsb,
    int M, long long bStride, long long rowStride, float Lf, int outOff)
{
    constexpr int STR = 136;
    __shared__ bf16 As[64*STR];
    __shared__ bf16 Ws[112*STR];
    __shared__ float nsqL[256];
    __shared__ float denL[256];
    int mt = blockIdx.x, bb = blockIdx.y;
    int tid = threadIdx.x;
    int lane = tid & 63, w = tid >> 6, n16 = lane & 15, quad = lane >> 4;
    bf16* base = qkv + (size_t)bb * bStride;
    int r0 = mt*64;
    uint4 z4 = {0u,0u,0u,0u};

    for (int idx = tid; idx < 64*16; idx += 256) {
        int r = idx >> 4, q = idx & 15;
        int m = r0 + r;
        uint4 v = z4;
        if (m < M && q < 13) v = *(const uint4*)(base + (size_t)m*rowStride + q*8);
        *(uint4*)(&As[r*STR + q*8]) = v;
    }
    for (int idx = tid; idx < 112*16; idx += 256) {
        int c = idx >> 4, q = idx & 15;
        *(uint4*)(&Ws[c*STR + q*8]) = z4;
    }
    __syncthreads();
    {
        const bf16* kb = kvsb + (size_t)bb * NTILE;
        for (int idx = tid; idx < 108*13; idx += 256) {
            int c = idx / 13, qu = idx - c*13;
            int lo = (c < 104) ? (c/26)*26 : (c-104)*26;
            *(uint*)(&Ws[c*STR + lo + qu*2]) = *(const uint*)(kb + (size_t)c*32 + qu*2);
        }
    }
    __syncthreads();

    short8v af[4];
    #pragma unroll
    for (int s = 0; s < 4; ++s)
        af[s] = *(const short8v*)(&As[(16*w + n16)*STR + s*32 + quad*8]);
    float4v acc[7];
    #pragma unroll
    for (int ct = 0; ct < 7; ++ct) { float4v z = {0.f,0.f,0.f,0.f}; acc[ct] = z; }
    #pragma unroll
    for (int ct = 0; ct < 7; ++ct) {
        #pragma unroll
        for (int s = 0; s < 4; ++s) {
            short8v bfr = *(const short8v*)(&Ws[(ct*16 + n16)*STR + s*32 + quad*8]);
            acc[ct] = __builtin_amdgcn_mfma_f32_16x16x32_bf16(af[s], bfr, acc[ct], 0, 0, 0);
        }
    }
    {
        int row = tid >> 2, hh = tid & 3;
        const bf16* qr = &As[row*STR + hh*26];
        float ss = 0.f;
        #pragma unroll
        for (int m = 0; m < HD; ++m) { float v = b2f(qr[m]); ss += v*v; }
        nsqL[row*4 + hh] = ss;
    }
    if (n16 >= 8 && n16 < 12) {
        #pragma unroll
        for (int reg = 0; reg < 4; ++reg)
            denL[(16*w + quad*4 + reg)*4 + (n16 - 8)] = acc[6][reg];
    }
    __syncthreads();
    // per-slot transform: nsqL <- iq, denL <- 1/den (one per thread)
    {
        float iq = rsqrtf(fmaxf(nsqL[tid], 1e-24f));
        float rd = 1.f / (iq * denL[tid] + Lf);
        nsqL[tid] = iq;
        denL[tid] = rd;
    }
    __syncthreads();
    #pragma unroll
    for (int ct = 0; ct < 7; ++ct) {
        int c = ct*16 + n16;
        if (c < 104) {
            int hh = c / 26;
            #pragma unroll
            for (int reg = 0; reg < 4; ++reg) {
                int lr = 16*w + quad*4 + reg;
                int m = r0 + lr;
                if (m < M) {
                    bf16* rp = base + (size_t)m*rowStride;
                    float num = nsqL[lr*4 + hh] * acc[ct][reg] + Lf * b2f(rp[208 + c]);
                    rp[outOff + c] = f2b(num * denL[lr*4 + hh]);
                }
            }
        }
    }
}

// ---------------- R8-R11: fused spatial attn + op projection ----------------
// R11: kvs band prefetched to regs at entry (removes the last exposed
// global-latency phase); per-slot iq/rden transform replaces ~56
// transcendentals/thread in the epilogue with 1 rsqrt + 1 div per thread.
__global__ void __launch_bounds__(256) attn_op(
    const bf16* __restrict__ qkv, const bf16* __restrict__ kvsb,
    const bf16* __restrict__ wt, const float* __restrict__ bias,
    bf16* __restrict__ Cout, float Lf)
{
    constexpr int SA = 328;      // 312 data + 16 pad (16B-aligned)
    constexpr int SW = 136;
    __shared__ bf16 Acat[64*SA];     // 41984 B
    __shared__ bf16 Ws[112*SW];      // 30464 B (band, then op-W halves)
    __shared__ float nsqL[256];
    __shared__ float denL[256];
    int mt = blockIdx.x, t = blockIdx.y;
    int tid = threadIdx.x;
    int lane = tid & 63, w = tid >> 6, n16 = lane & 15, quad = lane >> 4;
    const bf16* base = qkv + (size_t)t * ((size_t)NN*312);
    const bf16* kb = kvsb + (size_t)t * NTILE;
    int r0 = mt*64;
    uint4 z4 = {0u,0u,0u,0u};

    // T14: issue op-W half-1 + kvs-band loads NOW (fly under the A-stage).
    uint4 preW[7];
    #pragma unroll
    for (int j = 0; j < 7; ++j) {
        int idx = tid + j*256;               // 112*16 = 1792 slots
        int c = idx >> 4, q = idx & 15;
        uint4 v = z4;
        if (c < 104) v = *(const uint4*)(wt + (size_t)c*224 + q*8);
        preW[j] = v;
    }
    uint preKB[6];
    #pragma unroll
    for (int j = 0; j < 6; ++j) {
        int idx = tid + j*256;               // 108*13 = 1404 slots
        uint v = 0;
        if (idx < 1404) {
            int c = idx / 13, qu = idx - c*13;
            v = *(const uint*)(kb + (size_t)c*32 + qu*2);
        }
        preKB[j] = v;
    }

    // stage A rows: full qkv rows, cols 0..311 = [q|out_t|v]
    for (int idx = tid; idx < 64*39; idx += 256) {
        int r = idx / 39, q = idx - r*39;
        int m = r0 + r;
        uint4 v = z4;
        if (m < NN) v = *(const uint4*)(base + (size_t)m*312 + q*8);
        *(uint4*)(&Acat[r*SA + q*8]) = v;
    }
    // stage Ws: zero, then band committed from registers after the barrier
    for (int idx = tid; idx < 112*16; idx += 256) {
        int c = idx >> 4, q = idx & 15;
        *(uint4*)(&Ws[c*SW + q*8]) = z4;
    }
    __syncthreads();
    #pragma unroll
    for (int j = 0; j < 6; ++j) {
        int idx = tid + j*256;
        if (idx < 1404) {
            int c = idx / 13, qu = idx - c*13;
            int lo = (c < 104) ? (c/26)*26 : (c-104)*26;
            *(uint*)(&Ws[c*SW + lo + qu*2]) = preKB[j];
        }
    }
    __syncthreads();

    // ---- spatial attention ----
    short8v af[4];
    #pragma unroll
    for (int s = 0; s < 4; ++s)
        af[s] = *(const short8v*)(&Acat[(16*w + n16)*SA + s*32 + quad*8]);
    float4v acc[7];
    #pragma unroll
    for (int ct = 0; ct < 7; ++ct) { float4v z = {0.f,0.f,0.f,0.f}; acc[ct] = z; }
    #pragma unroll
    for (int ct = 0; ct < 7; ++ct) {
        #pragma unroll
        for (int s = 0; s < 4; ++s) {
            short8v bfr = *(const short8v*)(&Ws[(ct*16 + n16)*SW + s*32 + quad*8]);
            acc[ct] = __builtin_amdgcn_mfma_f32_16x16x32_bf16(af[s], bfr, acc[ct], 0, 0, 0);
        }
    }
    {
        int row = tid >> 2, hh = tid & 3;
        const bf16* qr = &Acat[row*SA + hh*26];
        float ss = 0.f;
        #pragma unroll
        for (int m = 0; m < HD; ++m) { float v = b2f(qr[m]); ss += v*v; }
        nsqL[row*4 + hh] = ss;
    }
    if (n16 >= 8 && n16 < 12) {
        #pragma unroll
        for (int reg = 0; reg < 4; ++reg)
            denL[(16*w + quad*4 + reg)*4 + (n16 - 8)] = acc[6][reg];
    }
    __syncthreads();      // attn reads of Ws/Acat(q) done; nsq/den published
    // per-slot transform: nsqL <- iq, denL <- 1/den (one per thread)
    {
        float iq = rsqrtf(fmaxf(nsqL[tid], 1e-24f));
        float rd = 1.f / (iq * denL[tid] + Lf);
        nsqL[tid] = iq;
        denL[tid] = rd;
    }
    __syncthreads();

    // ---- epilogue: out_s -> Acat cols 0..103 (v from LDS); commit preW1; issue preW2 ----
    #pragma unroll
    for (int ct = 0; ct < 7; ++ct) {
        int c = ct*16 + n16;
        if (c < 104) {
            int hh = c / 26;
            #pragma unroll
            for (int reg = 0; reg < 4; ++reg) {
                int lr = 16*w + quad*4 + reg;
                int m = r0 + lr;
                if (m < NN) {
                    float num = nsqL[lr*4 + hh] * acc[ct][reg] + Lf * b2f(Acat[lr*SA + 208 + c]);
                    Acat[lr*SA + c] = f2b(num * denL[lr*4 + hh]);
                }
            }
        }
    }
    #pragma unroll
    for (int j = 0; j < 7; ++j) {        // commit half 1 (waitcnt for entry loads)
        int idx = tid + j*256;
        int c = idx >> 4, q = idx & 15;
        *(uint4*)(&Ws[c*SW + q*8]) = preW[j];
    }
    #pragma unroll
    for (int j = 0; j < 7; ++j) {        // issue half 2; overlaps half-1 MFMAs
        int idx = tid + j*256;
        int c = idx >> 4, q = idx & 15;
        uint4 v = z4;
        if (c < 104 && q < 12) v = *(const uint4*)(wt + (size_t)c*224 + 128 + q*8);
        preW[j] = v;
    }
    __syncthreads();

    // ---- op projection: C = Acat(64x208) @ W(208x104) + bias ----
    short8v af2[7];
    #pragma unroll
    for (int s = 0; s < 7; ++s)
        af2[s] = *(const short8v*)(&Acat[(16*w + n16)*SA + s*32 + quad*8]);
    float4v acc2[7];
    #pragma unroll
    for (int ct = 0; ct < 7; ++ct) { float4v z = {0.f,0.f,0.f,0.f}; acc2[ct] = z; }
    #pragma unroll
    for (int ct = 0; ct < 7; ++ct)
        #pragma unroll
        for (int s = 0; s < 4; ++s) {
            short8v bfr = *(const short8v*)(&Ws[(ct*16 + n16)*SW + s*32 + quad*8]);
            acc2[ct] = __builtin_amdgcn_mfma_f32_16x16x32_bf16(af2[s], bfr, acc2[ct], 0, 0, 0);
        }
    __syncthreads();
    #pragma unroll
    for (int j = 0; j < 7; ++j) {        // commit half 2
        int idx = tid + j*256;
        int c = idx >> 4, q = idx & 15;
        *(uint4*)(&Ws[c*SW + q*8]) = preW[j];
    }
    __syncthreads();
    #pragma unroll
    for (int ct = 0; ct < 7; ++ct)
        #pragma unroll
        for (int s = 4; s < 7; ++s) {
            short8v bfr = *(const short8v*)(&Ws[(ct*16 + n16)*SW + (s-4)*32 + quad*8]);
            acc2[ct] = __builtin_amdgcn_mfma_f32_16x16x32_bf16(af2[s], bfr, acc2[ct], 0, 0, 0);
        }

    #pragma unroll
    for (int ct = 0; ct < 7; ++ct) {
        int c = ct*16 + n16;
        if (c < 104) {
            float b = bias[c];
            #pragma unroll
            for (int reg = 0; reg < 4; ++reg) {
                int m = r0 + 16*w + quad*4 + reg;
                if (m < NN)
                    Cout[((size_t)t*NN + m)*104 + c] = f2b(acc2[ct][reg] + b);
            }
        }
    }
}

__global__ void __launch_bounds__(256) y_init_kernel(float* __restrict__ y, const float* __restrict__ ep_b) {
    int i = blockIdx.x*256 + threadIdx.x;
    if (i < NN*104) y[i] = ep_b[i % 104];
}

// ---------------- fused tail: 2 rows/block, ILP on the dot chains ----------------
__global__ void __launch_bounds__(256) tail_kernel(
    const float* __restrict__ y,
    const float* __restrict__ ew1, const float* __restrict__ eb1,
    const float* __restrict__ ew2, const float* __restrict__ eb2,
    const float* __restrict__ out_w, const float* __restrict__ out_b,
    float* __restrict__ out)
{
    int n0 = blockIdx.x * 2;               // 200 blocks x 2 rows
    int tid = threadIdx.x;
    __shared__ float yr[2][104], hid[2][208];
    if (tid < 104) {
        yr[0][tid] = y[(size_t)n0*104 + tid];
        yr[1][tid] = y[(size_t)(n0+1)*104 + tid];
    }
    __syncthreads();
    for (int i = 0; i < 3; ++i) {
        const float* w1 = ew1 + (size_t)i*104*208;
        const float* b1 = eb1 + (size_t)i*208;
        const float* w2 = ew2 + (size_t)i*208*104;
        const float* b2 = eb2 + (size_t)i*104;
        if (tid < 208) {
            float a0 = b1[tid], a1 = a0;
            #pragma unroll 8
            for (int k = 0; k < 104; ++k) {
                float w = w1[(size_t)k*208 + tid];
                a0 += yr[0][k]*w; a1 += yr[1][k]*w;
            }
            hid[0][tid] = fmaxf(a0, 0.f);
            hid[1][tid] = fmaxf(a1, 0.f);
        }
        __syncthreads();
        float y0 = 0.f, y1 = 0.f;
        if (tid < 104) {
            float a0 = b2[tid], a1 = a0;
            #pragma unroll 8
            for (int k = 0; k < 208; ++k) {
                float w = w2[(size_t)k*104 + tid];
                a0 += hid[0][k]*w; a1 += hid[1][k]*w;
            }
            y0 = yr[0][tid] + a0; y1 = yr[1][tid] + a1;
        }
        __syncthreads();
        if (tid < 104) { yr[0][tid] = y0; yr[1][tid] = y1; }
        __syncthreads();
    }
    for (int t = tid; t < TT; t += 256) {
        float a0 = out_b[t], a1 = a0;
        #pragma unroll 8
        for (int d = 0; d < 104; ++d) {
            float w = out_w[(size_t)d*TT + t];
            a0 += yr[0][d]*w; a1 += yr[1][d]*w;
        }
        out[(size_t)n0*TT + t] = a0;
        out[(size_t)(n0+1)*TT + t] = a1;
    }
}

// ---------------- launch ----------------
extern "C" void kernel_launch(void* const* d_in, const int* in_sizes, int n_in,
                              void* d_out, int out_size, void* d_ws, size_t ws_size,
                              hipStream_t stream) {
    if (ws_size < WS_NEEDED) return;

    const float* x      = (const float*)d_in[0];
    const float* W_in   = (const float*)d_in[1];
    const float* b_in   = (const float*)d_in[2];
    const float* adp    = (const float*)d_in[3];
    const float* W_tp   = (const float*)d_in[4];
    const float* b_tp   = (const float*)d_in[5];
    const float* qkv_w  = (const float*)d_in[6];
    const float* op_w   = (const float*)d_in[7];
    const float* op_b   = (const float*)d_in[8];
    const float* pw_w   = (const float*)d_in[9];
    const float* pw_b   = (const float*)d_in[10];
    const float* fc_w1  = (const float*)d_in[11];
    const float* fc_b1  = (const float*)d_in[12];
    const float* fc_w2  = (const float*)d_in[13];
    const float* fc_b2  = (const float*)d_in[14];
    const float* ln1_g  = (const float*)d_in[15];
    const float* ln1_b  = (const float*)d_in[16];
    const float* ln2_g  = (const float*)d_in[17];
    const float* ln2_b  = (const float*)d_in[18];
    const float* ep_w   = (const float*)d_in[19];
    const float* ep_b   = (const float*)d_in[20];
    const float* enc_w1 = (const float*)d_in[21];
    const float* enc_b1 = (const float*)d_in[22];
    const float* enc_w2 = (const float*)d_in[23];
    const float* enc_b2 = (const float*)d_in[24];
    const float* out_w  = (const float*)d_in[25];
    const float* out_b  = (const float*)d_in[26];

    bf16* B0 = (bf16*)d_ws;
    bf16* B1 = B0 + NB0;
    bf16* B2 = B1 + NB1;
    bf16* B3 = B2 + NB2;
    bf16* kvsb_s = B3 + NB3;
    bf16* kvsb_t = kvsb_s + NKVSB_S;
    float* ybuf  = (float*)(kvsb_t + NKVSB_T);
    bf16* wtp   = (bf16*)(ybuf + NY);
    bf16* wqkv0 = wtp + NW_TP;
    bf16* wqkv1 = wqkv0 + NW_QKV;
    bf16* wop0  = wqkv1 + NW_QKV;
    bf16* wop1  = wop0 + NW_OP;
    bf16* wpw0  = wop1 + NW_OP;
    bf16* wpw1  = wpw0 + NW_PW;
    bf16* wfc1  = wpw1 + NW_PW;
    bf16* wfc2  = wfc1 + NW_FC1;
    bf16* wept  = wfc2 + NW_FC2;
    bf16* adp_bf = B2;
    bf16* hTbuf  = B2 + NADP;

    // 0. weight prep
    prep_w<<<CEILDIV(104*128,256), 256, 0, stream>>>(W_tp, wtp, 104, 104, 128);
    prep_w<<<CEILDIV(312*128,256), 256, 0, stream>>>(qkv_w, wqkv0, 104, 312, 128);
    prep_w<<<CEILDIV(312*128,256), 256, 0, stream>>>(qkv_w + 104*312, wqkv1, 104, 312, 128);
    prep_w<<<CEILDIV(104*224,256), 256, 0, stream>>>(op_w, wop0, 208, 104, 224);
    prep_w<<<CEILDIV(104*224,256), 256, 0, stream>>>(op_w + 208*104, wop1, 208, 104, 224);
    prep_w<<<CEILDIV(104*128,256), 256, 0, stream>>>(pw_w, wpw0, 104, 104, 128);
    prep_w<<<CEILDIV(104*128,256), 256, 0, stream>>>(pw_w + 104*104, wpw1, 104, 104, 128);
    prep_w<<<CEILDIV(208*128,256), 256, 0, stream>>>(fc_w1, wfc1, 104, 208, 128);
    prep_w<<<CEILDIV(104*224,256), 256, 0, stream>>>(fc_w2, wfc2, 208, 104, 224);
    prep_wT<<<CEILDIV(37960,64), 256, 0, stream>>>(ep_w, wept);

    const int GX = CEILDIV(TN, 64);     // 2282

    // 1. hcat -> B2
    hcat_kernel<<<CEILDIV(TN,16), 256, 0, stream>>>(x, W_in, b_in, adp, B2);
    // 2. h = hcat @ W_tp + b_tp -> B0
    gemm_mf<128><<<GX*2, 256, 0, stream>>>(B2, 104, 104, wtp, b_tp, B0, TN, 104, 0);
    // 2b. z1 pre-staging into B2
    prep_adp<<<CEILDIV((int)NADP,256), 256, 0, stream>>>(adp, adp_bf);
    ht_kernel<<<dim3(7, TT), 256, 0, stream>>>(B0, hTbuf);
    // 3. z1 -> B1
    z1_mf<<<Z1_BLOCKS, 512, 0, stream>>>(adp_bf, hTbuf, B1);
    // 4. attention 0 on h
    gemm_mf<128><<<GX*5, 256, 0, stream>>>(B0, 104, 104, wqkv0, nullptr, B2, TN, 312, 0);
    kvs_mf<<<TT+NN, 256, 0, stream>>>(B2, kvsb_s, kvsb_t);
    attn_mm<<<dim3(6, NN), 256, 0, stream>>>(B2, kvsb_t, TT, 312, (long long)NN*312, (float)TT, 104);
    attn_op<<<dim3(7, TT), 256, 0, stream>>>(B2, kvsb_s, wop0, op_b, B3, (float)NN);   // att0 -> B3
    // 5. attention 1 on z1
    gemm_mf<128><<<GX*5, 256, 0, stream>>>(B1, 104, 104, wqkv1, nullptr, B2, TN, 312, 0);
    kvs_mf<<<TT+NN, 256, 0, stream>>>(B2, kvsb_s, kvsb_t);
    attn_mm<<<dim3(6, NN), 256, 0, stream>>>(B2, kvsb_t, TT, 312, (long long)NN*312, (float)TT, 104);
    attn_op<<<dim3(7, TT), 256, 0, stream>>>(B2, kvsb_s, wop1, op_b + 104, B1, (float)NN); // att1 -> B1
    // 6+7. fused gates + LN1 (in-place B0 -> h1)
    gate_ln1<<<GX, 256, 0, stream>>>(B0, B3, B1, wpw0, wpw1, pw_b, ln1_g, ln1_b);
    // 8. MLP: fc1 -> hidden (B2), fused fc2+LN2 -> h2 (B3)
    gemm_mf<128><<<GX*4, 256, 0, stream>>>(B0, 104, 104, wfc1, fc_b1, B2, TN, 208, 1);
    fc2_ln2<<<GX, 256, 0, stream>>>(B2, wfc2, fc_b2, B0, ln2_g, ln2_b, B3);
    // 9. encoder_proj
    y_init_kernel<<<CEILDIV(NN*104,256), 256, 0, stream>>>(ybuf, ep_b);
    ep_mf<<<dim3(CEILDIV(NN,64), 2, CEILDIV(TT,8)), 256, 0, stream>>>(B3, wept, ybuf);
    // 10+11. fused residual MLP blocks + output projection (2 rows/block)
    tail_kernel<<<NN/2, 256, 0, stream>>>(ybuf, enc_w1, enc_b1, enc_w2, enc_b2,
                                          out_w, out_b, (float*)d_out);
}

// Round 12
// 1089.036 us; speedup vs baseline: 1.2512x; 1.0401x over previous
//
#include <hip/hip_runtime.h>
#include <hip/hip_bf16.h>
#include <cstddef>

// ---------------- problem constants ----------------
#define TT   365
#define NN   400
#define TN   (TT*NN)            // 146000
#define HD   26                 // head dim
#define NH   4                  // heads

#define CEILDIV(a,b) (((a)+(b)-1)/(b))

typedef __hip_bfloat16 bf16;
typedef short short8v __attribute__((ext_vector_type(8)));
typedef float float4v __attribute__((ext_vector_type(4)));
typedef float float16v __attribute__((ext_vector_type(16)));
__device__ __forceinline__ float b2f(bf16 v){ return __bfloat162float(v); }
__device__ __forceinline__ bf16  f2b(float v){ return __float2bfloat16(v); }

// ---------------- workspace layout ----------------
static constexpr size_t NB0 = (size_t)TN*104;   // h / h1
static constexpr size_t NB1 = (size_t)TN*104;   // z1 -> att1
static constexpr size_t NB2 = (size_t)TN*312;   // hcat -> [adp_bf|hT] -> qkv+concat -> hidden
static constexpr size_t NB3 = (size_t)TN*104;   // att0 -> h2
static constexpr size_t NBF = NB0+NB1+NB2+NB3;
// compact band KV tiles: per b, 108 rows x 32 (band cols 0..25), bf16
static constexpr size_t NTILE   = (size_t)108*32;
static constexpr size_t NKVSB_S = (size_t)TT*NTILE;
static constexpr size_t NKVSB_T = (size_t)NN*NTILE;
static constexpr size_t NY      = (size_t)NN*104;
// transposed bf16 weights (Wt[n][kp], zero-padded k)
static constexpr size_t NW_TP   = 104*128;
static constexpr size_t NW_QKV  = 312*128;   // x2
static constexpr size_t NW_OP   = 104*224;   // x2
static constexpr size_t NW_PW   = 104*128;   // x2
static constexpr size_t NW_FC1  = 208*128;
static constexpr size_t NW_FC2  = 104*224;
static constexpr size_t NW_EPT  = (size_t)104*37960;   // ep_w transposed, no pad
static constexpr size_t NWT     = NW_TP + 2*NW_QKV + 2*NW_OP + 2*NW_PW + NW_FC1 + NW_FC2 + NW_EPT;
static constexpr size_t WS_NEEDED = NBF*2 + (NKVSB_S+NKVSB_T)*2 + NY*4 + NWT*2;
// z1 scratch lives inside B2 (dead between step 2 and step 4):
static constexpr size_t NADP_ROWS = (size_t)TN + 64;
static constexpr size_t NADP = NADP_ROWS*96;
static constexpr size_t NHT  = ((size_t)TT*104 + 8)*448;
static_assert(NADP + NHT <= NB2, "z1 scratch must fit in B2");

// ---------------- weight prep: Wt[n*KP+k] = bf16(W[k*Nc+n]), zero pad k>=K ----------------
__global__ void __launch_bounds__(256) prep_w(
    const float* __restrict__ W, bf16* __restrict__ Wt, int K, int Nc, int KP)
{
    int idx = blockIdx.x*256 + threadIdx.x;
    if (idx >= Nc*KP) return;
    int n = idx / KP, k = idx - n*KP;
    Wt[idx] = (k < K) ? f2b(W[(size_t)k*Nc + n]) : f2b(0.f);
}

// coalesced LDS transpose for ep weights: Wt[n][k] = bf16(W[k][n]); W is 37960x104 fp32
__global__ void __launch_bounds__(256) prep_wT(
    const float* __restrict__ W, bf16* __restrict__ Wt)
{
    __shared__ float T[64][105];
    int k0 = blockIdx.x * 64;
    int tid = threadIdx.x;
    for (int idx = tid; idx < 64*104; idx += 256) {
        int r = idx / 104, c = idx - r*104;
        int k = k0 + r;
        T[r][c] = (k < 37960) ? W[(size_t)k*104 + c] : 0.f;
    }
    __syncthreads();
    for (int idx = tid; idx < 104*32; idx += 256) {
        int n = idx >> 5, kp = idx & 31;
        int k = kp*2;
        if (k0 + k + 1 < 37960 || k0 + k < 37960) {
            if (k0 + k < 37960) {
                bf16 lo = f2b(T[k][n]);
                bf16 hi = f2b(T[k+1][n]);   // k+1 row is zero-padded if OOB of tile data
                uint v = ((uint)(*(ushort*)&hi) << 16) | (*(ushort*)&lo);
                if (k0 + k + 1 < 37960) *(uint*)(Wt + (size_t)n*37960 + k0 + k) = v;
                else Wt[(size_t)n*37960 + k0 + k] = lo;
            }
        }
    }
}

// adp_bf[row][e] = bf16(adp[row][e]) for e<80 else 0; rows >= TN are zero.
__global__ void __launch_bounds__(256) prep_adp(
    const float* __restrict__ adp, bf16* __restrict__ out)
{
    size_t i = (size_t)blockIdx.x*256 + threadIdx.x;
    if (i >= NADP) return;
    size_t row = i / 96; int e = (int)(i - row*96);
    float v = (row < TN && e < 80) ? adp[row*80 + e] : 0.f;
    out[i] = f2b(v);
}

// hT[t][d][n] = h[t][n][d], n padded to 448 with zeros
__global__ void __launch_bounds__(256) ht_kernel(
    const bf16* __restrict__ h, bf16* __restrict__ hT)
{
    __shared__ bf16 As[64*106];
    int t = blockIdx.y, n0 = blockIdx.x*64;
    int tid = threadIdx.x;
    for (int idx = tid; idx < 64*52; idx += 256) {
        int r = idx / 52, k = idx - r*52;
        int n = n0 + r;
        uint v = 0;
        if (n < NN) v = *(const uint*)(h + ((size_t)t*NN + n)*104 + k*2);
        *(uint*)(&As[r*106 + k*2]) = v;
    }
    __syncthreads();
    for (int idx = tid; idx < 104*32; idx += 256) {
        int d = idx >> 5, np = idx & 31;
        int n = np*2;
        ushort lo = *(ushort*)&As[n*106 + d];
        ushort hi = *(ushort*)&As[(n+1)*106 + d];
        uint v = ((uint)hi << 16) | lo;
        *(uint*)(hT + ((size_t)t*104 + d)*448 + n0 + n) = v;
    }
}

// ---------------- hcat (16 rows/block, LDS-staged uint4 row writes) ----------------
__global__ void __launch_bounds__(256) hcat_kernel(
    const float* __restrict__ x, const float* __restrict__ W_in,
    const float* __restrict__ b_in, const float* __restrict__ adp,
    bf16* __restrict__ hcat)
{
    __shared__ bf16 T[16][112];          // 104 used; 224B row stride (16B-aligned)
    int r0 = blockIdx.x * 16;
    int tid = threadIdx.x;
    // proj cols 0..23
    for (int idx = tid; idx < 16*24; idx += 256) {
        int r = idx / 24, c = idx - r*24;
        int row = r0 + r;
        int t = row / NN, n = row - t*NN;
        size_t xb = ((size_t)n*TT + t)*3;
        float s = b_in[c] + x[xb]*W_in[c] + x[xb+1]*W_in[24+c] + x[xb+2]*W_in[48+c];
        T[r][c] = f2b(s);
    }
    // adp cols 24..103 (coalesced f32 reads)
    for (int idx = tid; idx < 16*80; idx += 256) {
        int r = idx / 80, e = idx - r*80;
        T[r][24+e] = f2b(adp[(size_t)(r0+r)*80 + e]);
    }
    __syncthreads();
    for (int idx = tid; idx < 16*13; idx += 256) {
        int r = idx / 13, q = idx - r*13;
        *(uint4*)(hcat + ((size_t)(r0+r))*104 + q*8) = *(const uint4*)(&T[r][q*8]);
    }
}

// ---------------- MFMA GEMM 64-tile ----------------
// 1-D grid with bijective XCD grouping (m204): column-tiles of one row-slab
// land adjacent on the SAME XCD so the A-slab is fetched from HBM once.
template<int KP>
__global__ void __launch_bounds__(256) gemm_mf(
    const bf16* __restrict__ A, int lda, int K,
    const bf16* __restrict__ Wt, const float* __restrict__ bias,
    bf16* __restrict__ C, int M, int Nc, int relu)
{
    constexpr int STR = KP + 8;
    constexpr int KPQ = KP/8;
    __shared__ bf16 As[64*STR];
    __shared__ bf16 Ws[64*STR];
    int nCol = (Nc + 63) >> 6;
    int nwg = gridDim.x;
    int bid = blockIdx.x;
    int xcd = bid & 7, kk = bid >> 3;
    int q8 = nwg >> 3, r8 = nwg & 7;
    int widx = (xcd < r8 ? xcd*(q8+1) : r8*(q8+1) + (xcd - r8)*q8) + kk;
    int mblk = widx / nCol;
    int m0 = mblk * 64;
    int c0 = (widx - mblk*nCol) * 64;
    int tid = threadIdx.x;
    const int KQ = K/8;
    uint4 z4 = {0u,0u,0u,0u};
    for (int idx = tid; idx < 64*KPQ; idx += 256) {
        int r = idx / KPQ, q = idx - r*KPQ;
        int m = m0 + r;
        uint4 v = z4;
        if (m < M && q < KQ) v = *(const uint4*)(A + (size_t)m*lda + q*8);
        *(uint4*)(&As[r*STR + q*8]) = v;
    }
    for (int idx = tid; idx < 64*KPQ; idx += 256) {
        int r = idx / KPQ, q = idx - r*KPQ;
        int n = c0 + r;
        uint4 v = z4;
        if (n < Nc) v = *(const uint4*)(Wt + (size_t)n*KP + q*8);
        *(uint4*)(&Ws[r*STR + q*8]) = v;
    }
    __syncthreads();

    int lane = tid & 63, w = tid >> 6;
    int n16 = lane & 15, quad = lane >> 4;
    constexpr int KS = KP/32;
    short8v af[KS];
    #pragma unroll
    for (int s = 0; s < KS; ++s)
        af[s] = *(const short8v*)(&As[(16*w + n16)*STR + s*32 + quad*8]);
    float4v acc[4];
    #pragma unroll
    for (int ct = 0; ct < 4; ++ct) { float4v z = {0.f,0.f,0.f,0.f}; acc[ct] = z; }
    #pragma unroll
    for (int ct = 0; ct < 4; ++ct) {
        #pragma unroll
        for (int s = 0; s < KS; ++s) {
            short8v bfr = *(const short8v*)(&Ws[(ct*16 + n16)*STR + s*32 + quad*8]);
            acc[ct] = __builtin_amdgcn_mfma_f32_16x16x32_bf16(af[s], bfr, acc[ct], 0, 0, 0);
        }
    }
    #pragma unroll
    for (int ct = 0; ct < 4; ++ct) {
        int c = c0 + ct*16 + n16;
        if (c < Nc) {
            float b = bias ? bias[c] : 0.f;
            #pragma unroll
            for (int reg = 0; reg < 4; ++reg) {
                int m = m0 + 16*w + quad*4 + reg;
                if (m < M) {
                    float v = acc[ct][reg] + b;
                    if (relu) v = fmaxf(v, 0.f);
                    C[(size_t)m*Nc + c] = f2b(v);
                }
            }
        }
    }
}

// ---------------- fused gates + LN1 ----------------
// h1 = LN(2*(h + att0*(h@pw0+b0) + 0.01*att1*(att0@pw1+b1))) in-place into h.
__global__ void __launch_bounds__(256) gate_ln1(
    bf16* __restrict__ h, const bf16* __restrict__ att0, const bf16* __restrict__ att1,
    const bf16* __restrict__ w0t, const bf16* __restrict__ w1t, const float* __restrict__ pwb,
    const float* __restrict__ gamma, const float* __restrict__ beta)
{
    constexpr int STR = 136;
    __shared__ bf16 A0s[64*STR];
    __shared__ bf16 A1s[64*STR];
    __shared__ bf16 Ws[112*STR];
    __shared__ float prm[416];     // pwb(208) | gamma(104) | beta(104)
    int m0 = blockIdx.x * 64;
    int tid = threadIdx.x;
    int lane = tid & 63, w = tid >> 6, n16 = lane & 15, quad = lane >> 4;
    uint4 z4 = {0u,0u,0u,0u};

    for (int idx = tid; idx < 64*16; idx += 256) {
        int r = idx >> 4, q = idx & 15;
        int m = m0 + r;
        uint4 v0 = z4, v1 = z4;
        if (m < TN && q < 13) {
            v0 = *(const uint4*)(h    + (size_t)m*104 + q*8);
            v1 = *(const uint4*)(att0 + (size_t)m*104 + q*8);
        }
        *(uint4*)(&A0s[r*STR + q*8]) = v0;
        *(uint4*)(&A1s[r*STR + q*8]) = v1;
    }
    for (int idx = tid; idx < 112*16; idx += 256) {
        int c = idx >> 4, q = idx & 15;
        uint4 v = z4;
        if (c < 104) v = *(const uint4*)(w0t + (size_t)c*128 + q*8);
        *(uint4*)(&Ws[c*STR + q*8]) = v;
    }
    for (int i = tid; i < 416; i += 256)
        prm[i] = (i < 208) ? pwb[i] : (i < 312 ? gamma[i-208] : beta[i-312]);
    __syncthreads();

    short8v a0f[4], a1f[4];
    #pragma unroll
    for (int s = 0; s < 4; ++s) {
        a0f[s] = *(const short8v*)(&A0s[(16*w + n16)*STR + s*32 + quad*8]);
        a1f[s] = *(const short8v*)(&A1s[(16*w + n16)*STR + s*32 + quad*8]);
    }
    float4v acc0[7], acc1[7];
    #pragma unroll
    for (int ct = 0; ct < 7; ++ct) { float4v z = {0.f,0.f,0.f,0.f}; acc0[ct] = z; acc1[ct] = z; }
    #pragma unroll
    for (int ct = 0; ct < 7; ++ct)
        #pragma unroll
        for (int s = 0; s < 4; ++s) {
            short8v bfr = *(const short8v*)(&Ws[(ct*16 + n16)*STR + s*32 + quad*8]);
            acc0[ct] = __builtin_amdgcn_mfma_f32_16x16x32_bf16(a0f[s], bfr, acc0[ct], 0, 0, 0);
        }
    __syncthreads();
    for (int idx = tid; idx < 112*16; idx += 256) {
        int c = idx >> 4, q = idx & 15;
        uint4 v = z4;
        if (c < 104) v = *(const uint4*)(w1t + (size_t)c*128 + q*8);
        *(uint4*)(&Ws[c*STR + q*8]) = v;
    }
    __syncthreads();
    #pragma unroll
    for (int ct = 0; ct < 7; ++ct)
        #pragma unroll
        for (int s = 0; s < 4; ++s) {
            short8v bfr = *(const short8v*)(&Ws[(ct*16 + n16)*STR + s*32 + quad*8]);
            acc1[ct] = __builtin_amdgcn_mfma_f32_16x16x32_bf16(a1f[s], bfr, acc1[ct], 0, 0, 0);
        }

    // epilogue: g -> LN (row distributed across the 16 n16 lanes)
    float sum[4] = {0.f,0.f,0.f,0.f};
    #pragma unroll
    for (int ct = 0; ct < 7; ++ct) {
        int c = ct*16 + n16;
        bool colok = c < 104;
        float b0 = colok ? prm[c] : 0.f;
        float b1 = colok ? prm[104 + c] : 0.f;
        #pragma unroll
        for (int reg = 0; reg < 4; ++reg) {
            int r = 16*w + quad*4 + reg;
            int m = m0 + r;
            float xv = 0.f;
            if (colok && m < TN) {
                float p0 = acc0[ct][reg] + b0;
                float p1 = acc1[ct][reg] + b1;
                float hv = b2f(A0s[r*STR + c]);
                float a0 = b2f(A1s[r*STR + c]);
                float a1 = b2f(att1[(size_t)m*104 + c]);
                xv = 2.f*(hv + a0*p0 + 0.01f*a1*p1);
            }
            acc0[ct][reg] = xv;
            sum[reg] += xv;
        }
    }
    #pragma unroll
    for (int reg = 0; reg < 4; ++reg) {
        float v = sum[reg];
        v += __shfl_xor(v,1,64); v += __shfl_xor(v,2,64);
        v += __shfl_xor(v,4,64); v += __shfl_xor(v,8,64);
        sum[reg] = v * (1.f/104.f);                     // mean
    }
    float var[4] = {0.f,0.f,0.f,0.f};
    #pragma unroll
    for (int ct = 0; ct < 7; ++ct) {
        bool colok = (ct*16 + n16) < 104;
        #pragma unroll
        for (int reg = 0; reg < 4; ++reg) {
            if (colok) {
                float d = acc0[ct][reg] - sum[reg];
                acc0[ct][reg] = d;
                var[reg] += d*d;
            }
        }
    }
    #pragma unroll
    for (int reg = 0; reg < 4; ++reg) {
        float v = var[reg];
        v += __shfl_xor(v,1,64); v += __shfl_xor(v,2,64);
        v += __shfl_xor(v,4,64); v += __shfl_xor(v,8,64);
        var[reg] = rsqrtf(v * (1.f/104.f) + 1e-5f);
    }
    #pragma unroll
    for (int ct = 0; ct < 7; ++ct) {
        int c = ct*16 + n16;
        if (c < 104) {
            float g = prm[208 + c], be = prm[312 + c];
            #pragma unroll
            for (int reg = 0; reg < 4; ++reg) {
                int m = m0 + 16*w + quad*4 + reg;
                if (m < TN)
                    h[(size_t)m*104 + c] = f2b(acc0[ct][reg]*var[reg]*g + be);
            }
        }
    }
}

// ---------------- fused fc2 + LN2: h2 = LN(h1 + hidden@fc_w2 + b) ----------------
__global__ void __launch_bounds__(256) fc2_ln2(
    const bf16* __restrict__ hidden, const bf16* __restrict__ w2t, const float* __restrict__ b2,
    const bf16* __restrict__ h1, const float* __restrict__ gamma, const float* __restrict__ beta,
    bf16* __restrict__ h2)
{
    constexpr int STRA = 232;   // 224 + 8
    constexpr int STRW = 136;   // 128 + 8 (per half)
    __shared__ bf16 As[64*STRA];
    __shared__ bf16 Ws[112*STRW];
    __shared__ float prm[312];  // b2(104) | gamma(104) | beta(104)
    int m0 = blockIdx.x * 64;
    int tid = threadIdx.x;
    int lane = tid & 63, w = tid >> 6, n16 = lane & 15, quad = lane >> 4;
    uint4 z4 = {0u,0u,0u,0u};

    for (int idx = tid; idx < 64*28; idx += 256) {
        int r = idx / 28, q = idx - r*28;
        int m = m0 + r;
        uint4 v = z4;
        if (m < TN && q < 26) v = *(const uint4*)(hidden + (size_t)m*208 + q*8);
        *(uint4*)(&As[r*STRA + q*8]) = v;
    }
    for (int idx = tid; idx < 112*16; idx += 256) {
        int c = idx >> 4, q = idx & 15;
        uint4 v = z4;
        if (c < 104) v = *(const uint4*)(w2t + (size_t)c*224 + q*8);
        *(uint4*)(&Ws[c*STRW + q*8]) = v;
    }
    for (int i = tid; i < 312; i += 256)
        prm[i] = (i < 104) ? b2[i] : (i < 208 ? gamma[i-104] : beta[i-208]);
    __syncthreads();

    short8v af[7];
    #pragma unroll
    for (int s = 0; s < 7; ++s)
        af[s] = *(const short8v*)(&As[(16*w + n16)*STRA + s*32 + quad*8]);
    float4v acc[7];
    #pragma unroll
    for (int ct = 0; ct < 7; ++ct) { float4v z = {0.f,0.f,0.f,0.f}; acc[ct] = z; }
    #pragma unroll
    for (int ct = 0; ct < 7; ++ct)
        #pragma unroll
        for (int s = 0; s < 4; ++s) {
            short8v bfr = *(const short8v*)(&Ws[(ct*16 + n16)*STRW + s*32 + quad*8]);
            acc[ct] = __builtin_amdgcn_mfma_f32_16x16x32_bf16(af[s], bfr, acc[ct], 0, 0, 0);
        }
    __syncthreads();
    for (int idx = tid; idx < 112*16; idx += 256) {   // half 2: k 128..223 (12 data uint4)
        int c = idx >> 4, q = idx & 15;
        uint4 v = z4;
        if (c < 104 && q < 12) v = *(const uint4*)(w2t + (size_t)c*224 + 128 + q*8);
        *(uint4*)(&Ws[c*STRW + q*8]) = v;
    }
    __syncthreads();
    #pragma unroll
    for (int ct = 0; ct < 7; ++ct)
        #pragma unroll
        for (int s = 4; s < 7; ++s) {
            short8v bfr = *(const short8v*)(&Ws[(ct*16 + n16)*STRW + (s-4)*32 + quad*8]);
            acc[ct] = __builtin_amdgcn_mfma_f32_16x16x32_bf16(af[s], bfr, acc[ct], 0, 0, 0);
        }

    // epilogue: x = h1 + m  -> LN
    float sum[4] = {0.f,0.f,0.f,0.f};
    #pragma unroll
    for (int ct = 0; ct < 7; ++ct) {
        int c = ct*16 + n16;
        bool colok = c < 104;
        float bb = colok ? prm[c] : 0.f;
        #pragma unroll
        for (int reg = 0; reg < 4; ++reg) {
            int m = m0 + 16*w + quad*4 + reg;
            float xv = 0.f;
            if (colok && m < TN)
                xv = b2f(h1[(size_t)m*104 + c]) + acc[ct][reg] + bb;
            acc[ct][reg] = xv;
            sum[reg] += xv;
        }
    }
    #pragma unroll
    for (int reg = 0; reg < 4; ++reg) {
        float v = sum[reg];
        v += __shfl_xor(v,1,64); v += __shfl_xor(v,2,64);
        v += __shfl_xor(v,4,64); v += __shfl_xor(v,8,64);
        sum[reg] = v * (1.f/104.f);
    }
    float var[4] = {0.f,0.f,0.f,0.f};
    #pragma unroll
    for (int ct = 0; ct < 7; ++ct) {
        bool colok = (ct*16 + n16) < 104;
        #pragma unroll
        for (int reg = 0; reg < 4; ++reg) {
            if (colok) {
                float d = acc[ct][reg] - sum[reg];
                acc[ct][reg] = d;
                var[reg] += d*d;
            }
        }
    }
    #pragma unroll
    for (int reg = 0; reg < 4; ++reg) {
        float v = var[reg];
        v += __shfl_xor(v,1,64); v += __shfl_xor(v,2,64);
        v += __shfl_xor(v,4,64); v += __shfl_xor(v,8,64);
        var[reg] = rsqrtf(v * (1.f/104.f) + 1e-5f);
    }
    #pragma unroll
    for (int ct = 0; ct < 7; ++ct) {
        int c = ct*16 + n16;
        if (c < 104) {
            float g = prm[104 + c], be = prm[208 + c];
            #pragma unroll
            for (int reg = 0; reg < 4; ++reg) {
                int m = m0 + 16*w + quad*4 + reg;
                if (m < TN)
                    h2[(size_t)m*104 + c] = f2b(acc[ct][reg]*var[reg]*g + be);
            }
        }
    }
}

// ---------------- MFMA encoder_proj ----------------
__global__ void __launch_bounds__(256) ep_mf(
    const bf16* __restrict__ h2, const bf16* __restrict__ wt, float* __restrict__ y)
{
    constexpr int STR = 136;
    __shared__ bf16 As[64*STR];
    __shared__ bf16 Ws[64*STR];
    int m0 = blockIdx.x * 64;
    int c0 = blockIdx.y * 64;
    int t0 = blockIdx.z * 8;
    int t1 = min(TT, t0 + 8);
    int tid = threadIdx.x;
    int lane = tid & 63, w = tid >> 6, n16 = lane & 15, quad = lane >> 4;
    uint4 z4 = {0u,0u,0u,0u};

    float4v acc[4];
    #pragma unroll
    for (int ct = 0; ct < 4; ++ct) { float4v z = {0.f,0.f,0.f,0.f}; acc[ct] = z; }

    for (int t = t0; t < t1; ++t) {
        for (int idx = tid; idx < 64*16; idx += 256) {
            int r = idx >> 4, q = idx & 15;
            int m = m0 + r;
            uint4 va = z4;
            if (m < NN && q < 13) va = *(const uint4*)(h2 + ((size_t)t*NN + m)*104 + q*8);
            *(uint4*)(&As[r*STR + q*8]) = va;
            int c = c0 + r;
            uint4 vw = z4;
            if (c < 104 && q < 13) vw = *(const uint4*)(wt + (size_t)c*37960 + t*104 + q*8);
            *(uint4*)(&Ws[r*STR + q*8]) = vw;
        }
        __syncthreads();
        short8v af[4];
        #pragma unroll
        for (int s = 0; s < 4; ++s)
            af[s] = *(const short8v*)(&As[(16*w + n16)*STR + s*32 + quad*8]);
        #pragma unroll
        for (int ct = 0; ct < 4; ++ct) {
            #pragma unroll
            for (int s = 0; s < 4; ++s) {
                short8v bfr = *(const short8v*)(&Ws[(ct*16 + n16)*STR + s*32 + quad*8]);
                acc[ct] = __builtin_amdgcn_mfma_f32_16x16x32_bf16(af[s], bfr, acc[ct], 0, 0, 0);
            }
        }
        __syncthreads();
    }
    #pragma unroll
    for (int ct = 0; ct < 4; ++ct) {
        int c = c0 + ct*16 + n16;
        if (c < 104) {
            #pragma unroll
            for (int reg = 0; reg < 4; ++reg) {
                int m = m0 + 16*w + quad*4 + reg;
                if (m < NN) atomicAdd(&y[(size_t)m*104 + c], acc[ct][reg]);
            }
        }
    }
}

// ---------------- MFMA z1 (R5 structure, unchanged) ----------------
static constexpr int Z1_TQ = CEILDIV(TT, 8);          // 46
static constexpr int Z1_BLOCKS = 8 * Z1_TQ * 4;       // 1472
__global__ void __launch_bounds__(512, 4) z1_mf(
    const bf16* __restrict__ adp_bf, const bf16* __restrict__ hT, bf16* __restrict__ z1)
{
    constexpr int SA  = 104;   // Asq/Bt row stride (96 data + pad), 16B-aligned
    constexpr int SH  = 72;    // Hs row stride (64 data + pad)
    constexpr int SPP = 72;    // P  row stride (64 data + pad)
    __shared__ bf16 Asq[2][64*SA];   // 26624 B: per-slab q rows (persist)
    __shared__ bf16 Bt[64*SA];       // 13312 B: shared c-rows tile
    __shared__ bf16 Hs[128*SH];      // 18432 B: shared hT tile (rows 104..127 zero)
    __shared__ bf16 P[2][64*SPP];    // 18432 B: per-slab probabilities
    __shared__ float rsb[2][2][64];  //  2048 B

    int bid = blockIdx.x;
    int xcd = bid & 7;               // all blocks of one t share an XCD/L2
    int j = bid >> 3;
    int tq = j >> 2, pair = j & 3;
    int t = tq*8 + xcd;
    if (t >= TT) return;

    int tid = threadIdx.x;
    int lane = tid & 63, w = tid >> 6;            // 8 waves
    int slab = w >> 2, wsl = w & 3;
    int qi = wsl >> 1, ci = wsl & 1;
    int n32 = lane & 31, koct = lane >> 5;
    int r0 = (pair*2 + slab)*64;                  // up to 448; masked at write

    {
        const uint4* src = (const uint4*)(adp_bf + ((size_t)t*NN + pair*128)*96);
        #pragma unroll
        for (int i = 0; i < 3; ++i) {
            int idx = tid + i*512;                // < 1536
            int s2 = idx / 768, rem = idx - s2*768;
            int r = rem / 12, q = rem - r*12;
            *(uint4*)(&Asq[s2][r*SA + q*8]) = src[idx];
        }
    }
    {
        uint4 z4v = {0u,0u,0u,0u};
        for (int idx = tid; idx < 216; idx += 512) {
            int rr = idx / 9;
            int r = 104 + rr, q = idx - rr*9;
            *(uint4*)(&Hs[r*SH + q*8]) = z4v;
        }
    }

    float16v on0, on1;
    #pragma unroll
    for (int i = 0; i < 16; ++i) { on0[i] = 0.f; on1[i] = 0.f; }
    float rs2[16];
    #pragma unroll
    for (int i = 0; i < 16; ++i) rs2[i] = 0.f;

    const bf16* hbase = hT + (size_t)t*104*448;

    uint4 preB0, preB1, preH0, preH1;
    {
        const uint4* srcB = (const uint4*)(adp_bf + (size_t)t*NN*96);
        preB0 = srcB[tid];
        if (tid < 256) preB1 = srcB[tid + 512];
        { int r = tid >> 3, q = tid & 7;
          preH0 = *(const uint4*)(hbase + (size_t)r*448 + q*8); }
        if (tid < 320) { int idx = tid + 512; int r = idx >> 3, q = idx & 7;
          preH1 = *(const uint4*)(hbase + (size_t)r*448 + q*8); }
    }

    for (int c0 = 0; c0 < NN; c0 += 64) {
        { int r = tid / 12, q = tid - (tid/12)*12;
          *(uint4*)(&Bt[r*SA + q*8]) = preB0; }
        if (tid < 256) { int idx = tid + 512; int r = idx / 12, q = idx - r*12;
          *(uint4*)(&Bt[r*SA + q*8]) = preB1; }
        { int r = tid >> 3, q = tid & 7;
          *(uint4*)(&Hs[r*SH + q*8]) = preH0; }
        if (tid < 320) { int idx = tid + 512; int r = idx >> 3, q = idx & 7;
          *(uint4*)(&Hs[r*SH + q*8]) = preH1; }
        __syncthreads();                          // barA (covers Asq on iter 0)
        int cn = c0 + 64;
        if (cn < NN) {
            const uint4* srcB = (const uint4*)(adp_bf + ((size_t)t*NN + cn)*96);
            preB0 = srcB[tid];
            if (tid < 256) preB1 = srcB[tid + 512];
            { int r = tid >> 3, q = tid & 7;
              preH0 = *(const uint4*)(hbase + (size_t)r*448 + cn + q*8); }
            if (tid < 320) { int idx = tid + 512; int r = idx >> 3, q = idx & 7;
              preH1 = *(const uint4*)(hbase + (size_t)r*448 + cn + q*8); }
        }
        float16v sc;
        #pragma unroll
        for (int i = 0; i < 16; ++i) sc[i] = 0.f;
        #pragma unroll
        for (int s = 0; s < 6; ++s) {
            short8v afq = *(const short8v*)(&Asq[slab][(qi*32 + n32)*SA + s*16 + koct*8]);
            short8v bfr = *(const short8v*)(&Bt[(ci*32 + n32)*SA + s*16 + koct*8]);
            sc = __builtin_amdgcn_mfma_f32_32x32x16_bf16(afq, bfr, sc, 0, 0, 0);
        }
        bool colok = (c0 + ci*32 + n32) < NN;
        #pragma unroll
        for (int reg = 0; reg < 16; ++reg) {
            int crow = (reg & 3) + 8*(reg >> 2) + 4*koct;
            float e = colok ? __expf(fmaxf(sc[reg], 0.f)) : 0.f;
            rs2[reg] += e;
            P[slab][(qi*32 + crow)*SPP + ci*32 + n32] = f2b(e);
        }
        __syncthreads();                          // barB: P complete (cross-wave)
        short8v pA[4];
        #pragma unroll
        for (int s = 0; s < 4; ++s)
            pA[s] = *(const short8v*)(&P[slab][(qi*32 + n32)*SPP + s*16 + koct*8]);
        #pragma unroll
        for (int s = 0; s < 4; ++s) {
            short8v hb0 = *(const short8v*)(&Hs[(ci*32 + n32)*SH + s*16 + koct*8]);
            on0 = __builtin_amdgcn_mfma_f32_32x32x16_bf16(pA[s], hb0, on0, 0, 0, 0);
        }
        #pragma unroll
        for (int s = 0; s < 4; ++s) {
            short8v hb1 = *(const short8v*)(&Hs[((ci+2)*32 + n32)*SH + s*16 + koct*8]);
            on1 = __builtin_amdgcn_mfma_f32_32x32x16_bf16(pA[s], hb1, on1, 0, 0, 0);
        }
        __syncthreads();                          // barC: reads done before restage
    }

    #pragma unroll
    for (int reg = 0; reg < 16; ++reg) {
        float v = rs2[reg];
        v += __shfl_xor(v, 1, 64);
        v += __shfl_xor(v, 2, 64);
        v += __shfl_xor(v, 4, 64);
        v += __shfl_xor(v, 8, 64);
        v += __shfl_xor(v, 16, 64);
        if (n32 == 0) {
            int crow = (reg & 3) + 8*(reg >> 2) + 4*koct;
            rsb[slab][ci][qi*32 + crow] = v;
        }
    }
    __syncthreads();

    #pragma unroll
    for (int reg = 0; reg < 16; ++reg) {
        int crow = (reg & 3) + 8*(reg >> 2) + 4*koct;
        int qrow = qi*32 + crow;
        int gq = r0 + qrow;
        if (gq < NN) {
            float inv = 1.f / (rsb[slab][0][qrow] + rsb[slab][1][qrow]);
            int d0 = ci*32 + n32;
            z1[((size_t)t*NN + gq)*104 + d0] = f2b(on0[reg] * inv);
            int d1 = (ci + 2)*32 + n32;
            if (d1 < 104)
                z1[((size_t)t*NN + gq)*104 + d1] = f2b(on1[reg] * inv);
        }
    }
}

// ---------------- MFMA KV summaries (spatial + temporal) ----------------
__global__ void __launch_bounds__(256) kvs_mf(
    const bf16* __restrict__ qkv, bf16* __restrict__ kvsb_s, bf16* __restrict__ kvsb_t)
{
    constexpr int CK = 32;          // l-chunk
    constexpr int TS = 40;          // padded row stride
    __shared__ bf16 raw[CK][216];   // 208 used (k|v span, qkv cols 104..311)
    __shared__ bf16 kTn[4][32][TS]; // per-head kn^T tile (rows 26..31 unused)
    __shared__ bf16 vT [4][32][TS]; // per-head v^T tile + ones row 26
    __shared__ float invs[CK][4];

    int bb = blockIdx.x;
    bf16* out; int L; long long strideL, base;
    if (bb < TT) { out = kvsb_s + (size_t)bb*NTILE; L = NN; base = (long long)bb*NN*312 + 104; strideL = 312; }
    else { int n = bb - TT; out = kvsb_t + (size_t)n*NTILE; L = TT; base = (long long)n*312 + 104; strideL = (long long)NN*312; }

    int tid = threadIdx.x;
    int lane = tid & 63, w = tid >> 6;       // wave = head
    int n32 = lane & 31, koct = lane >> 5;
    uint4 z4 = {0u,0u,0u,0u};

    float16v acc;
    #pragma unroll
    for (int i = 0; i < 16; ++i) acc[i] = 0.f;

    uint4 pre[4];
    #pragma unroll
    for (int j = 0; j < 4; ++j) {
        int idx = tid + j*256;
        uint4 v = z4;
        if (idx < CK*26) {
            int r = idx / 26, q = idx - r*26;
            if (r < L) v = *(const uint4*)(qkv + base + (long long)r*strideL + q*8);
        }
        pre[j] = v;
    }

    for (int l0 = 0; l0 < L; l0 += CK) {
        int lw = min(CK, L - l0);
        __syncthreads();
        #pragma unroll
        for (int j = 0; j < 4; ++j) {
            int idx = tid + j*256;
            if (idx < CK*26) {
                int r = idx / 26, q = idx - r*26;
                *(uint4*)(&raw[r][q*8]) = pre[j];
            }
        }
        __syncthreads();
        {
            int ln0 = l0 + CK;
            #pragma unroll
            for (int j = 0; j < 4; ++j) {
                int idx = tid + j*256;
                uint4 v = z4;
                if (idx < CK*26 && ln0 < L) {
                    int r = idx / 26, q = idx - r*26;
                    if (r < L - ln0) v = *(const uint4*)(qkv + base + (long long)(ln0 + r)*strideL + q*8);
                }
                pre[j] = v;
            }
        }
        if (tid < CK*4) {
            int l = tid >> 2, h = tid & 3;
            float ss = 0.f;
            #pragma unroll
            for (int m = 0; m < HD; ++m) { float v = b2f(raw[l][h*HD + m]); ss += v*v; }
            invs[l][h] = (l < lw) ? 1.f/fmaxf(sqrtf(ss), 1e-12f) : 0.f;
        }
        __syncthreads();
        for (int idx = tid; idx < 4*CK*HD; idx += 256) {
            int h = idx / (CK*HD); int rem = idx - h*CK*HD;
            int l = rem / HD; int m = rem - l*HD;
            float iv = invs[l][h];
            kTn[h][m][l] = f2b(b2f(raw[l][h*HD + m]) * iv);
            vT[h][m][l]  = raw[l][104 + h*HD + m];
        }
        if (tid < 4*CK) {
            int h = tid >> 5, l = tid & 31;
            vT[h][26][l] = f2b((l < lw) ? 1.f : 0.f);
        }
        __syncthreads();
        #pragma unroll
        for (int s = 0; s < 2; ++s) {
            short8v a = *(const short8v*)(&kTn[w][n32][s*16 + koct*8]);
            short8v b = *(const short8v*)(&vT [w][n32][s*16 + koct*8]);
            acc = __builtin_amdgcn_mfma_f32_32x32x16_bf16(a, b, acc, 0, 0, 0);
        }
    }

    int lo = w*HD;
    #pragma unroll
    for (int reg = 0; reg < 16; ++reg) {
        int m = (reg & 3) + 8*(reg >> 2) + 4*koct;
        if (m < HD) {
            if (n32 < HD)       out[(size_t)(lo + n32)*32 + m] = f2b(acc[reg]);
            else if (n32 == HD) out[(size_t)(104 + w)*32 + m] = f2b(acc[reg]);
        }
    }
}

// ---------------- MFMA linear-attention apply (temporal only) ----------------
// R12: A-tile + kvs band register-prefetched at entry (T14); per-slot
// iq/rden transform from R11.
__global__ void __launch_bounds__(256) attn_mm(
    bf16* __restrict__ qkv, const bf16* __restrict__ kvsb,
    int M, long long bStride, long long rowStride, float Lf, int outOff)
{
    constexpr int STR = 136;
    __shared__ bf16 As[64*STR];
    __shared__ bf16 Ws[112*STR];
    __shared__ float nsqL[256];
    __shared__ float denL[256];
    int mt = blockIdx.x, bb = blockIdx.y;
    int tid = threadIdx.x;
    int lane = tid & 63, w = tid >> 6, n16 = lane & 15, quad = lane >> 4;
    bf16* base = qkv + (size_t)bb * bStride;
    const bf16* kb = kvsb + (size_t)bb * NTILE;
    int r0 = mt*64;
    uint4 z4 = {0u,0u,0u,0u};

    // T14: issue A-tile + band loads at entry (all in flight at once)
    uint4 preA[4];
    #pragma unroll
    for (int j = 0; j < 4; ++j) {
        int idx = tid + j*256;
        int r = idx >> 4, q = idx & 15;
        int m = r0 + r;
        uint4 v = z4;
        if (m < M && q < 13) v = *(const uint4*)(base + (size_t)m*rowStride + q*8);
        preA[j] = v;
    }
    uint preKB[6];
    #pragma unroll
    for (int j = 0; j < 6; ++j) {
        int idx = tid + j*256;               // 108*13 = 1404 slots
        uint v = 0;
        if (idx < 1404) {
            int c = idx / 13, qu = idx - c*13;
            v = *(const uint*)(kb + (size_t)c*32 + qu*2);
        }
        preKB[j] = v;
    }

    #pragma unroll
    for (int j = 0; j < 4; ++j) {
        int idx = tid + j*256;
        int r = idx >> 4, q = idx & 15;
        *(uint4*)(&As[r*STR + q*8]) = preA[j];
    }
    for (int idx = tid; idx < 112*16; idx += 256) {
        int c = idx >> 4, q = idx & 15;
        *(uint4*)(&Ws[c*STR + q*8]) = z4;
    }
    __syncthreads();
    #pragma unroll
    for (int j = 0; j < 6; ++j) {
        int idx = tid + j*256;
        if (idx < 1404) {
            int c = idx / 13, qu = idx - c*13;
            int lo = (c < 104) ? (c/26)*26 : (c-104)*26;
            *(uint*)(&Ws[c*STR + lo + qu*2]) = preKB[j];
        }
    }
    __syncthreads();

    short8v af[4];
    #pragma unroll
    for (int s = 0; s < 4; ++s)
        af[s] = *(const short8v*)(&As[(16*w + n16)*STR + s*32 + quad*8]);
    float4v acc[7];
    #pragma unroll
    for (int ct = 0; ct < 7; ++ct) { float4v z = {0.f,0.f,0.f,0.f}; acc[ct] = z; }
    #pragma unroll
    for (int ct = 0; ct < 7; ++ct) {
        #pragma unroll
        for (int s = 0; s < 4; ++s) {
            short8v bfr = *(const short8v*)(&Ws[(ct*16 + n16)*STR + s*32 + quad*8]);
            acc[ct] = __builtin_amdgcn_mfma_f32_16x16x32_bf16(af[s], bfr, acc[ct], 0, 0, 0);
        }
    }
    {
        int row = tid >> 2, hh = tid & 3;
        const bf16* qr = &As[row*STR + hh*26];
        float ss = 0.f;
        #pragma unroll
        for (int m = 0; m < HD; ++m) { float v = b2f(qr[m]); ss += v*v; }
        nsqL[row*4 + hh] = ss;
    }
    if (n16 >= 8 && n16 < 12) {
        #pragma unroll
        for (int reg = 0; reg < 4; ++reg)
            denL[(16*w + quad*4 + reg)*4 + (n16 - 8)] = acc[6][reg];
    }
    __syncthreads();
    // per-slot transform: nsqL <- iq, denL <- 1/den (one per thread)
    {
        float iq = rsqrtf(fmaxf(nsqL[tid], 1e-24f));
        float rd = 1.f / (iq * denL[tid] + Lf);
        nsqL[tid] = iq;
        denL[tid] = rd;
    }
    __syncthreads();
    #pragma unroll
    for (int ct = 0; ct < 7; ++ct) {
        int c = ct*16 + n16;
        if (c < 104) {
            int hh = c / 26;
            #pragma unroll
            for (int reg = 0; reg < 4; ++reg) {
                int lr = 16*w + quad*4 + reg;
                int m = r0 + lr;
                if (m < M) {
                    bf16* rp = base + (size_t)m*rowStride;
                    float num = nsqL[lr*4 + hh] * acc[ct][reg] + Lf * b2f(rp[208 + c]);
                    rp[outOff + c] = f2b(num * denL[lr*4 + hh]);
                }
            }
        }
    }
}

// ---------------- R8-R12: fused spatial attn + op projection ----------------
// R12: A-tile also register-prefetched at entry (10 uint4/thread, issued
// FIRST so its waitcnt leaves band/W loads in flight) -- the whole 23-slot
// load program per thread now flies in one HBM latency window.
// launch_bounds(256,2): LDS caps at 2 blocks/CU (= 2 waves/SIMD), so let
// regalloc use the 256-VGPR budget instead of targeting higher occupancy.
__global__ void __launch_bounds__(256, 2) attn_op(
    const bf16* __restrict__ qkv, const bf16* __restrict__ kvsb,
    const bf16* __restrict__ wt, const float* __restrict__ bias,
    bf16* __restrict__ Cout, float Lf)
{
    constexpr int SA = 328;      // 312 data + 16 pad (16B-aligned)
    constexpr int SW = 136;
    __shared__ bf16 Acat[64*SA];     // 41984 B
    __shared__ bf16 Ws[112*SW];      // 30464 B (band, then op-W halves)
    __shared__ float nsqL[256];
    __shared__ float denL[256];
    int mt = blockIdx.x, t = blockIdx.y;
    int tid = threadIdx.x;
    int lane = tid & 63, w = tid >> 6, n16 = lane & 15, quad = lane >> 4;
    const bf16* base = qkv + (size_t)t * ((size_t)NN*312);
    const bf16* kb = kvsb + (size_t)t * NTILE;
    int r0 = mt*64;
    uint4 z4 = {0u,0u,0u,0u};

    // T14: issue A-tile (consumed first), band, then op-W half-1 loads NOW.
    uint4 preA[10];
    #pragma unroll
    for (int j = 0; j < 10; ++j) {
        int idx = tid + j*256;               // 64*39 = 2496 slots
        uint4 v = z4;
        if (idx < 2496) {
            int r = idx / 39, q = idx - r*39;
            int m = r0 + r;
            if (m < NN) v = *(const uint4*)(base + (size_t)m*312 + q*8);
        }
        preA[j] = v;
    }
    uint preKB[6];
    #pragma unroll
    for (int j = 0; j < 6; ++j) {
        int idx = tid + j*256;               // 108*13 = 1404 slots
        uint v = 0;
        if (idx < 1404) {
            int c = idx / 13, qu = idx - c*13;
            v = *(const uint*)(kb + (size_t)c*32 + qu*2);
        }
        preKB[j] = v;
    }
    uint4 preW[7];
    #pragma unroll
    for (int j = 0; j < 7; ++j) {
        int idx = tid + j*256;               // 112*16 = 1792 slots
        int c = idx >> 4, q = idx & 15;
        uint4 v = z4;
        if (c < 104) v = *(const uint4*)(wt + (size_t)c*224 + q*8);
        preW[j] = v;
    }

    // commit A rows (full qkv rows, cols 0..311 = [q|out_t|v])
    #pragma unroll
    for (int j = 0; j < 10; ++j) {
        int idx = tid + j*256;
        if (idx < 2496) {
            int r = idx / 39, q = idx - r*39;
            *(uint4*)(&Acat[r*SA + q*8]) = preA[j];
        }
    }
    // stage Ws: zero, then band committed from registers after the barrier
    for (int idx = tid; idx < 112*16; idx += 256) {
        int c = idx >> 4, q = idx & 15;
        *(uint4*)(&Ws[c*SW + q*8]) = z4;
    }
    __syncthreads();
    #pragma unroll
    for (int j = 0; j < 6; ++j) {
        int idx = tid + j*256;
        if (idx < 1404) {
            int c = idx / 13, qu = idx - c*13;
            int lo = (c < 104) ? (c/26)*26 : (c-104)*26;
            *(uint*)(&Ws[c*SW + lo + qu*2]) = preKB[j];
        }
    }
    __syncthreads();

    // ---- spatial attention ----
    short8v af[4];
    #pragma unroll
    for (int s = 0; s < 4; ++s)
        af[s] = *(const short8v*)(&Acat[(16*w + n16)*SA + s*32 + quad*8]);
    float4v acc[7];
    #pragma unroll
    for (int ct = 0; ct < 7; ++ct) { float4v z = {0.f,0.f,0.f,0.f}; acc[ct] = z; }
    #pragma unroll
    for (int ct = 0; ct < 7; ++ct) {
        #pragma unroll
        for (int s = 0; s < 4; ++s) {
            short8v bfr = *(const short8v*)(&Ws[(ct*16 + n16)*SW + s*32 + quad*8]);
            acc[ct] = __builtin_amdgcn_mfma_f32_16x16x32_bf16(af[s], bfr, acc[ct], 0, 0, 0);
        }
    }
    {
        int row = tid >> 2, hh = tid & 3;
        const bf16* qr = &Acat[row*SA + hh*26];
        float ss = 0.f;
        #pragma unroll
        for (int m = 0; m < HD; ++m) { float v = b2f(qr[m]); ss += v*v; }
        nsqL[row*4 + hh] = ss;
    }
    if (n16 >= 8 && n16 < 12) {
        #pragma unroll
        for (int reg = 0; reg < 4; ++reg)
            denL[(16*w + quad*4 + reg)*4 + (n16 - 8)] = acc[6][reg];
    }
    __syncthreads();      // attn reads of Ws/Acat(q) done; nsq/den published
    // per-slot transform: nsqL <- iq, denL <- 1/den (one per thread)
    {
        float iq = rsqrtf(fmaxf(nsqL[tid], 1e-24f));
        float rd = 1.f / (iq * denL[tid] + Lf);
        nsqL[tid] = iq;
        denL[tid] = rd;
    }
    __syncthreads();

    // ---- epilogue: out_s -> Acat cols 0..103 (v from LDS); commit preW1; issue preW2 ----
    #pragma unroll
    for (int ct = 0; ct < 7; ++ct) {
        int c = ct*16 + n16;
        if (c < 104) {
            int hh = c / 26;
            #pragma unroll
            for (int reg = 0; reg < 4; ++reg) {
                int lr = 16*w + quad*4 + reg;
                int m = r0 + lr;
                if (m < NN) {
                    float num = nsqL[lr*4 + hh] * acc[ct][reg] + Lf * b2f(Acat[lr*SA + 208 + c]);
                    Acat[lr*SA + c] = f2b(num * denL[lr*4 + hh]);
                }
            }
        }
    }
    #pragma unroll
    for (int j = 0; j < 7; ++j) {        // commit half 1 (waitcnt for entry loads)
        int idx = tid + j*256;
        int c = idx >> 4, q = idx & 15;
        *(uint4*)(&Ws[c*SW + q*8]) = preW[j];
    }
    #pragma unroll
    for (int j = 0; j < 7; ++j) {        // issue half 2; overlaps half-1 MFMAs
        int idx = tid + j*256;
        int c = idx >> 4, q = idx & 15;
        uint4 v = z4;
        if (c < 104 && q < 12) v = *(const uint4*)(wt + (size_t)c*224 + 128 + q*8);
        preW[j] = v;
    }
    __syncthreads();

    // ---- op projection: C = Acat(64x208) @ W(208x104) + bias ----
    short8v af2[7];
    #pragma unroll
    for (int s = 0; s < 7; ++s)
        af2[s] = *(const short8v*)(&Acat[(16*w + n16)*SA + s*32 + quad*8]);
    float4v acc2[7];
    #pragma unroll
    for (int ct = 0; ct < 7; ++ct) { float4v z = {0.f,0.f,0.f,0.f}; acc2[ct] = z; }
    #pragma unroll
    for (int ct = 0; ct < 7; ++ct)
        #pragma unroll
        for (int s = 0; s < 4; ++s) {
            short8v bfr = *(const short8v*)(&Ws[(ct*16 + n16)*SW + s*32 + quad*8]);
            acc2[ct] = __builtin_amdgcn_mfma_f32_16x16x32_bf16(af2[s], bfr, acc2[ct], 0, 0, 0);
        }
    __syncthreads();
    #pragma unroll
    for (int j = 0; j < 7; ++j) {        // commit half 2
        int idx = tid + j*256;
        int c = idx >> 4, q = idx & 15;
        *(uint4*)(&Ws[c*SW + q*8]) = preW[j];
    }
    __syncthreads();
    #pragma unroll
    for (int ct = 0; ct < 7; ++ct)
        #pragma unroll
        for (int s = 4; s < 7; ++s) {
            short8v bfr = *(const short8v*)(&Ws[(ct*16 + n16)*SW + (s-4)*32 + quad*8]);
            acc2[ct] = __builtin_amdgcn_mfma_f32_16x16x32_bf16(af2[s], bfr, acc2[ct], 0, 0, 0);
        }

    #pragma unroll
    for (int ct = 0; ct < 7; ++ct) {
        int c = ct*16 + n16;
        if (c < 104) {
            float b = bias[c];
            #pragma unroll
            for (int reg = 0; reg < 4; ++reg) {
                int m = r0 + 16*w + quad*4 + reg;
                if (m < NN)
                    Cout[((size_t)t*NN + m)*104 + c] = f2b(acc2[ct][reg] + b);
            }
        }
    }
}

__global__ void __launch_bounds__(256) y_init_kernel(float* __restrict__ y, const float* __restrict__ ep_b) {
    int i = blockIdx.x*256 + threadIdx.x;
    if (i < NN*104) y[i] = ep_b[i % 104];
}

// ---------------- fused tail: 2 rows/block, ILP on the dot chains ----------------
__global__ void __launch_bounds__(256) tail_kernel(
    const float* __restrict__ y,
    const float* __restrict__ ew1, const float* __restrict__ eb1,
    const float* __restrict__ ew2, const float* __restrict__ eb2,
    const float* __restrict__ out_w, const float* __restrict__ out_b,
    float* __restrict__ out)
{
    int n0 = blockIdx.x * 2;               // 200 blocks x 2 rows
    int tid = threadIdx.x;
    __shared__ float yr[2][104], hid[2][208];
    if (tid < 104) {
        yr[0][tid] = y[(size_t)n0*104 + tid];
        yr[1][tid] = y[(size_t)(n0+1)*104 + tid];
    }
    __syncthreads();
    for (int i = 0; i < 3; ++i) {
        const float* w1 = ew1 + (size_t)i*104*208;
        const float* b1 = eb1 + (size_t)i*208;
        const float* w2 = ew2 + (size_t)i*208*104;
        const float* b2 = eb2 + (size_t)i*104;
        if (tid < 208) {
            float a0 = b1[tid], a1 = a0;
            #pragma unroll 8
            for (int k = 0; k < 104; ++k) {
                float w = w1[(size_t)k*208 + tid];
                a0 += yr[0][k]*w; a1 += yr[1][k]*w;
            }
            hid[0][tid] = fmaxf(a0, 0.f);
            hid[1][tid] = fmaxf(a1, 0.f);
        }
        __syncthreads();
        float y0 = 0.f, y1 = 0.f;
        if (tid < 104) {
            float a0 = b2[tid], a1 = a0;
            #pragma unroll 8
            for (int k = 0; k < 208; ++k) {
                float w = w2[(size_t)k*104 + tid];
                a0 += hid[0][k]*w; a1 += hid[1][k]*w;
            }
            y0 = yr[0][tid] + a0; y1 = yr[1][tid] + a1;
        }
        __syncthreads();
        if (tid < 104) { yr[0][tid] = y0; yr[1][tid] = y1; }
        __syncthreads();
    }
    for (int t = tid; t < TT; t += 256) {
        float a0 = out_b[t], a1 = a0;
        #pragma unroll 8
        for (int d = 0; d < 104; ++d) {
            float w = out_w[(size_t)d*TT + t];
            a0 += yr[0][d]*w; a1 += yr[1][d]*w;
        }
        out[(size_t)n0*TT + t] = a0;
        out[(size_t)(n0+1)*TT + t] = a1;
    }
}

// ---------------- launch ----------------
extern "C" void kernel_launch(void* const* d_in, const int* in_sizes, int n_in,
                              void* d_out, int out_size, void* d_ws, size_t ws_size,
                              hipStream_t stream) {
    if (ws_size < WS_NEEDED) return;

    const float* x      = (const float*)d_in[0];
    const float* W_in   = (const float*)d_in[1];
    const float* b_in   = (const float*)d_in[2];
    const float* adp    = (const float*)d_in[3];
    const float* W_tp   = (const float*)d_in[4];
    const float* b_tp   = (const float*)d_in[5];
    const float* qkv_w  = (const float*)d_in[6];
    const float* op_w   = (const float*)d_in[7];
    const float* op_b   = (const float*)d_in[8];
    const float* pw_w   = (const float*)d_in[9];
    const float* pw_b   = (const float*)d_in[10];
    const float* fc_w1  = (const float*)d_in[11];
    const float* fc_b1  = (const float*)d_in[12];
    const float* fc_w2  = (const float*)d_in[13];
    const float* fc_b2  = (const float*)d_in[14];
    const float* ln1_g  = (const float*)d_in[15];
    const float* ln1_b  = (const float*)d_in[16];
    const float* ln2_g  = (const float*)d_in[17];
    const float* ln2_b  = (const float*)d_in[18];
    const float* ep_w   = (const float*)d_in[19];
    const float* ep_b   = (const float*)d_in[20];
    const float* enc_w1 = (const float*)d_in[21];
    const float* enc_b1 = (const float*)d_in[22];
    const float* enc_w2 = (const float*)d_in[23];
    const float* enc_b2 = (const float*)d_in[24];
    const float* out_w  = (const float*)d_in[25];
    const float* out_b  = (const float*)d_in[26];

    bf16* B0 = (bf16*)d_ws;
    bf16* B1 = B0 + NB0;
    bf16* B2 = B1 + NB1;
    bf16* B3 = B2 + NB2;
    bf16* kvsb_s = B3 + NB3;
    bf16* kvsb_t = kvsb_s + NKVSB_S;
    float* ybuf  = (float*)(kvsb_t + NKVSB_T);
    bf16* wtp   = (bf16*)(ybuf + NY);
    bf16* wqkv0 = wtp + NW_TP;
    bf16* wqkv1 = wqkv0 + NW_QKV;
    bf16* wop0  = wqkv1 + NW_QKV;
    bf16* wop1  = wop0 + NW_OP;
    bf16* wpw0  = wop1 + NW_OP;
    bf16* wpw1  = wpw0 + NW_PW;
    bf16* wfc1  = wpw1 + NW_PW;
    bf16* wfc2  = wfc1 + NW_FC1;
    bf16* wept  = wfc2 + NW_FC2;
    bf16* adp_bf = B2;
    bf16* hTbuf  = B2 + NADP;

    // 0. weight prep
    prep_w<<<CEILDIV(104*128,256), 256, 0, stream>>>(W_tp, wtp, 104, 104, 128);
    prep_w<<<CEILDIV(312*128,256), 256, 0, stream>>>(qkv_w, wqkv0, 104, 312, 128);
    prep_w<<<CEILDIV(312*128,256), 256, 0, stream>>>(qkv_w + 104*312, wqkv1, 104, 312, 128);
    prep_w<<<CEILDIV(104*224,256), 256, 0, stream>>>(op_w, wop0, 208, 104, 224);
    prep_w<<<CEILDIV(104*224,256), 256, 0, stream>>>(op_w + 208*104, wop1, 208, 104, 224);
    prep_w<<<CEILDIV(104*128,256), 256, 0, stream>>>(pw_w, wpw0, 104, 104, 128);
    prep_w<<<CEILDIV(104*128,256), 256, 0, stream>>>(pw_w + 104*104, wpw1, 104, 104, 128);
    prep_w<<<CEILDIV(208*128,256), 256, 0, stream>>>(fc_w1, wfc1, 104, 208, 128);
    prep_w<<<CEILDIV(104*224,256), 256, 0, stream>>>(fc_w2, wfc2, 208, 104, 224);
    prep_wT<<<CEILDIV(37960,64), 256, 0, stream>>>(ep_w, wept);

    const int GX = CEILDIV(TN, 64);     // 2282

    // 1. hcat -> B2
    hcat_kernel<<<CEILDIV(TN,16), 256, 0, stream>>>(x, W_in, b_in, adp, B2);
    // 2. h = hcat @ W_tp + b_tp -> B0
    gemm_mf<128><<<GX*2, 256, 0, stream>>>(B2, 104, 104, wtp, b_tp, B0, TN, 104, 0);
    // 2b. z1 pre-staging into B2
    prep_adp<<<CEILDIV((int)NADP,256), 256, 0, stream>>>(adp, adp_bf);
    ht_kernel<<<dim3(7, TT), 256, 0, stream>>>(B0, hTbuf);
    // 3. z1 -> B1
    z1_mf<<<Z1_BLOCKS, 512, 0, stream>>>(adp_bf, hTbuf, B1);
    // 4. attention 0 on h
    gemm_mf<128><<<GX*5, 256, 0, stream>>>(B0, 104, 104, wqkv0, nullptr, B2, TN, 312, 0);
    kvs_mf<<<TT+NN, 256, 0, stream>>>(B2, kvsb_s, kvsb_t);
    attn_mm<<<dim3(6, NN), 256, 0, stream>>>(B2, kvsb_t, TT, 312, (long long)NN*312, (float)TT, 104);
    attn_op<<<dim3(7, TT), 256, 0, stream>>>(B2, kvsb_s, wop0, op_b, B3, (float)NN);   // att0 -> B3
    // 5. attention 1 on z1
    gemm_mf<128><<<GX*5, 256, 0, stream>>>(B1, 104, 104, wqkv1, nullptr, B2, TN, 312, 0);
    kvs_mf<<<TT+NN, 256, 0, stream>>>(B2, kvsb_s, kvsb_t);
    attn_mm<<<dim3(6, NN), 256, 0, stream>>>(B2, kvsb_t, TT, 312, (long long)NN*312, (float)TT, 104);
    attn_op<<<dim3(7, TT), 256, 0, stream>>>(B2, kvsb_s, wop1, op_b + 104, B1, (float)NN); // att1 -> B1
    // 6+7. fused gates + LN1 (in-place B0 -> h1)
    gate_ln1<<<GX, 256, 0, stream>>>(B0, B3, B1, wpw0, wpw1, pw_b, ln1_g, ln1_b);
    // 8. MLP: fc1 -> hidden (B2), fused fc2+LN2 -> h2 (B3)
    gemm_mf<128><<<GX*4, 256, 0, stream>>>(B0, 104, 104, wfc1, fc_b1, B2, TN, 208, 1);
    fc2_ln2<<<GX, 256, 0, stream>>>(B2, wfc2, fc_b2, B0, ln2_g, ln2_b, B3);
    // 9. encoder_proj
    y_init_kernel<<<CEILDIV(NN*104,256), 256, 0, stream>>>(ybuf, ep_b);
    ep_mf<<<dim3(CEILDIV(NN,64), 2, CEILDIV(TT,8)), 256, 0, stream>>>(B3, wept, ybuf);
    // 10+11. fused residual MLP blocks + output projection (2 rows/block)
    tail_kernel<<<NN/2, 256, 0, stream>>>(ybuf, enc_w1, enc_b1, enc_w2, enc_b2,
                                          out_w, out_b, (float*)d_out);
}